// Round 2
// baseline (11524.303 us; speedup 1.0000x reference)
//
#include <hip/hip_runtime.h>

#define DI __device__ __forceinline__

constexpr float BN_EPS_C = 1e-5f;
constexpr float LN_EPS_C = 1e-5f;

// ---------------- workspace layout (float offsets), peak 50,855,936 floats = 194 MiB ----------
// Region A [0 .. 29,360,128): per-batch conv scratch, then q/k/v, then ln.
constexpr size_t OFF_H0   = 0;            // [64,256,256]  = 4,194,304 (per-batch)
constexpr size_t OFF_H1   = 4194304;      // [128,256,256] = 8,388,608 (per-batch)
constexpr size_t OFF_H2   = 12582912;     // [256,256,256] = 16,777,216 (per-batch)
constexpr size_t OFF_Q    = 0;            // [32,4096,64] = 8,388,608 (convs dead)
constexpr size_t OFF_K    = 8388608;
constexpr size_t OFF_V    = 16777216;
constexpr size_t OFF_LN   = 0;            // [16384,800] = 13,107,200 (q dead after combine)
// Region B [29,360,128 .. 42,467,328): tok, then kT + small buffers.
constexpr size_t OFF_TOK  = 29360128;     // [16384,800] = 13,107,200
constexpr size_t OFF_KT   = 29360128;     // [32,64,4096] = 8,388,608 (tok dead after qkv)
constexpr size_t OFF_QL   = 37748736;     // [32,64,64] = 131,072 each below
constexpr size_t OFF_KL   = 37879808;
constexpr size_t OFF_A2   = 38010880;
constexpr size_t OFF_PV   = 38141952;
constexpr size_t OFF_W2   = 38273024;
constexpr size_t OFF_A3V  = 38404096;
constexpr size_t OFF_SCAL = 38535168;     // 2 floats (zeroed AFTER tok is dead!)
// Region C [42,467,328 .. 50,855,936):
constexpr size_t OFF_ATT  = 42467328;     // [16384,512] = 8,388,608

// ---------------- helpers ----------------
DI float blockReduceSum(float v) {
  #pragma unroll
  for (int o = 32; o; o >>= 1) v += __shfl_xor(v, o);
  __shared__ float red[4];
  int w = threadIdx.x >> 6;
  __syncthreads();
  if ((threadIdx.x & 63) == 0) red[w] = v;
  __syncthreads();
  return red[0] + red[1] + red[2] + red[3];
}

template <int LP, int RP>
DI void mm16(const float* L, const float* R, int r0, int c0, float reg[4][4]) {
  #pragma unroll
  for (int i = 0; i < 4; ++i)
    #pragma unroll
    for (int j = 0; j < 4; ++j) reg[i][j] = 0.f;
  for (int dd = 0; dd < 64; ++dd) {
    float l[4], r[4];
    #pragma unroll
    for (int i = 0; i < 4; ++i) l[i] = L[(size_t)(r0 + i) * LP + dd];
    #pragma unroll
    for (int j = 0; j < 4; ++j) r[j] = R[(size_t)dd * RP + c0 + j];
    #pragma unroll
    for (int i = 0; i < 4; ++i)
      #pragma unroll
      for (int j = 0; j < 4; ++j) reg[i][j] = fmaf(l[i], r[j], reg[i][j]);
  }
}

// ---------------- init (zero the atomic-max scalars) ----------------
__global__ void k_init(float* scal) {
  if (threadIdx.x < 2) scal[threadIdx.x] = 0.f;
}

// ---------------- 3x3 conv + BN + ReLU (stride1 pad1), single image 256x256 ----------------
template <int CIN>
__global__ __launch_bounds__(256) void k_conv3x3(
    const float* __restrict__ in, const float* __restrict__ w, const float* __restrict__ bias,
    const float* __restrict__ g, const float* __restrict__ be, const float* __restrict__ mu,
    const float* __restrict__ var, float* __restrict__ out, int CO) {
  __shared__ float sW[CIN * 36];
  __shared__ float sIn[2][6 * 264];
  const int t = threadIdx.x;
  const int co0 = blockIdx.x * 4;
  const int y0 = blockIdx.y * 4;
  for (int e = t; e < CIN * 36; e += 256) {
    int cl = e & 3;
    int qq = (e >> 2) % 9;
    int ci = e / 36;
    sW[e] = w[((size_t)(co0 + cl) * CIN + ci) * 9 + qq];
  }
  const int tx = t & 63, ty = t >> 6;
  {
    const float* src = in;
    #pragma unroll
    for (int rr = 0; rr < 6; ++rr) {
      int gy = y0 - 1 + rr;
      bool yok = (unsigned)gy < 256u;
      for (int cc = t; cc < 258; cc += 256) {
        int gx = cc - 1;
        float val = 0.f;
        if (yok && (unsigned)gx < 256u) val = src[gy * 256 + gx];
        sIn[0][rr * 264 + cc] = val;
      }
    }
  }
  __syncthreads();
  float acc[4][4] = {};
  for (int ci = 0; ci < CIN; ++ci) {
    const int cur = ci & 1;
    if (ci + 1 < CIN) {
      const float* src = in + (size_t)(ci + 1) * 65536;
      #pragma unroll
      for (int rr = 0; rr < 6; ++rr) {
        int gy = y0 - 1 + rr;
        bool yok = (unsigned)gy < 256u;
        for (int cc = t; cc < 258; cc += 256) {
          int gx = cc - 1;
          float val = 0.f;
          if (yok && (unsigned)gx < 256u) val = src[gy * 256 + gx];
          sIn[cur ^ 1][rr * 264 + cc] = val;
        }
      }
    }
    const float* sw = &sW[ci * 36];
    #pragma unroll
    for (int dy = 0; dy < 3; ++dy) {
      const float* rp = &sIn[cur][(ty + dy) * 264 + (tx << 2)];
      float in6[6];
      #pragma unroll
      for (int u = 0; u < 6; ++u) in6[u] = rp[u];
      #pragma unroll
      for (int dx = 0; dx < 3; ++dx) {
        float wv[4];
        *reinterpret_cast<float4*>(wv) = *reinterpret_cast<const float4*>(&sw[(dy * 3 + dx) * 4]);
        #pragma unroll
        for (int xx = 0; xx < 4; ++xx) {
          float iv = in6[dx + xx];
          #pragma unroll
          for (int cl = 0; cl < 4; ++cl) acc[cl][xx] = fmaf(wv[cl], iv, acc[cl][xx]);
        }
      }
    }
    __syncthreads();
  }
  const int y = y0 + ty;
  #pragma unroll
  for (int cl = 0; cl < 4; ++cl) {
    int co = co0 + cl;
    float s = g[co] * rsqrtf(var[co] + BN_EPS_C);
    float sh = fmaf(bias[co] - mu[co], s, be[co]);
    float4 o;
    o.x = fmaxf(fmaf(acc[cl][0], s, sh), 0.f);
    o.y = fmaxf(fmaf(acc[cl][1], s, sh), 0.f);
    o.z = fmaxf(fmaf(acc[cl][2], s, sh), 0.f);
    o.w = fmaxf(fmaf(acc[cl][3], s, sh), 0.f);
    *reinterpret_cast<float4*>(&out[((size_t)co * 256 + y) * 256 + (tx << 2)]) = o;
  }
}

// ---------------- conv3 (patch conv) as GEMM: [4096 x 4096] * [4096 x 800] + BN + ReLU -------
// single image h2 [256,256,256] -> tokb [4096,800]
__global__ __launch_bounds__(256) void k_conv3(
    const float* __restrict__ h2, const float* __restrict__ w3, const float* __restrict__ b3,
    const float* __restrict__ g3, const float* __restrict__ be3, const float* __restrict__ mu3,
    const float* __restrict__ var3, float* __restrict__ tokb) {
  __shared__ float sA[16 * 68], sB[16 * 68];
  const int t = threadIdx.x, tx = t & 15, ty = t >> 4;
  const int py = blockIdx.y;            // 0..63 (output row of 64 tokens)
  const int c0 = blockIdx.x * 64;
  const float* h2b = h2 + (size_t)py * 1024;  // py*4*256
  float acc[4][4] = {};
  for (int k0 = 0; k0 < 4096; k0 += 16) {
    const int ci = k0 >> 4;
    const float* src = h2b + (size_t)ci * 65536;
    #pragma unroll
    for (int u = 0; u < 4; ++u) {
      int e = t + u * 256;
      int r = e >> 4, kk = e & 15;
      int iy = kk >> 2, ix = kk & 3;
      sA[kk * 68 + r] = src[iy * 256 + r * 4 + ix];
    }
    #pragma unroll
    for (int u = 0; u < 4; ++u) {
      int e = t + u * 256;
      int c = e >> 4, kk = e & 15;
      int col = c0 + c;
      sB[kk * 68 + c] = (col < 800) ? w3[(size_t)col * 4096 + k0 + kk] : 0.f;
    }
    __syncthreads();
    #pragma unroll
    for (int kk = 0; kk < 16; ++kk) {
      float av[4], bv[4];
      *reinterpret_cast<float4*>(av) = *reinterpret_cast<const float4*>(&sA[kk * 68 + ty * 4]);
      *reinterpret_cast<float4*>(bv) = *reinterpret_cast<const float4*>(&sB[kk * 68 + tx * 4]);
      #pragma unroll
      for (int i = 0; i < 4; ++i)
        #pragma unroll
        for (int j = 0; j < 4; ++j) acc[i][j] = fmaf(av[i], bv[j], acc[i][j]);
    }
    __syncthreads();
  }
  const int row0 = py * 64;
  #pragma unroll
  for (int j = 0; j < 4; ++j) {
    int co = c0 + tx * 4 + j;
    if (co < 800) {
      float s = g3[co] * rsqrtf(var3[co] + BN_EPS_C);
      float sh = fmaf(b3[co] - mu3[co], s, be3[co]);
      #pragma unroll
      for (int i = 0; i < 4; ++i) {
        int row = row0 + ty * 4 + i;
        tokb[(size_t)row * 800 + co] = fmaxf(fmaf(acc[i][j], s, sh), 0.f);
      }
    }
  }
}

// ---------------- qkv GEMM: tok[16384,800] @ qkv_w[800,1536] -> q,k,v [32,4096,64] ----------
__global__ __launch_bounds__(256) void k_qkv(
    const float* __restrict__ tok, const float* __restrict__ wq,
    float* __restrict__ qx, float* __restrict__ kx, float* __restrict__ vx) {
  __shared__ float sA[16 * 68], sB[16 * 68];
  const int t = threadIdx.x, tx = t & 15, ty = t >> 4;
  const int row0 = blockIdx.y * 64, c0 = blockIdx.x * 64;
  float acc[4][4] = {};
  for (int k0 = 0; k0 < 800; k0 += 16) {
    #pragma unroll
    for (int u = 0; u < 4; ++u) {
      int e = t + u * 256;
      int r = e >> 4, kk = e & 15;
      sA[kk * 68 + r] = tok[(size_t)(row0 + r) * 800 + k0 + kk];
    }
    #pragma unroll
    for (int u = 0; u < 4; ++u) {
      int e = t + u * 256;
      int kk = e >> 6, c = e & 63;
      sB[kk * 68 + c] = wq[(size_t)(k0 + kk) * 1536 + c0 + c];
    }
    __syncthreads();
    #pragma unroll
    for (int kk = 0; kk < 16; ++kk) {
      float av[4], bv[4];
      *reinterpret_cast<float4*>(av) = *reinterpret_cast<const float4*>(&sA[kk * 68 + ty * 4]);
      *reinterpret_cast<float4*>(bv) = *reinterpret_cast<const float4*>(&sB[kk * 68 + tx * 4]);
      #pragma unroll
      for (int i = 0; i < 4; ++i)
        #pragma unroll
        for (int j = 0; j < 4; ++j) acc[i][j] = fmaf(av[i], bv[j], acc[i][j]);
    }
    __syncthreads();
  }
  const int seg = blockIdx.x >> 3, h = blockIdx.x & 7;
  const float scale = (seg == 0) ? 0.125f : 1.0f;
  float* dst = (seg == 0) ? qx : (seg == 1) ? kx : vx;
  #pragma unroll
  for (int i = 0; i < 4; ++i) {
    int row = row0 + ty * 4 + i;
    int b = row >> 12, nn = row & 4095;
    float4 o = make_float4(acc[i][0] * scale, acc[i][1] * scale, acc[i][2] * scale, acc[i][3] * scale);
    *reinterpret_cast<float4*>(&dst[((size_t)(b * 8 + h) * 4096 + nn) * 64 + tx * 4]) = o;
  }
}

// ---------------- transpose k -> kT [bh][d][n] ----------------
__global__ __launch_bounds__(256) void k_transpose(const float* __restrict__ kx, float* __restrict__ kT) {
  __shared__ float tile[64 * 65];
  const int bh = blockIdx.y, n0 = blockIdx.x * 64;
  const float* src = kx + ((size_t)bh * 4096 + n0) * 64;
  const int t = threadIdx.x;
  #pragma unroll
  for (int u = 0; u < 16; ++u) {
    int e = t + u * 256;
    int r = e >> 6, d = e & 63;
    tile[d * 65 + r] = src[e];
  }
  __syncthreads();
  float* dst = kT + (size_t)bh * 262144 + n0;
  #pragma unroll
  for (int u = 0; u < 16; ++u) {
    int e = t + u * 256;
    int d = e >> 6, j = e & 63;
    dst[(size_t)d * 4096 + j] = tile[d * 65 + j];
  }
}

// ---------------- landmarks: block-mean of q and k over 64-token blocks ----------------
__global__ __launch_bounds__(64) void k_landmark(
    const float* __restrict__ qx, const float* __restrict__ kx,
    float* __restrict__ ql, float* __restrict__ kl) {
  const int d = threadIdx.x;
  const int m = blockIdx.x, bh = blockIdx.y;
  const float* qp = qx + ((size_t)bh * 4096 + m * 64) * 64 + d;
  const float* kp = kx + ((size_t)bh * 4096 + m * 64) * 64 + d;
  float sq = 0.f, sk = 0.f;
  #pragma unroll 8
  for (int j = 0; j < 64; ++j) {
    sq += qp[(size_t)j * 64];
    sk += kp[(size_t)j * 64];
  }
  ql[((size_t)bh * 64 + m) * 64 + d] = sq * (1.f / 64.f);
  kl[((size_t)bh * 64 + m) * 64 + d] = sk * (1.f / 64.f);
}

// ---------------- a2 = softmax(ql @ kl^T) [bh][64][64] + global max row/col sums ----------
__global__ __launch_bounds__(64) void k_a2(
    const float* __restrict__ ql, const float* __restrict__ kl,
    float* __restrict__ a2, float* __restrict__ scal) {
  __shared__ float sp[64 * 65];
  const int bh = blockIdx.x, t = threadIdx.x;  // t = row
  const float* qr = ql + ((size_t)bh * 64 + t) * 64;
  const float* kb = kl + (size_t)bh * 4096;
  float mx = -1e30f;
  for (int c = 0; c < 64; ++c) {
    float acc = 0.f;
    #pragma unroll 8
    for (int dd = 0; dd < 64; ++dd) acc = fmaf(qr[dd], kb[c * 64 + dd], acc);
    sp[t * 65 + c] = acc;
    mx = fmaxf(mx, acc);
  }
  float sum = 0.f;
  for (int c = 0; c < 64; ++c) {
    float e = expf(sp[t * 65 + c] - mx);
    sp[t * 65 + c] = e;
    sum += e;
  }
  float inv = 1.f / sum;
  float rs = 0.f;
  for (int c = 0; c < 64; ++c) {
    float p = sp[t * 65 + c] * inv;
    sp[t * 65 + c] = p;
    a2[(size_t)bh * 4096 + t * 64 + c] = p;
    rs += p;
  }
  atomicMax(reinterpret_cast<int*>(scal), __float_as_int(rs));
  __syncthreads();
  float cs = 0.f;
  for (int r = 0; r < 64; ++r) cs += sp[r * 65 + t];
  atomicMax(reinterpret_cast<int*>(scal) + 1, __float_as_int(cs));
}

// ---------------- fused a3 = softmax(ql @ k^T over n); a3v = a3 @ v [bh][64][64] ------------
__global__ __launch_bounds__(256) void k_a3v(
    const float* __restrict__ ql, const float* __restrict__ kT,
    const float* __restrict__ vx, float* __restrict__ a3v) {
  __shared__ float sq[64];
  __shared__ float sP[4096];
  __shared__ float red[4];
  __shared__ float red2[4][64];
  const int t = threadIdx.x;
  const int m = blockIdx.x, bh = blockIdx.y;
  if (t < 64) sq[t] = ql[((size_t)bh * 64 + m) * 64 + t];
  __syncthreads();
  const float* kb = kT + (size_t)bh * 262144;
  float sc[16];
  #pragma unroll
  for (int i = 0; i < 16; ++i) sc[i] = 0.f;
  for (int dd = 0; dd < 64; ++dd) {
    float qv = sq[dd];
    const float* kr = kb + (size_t)dd * 4096 + t;
    #pragma unroll
    for (int i = 0; i < 16; ++i) sc[i] = fmaf(qv, kr[i * 256], sc[i]);
  }
  float mx = sc[0];
  #pragma unroll
  for (int i = 1; i < 16; ++i) mx = fmaxf(mx, sc[i]);
  #pragma unroll
  for (int o = 32; o; o >>= 1) mx = fmaxf(mx, __shfl_xor(mx, o));
  if ((t & 63) == 0) red[t >> 6] = mx;
  __syncthreads();
  mx = fmaxf(fmaxf(red[0], red[1]), fmaxf(red[2], red[3]));
  __syncthreads();
  float sum = 0.f;
  #pragma unroll
  for (int i = 0; i < 16; ++i) {
    sc[i] = expf(sc[i] - mx);
    sum += sc[i];
  }
  #pragma unroll
  for (int o = 32; o; o >>= 1) sum += __shfl_xor(sum, o);
  if ((t & 63) == 0) red[t >> 6] = sum;
  __syncthreads();
  sum = red[0] + red[1] + red[2] + red[3];
  float inv = 1.f / sum;
  #pragma unroll
  for (int i = 0; i < 16; ++i) sP[t + i * 256] = sc[i] * inv;
  __syncthreads();
  const int d = t & 63, seg = t >> 6;
  const float* vb = vx + (size_t)bh * 262144;
  float acc = 0.f;
  for (int n = seg * 1024; n < seg * 1024 + 1024; ++n)
    acc = fmaf(sP[n], vb[(size_t)n * 64 + d], acc);
  red2[seg][d] = acc;
  __syncthreads();
  if (seg == 0)
    a3v[((size_t)bh * 64 + m) * 64 + d] = red2[0][d] + red2[1][d] + red2[2][d] + red2[3][d];
}

// ---------------- Moore-Penrose pinv of a2, 6 iters, per (b,h) block ----------------
__global__ __launch_bounds__(256) void k_pinv(
    const float* __restrict__ a2g, const float* __restrict__ scal, float* __restrict__ pv) {
  __shared__ float z[64 * 65];
  __shared__ float az[64 * 65];
  __shared__ float tb[64 * 65];
  const int bh = blockIdx.x, t = threadIdx.x;
  const int r0 = (t >> 4) << 2, c0 = (t & 15) << 2;
  const float* ag = a2g + (size_t)bh * 4096;
  const float denom = 1.f / (scal[0] * scal[1]);
  #pragma unroll
  for (int i = 0; i < 4; ++i)
    #pragma unroll
    for (int j = 0; j < 4; ++j)
      z[(r0 + i) * 65 + c0 + j] = ag[(c0 + j) * 64 + r0 + i] * denom;
  __syncthreads();
  float reg[4][4], val[4][4];
  for (int it = 0; it < 6; ++it) {
    mm16<64, 65>(ag, z, r0, c0, reg);
    #pragma unroll
    for (int i = 0; i < 4; ++i)
      #pragma unroll
      for (int j = 0; j < 4; ++j) az[(r0 + i) * 65 + c0 + j] = reg[i][j];
    __syncthreads();
    mm16<65, 65>(az, az, r0, c0, reg);
    #pragma unroll
    for (int i = 0; i < 4; ++i)
      #pragma unroll
      for (int j = 0; j < 4; ++j)
        tb[(r0 + i) * 65 + c0 + j] = 7.f * az[(r0 + i) * 65 + c0 + j] - reg[i][j];
    __syncthreads();
    mm16<65, 65>(az, tb, r0, c0, reg);
    #pragma unroll
    for (int i = 0; i < 4; ++i)
      #pragma unroll
      for (int j = 0; j < 4; ++j)
        val[i][j] = 15.f * az[(r0 + i) * 65 + c0 + j] - reg[i][j];
    __syncthreads();
    #pragma unroll
    for (int i = 0; i < 4; ++i)
      #pragma unroll
      for (int j = 0; j < 4; ++j) tb[(r0 + i) * 65 + c0 + j] = val[i][j];
    __syncthreads();
    mm16<65, 65>(z, tb, r0, c0, reg);
    #pragma unroll
    for (int i = 0; i < 4; ++i)
      #pragma unroll
      for (int j = 0; j < 4; ++j)
        val[i][j] = 0.25f * (13.f * z[(r0 + i) * 65 + c0 + j] - reg[i][j]);
    __syncthreads();
    #pragma unroll
    for (int i = 0; i < 4; ++i)
      #pragma unroll
      for (int j = 0; j < 4; ++j) z[(r0 + i) * 65 + c0 + j] = val[i][j];
    __syncthreads();
  }
  #pragma unroll
  for (int i = 0; i < 4; ++i)
    #pragma unroll
    for (int j = 0; j < 4; ++j)
      pv[(size_t)bh * 4096 + (r0 + i) * 64 + c0 + j] = z[(r0 + i) * 65 + c0 + j];
}

// ---------------- W2 = pinv @ a3v [bh][64][64] ----------------
__global__ __launch_bounds__(256) void k_w2(
    const float* __restrict__ pv, const float* __restrict__ a3v, float* __restrict__ w2) {
  const int bh = blockIdx.x, t = threadIdx.x;
  const int r0 = (t >> 4) << 2, c0 = (t & 15) << 2;
  float reg[4][4];
  mm16<64, 64>(pv + (size_t)bh * 4096, a3v + (size_t)bh * 4096, r0, c0, reg);
  #pragma unroll
  for (int i = 0; i < 4; ++i)
    #pragma unroll
    for (int j = 0; j < 4; ++j)
      w2[(size_t)bh * 4096 + (r0 + i) * 64 + c0 + j] = reg[i][j];
}

// ------- fused: a1 = softmax(q@kl^T); att = a1 @ W2 + depthwise-residual(v) ------------
__global__ __launch_bounds__(256) void k_combine(
    const float* __restrict__ qx, const float* __restrict__ kl,
    const float* __restrict__ w2, const float* __restrict__ vx,
    const float* __restrict__ rw, float* __restrict__ att) {
  __shared__ float sKL[64 * 65];
  __shared__ float sW2[64 * 65];
  __shared__ float sQ[64 * 64];
  __shared__ float sP[4][64];
  __shared__ float sR[33];
  const int t = threadIdx.x, lane = t & 63, wv = t >> 6;
  const int n0 = blockIdx.x * 64;
  const int h = blockIdx.y, b = blockIdx.z, bh = b * 8 + h;
  #pragma unroll
  for (int u = 0; u < 16; ++u) {
    int e = t + u * 256;
    int m = e >> 6, d = e & 63;
    sKL[m * 65 + d] = kl[(size_t)bh * 4096 + e];
    sW2[m * 65 + d] = w2[(size_t)bh * 4096 + e];
    sQ[e] = qx[((size_t)bh * 4096 + n0) * 64 + e];
  }
  if (t < 33) sR[t] = rw[h * 33 + t];
  __syncthreads();
  const float* vb = vx + (size_t)bh * 262144;
  for (int s = 0; s < 16; ++s) {
    const int nloc = wv * 16 + s;
    const int n = n0 + nloc;
    // scores: lane = m
    float acc = 0.f;
    const float* qrow = &sQ[nloc * 64];
    const float* klrow = &sKL[lane * 65];
    #pragma unroll
    for (int d = 0; d < 64; ++d) acc = fmaf(qrow[d], klrow[d], acc);
    float mx = acc;
    #pragma unroll
    for (int o = 32; o; o >>= 1) mx = fmaxf(mx, __shfl_xor(mx, o));
    float ex = expf(acc - mx);
    float sm = ex;
    #pragma unroll
    for (int o = 32; o; o >>= 1) sm += __shfl_xor(sm, o);
    sP[wv][lane] = ex / sm;   // wave-local produce/consume (no cross-wave sharing)
    // output: lane = d
    float out = 0.f;
    #pragma unroll
    for (int m = 0; m < 64; ++m) out = fmaf(sP[wv][m], sW2[m * 65 + lane], out);
    #pragma unroll
    for (int j = 0; j < 33; ++j) {
      int nn = n + j - 16;
      if ((unsigned)nn < 4096u) out = fmaf(sR[j], vb[(size_t)nn * 64 + lane], out);
    }
    att[((size_t)b * 4096 + n) * 512 + h * 64 + lane] = out;
  }
}

// ---------------- out-proj GEMM: att[16384,512] @ out_w[512,800] + bias ----------------
__global__ __launch_bounds__(256) void k_outproj(
    const float* __restrict__ att, const float* __restrict__ ow, const float* __restrict__ ob,
    float* __restrict__ outb) {
  __shared__ float sA[16 * 68], sB[16 * 68];
  const int t = threadIdx.x, tx = t & 15, ty = t >> 4;
  const int row0 = blockIdx.y * 64, c0 = blockIdx.x * 64;
  float acc[4][4] = {};
  for (int k0 = 0; k0 < 512; k0 += 16) {
    #pragma unroll
    for (int u = 0; u < 4; ++u) {
      int e = t + u * 256;
      int r = e >> 4, kk = e & 15;
      sA[kk * 68 + r] = att[(size_t)(row0 + r) * 512 + k0 + kk];
    }
    #pragma unroll
    for (int u = 0; u < 4; ++u) {
      int e = t + u * 256;
      int kk = e >> 6, c = e & 63;
      int col = c0 + c;
      sB[kk * 68 + c] = (col < 800) ? ow[(size_t)(k0 + kk) * 800 + col] : 0.f;
    }
    __syncthreads();
    #pragma unroll
    for (int kk = 0; kk < 16; ++kk) {
      float av[4], bv[4];
      *reinterpret_cast<float4*>(av) = *reinterpret_cast<const float4*>(&sA[kk * 68 + ty * 4]);
      *reinterpret_cast<float4*>(bv) = *reinterpret_cast<const float4*>(&sB[kk * 68 + tx * 4]);
      #pragma unroll
      for (int i = 0; i < 4; ++i)
        #pragma unroll
        for (int j = 0; j < 4; ++j) acc[i][j] = fmaf(av[i], bv[j], acc[i][j]);
    }
    __syncthreads();
  }
  #pragma unroll
  for (int j = 0; j < 4; ++j) {
    int col = c0 + tx * 4 + j;
    if (col < 800) {
      float bv = ob[col];
      #pragma unroll
      for (int i = 0; i < 4; ++i)
        outb[(size_t)(row0 + ty * 4 + i) * 800 + col] = acc[i][j] + bv;
    }
  }
}

// ---------------- LayerNorm in place over E=800 ----------------
__global__ __launch_bounds__(256) void k_ln(
    float* __restrict__ buf, const float* __restrict__ g, const float* __restrict__ bb) {
  const int t = threadIdx.x;
  float* p = buf + (size_t)blockIdx.x * 800;
  float x0 = p[t], x1 = p[t + 256], x2 = p[t + 512];
  float x3 = (t < 32) ? p[t + 768] : 0.f;
  float s = blockReduceSum(x0 + x1 + x2 + x3);
  float mean = s * (1.f / 800.f);
  float d0 = x0 - mean, d1 = x1 - mean, d2 = x2 - mean;
  float d3 = (t < 32) ? x3 - mean : 0.f;
  float s2 = blockReduceSum(d0 * d0 + d1 * d1 + d2 * d2 + d3 * d3);
  float rstd = rsqrtf(s2 * (1.f / 800.f) + LN_EPS_C);
  p[t] = d0 * rstd * g[t] + bb[t];
  p[t + 256] = d1 * rstd * g[t + 256] + bb[t + 256];
  p[t + 512] = d2 * rstd * g[t + 512] + bb[t + 512];
  if (t < 32) p[t + 768] = d3 * rstd * g[t + 768] + bb[t + 768];
}

// ---------------- head: sigmoid(ln @ head_w + head_b) ----------------
__global__ __launch_bounds__(256) void k_head(
    const float* __restrict__ ln, const float* __restrict__ hw, const float* __restrict__ hb,
    float* __restrict__ out) {
  const int t = threadIdx.x;
  const int o = t & 15, rsub = t >> 4;
  const size_t row = (size_t)blockIdx.x * 16 + rsub;
  const float* lp = ln + row * 800;
  float acc = hb[o];
  for (int e = 0; e < 800; ++e) acc = fmaf(lp[e], hw[e * 16 + o], acc);
  out[row * 16 + o] = 1.f / (1.f + expf(-acc));
}

// ---------------- launcher ----------------
extern "C" void kernel_launch(void* const* d_in, const int* in_sizes, int n_in,
                              void* d_out, int out_size, void* d_ws, size_t ws_size,
                              hipStream_t stream) {
  (void)in_sizes; (void)n_in; (void)out_size; (void)ws_size;
  const float* x     = (const float*)d_in[0];
  const float* w0    = (const float*)d_in[1];
  const float* b0    = (const float*)d_in[2];
  const float* g0    = (const float*)d_in[3];
  const float* be0   = (const float*)d_in[4];
  const float* mu0   = (const float*)d_in[5];
  const float* var0  = (const float*)d_in[6];
  const float* w1    = (const float*)d_in[7];
  const float* b1    = (const float*)d_in[8];
  const float* g1    = (const float*)d_in[9];
  const float* be1   = (const float*)d_in[10];
  const float* mu1   = (const float*)d_in[11];
  const float* var1  = (const float*)d_in[12];
  const float* w2c   = (const float*)d_in[13];
  const float* b2    = (const float*)d_in[14];
  const float* g2    = (const float*)d_in[15];
  const float* be2   = (const float*)d_in[16];
  const float* mu2   = (const float*)d_in[17];
  const float* var2  = (const float*)d_in[18];
  const float* w3    = (const float*)d_in[19];
  const float* b3    = (const float*)d_in[20];
  const float* g3    = (const float*)d_in[21];
  const float* be3   = (const float*)d_in[22];
  const float* mu3   = (const float*)d_in[23];
  const float* var3  = (const float*)d_in[24];
  const float* qkvw  = (const float*)d_in[25];
  const float* outw  = (const float*)d_in[26];
  const float* outbv = (const float*)d_in[27];
  const float* resw  = (const float*)d_in[28];
  const float* lng   = (const float*)d_in[29];
  const float* lnbv  = (const float*)d_in[30];
  const float* headw = (const float*)d_in[31];
  const float* headb = (const float*)d_in[32];

  float* ws = (float*)d_ws;
  float* h0   = ws + OFF_H0;
  float* h1   = ws + OFF_H1;
  float* h2   = ws + OFF_H2;
  float* tok  = ws + OFF_TOK;
  float* qb   = ws + OFF_Q;
  float* kb   = ws + OFF_K;
  float* vb   = ws + OFF_V;
  float* kT   = ws + OFF_KT;
  float* ql   = ws + OFF_QL;
  float* kl   = ws + OFF_KL;
  float* a2   = ws + OFF_A2;
  float* pv   = ws + OFF_PV;
  float* w2b  = ws + OFF_W2;
  float* a3v  = ws + OFF_A3V;
  float* scal = ws + OFF_SCAL;
  float* attb = ws + OFF_ATT;
  float* lnb  = ws + OFF_LN;

  // conv stack, per batch (scratch h0/h1/h2 reused; tok accumulated full-batch)
  for (int b = 0; b < 4; ++b) {
    k_conv3x3<1><<<dim3(16, 64, 1), 256, 0, stream>>>(
        x + (size_t)b * 65536, w0, b0, g0, be0, mu0, var0, h0, 64);
    k_conv3x3<64><<<dim3(32, 64, 1), 256, 0, stream>>>(
        h0, w1, b1, g1, be1, mu1, var1, h1, 128);
    k_conv3x3<128><<<dim3(64, 64, 1), 256, 0, stream>>>(
        h1, w2c, b2, g2, be2, mu2, var2, h2, 256);
    k_conv3<<<dim3(13, 64), 256, 0, stream>>>(
        h2, w3, b3, g3, be3, mu3, var3, tok + (size_t)b * 4096 * 800);
  }
  // attention (full batch)
  k_qkv<<<dim3(24, 256), 256, 0, stream>>>(tok, qkvw, qb, kb, vb);
  k_init<<<dim3(1), dim3(64), 0, stream>>>(scal);  // AFTER qkv: scal slot overlays tok
  k_transpose<<<dim3(64, 32), 256, 0, stream>>>(kb, kT);
  k_landmark<<<dim3(64, 32), 64, 0, stream>>>(qb, kb, ql, kl);
  k_a2<<<dim3(32), 64, 0, stream>>>(ql, kl, a2, scal);
  k_a3v<<<dim3(64, 32), 256, 0, stream>>>(ql, kT, vb, a3v);
  k_pinv<<<dim3(32), 256, 0, stream>>>(a2, scal, pv);
  k_w2<<<dim3(32), 256, 0, stream>>>(pv, a3v, w2b);
  k_combine<<<dim3(64, 8, 4), 256, 0, stream>>>(qb, kl, w2b, vb, resw, attb);
  // projection + LN + head
  k_outproj<<<dim3(13, 256), 256, 0, stream>>>(attb, outw, outbv, lnb);
  k_ln<<<dim3(16384), 256, 0, stream>>>(lnb, lng, lnbv);
  k_head<<<dim3(1024), 256, 0, stream>>>(lnb, headw, headb, (float*)d_out);
}

// Round 3
// 4104.513 us; speedup vs baseline: 2.8077x; 2.8077x over previous
//
#include <hip/hip_runtime.h>

#define DI __device__ __forceinline__

constexpr float BN_EPS_C = 1e-5f;
constexpr float LN_EPS_C = 1e-5f;

typedef _Float16 half8 __attribute__((ext_vector_type(8)));
typedef float f32x4 __attribute__((ext_vector_type(4)));

// ---------------- workspace layout (BYTE offsets), peak ~191 MB ----------------
// conv scratch (per image, f16 NHWC):
constexpr size_t B_H0   = 0;             // 65536*64*2  = 8,388,608
constexpr size_t B_H1   = 8388608;       // 65536*128*2 = 16,777,216
constexpr size_t B_H2   = 25165824;      // 65536*256*2 = 33,554,432  (end 58,720,256)
// after convs: q/k/v fp32 [32][4096][64]
constexpr size_t B_Q    = 0;             // 33,554,432
constexpr size_t B_K    = 33554432;      // 33,554,432
constexpr size_t B_V    = 67108864;      // 33,554,432  (end 100,663,296)
constexpr size_t B_LNB  = 0;             // fp32 [16384][800] = 52,428,800 (q,k dead by outproj)
constexpr size_t B_KT   = 100663296;     // fp32 [32][64][4096] = 33,554,432
constexpr size_t B_TOK  = 134217728;     // f16 [16384][800] = 26,214,400
constexpr size_t B_ATT  = 160432128;     // f16 [16384][512] = 16,777,216
// packed weights (f16):
constexpr size_t B_WP1  = 177209344;     // 128*9*64   = 73,728 el
constexpr size_t B_WP2  = 177356800;     // 256*9*128  = 294,912 el
constexpr size_t B_WP3  = 177946624;     // 800*16*256 = 3,276,800 el
constexpr size_t B_QKVT = 184500224;     // 1536*800
constexpr size_t B_OWT  = 186957824;     // 800*512
// small fp32 buffers:
constexpr size_t B_QL   = 187777024;
constexpr size_t B_KL   = 188301312;
constexpr size_t B_A2   = 188825600;
constexpr size_t B_PV   = 189349888;
constexpr size_t B_W2   = 189874176;
constexpr size_t B_A3V  = 190398464;
constexpr size_t B_SCAL = 190922752;     // 2 floats

// ---------------- helpers ----------------
DI float blockReduceSum(float v) {
  #pragma unroll
  for (int o = 32; o; o >>= 1) v += __shfl_xor(v, o);
  __shared__ float red[4];
  int w = threadIdx.x >> 6;
  __syncthreads();
  if ((threadIdx.x & 63) == 0) red[w] = v;
  __syncthreads();
  return red[0] + red[1] + red[2] + red[3];
}

template <int LP, int RP>
DI void mm16(const float* L, const float* R, int r0, int c0, float reg[4][4]) {
  #pragma unroll
  for (int i = 0; i < 4; ++i)
    #pragma unroll
    for (int j = 0; j < 4; ++j) reg[i][j] = 0.f;
  for (int dd = 0; dd < 64; ++dd) {
    float l[4], r[4];
    #pragma unroll
    for (int i = 0; i < 4; ++i) l[i] = L[(size_t)(r0 + i) * LP + dd];
    #pragma unroll
    for (int j = 0; j < 4; ++j) r[j] = R[(size_t)dd * RP + c0 + j];
    #pragma unroll
    for (int i = 0; i < 4; ++i)
      #pragma unroll
      for (int j = 0; j < 4; ++j) reg[i][j] = fmaf(l[i], r[j], reg[i][j]);
  }
}

// ---------------- init ----------------
__global__ void k_init(float* scal) {
  if (threadIdx.x < 2) scal[threadIdx.x] = 0.f;
}

// ---------------- weight packing ----------------
// src fp32 [CO][CI][Q] -> dst f16 [CO][Q][CI]
__global__ void k_pack_w(const float* __restrict__ src, _Float16* __restrict__ dst,
                         int CO, int CI, int Q) {
  int i = blockIdx.x * 256 + threadIdx.x;
  if (i >= CO * CI * Q) return;
  int q = i % Q, ci = (i / Q) % CI, co = i / (Q * CI);
  dst[((size_t)co * Q + q) * CI + ci] = (_Float16)src[i];
}

// src fp32 [K][N] -> dst f16 [N][K]
__global__ void k_pack_t(const float* __restrict__ src, _Float16* __restrict__ dst,
                         int K, int N) {
  int i = blockIdx.x * 256 + threadIdx.x;
  if (i >= K * N) return;
  int n = i % N, k = i / N;
  dst[(size_t)n * K + k] = (_Float16)src[i];
}

// ---------------- conv0: CI=1 fp32 direct conv -> h0 NHWC f16 [256][256][64] --------------
__global__ __launch_bounds__(256) void k_conv0(
    const float* __restrict__ xb, const float* __restrict__ w0, const float* __restrict__ b0,
    const float* __restrict__ g0, const float* __restrict__ be0, const float* __restrict__ mu0,
    const float* __restrict__ var0, _Float16* __restrict__ h0) {
  const int t = threadIdx.x, co = t & 63, xg = t >> 6;
  const int y = blockIdx.x;
  float wreg[9];
  #pragma unroll
  for (int q = 0; q < 9; ++q) wreg[q] = w0[co * 9 + q];
  float s = g0[co] * rsqrtf(var0[co] + BN_EPS_C);
  float sh = fmaf(b0[co] - mu0[co], s, be0[co]);
  for (int xl = 0; xl < 64; ++xl) {
    int xx = xg * 64 + xl;
    float acc = 0.f;
    #pragma unroll
    for (int dy = 0; dy < 3; ++dy) {
      int yy = y + dy - 1;
      if ((unsigned)yy >= 256u) continue;
      #pragma unroll
      for (int dx = 0; dx < 3; ++dx) {
        int xi = xx + dx - 1;
        if ((unsigned)xi >= 256u) continue;
        acc = fmaf(wreg[dy * 3 + dx], xb[yy * 256 + xi], acc);
      }
    }
    float v = fmaxf(fmaf(acc, s, sh), 0.f);
    h0[((size_t)y * 256 + xx) * 64 + co] = (_Float16)v;
  }
}

// ---------------- MFMA implicit 3x3 conv: in NHWC f16 [256][256][CI], wp f16 [CO][9][CI] ----
// block: 64 x-cols (wave w -> 16), 64 co; grid (4, 256y, CO/64)
template <int CI>
__global__ __launch_bounds__(256) void k_convm(
    const _Float16* __restrict__ in, const _Float16* __restrict__ wp,
    const float* __restrict__ bias, const float* __restrict__ g, const float* __restrict__ be,
    const float* __restrict__ mu, const float* __restrict__ var,
    _Float16* __restrict__ out, int CO) {
  const int t = threadIdx.x, w = t >> 6, lo = t & 15, hi = (t >> 4) & 3;
  const int x0 = blockIdx.x * 64;
  const int y = blockIdx.y;
  const int c0 = blockIdx.z * 64;
  f32x4 acc[4] = {};
  for (int dy = 0; dy < 3; ++dy) {
    int yy = y + dy - 1;
    bool yok = (unsigned)yy < 256u;
    for (int dx = 0; dx < 3; ++dx) {
      int xi = x0 + w * 16 + lo + dx - 1;
      bool aok = yok && (unsigned)xi < 256u;
      const _Float16* ap = in + ((size_t)yy * 256 + xi) * CI + 8 * hi;
      const _Float16* bp = wp + (size_t)(dy * 3 + dx) * CI + 8 * hi;
      #pragma unroll
      for (int c = 0; c < CI; c += 32) {
        half8 a = {};
        if (aok) a = *reinterpret_cast<const half8*>(ap + c);
        #pragma unroll
        for (int nt = 0; nt < 4; ++nt) {
          int co = c0 + nt * 16 + lo;
          half8 b = *reinterpret_cast<const half8*>(bp + (size_t)co * 9 * CI + c);
          acc[nt] = __builtin_amdgcn_mfma_f32_16x16x32_f16(a, b, acc[nt], 0, 0, 0);
        }
      }
    }
  }
  #pragma unroll
  for (int nt = 0; nt < 4; ++nt) {
    int co = c0 + nt * 16 + lo;
    float s = g[co] * rsqrtf(var[co] + BN_EPS_C);
    float sh = fmaf(bias[co] - mu[co], s, be[co]);
    #pragma unroll
    for (int r = 0; r < 4; ++r) {
      int x = x0 + w * 16 + hi * 4 + r;
      float v = fmaxf(fmaf(acc[nt][r], s, sh), 0.f);
      out[((size_t)y * 256 + x) * CO + co] = (_Float16)v;
    }
  }
}

// ---------------- conv3 MFMA: h2 NHWC f16 -> tok f16 [4096][800] (per image) -----------------
// K = (iy*4+ix)*256 + ci ; wp3 f16 [800][16][256] ; grid (13, 64py)
__global__ __launch_bounds__(256) void k_c3(
    const _Float16* __restrict__ h2, const _Float16* __restrict__ wp3,
    const float* __restrict__ b3, const float* __restrict__ g3, const float* __restrict__ be3,
    const float* __restrict__ mu3, const float* __restrict__ var3,
    _Float16* __restrict__ tokb) {
  const int t = threadIdx.x, w = t >> 6, lo = t & 15, hi = (t >> 4) & 3;
  const int c0 = blockIdx.x * 64;
  const int py = blockIdx.y;
  const int px = w * 16 + lo;
  f32x4 acc[4] = {};
  for (int q = 0; q < 16; ++q) {
    int iy = q >> 2, ix = q & 3;
    const _Float16* ap = h2 + (((size_t)(py * 4 + iy)) * 256 + px * 4 + ix) * 256 + 8 * hi;
    const _Float16* bp = wp3 + (size_t)q * 256 + 8 * hi;
    #pragma unroll
    for (int c = 0; c < 256; c += 32) {
      half8 a = *reinterpret_cast<const half8*>(ap + c);
      #pragma unroll
      for (int nt = 0; nt < 4; ++nt) {
        int co = min(c0 + nt * 16 + lo, 799);
        half8 b = *reinterpret_cast<const half8*>(bp + (size_t)co * 4096 + c);
        acc[nt] = __builtin_amdgcn_mfma_f32_16x16x32_f16(a, b, acc[nt], 0, 0, 0);
      }
    }
  }
  #pragma unroll
  for (int nt = 0; nt < 4; ++nt) {
    int co = c0 + nt * 16 + lo;
    if (co < 800) {
      float s = g3[co] * rsqrtf(var3[co] + BN_EPS_C);
      float sh = fmaf(b3[co] - mu3[co], s, be3[co]);
      #pragma unroll
      for (int r = 0; r < 4; ++r) {
        int row = py * 64 + w * 16 + hi * 4 + r;
        float v = fmaxf(fmaf(acc[nt][r], s, sh), 0.f);
        tokb[(size_t)row * 800 + co] = (_Float16)v;
      }
    }
  }
}

// ---------------- qkv MFMA: tok f16 [16384][800] @ qkvT f16 [1536][800] -> q/k/v fp32 -------
__global__ __launch_bounds__(256) void k_qkv_m(
    const _Float16* __restrict__ tok, const _Float16* __restrict__ qkvT,
    float* __restrict__ qx, float* __restrict__ kx, float* __restrict__ vx) {
  const int t = threadIdx.x, w = t >> 6, lo = t & 15, hi = (t >> 4) & 3;
  const int c0 = blockIdx.x * 64;
  const int row0 = blockIdx.y * 64;
  const _Float16* ap = tok + (size_t)(row0 + w * 16 + lo) * 800 + 8 * hi;
  f32x4 acc[4] = {};
  for (int k = 0; k < 800; k += 32) {
    half8 a = *reinterpret_cast<const half8*>(ap + k);
    #pragma unroll
    for (int nt = 0; nt < 4; ++nt) {
      int co = c0 + nt * 16 + lo;
      half8 b = *reinterpret_cast<const half8*>(qkvT + (size_t)co * 800 + 8 * hi + k);
      acc[nt] = __builtin_amdgcn_mfma_f32_16x16x32_f16(a, b, acc[nt], 0, 0, 0);
    }
  }
  const int seg = blockIdx.x >> 3, h = blockIdx.x & 7;
  const float scale = (seg == 0) ? 0.125f : 1.0f;
  float* dst = (seg == 0) ? qx : (seg == 1) ? kx : vx;
  #pragma unroll
  for (int nt = 0; nt < 4; ++nt) {
    int d = nt * 16 + lo;
    #pragma unroll
    for (int r = 0; r < 4; ++r) {
      int row = row0 + w * 16 + hi * 4 + r;
      int b = row >> 12, nn = row & 4095;
      dst[((size_t)(b * 8 + h) * 4096 + nn) * 64 + d] = acc[nt][r] * scale;
    }
  }
}

// ---------------- transpose k -> kT [bh][d][n] ----------------
__global__ __launch_bounds__(256) void k_transpose(const float* __restrict__ kx, float* __restrict__ kT) {
  __shared__ float tile[64 * 65];
  const int bh = blockIdx.y, n0 = blockIdx.x * 64;
  const float* src = kx + ((size_t)bh * 4096 + n0) * 64;
  const int t = threadIdx.x;
  #pragma unroll
  for (int u = 0; u < 16; ++u) {
    int e = t + u * 256;
    int r = e >> 6, d = e & 63;
    tile[d * 65 + r] = src[e];
  }
  __syncthreads();
  float* dst = kT + (size_t)bh * 262144 + n0;
  #pragma unroll
  for (int u = 0; u < 16; ++u) {
    int e = t + u * 256;
    int d = e >> 6, j = e & 63;
    dst[(size_t)d * 4096 + j] = tile[d * 65 + j];
  }
}

// ---------------- landmarks ----------------
__global__ __launch_bounds__(64) void k_landmark(
    const float* __restrict__ qx, const float* __restrict__ kx,
    float* __restrict__ ql, float* __restrict__ kl) {
  const int d = threadIdx.x;
  const int m = blockIdx.x, bh = blockIdx.y;
  const float* qp = qx + ((size_t)bh * 4096 + m * 64) * 64 + d;
  const float* kp = kx + ((size_t)bh * 4096 + m * 64) * 64 + d;
  float sq = 0.f, sk = 0.f;
  #pragma unroll 8
  for (int j = 0; j < 64; ++j) {
    sq += qp[(size_t)j * 64];
    sk += kp[(size_t)j * 64];
  }
  ql[((size_t)bh * 64 + m) * 64 + d] = sq * (1.f / 64.f);
  kl[((size_t)bh * 64 + m) * 64 + d] = sk * (1.f / 64.f);
}

// ---------------- a2 + global max row/col sums ----------------
__global__ __launch_bounds__(64) void k_a2(
    const float* __restrict__ ql, const float* __restrict__ kl,
    float* __restrict__ a2, float* __restrict__ scal) {
  __shared__ float sp[64 * 65];
  const int bh = blockIdx.x, t = threadIdx.x;
  const float* qr = ql + ((size_t)bh * 64 + t) * 64;
  const float* kb = kl + (size_t)bh * 4096;
  float mx = -1e30f;
  for (int c = 0; c < 64; ++c) {
    float acc = 0.f;
    #pragma unroll 8
    for (int dd = 0; dd < 64; ++dd) acc = fmaf(qr[dd], kb[c * 64 + dd], acc);
    sp[t * 65 + c] = acc;
    mx = fmaxf(mx, acc);
  }
  float sum = 0.f;
  for (int c = 0; c < 64; ++c) {
    float e = expf(sp[t * 65 + c] - mx);
    sp[t * 65 + c] = e;
    sum += e;
  }
  float inv = 1.f / sum;
  float rs = 0.f;
  for (int c = 0; c < 64; ++c) {
    float p = sp[t * 65 + c] * inv;
    sp[t * 65 + c] = p;
    a2[(size_t)bh * 4096 + t * 64 + c] = p;
    rs += p;
  }
  atomicMax(reinterpret_cast<int*>(scal), __float_as_int(rs));
  __syncthreads();
  float cs = 0.f;
  for (int r = 0; r < 64; ++r) cs += sp[r * 65 + t];
  atomicMax(reinterpret_cast<int*>(scal) + 1, __float_as_int(cs));
}

// ---------------- fused a3 softmax + a3@v ----------------
__global__ __launch_bounds__(256) void k_a3v(
    const float* __restrict__ ql, const float* __restrict__ kT,
    const float* __restrict__ vx, float* __restrict__ a3v) {
  __shared__ float sq[64];
  __shared__ float sP[4096];
  __shared__ float red[4];
  __shared__ float red2[4][64];
  const int t = threadIdx.x;
  const int m = blockIdx.x, bh = blockIdx.y;
  if (t < 64) sq[t] = ql[((size_t)bh * 64 + m) * 64 + t];
  __syncthreads();
  const float* kb = kT + (size_t)bh * 262144;
  float sc[16];
  #pragma unroll
  for (int i = 0; i < 16; ++i) sc[i] = 0.f;
  for (int dd = 0; dd < 64; ++dd) {
    float qv = sq[dd];
    const float* kr = kb + (size_t)dd * 4096 + t;
    #pragma unroll
    for (int i = 0; i < 16; ++i) sc[i] = fmaf(qv, kr[i * 256], sc[i]);
  }
  float mx = sc[0];
  #pragma unroll
  for (int i = 1; i < 16; ++i) mx = fmaxf(mx, sc[i]);
  #pragma unroll
  for (int o = 32; o; o >>= 1) mx = fmaxf(mx, __shfl_xor(mx, o));
  if ((t & 63) == 0) red[t >> 6] = mx;
  __syncthreads();
  mx = fmaxf(fmaxf(red[0], red[1]), fmaxf(red[2], red[3]));
  __syncthreads();
  float sum = 0.f;
  #pragma unroll
  for (int i = 0; i < 16; ++i) {
    sc[i] = expf(sc[i] - mx);
    sum += sc[i];
  }
  #pragma unroll
  for (int o = 32; o; o >>= 1) sum += __shfl_xor(sum, o);
  if ((t & 63) == 0) red[t >> 6] = sum;
  __syncthreads();
  sum = red[0] + red[1] + red[2] + red[3];
  float inv = 1.f / sum;
  #pragma unroll
  for (int i = 0; i < 16; ++i) sP[t + i * 256] = sc[i] * inv;
  __syncthreads();
  const int d = t & 63, seg = t >> 6;
  const float* vb = vx + (size_t)bh * 262144;
  float acc = 0.f;
  for (int n = seg * 1024; n < seg * 1024 + 1024; ++n)
    acc = fmaf(sP[n], vb[(size_t)n * 64 + d], acc);
  red2[seg][d] = acc;
  __syncthreads();
  if (seg == 0)
    a3v[((size_t)bh * 64 + m) * 64 + d] = red2[0][d] + red2[1][d] + red2[2][d] + red2[3][d];
}

// ---------------- Moore-Penrose pinv ----------------
__global__ __launch_bounds__(256) void k_pinv(
    const float* __restrict__ a2g, const float* __restrict__ scal, float* __restrict__ pv) {
  __shared__ float z[64 * 65];
  __shared__ float az[64 * 65];
  __shared__ float tb[64 * 65];
  const int bh = blockIdx.x, t = threadIdx.x;
  const int r0 = (t >> 4) << 2, c0 = (t & 15) << 2;
  const float* ag = a2g + (size_t)bh * 4096;
  const float denom = 1.f / (scal[0] * scal[1]);
  #pragma unroll
  for (int i = 0; i < 4; ++i)
    #pragma unroll
    for (int j = 0; j < 4; ++j)
      z[(r0 + i) * 65 + c0 + j] = ag[(c0 + j) * 64 + r0 + i] * denom;
  __syncthreads();
  float reg[4][4], val[4][4];
  for (int it = 0; it < 6; ++it) {
    mm16<64, 65>(ag, z, r0, c0, reg);
    #pragma unroll
    for (int i = 0; i < 4; ++i)
      #pragma unroll
      for (int j = 0; j < 4; ++j) az[(r0 + i) * 65 + c0 + j] = reg[i][j];
    __syncthreads();
    mm16<65, 65>(az, az, r0, c0, reg);
    #pragma unroll
    for (int i = 0; i < 4; ++i)
      #pragma unroll
      for (int j = 0; j < 4; ++j)
        tb[(r0 + i) * 65 + c0 + j] = 7.f * az[(r0 + i) * 65 + c0 + j] - reg[i][j];
    __syncthreads();
    mm16<65, 65>(az, tb, r0, c0, reg);
    #pragma unroll
    for (int i = 0; i < 4; ++i)
      #pragma unroll
      for (int j = 0; j < 4; ++j)
        val[i][j] = 15.f * az[(r0 + i) * 65 + c0 + j] - reg[i][j];
    __syncthreads();
    #pragma unroll
    for (int i = 0; i < 4; ++i)
      #pragma unroll
      for (int j = 0; j < 4; ++j) tb[(r0 + i) * 65 + c0 + j] = val[i][j];
    __syncthreads();
    mm16<65, 65>(z, tb, r0, c0, reg);
    #pragma unroll
    for (int i = 0; i < 4; ++i)
      #pragma unroll
      for (int j = 0; j < 4; ++j)
        val[i][j] = 0.25f * (13.f * z[(r0 + i) * 65 + c0 + j] - reg[i][j]);
    __syncthreads();
    #pragma unroll
    for (int i = 0; i < 4; ++i)
      #pragma unroll
      for (int j = 0; j < 4; ++j) z[(r0 + i) * 65 + c0 + j] = val[i][j];
    __syncthreads();
  }
  #pragma unroll
  for (int i = 0; i < 4; ++i)
    #pragma unroll
    for (int j = 0; j < 4; ++j)
      pv[(size_t)bh * 4096 + (r0 + i) * 64 + c0 + j] = z[(r0 + i) * 65 + c0 + j];
}

// ---------------- W2 = pinv @ a3v ----------------
__global__ __launch_bounds__(256) void k_w2(
    const float* __restrict__ pv, const float* __restrict__ a3v, float* __restrict__ w2) {
  const int bh = blockIdx.x, t = threadIdx.x;
  const int r0 = (t >> 4) << 2, c0 = (t & 15) << 2;
  float reg[4][4];
  mm16<64, 64>(pv + (size_t)bh * 4096, a3v + (size_t)bh * 4096, r0, c0, reg);
  #pragma unroll
  for (int i = 0; i < 4; ++i)
    #pragma unroll
    for (int j = 0; j < 4; ++j)
      w2[(size_t)bh * 4096 + (r0 + i) * 64 + c0 + j] = reg[i][j];
}

// ------- fused: a1 softmax; att = a1 @ W2 + depthwise residual; write f16 ------------
__global__ __launch_bounds__(256) void k_combine(
    const float* __restrict__ qx, const float* __restrict__ kl,
    const float* __restrict__ w2, const float* __restrict__ vx,
    const float* __restrict__ rw, _Float16* __restrict__ att) {
  __shared__ float sKL[64 * 65];
  __shared__ float sW2[64 * 65];
  __shared__ float sQ[64 * 64];
  __shared__ float sP[4][64];
  __shared__ float sR[33];
  const int t = threadIdx.x, lane = t & 63, wv = t >> 6;
  const int n0 = blockIdx.x * 64;
  const int h = blockIdx.y, b = blockIdx.z, bh = b * 8 + h;
  #pragma unroll
  for (int u = 0; u < 16; ++u) {
    int e = t + u * 256;
    int m = e >> 6, d = e & 63;
    sKL[m * 65 + d] = kl[(size_t)bh * 4096 + e];
    sW2[m * 65 + d] = w2[(size_t)bh * 4096 + e];
    sQ[e] = qx[((size_t)bh * 4096 + n0) * 64 + e];
  }
  if (t < 33) sR[t] = rw[h * 33 + t];
  __syncthreads();
  const float* vb = vx + (size_t)bh * 262144;
  for (int s = 0; s < 16; ++s) {
    const int nloc = wv * 16 + s;
    const int n = n0 + nloc;
    float acc = 0.f;
    const float* qrow = &sQ[nloc * 64];
    const float* klrow = &sKL[lane * 65];
    #pragma unroll
    for (int d = 0; d < 64; ++d) acc = fmaf(qrow[d], klrow[d], acc);
    float mx = acc;
    #pragma unroll
    for (int o = 32; o; o >>= 1) mx = fmaxf(mx, __shfl_xor(mx, o));
    float ex = expf(acc - mx);
    float sm = ex;
    #pragma unroll
    for (int o = 32; o; o >>= 1) sm += __shfl_xor(sm, o);
    sP[wv][lane] = ex / sm;
    float out = 0.f;
    #pragma unroll
    for (int m = 0; m < 64; ++m) out = fmaf(sP[wv][m], sW2[m * 65 + lane], out);
    #pragma unroll
    for (int j = 0; j < 33; ++j) {
      int nn = n + j - 16;
      if ((unsigned)nn < 4096u) out = fmaf(sR[j], vb[(size_t)nn * 64 + lane], out);
    }
    att[((size_t)b * 4096 + n) * 512 + h * 64 + lane] = (_Float16)out;
  }
}

// ---------------- out-proj MFMA: attb f16 [16384][512] @ owT f16 [800][512] + bias -> fp32 --
__global__ __launch_bounds__(256) void k_outproj_m(
    const _Float16* __restrict__ attb, const _Float16* __restrict__ owT,
    const float* __restrict__ ob, float* __restrict__ lnb) {
  const int t = threadIdx.x, w = t >> 6, lo = t & 15, hi = (t >> 4) & 3;
  const int c0 = blockIdx.x * 64;
  const int row0 = blockIdx.y * 64;
  const _Float16* ap = attb + (size_t)(row0 + w * 16 + lo) * 512 + 8 * hi;
  f32x4 acc[4] = {};
  #pragma unroll 4
  for (int k = 0; k < 512; k += 32) {
    half8 a = *reinterpret_cast<const half8*>(ap + k);
    #pragma unroll
    for (int nt = 0; nt < 4; ++nt) {
      int co = min(c0 + nt * 16 + lo, 799);
      half8 b = *reinterpret_cast<const half8*>(owT + (size_t)co * 512 + 8 * hi + k);
      acc[nt] = __builtin_amdgcn_mfma_f32_16x16x32_f16(a, b, acc[nt], 0, 0, 0);
    }
  }
  #pragma unroll
  for (int nt = 0; nt < 4; ++nt) {
    int co = c0 + nt * 16 + lo;
    if (co < 800) {
      float bv = ob[co];
      #pragma unroll
      for (int r = 0; r < 4; ++r) {
        int row = row0 + w * 16 + hi * 4 + r;
        lnb[(size_t)row * 800 + co] = acc[nt][r] + bv;
      }
    }
  }
}

// ---------------- LayerNorm in place over E=800 ----------------
__global__ __launch_bounds__(256) void k_ln(
    float* __restrict__ buf, const float* __restrict__ g, const float* __restrict__ bb) {
  const int t = threadIdx.x;
  float* p = buf + (size_t)blockIdx.x * 800;
  float x0 = p[t], x1 = p[t + 256], x2 = p[t + 512];
  float x3 = (t < 32) ? p[t + 768] : 0.f;
  float s = blockReduceSum(x0 + x1 + x2 + x3);
  float mean = s * (1.f / 800.f);
  float d0 = x0 - mean, d1 = x1 - mean, d2 = x2 - mean;
  float d3 = (t < 32) ? x3 - mean : 0.f;
  float s2 = blockReduceSum(d0 * d0 + d1 * d1 + d2 * d2 + d3 * d3);
  float rstd = rsqrtf(s2 * (1.f / 800.f) + LN_EPS_C);
  p[t] = d0 * rstd * g[t] + bb[t];
  p[t + 256] = d1 * rstd * g[t + 256] + bb[t + 256];
  p[t + 512] = d2 * rstd * g[t + 512] + bb[t + 512];
  if (t < 32) p[t + 768] = d3 * rstd * g[t + 768] + bb[t + 768];
}

// ---------------- head: sigmoid(ln @ head_w + head_b) ----------------
__global__ __launch_bounds__(256) void k_head(
    const float* __restrict__ ln, const float* __restrict__ hw, const float* __restrict__ hb,
    float* __restrict__ out) {
  const int t = threadIdx.x;
  const int o = t & 15, rsub = t >> 4;
  const size_t row = (size_t)blockIdx.x * 16 + rsub;
  const float* lp = ln + row * 800;
  float acc = hb[o];
  for (int e = 0; e < 800; ++e) acc = fmaf(lp[e], hw[e * 16 + o], acc);
  out[row * 16 + o] = 1.f / (1.f + expf(-acc));
}

// ---------------- launcher ----------------
extern "C" void kernel_launch(void* const* d_in, const int* in_sizes, int n_in,
                              void* d_out, int out_size, void* d_ws, size_t ws_size,
                              hipStream_t stream) {
  (void)in_sizes; (void)n_in; (void)out_size; (void)ws_size;
  const float* x     = (const float*)d_in[0];
  const float* w0    = (const float*)d_in[1];
  const float* b0    = (const float*)d_in[2];
  const float* g0    = (const float*)d_in[3];
  const float* be0   = (const float*)d_in[4];
  const float* mu0   = (const float*)d_in[5];
  const float* var0  = (const float*)d_in[6];
  const float* w1    = (const float*)d_in[7];
  const float* b1    = (const float*)d_in[8];
  const float* g1    = (const float*)d_in[9];
  const float* be1   = (const float*)d_in[10];
  const float* mu1   = (const float*)d_in[11];
  const float* var1  = (const float*)d_in[12];
  const float* w2c   = (const float*)d_in[13];
  const float* b2    = (const float*)d_in[14];
  const float* g2    = (const float*)d_in[15];
  const float* be2   = (const float*)d_in[16];
  const float* mu2   = (const float*)d_in[17];
  const float* var2  = (const float*)d_in[18];
  const float* w3    = (const float*)d_in[19];
  const float* b3    = (const float*)d_in[20];
  const float* g3    = (const float*)d_in[21];
  const float* be3   = (const float*)d_in[22];
  const float* mu3   = (const float*)d_in[23];
  const float* var3  = (const float*)d_in[24];
  const float* qkvw  = (const float*)d_in[25];
  const float* outw  = (const float*)d_in[26];
  const float* outbv = (const float*)d_in[27];
  const float* resw  = (const float*)d_in[28];
  const float* lng   = (const float*)d_in[29];
  const float* lnbv  = (const float*)d_in[30];
  const float* headw = (const float*)d_in[31];
  const float* headb = (const float*)d_in[32];

  char* wsb = (char*)d_ws;
  _Float16* h0   = (_Float16*)(wsb + B_H0);
  _Float16* h1   = (_Float16*)(wsb + B_H1);
  _Float16* h2   = (_Float16*)(wsb + B_H2);
  _Float16* tok  = (_Float16*)(wsb + B_TOK);
  _Float16* attb = (_Float16*)(wsb + B_ATT);
  _Float16* wp1  = (_Float16*)(wsb + B_WP1);
  _Float16* wp2  = (_Float16*)(wsb + B_WP2);
  _Float16* wp3  = (_Float16*)(wsb + B_WP3);
  _Float16* qkvT = (_Float16*)(wsb + B_QKVT);
  _Float16* owT  = (_Float16*)(wsb + B_OWT);
  float* qb   = (float*)(wsb + B_Q);
  float* kb   = (float*)(wsb + B_K);
  float* vb   = (float*)(wsb + B_V);
  float* kT   = (float*)(wsb + B_KT);
  float* ql   = (float*)(wsb + B_QL);
  float* kl   = (float*)(wsb + B_KL);
  float* a2   = (float*)(wsb + B_A2);
  float* pv   = (float*)(wsb + B_PV);
  float* w2b  = (float*)(wsb + B_W2);
  float* a3v  = (float*)(wsb + B_A3V);
  float* scal = (float*)(wsb + B_SCAL);
  float* lnb  = (float*)(wsb + B_LNB);

  // weight packing + scal init
  k_pack_w<<<(128 * 64 * 9 + 255) / 256, 256, 0, stream>>>(w1, wp1, 128, 64, 9);
  k_pack_w<<<(256 * 128 * 9 + 255) / 256, 256, 0, stream>>>(w2c, wp2, 256, 128, 9);
  k_pack_w<<<(800 * 256 * 16 + 255) / 256, 256, 0, stream>>>(w3, wp3, 800, 256, 16);
  k_pack_t<<<(800 * 1536 + 255) / 256, 256, 0, stream>>>(qkvw, qkvT, 800, 1536);
  k_pack_t<<<(512 * 800 + 255) / 256, 256, 0, stream>>>(outw, owT, 512, 800);
  k_init<<<1, 64, 0, stream>>>(scal);

  // conv stack, per image (f16 NHWC activations)
  for (int img = 0; img < 4; ++img) {
    k_conv0<<<dim3(256), 256, 0, stream>>>(
        x + (size_t)img * 65536, w0, b0, g0, be0, mu0, var0, h0);
    k_convm<64><<<dim3(4, 256, 2), 256, 0, stream>>>(
        h0, wp1, b1, g1, be1, mu1, var1, h1, 128);
    k_convm<128><<<dim3(4, 256, 4), 256, 0, stream>>>(
        h1, wp2, b2, g2, be2, mu2, var2, h2, 256);
    k_c3<<<dim3(13, 64), 256, 0, stream>>>(
        h2, wp3, b3, g3, be3, mu3, var3, tok + (size_t)img * 4096 * 800);
  }
  // attention
  k_qkv_m<<<dim3(24, 256), 256, 0, stream>>>(tok, qkvT, qb, kb, vb);
  k_transpose<<<dim3(64, 32), 256, 0, stream>>>(kb, kT);
  k_landmark<<<dim3(64, 32), 64, 0, stream>>>(qb, kb, ql, kl);
  k_a2<<<dim3(32), 64, 0, stream>>>(ql, kl, a2, scal);
  k_a3v<<<dim3(64, 32), 256, 0, stream>>>(ql, kT, vb, a3v);
  k_pinv<<<dim3(32), 256, 0, stream>>>(a2, scal, pv);
  k_w2<<<dim3(32), 256, 0, stream>>>(pv, a3v, w2b);
  k_combine<<<dim3(64, 8, 4), 256, 0, stream>>>(qb, kl, w2b, vb, resw, attb);
  // projection + LN + head
  k_outproj_m<<<dim3(13, 256), 256, 0, stream>>>(attb, owT, outbv, lnb);
  k_ln<<<dim3(16384), 256, 0, stream>>>(lnb, lng, lnbv);
  k_head<<<dim3(1024), 256, 0, stream>>>(lnb, headw, headb, (float*)d_out);
}

// Round 4
// 2650.824 us; speedup vs baseline: 4.3474x; 1.5484x over previous
//
#include <hip/hip_runtime.h>

#define DI __device__ __forceinline__

constexpr float BN_EPS_C = 1e-5f;
constexpr float LN_EPS_C = 1e-5f;

typedef _Float16 half8 __attribute__((ext_vector_type(8)));
typedef float f32x4 __attribute__((ext_vector_type(4)));

// ---------------- workspace layout (BYTE offsets), peak ~133 MB ----------------
// Region A [0 .. 58,720,256): per-image conv scratch; then q/k/v f16; then lnb f32.
constexpr size_t B_H0   = 0;             // f16 [256][256][64]  = 8,388,608
constexpr size_t B_H1   = 8388608;       // f16 [256][256][128] = 16,777,216
constexpr size_t B_H2   = 25165824;      // f16 [256][256][256] = 33,554,432 (end 58,720,256)
constexpr size_t B_Q    = 0;             // f16 [32][4096][64] = 16,777,216
constexpr size_t B_K    = 16777216;      // f16 16,777,216
constexpr size_t B_V    = 33554432;      // f16 16,777,216 (end 50,331,648)
constexpr size_t B_LNB  = 0;             // f32 [16384][800] = 52,428,800 (q/k/v dead by outproj)
// Region B:
constexpr size_t B_KT   = 58720256;      // f16 [32][64][4096] = 16,777,216
constexpr size_t B_TOK  = 75497472;      // f16 [16384][800] = 26,214,400
constexpr size_t B_ATT  = 101711872;     // f16 [16384][512] = 16,777,216
// packed weights (f16):
constexpr size_t B_WP1  = 118489088;     // 128*9*64  *2 = 147,456
constexpr size_t B_WP2  = 118636544;     // 256*9*128 *2 = 589,824
constexpr size_t B_WP3  = 119226368;     // 800*16*256*2 = 6,553,600
constexpr size_t B_QKVT = 125779968;     // 1536*800*2 = 2,457,600
constexpr size_t B_OWT  = 128237568;     // 800*512*2 = 819,200
// small buffers:
constexpr size_t B_QL   = 129056768;     // f32 [32][64][64] = 524,288
constexpr size_t B_KL   = 129581056;     // f32 524,288
constexpr size_t B_KLH  = 130105344;     // f16 262,144
constexpr size_t B_A2   = 130367488;     // f32 524,288
constexpr size_t B_PV   = 130891776;     // f32 524,288
constexpr size_t B_W2T  = 131416064;     // f16 262,144 (w2^T: [bh][d][m])
constexpr size_t B_A3V  = 131678208;     // f32 524,288
constexpr size_t B_SCAL = 132202496;     // 2 floats

// ---------------- helpers ----------------
DI float blockReduceSum(float v) {
  #pragma unroll
  for (int o = 32; o; o >>= 1) v += __shfl_xor(v, o);
  __shared__ float red[4];
  int w = threadIdx.x >> 6;
  __syncthreads();
  if ((threadIdx.x & 63) == 0) red[w] = v;
  __syncthreads();
  return red[0] + red[1] + red[2] + red[3];
}

template <int LP, int RP>
DI void mm16(const float* L, const float* R, int r0, int c0, float reg[4][4]) {
  #pragma unroll
  for (int i = 0; i < 4; ++i)
    #pragma unroll
    for (int j = 0; j < 4; ++j) reg[i][j] = 0.f;
  for (int dd = 0; dd < 64; ++dd) {
    float l[4], r[4];
    #pragma unroll
    for (int i = 0; i < 4; ++i) l[i] = L[(size_t)(r0 + i) * LP + dd];
    #pragma unroll
    for (int j = 0; j < 4; ++j) r[j] = R[(size_t)dd * RP + c0 + j];
    #pragma unroll
    for (int i = 0; i < 4; ++i)
      #pragma unroll
      for (int j = 0; j < 4; ++j) reg[i][j] = fmaf(l[i], r[j], reg[i][j]);
  }
}

// ---------------- init ----------------
__global__ void k_init(float* scal) {
  if (threadIdx.x < 2) scal[threadIdx.x] = 0.f;
}

// ---------------- weight packing ----------------
__global__ void k_pack_w(const float* __restrict__ src, _Float16* __restrict__ dst,
                         int CO, int CI, int Q) {
  int i = blockIdx.x * 256 + threadIdx.x;
  if (i >= CO * CI * Q) return;
  int q = i % Q, ci = (i / Q) % CI, co = i / (Q * CI);
  dst[((size_t)co * Q + q) * CI + ci] = (_Float16)src[i];
}

__global__ void k_pack_t(const float* __restrict__ src, _Float16* __restrict__ dst,
                         int K, int N) {
  int i = blockIdx.x * 256 + threadIdx.x;
  if (i >= K * N) return;
  int n = i % N, k = i / N;
  dst[(size_t)n * K + k] = (_Float16)src[i];
}

// ---------------- conv0: CI=1 fp32 direct conv -> h0 NHWC f16 ----------------
__global__ __launch_bounds__(256) void k_conv0(
    const float* __restrict__ xb, const float* __restrict__ w0, const float* __restrict__ b0,
    const float* __restrict__ g0, const float* __restrict__ be0, const float* __restrict__ mu0,
    const float* __restrict__ var0, _Float16* __restrict__ h0) {
  const int t = threadIdx.x, co = t & 63, xg = t >> 6;
  const int y = blockIdx.x;
  float wreg[9];
  #pragma unroll
  for (int q = 0; q < 9; ++q) wreg[q] = w0[co * 9 + q];
  float s = g0[co] * rsqrtf(var0[co] + BN_EPS_C);
  float sh = fmaf(b0[co] - mu0[co], s, be0[co]);
  for (int xl = 0; xl < 64; ++xl) {
    int xx = xg * 64 + xl;
    float acc = 0.f;
    #pragma unroll
    for (int dy = 0; dy < 3; ++dy) {
      int yy = y + dy - 1;
      if ((unsigned)yy >= 256u) continue;
      #pragma unroll
      for (int dx = 0; dx < 3; ++dx) {
        int xi = xx + dx - 1;
        if ((unsigned)xi >= 256u) continue;
        acc = fmaf(wreg[dy * 3 + dx], xb[yy * 256 + xi], acc);
      }
    }
    float v = fmaxf(fmaf(acc, s, sh), 0.f);
    h0[((size_t)y * 256 + xx) * 64 + co] = (_Float16)v;
  }
}

// ---------------- MFMA implicit 3x3 conv, m-repeat 2: block = 128 x-cols x 64 co ----------
// grid (2, 256y, CO/64)
template <int CI>
__global__ __launch_bounds__(256) void k_convm(
    const _Float16* __restrict__ in, const _Float16* __restrict__ wp,
    const float* __restrict__ bias, const float* __restrict__ g, const float* __restrict__ be,
    const float* __restrict__ mu, const float* __restrict__ var,
    _Float16* __restrict__ out, int CO) {
  const int t = threadIdx.x, w = t >> 6, lo = t & 15, hi = (t >> 4) & 3;
  const int x0 = blockIdx.x * 128;
  const int y = blockIdx.y;
  const int c0 = blockIdx.z * 64;
  f32x4 acc[2][4] = {};
  for (int dy = 0; dy < 3; ++dy) {
    int yy = y + dy - 1;
    bool yok = (unsigned)yy < 256u;
    for (int dx = 0; dx < 3; ++dx) {
      int xa = x0 + w * 32 + lo + dx - 1;
      int xb2 = xa + 16;
      bool ok0 = yok && (unsigned)xa < 256u;
      bool ok1 = yok && (unsigned)xb2 < 256u;
      const _Float16* ap0 = in + ((size_t)yy * 256 + xa) * CI + 8 * hi;
      const _Float16* ap1 = ap0 + (size_t)16 * CI;
      const _Float16* bp = wp + (size_t)(dy * 3 + dx) * CI + 8 * hi;
      #pragma unroll
      for (int c = 0; c < CI; c += 32) {
        half8 a0 = {}, a1 = {};
        if (ok0) a0 = *reinterpret_cast<const half8*>(ap0 + c);
        if (ok1) a1 = *reinterpret_cast<const half8*>(ap1 + c);
        #pragma unroll
        for (int nt = 0; nt < 4; ++nt) {
          int co = c0 + nt * 16 + lo;
          half8 b = *reinterpret_cast<const half8*>(bp + (size_t)co * 9 * CI + c);
          acc[0][nt] = __builtin_amdgcn_mfma_f32_16x16x32_f16(a0, b, acc[0][nt], 0, 0, 0);
          acc[1][nt] = __builtin_amdgcn_mfma_f32_16x16x32_f16(a1, b, acc[1][nt], 0, 0, 0);
        }
      }
    }
  }
  #pragma unroll
  for (int nt = 0; nt < 4; ++nt) {
    int co = c0 + nt * 16 + lo;
    float s = g[co] * rsqrtf(var[co] + BN_EPS_C);
    float sh = fmaf(bias[co] - mu[co], s, be[co]);
    #pragma unroll
    for (int m = 0; m < 2; ++m)
      #pragma unroll
      for (int r = 0; r < 4; ++r) {
        int x = x0 + w * 32 + m * 16 + hi * 4 + r;
        float v = fmaxf(fmaf(acc[m][nt][r], s, sh), 0.f);
        out[((size_t)y * 256 + x) * CO + co] = (_Float16)v;
      }
  }
}

// ---------------- conv3 MFMA, m-repeat 2: grid (13, 32); block = 128 token rows ----------
__global__ __launch_bounds__(256) void k_c3(
    const _Float16* __restrict__ h2, const _Float16* __restrict__ wp3,
    const float* __restrict__ b3, const float* __restrict__ g3, const float* __restrict__ be3,
    const float* __restrict__ mu3, const float* __restrict__ var3,
    _Float16* __restrict__ tokb) {
  const int t = threadIdx.x, w = t >> 6, lo = t & 15, hi = (t >> 4) & 3;
  const int c0 = blockIdx.x * 64;
  const int r0 = blockIdx.y * 128;
  const int ra = r0 + w * 32 + lo, rb = ra + 16;
  f32x4 acc[2][4] = {};
  for (int q = 0; q < 16; ++q) {
    int iy = q >> 2, ix = q & 3;
    const _Float16* ap0 = h2 + (((size_t)((ra >> 6) * 4 + iy)) * 256 + (ra & 63) * 4 + ix) * 256 + 8 * hi;
    const _Float16* ap1 = h2 + (((size_t)((rb >> 6) * 4 + iy)) * 256 + (rb & 63) * 4 + ix) * 256 + 8 * hi;
    const _Float16* bp = wp3 + (size_t)q * 256 + 8 * hi;
    #pragma unroll
    for (int c = 0; c < 256; c += 32) {
      half8 a0 = *reinterpret_cast<const half8*>(ap0 + c);
      half8 a1 = *reinterpret_cast<const half8*>(ap1 + c);
      #pragma unroll
      for (int nt = 0; nt < 4; ++nt) {
        int co = min(c0 + nt * 16 + lo, 799);
        half8 b = *reinterpret_cast<const half8*>(bp + (size_t)co * 4096 + c);
        acc[0][nt] = __builtin_amdgcn_mfma_f32_16x16x32_f16(a0, b, acc[0][nt], 0, 0, 0);
        acc[1][nt] = __builtin_amdgcn_mfma_f32_16x16x32_f16(a1, b, acc[1][nt], 0, 0, 0);
      }
    }
  }
  #pragma unroll
  for (int nt = 0; nt < 4; ++nt) {
    int co = c0 + nt * 16 + lo;
    if (co < 800) {
      float s = g3[co] * rsqrtf(var3[co] + BN_EPS_C);
      float sh = fmaf(b3[co] - mu3[co], s, be3[co]);
      #pragma unroll
      for (int m = 0; m < 2; ++m)
        #pragma unroll
        for (int r = 0; r < 4; ++r) {
          int row = r0 + w * 32 + m * 16 + hi * 4 + r;
          float v = fmaxf(fmaf(acc[m][nt][r], s, sh), 0.f);
          tokb[(size_t)row * 800 + co] = (_Float16)v;
        }
    }
  }
}

// ---------------- qkv MFMA, m-repeat 2 -> q/k/v f16 [32][4096][64]; grid (24, 128) --------
__global__ __launch_bounds__(256) void k_qkv_m(
    const _Float16* __restrict__ tok, const _Float16* __restrict__ qkvT,
    _Float16* __restrict__ qx, _Float16* __restrict__ kx, _Float16* __restrict__ vx) {
  const int t = threadIdx.x, w = t >> 6, lo = t & 15, hi = (t >> 4) & 3;
  const int c0 = blockIdx.x * 64;
  const int row0 = blockIdx.y * 128;
  const _Float16* ap0 = tok + (size_t)(row0 + w * 32 + lo) * 800 + 8 * hi;
  const _Float16* ap1 = ap0 + (size_t)16 * 800;
  f32x4 acc[2][4] = {};
  for (int k = 0; k < 800; k += 32) {
    half8 a0 = *reinterpret_cast<const half8*>(ap0 + k);
    half8 a1 = *reinterpret_cast<const half8*>(ap1 + k);
    #pragma unroll
    for (int nt = 0; nt < 4; ++nt) {
      int co = c0 + nt * 16 + lo;
      half8 b = *reinterpret_cast<const half8*>(qkvT + (size_t)co * 800 + 8 * hi + k);
      acc[0][nt] = __builtin_amdgcn_mfma_f32_16x16x32_f16(a0, b, acc[0][nt], 0, 0, 0);
      acc[1][nt] = __builtin_amdgcn_mfma_f32_16x16x32_f16(a1, b, acc[1][nt], 0, 0, 0);
    }
  }
  const int seg = blockIdx.x >> 3, h = blockIdx.x & 7;
  const float scale = (seg == 0) ? 0.125f : 1.0f;
  _Float16* dst = (seg == 0) ? qx : (seg == 1) ? kx : vx;
  #pragma unroll
  for (int nt = 0; nt < 4; ++nt) {
    int d = nt * 16 + lo;
    #pragma unroll
    for (int m = 0; m < 2; ++m)
      #pragma unroll
      for (int r = 0; r < 4; ++r) {
        int row = row0 + w * 32 + m * 16 + hi * 4 + r;
        int b = row >> 12, nn = row & 4095;
        dst[((size_t)(b * 8 + h) * 4096 + nn) * 64 + d] = (_Float16)(acc[m][nt][r] * scale);
      }
  }
}

// ---------------- transpose k -> kT f16 [bh][d][n] ----------------
__global__ __launch_bounds__(256) void k_transpose(const _Float16* __restrict__ kx,
                                                   _Float16* __restrict__ kT) {
  __shared__ _Float16 tile[64 * 66];
  const int bh = blockIdx.y, n0 = blockIdx.x * 64;
  const _Float16* src = kx + ((size_t)bh * 4096 + n0) * 64;
  const int t = threadIdx.x;
  #pragma unroll
  for (int u = 0; u < 16; ++u) {
    int e = t + u * 256;
    int r = e >> 6, d = e & 63;
    tile[d * 66 + r] = src[e];
  }
  __syncthreads();
  _Float16* dst = kT + (size_t)bh * 262144 + n0;
  #pragma unroll
  for (int u = 0; u < 16; ++u) {
    int e = t + u * 256;
    int d = e >> 6, j = e & 63;
    dst[(size_t)d * 4096 + j] = tile[d * 66 + j];
  }
}

// ---------------- landmarks: means over 64-token blocks (f16 in, f32 + f16 out) ----------
__global__ __launch_bounds__(64) void k_landmark(
    const _Float16* __restrict__ qx, const _Float16* __restrict__ kx,
    float* __restrict__ ql, float* __restrict__ kl, _Float16* __restrict__ klh) {
  const int d = threadIdx.x;
  const int m = blockIdx.x, bh = blockIdx.y;
  const _Float16* qp = qx + ((size_t)bh * 4096 + m * 64) * 64 + d;
  const _Float16* kp = kx + ((size_t)bh * 4096 + m * 64) * 64 + d;
  float sq = 0.f, sk = 0.f;
  #pragma unroll 8
  for (int j = 0; j < 64; ++j) {
    sq += (float)qp[(size_t)j * 64];
    sk += (float)kp[(size_t)j * 64];
  }
  sq *= (1.f / 64.f);
  sk *= (1.f / 64.f);
  ql[((size_t)bh * 64 + m) * 64 + d] = sq;
  kl[((size_t)bh * 64 + m) * 64 + d] = sk;
  klh[((size_t)bh * 64 + m) * 64 + d] = (_Float16)sk;
}

// ---------------- a2 + global max row/col sums ----------------
__global__ __launch_bounds__(64) void k_a2(
    const float* __restrict__ ql, const float* __restrict__ kl,
    float* __restrict__ a2, float* __restrict__ scal) {
  __shared__ float sp[64 * 65];
  const int bh = blockIdx.x, t = threadIdx.x;
  const float* qr = ql + ((size_t)bh * 64 + t) * 64;
  const float* kb = kl + (size_t)bh * 4096;
  float mx = -1e30f;
  for (int c = 0; c < 64; ++c) {
    float acc = 0.f;
    #pragma unroll 8
    for (int dd = 0; dd < 64; ++dd) acc = fmaf(qr[dd], kb[c * 64 + dd], acc);
    sp[t * 65 + c] = acc;
    mx = fmaxf(mx, acc);
  }
  float sum = 0.f;
  for (int c = 0; c < 64; ++c) {
    float e = expf(sp[t * 65 + c] - mx);
    sp[t * 65 + c] = e;
    sum += e;
  }
  float inv = 1.f / sum;
  float rs = 0.f;
  for (int c = 0; c < 64; ++c) {
    float p = sp[t * 65 + c] * inv;
    sp[t * 65 + c] = p;
    a2[(size_t)bh * 4096 + t * 64 + c] = p;
    rs += p;
  }
  atomicMax(reinterpret_cast<int*>(scal), __float_as_int(rs));
  __syncthreads();
  float cs = 0.f;
  for (int r = 0; r < 64; ++r) cs += sp[r * 65 + t];
  atomicMax(reinterpret_cast<int*>(scal) + 1, __float_as_int(cs));
}

// ---------------- fused a3 softmax + a3@v (f16 kT, v) ----------------
__global__ __launch_bounds__(256) void k_a3v(
    const float* __restrict__ ql, const _Float16* __restrict__ kT,
    const _Float16* __restrict__ vx, float* __restrict__ a3v) {
  __shared__ float sq[64];
  __shared__ float sP[4096];
  __shared__ float red[4];
  __shared__ float red2[4][64];
  const int t = threadIdx.x;
  const int m = blockIdx.x, bh = blockIdx.y;
  if (t < 64) sq[t] = ql[((size_t)bh * 64 + m) * 64 + t];
  __syncthreads();
  const _Float16* kb = kT + (size_t)bh * 262144;
  float sc[16];
  #pragma unroll
  for (int i = 0; i < 16; ++i) sc[i] = 0.f;
  for (int dd = 0; dd < 64; ++dd) {
    float qv = sq[dd];
    const _Float16* kr = kb + (size_t)dd * 4096 + t;
    #pragma unroll
    for (int i = 0; i < 16; ++i) sc[i] = fmaf(qv, (float)kr[i * 256], sc[i]);
  }
  float mx = sc[0];
  #pragma unroll
  for (int i = 1; i < 16; ++i) mx = fmaxf(mx, sc[i]);
  #pragma unroll
  for (int o = 32; o; o >>= 1) mx = fmaxf(mx, __shfl_xor(mx, o));
  if ((t & 63) == 0) red[t >> 6] = mx;
  __syncthreads();
  mx = fmaxf(fmaxf(red[0], red[1]), fmaxf(red[2], red[3]));
  __syncthreads();
  float sum = 0.f;
  #pragma unroll
  for (int i = 0; i < 16; ++i) {
    sc[i] = expf(sc[i] - mx);
    sum += sc[i];
  }
  #pragma unroll
  for (int o = 32; o; o >>= 1) sum += __shfl_xor(sum, o);
  if ((t & 63) == 0) red[t >> 6] = sum;
  __syncthreads();
  sum = red[0] + red[1] + red[2] + red[3];
  float inv = 1.f / sum;
  #pragma unroll
  for (int i = 0; i < 16; ++i) sP[t + i * 256] = sc[i] * inv;
  __syncthreads();
  const int d = t & 63, seg = t >> 6;
  const _Float16* vb = vx + (size_t)bh * 262144;
  float acc = 0.f;
  for (int n = seg * 1024; n < seg * 1024 + 1024; ++n)
    acc = fmaf(sP[n], (float)vb[(size_t)n * 64 + d], acc);
  red2[seg][d] = acc;
  __syncthreads();
  if (seg == 0)
    a3v[((size_t)bh * 64 + m) * 64 + d] = red2[0][d] + red2[1][d] + red2[2][d] + red2[3][d];
}

// ---------------- Moore-Penrose pinv (fp32) ----------------
__global__ __launch_bounds__(256) void k_pinv(
    const float* __restrict__ a2g, const float* __restrict__ scal, float* __restrict__ pv) {
  __shared__ float z[64 * 65];
  __shared__ float az[64 * 65];
  __shared__ float tb[64 * 65];
  const int bh = blockIdx.x, t = threadIdx.x;
  const int r0 = (t >> 4) << 2, c0 = (t & 15) << 2;
  const float* ag = a2g + (size_t)bh * 4096;
  const float denom = 1.f / (scal[0] * scal[1]);
  #pragma unroll
  for (int i = 0; i < 4; ++i)
    #pragma unroll
    for (int j = 0; j < 4; ++j)
      z[(r0 + i) * 65 + c0 + j] = ag[(c0 + j) * 64 + r0 + i] * denom;
  __syncthreads();
  float reg[4][4], val[4][4];
  for (int it = 0; it < 6; ++it) {
    mm16<64, 65>(ag, z, r0, c0, reg);
    #pragma unroll
    for (int i = 0; i < 4; ++i)
      #pragma unroll
      for (int j = 0; j < 4; ++j) az[(r0 + i) * 65 + c0 + j] = reg[i][j];
    __syncthreads();
    mm16<65, 65>(az, az, r0, c0, reg);
    #pragma unroll
    for (int i = 0; i < 4; ++i)
      #pragma unroll
      for (int j = 0; j < 4; ++j)
        tb[(r0 + i) * 65 + c0 + j] = 7.f * az[(r0 + i) * 65 + c0 + j] - reg[i][j];
    __syncthreads();
    mm16<65, 65>(az, tb, r0, c0, reg);
    #pragma unroll
    for (int i = 0; i < 4; ++i)
      #pragma unroll
      for (int j = 0; j < 4; ++j)
        val[i][j] = 15.f * az[(r0 + i) * 65 + c0 + j] - reg[i][j];
    __syncthreads();
    #pragma unroll
    for (int i = 0; i < 4; ++i)
      #pragma unroll
      for (int j = 0; j < 4; ++j) tb[(r0 + i) * 65 + c0 + j] = val[i][j];
    __syncthreads();
    mm16<65, 65>(z, tb, r0, c0, reg);
    #pragma unroll
    for (int i = 0; i < 4; ++i)
      #pragma unroll
      for (int j = 0; j < 4; ++j)
        val[i][j] = 0.25f * (13.f * z[(r0 + i) * 65 + c0 + j] - reg[i][j]);
    __syncthreads();
    #pragma unroll
    for (int i = 0; i < 4; ++i)
      #pragma unroll
      for (int j = 0; j < 4; ++j) z[(r0 + i) * 65 + c0 + j] = val[i][j];
    __syncthreads();
  }
  #pragma unroll
  for (int i = 0; i < 4; ++i)
    #pragma unroll
    for (int j = 0; j < 4; ++j)
      pv[(size_t)bh * 4096 + (r0 + i) * 64 + c0 + j] = z[(r0 + i) * 65 + c0 + j];
}

// ---------------- w2t = (pinv @ a3v)^T as f16 [bh][d][m] ----------------
__global__ __launch_bounds__(256) void k_w2(
    const float* __restrict__ pv, const float* __restrict__ a3v, _Float16* __restrict__ w2t) {
  const int bh = blockIdx.x, t = threadIdx.x;
  const int r0 = (t >> 4) << 2, c0 = (t & 15) << 2;
  float reg[4][4];
  mm16<64, 64>(pv + (size_t)bh * 4096, a3v + (size_t)bh * 4096, r0, c0, reg);
  #pragma unroll
  for (int i = 0; i < 4; ++i)
    #pragma unroll
    for (int j = 0; j < 4; ++j)
      w2t[(size_t)bh * 4096 + (c0 + j) * 64 + (r0 + i)] = (_Float16)reg[i][j];
}

// ------- fused MFMA combine: S=q@kl^T -> softmax -> P@W2 + Toeplitz(res)@v -> att f16 ------
__global__ __launch_bounds__(256) void k_combine_m(
    const _Float16* __restrict__ qx, const _Float16* __restrict__ klh,
    const _Float16* __restrict__ w2t, const _Float16* __restrict__ vx,
    const float* __restrict__ rw, _Float16* __restrict__ att) {
  __shared__ _Float16 sP[64 * 72];     // P[n][m], pitch 72 (144B = 9*16)
  __shared__ _Float16 sVT[64 * 104];   // vT[d][r], r=0..95, pitch 104 (208B = 13*16)
  __shared__ _Float16 sT[64 * 104];    // Toeplitz[i][r]
  __shared__ float sR[33];
  const int t = threadIdx.x, w = t >> 6, lo = t & 15, hi = (t >> 4) & 3;
  const int n0 = blockIdx.x * 64;
  const int h = blockIdx.y, b = blockIdx.z, bh = b * 8 + h;
  if (t < 33) sR[t] = rw[h * 33 + t];
  __syncthreads();
  // stage vT (zero-padded halo) and Toeplitz
  const _Float16* vb = vx + (size_t)bh * 262144;
  #pragma unroll
  for (int u = 0; u < 24; ++u) {
    int e = t + u * 256;
    int r = e >> 6, d = e & 63;
    int nn = n0 - 16 + r;
    sVT[d * 104 + r] = ((unsigned)nn < 4096u) ? vb[(size_t)nn * 64 + d] : (_Float16)0.f;
  }
  #pragma unroll
  for (int u = 0; u < 24; ++u) {
    int e = t + u * 256;
    int r = e % 96, i = e / 96;
    int j = r - i;
    sT[i * 104 + r] = (j >= 0 && j < 33) ? (_Float16)sR[j] : (_Float16)0.f;
  }
  // Phase A: S = q @ kl^T  (A rows = wave's 16 n, B cols = 64 m)
  f32x4 sa[4] = {};
  const _Float16* qp = qx + ((size_t)bh * 4096 + n0 + w * 16 + lo) * 64 + 8 * hi;
  const _Float16* klp = klh + (size_t)bh * 4096;
  #pragma unroll
  for (int c = 0; c < 2; ++c) {
    half8 a = *reinterpret_cast<const half8*>(qp + 32 * c);
    #pragma unroll
    for (int ct = 0; ct < 4; ++ct) {
      half8 bf = *reinterpret_cast<const half8*>(klp + (size_t)(ct * 16 + lo) * 64 + 8 * hi + 32 * c);
      sa[ct] = __builtin_amdgcn_mfma_f32_16x16x32_f16(a, bf, sa[ct], 0, 0, 0);
    }
  }
  // row softmax over m: cols live in (ct, lo); rows in (hi, r)
  #pragma unroll
  for (int r = 0; r < 4; ++r) {
    float mx = fmaxf(fmaxf(sa[0][r], sa[1][r]), fmaxf(sa[2][r], sa[3][r]));
    #pragma unroll
    for (int o = 8; o; o >>= 1) mx = fmaxf(mx, __shfl_xor(mx, o));
    float e0 = expf(sa[0][r] - mx), e1 = expf(sa[1][r] - mx);
    float e2 = expf(sa[2][r] - mx), e3 = expf(sa[3][r] - mx);
    float sm = e0 + e1 + e2 + e3;
    #pragma unroll
    for (int o = 8; o; o >>= 1) sm += __shfl_xor(sm, o);
    float inv = 1.f / sm;
    int row = w * 16 + hi * 4 + r;
    sP[row * 72 + lo] = (_Float16)(e0 * inv);
    sP[row * 72 + 16 + lo] = (_Float16)(e1 * inv);
    sP[row * 72 + 32 + lo] = (_Float16)(e2 * inv);
    sP[row * 72 + 48 + lo] = (_Float16)(e3 * inv);
  }
  __syncthreads();   // sVT/sT visible to all waves (sP is wave-local rows)
  // Phase B: out = P @ W2 + T @ V
  f32x4 ao[4] = {};
  const _Float16* w2p = w2t + (size_t)bh * 4096;
  #pragma unroll
  for (int c = 0; c < 2; ++c) {
    half8 a = *reinterpret_cast<const half8*>(&sP[(w * 16 + lo) * 72 + 8 * hi + 32 * c]);
    #pragma unroll
    for (int ct = 0; ct < 4; ++ct) {
      half8 bf = *reinterpret_cast<const half8*>(w2p + (size_t)(ct * 16 + lo) * 64 + 8 * hi + 32 * c);
      ao[ct] = __builtin_amdgcn_mfma_f32_16x16x32_f16(a, bf, ao[ct], 0, 0, 0);
    }
  }
  #pragma unroll
  for (int c = 0; c < 3; ++c) {
    half8 a = *reinterpret_cast<const half8*>(&sT[(w * 16 + lo) * 104 + 8 * hi + 32 * c]);
    #pragma unroll
    for (int ct = 0; ct < 4; ++ct) {
      half8 bf = *reinterpret_cast<const half8*>(&sVT[(ct * 16 + lo) * 104 + 8 * hi + 32 * c]);
      ao[ct] = __builtin_amdgcn_mfma_f32_16x16x32_f16(a, bf, ao[ct], 0, 0, 0);
    }
  }
  _Float16* ab = att + ((size_t)b * 4096) * 512 + (size_t)h * 64;
  #pragma unroll
  for (int ct = 0; ct < 4; ++ct)
    #pragma unroll
    for (int r = 0; r < 4; ++r) {
      int n = n0 + w * 16 + hi * 4 + r;
      ab[(size_t)n * 512 + ct * 16 + lo] = (_Float16)ao[ct][r];
    }
}

// ---------------- out-proj MFMA, m-repeat 2: grid (13, 128) -> lnb f32 ----------------
__global__ __launch_bounds__(256) void k_outproj_m(
    const _Float16* __restrict__ attb, const _Float16* __restrict__ owT,
    const float* __restrict__ ob, float* __restrict__ lnb) {
  const int t = threadIdx.x, w = t >> 6, lo = t & 15, hi = (t >> 4) & 3;
  const int c0 = blockIdx.x * 64;
  const int row0 = blockIdx.y * 128;
  const _Float16* ap0 = attb + (size_t)(row0 + w * 32 + lo) * 512 + 8 * hi;
  const _Float16* ap1 = ap0 + (size_t)16 * 512;
  f32x4 acc[2][4] = {};
  #pragma unroll 2
  for (int k = 0; k < 512; k += 32) {
    half8 a0 = *reinterpret_cast<const half8*>(ap0 + k);
    half8 a1 = *reinterpret_cast<const half8*>(ap1 + k);
    #pragma unroll
    for (int nt = 0; nt < 4; ++nt) {
      int co = min(c0 + nt * 16 + lo, 799);
      half8 b = *reinterpret_cast<const half8*>(owT + (size_t)co * 512 + 8 * hi + k);
      acc[0][nt] = __builtin_amdgcn_mfma_f32_16x16x32_f16(a0, b, acc[0][nt], 0, 0, 0);
      acc[1][nt] = __builtin_amdgcn_mfma_f32_16x16x32_f16(a1, b, acc[1][nt], 0, 0, 0);
    }
  }
  #pragma unroll
  for (int nt = 0; nt < 4; ++nt) {
    int co = c0 + nt * 16 + lo;
    if (co < 800) {
      float bv = ob[co];
      #pragma unroll
      for (int m = 0; m < 2; ++m)
        #pragma unroll
        for (int r = 0; r < 4; ++r) {
          int row = row0 + w * 32 + m * 16 + hi * 4 + r;
          lnb[(size_t)row * 800 + co] = acc[m][nt][r] + bv;
        }
    }
  }
}

// ---------------- LayerNorm in place over E=800 ----------------
__global__ __launch_bounds__(256) void k_ln(
    float* __restrict__ buf, const float* __restrict__ g, const float* __restrict__ bb) {
  const int t = threadIdx.x;
  float* p = buf + (size_t)blockIdx.x * 800;
  float x0 = p[t], x1 = p[t + 256], x2 = p[t + 512];
  float x3 = (t < 32) ? p[t + 768] : 0.f;
  float s = blockReduceSum(x0 + x1 + x2 + x3);
  float mean = s * (1.f / 800.f);
  float d0 = x0 - mean, d1 = x1 - mean, d2 = x2 - mean;
  float d3 = (t < 32) ? x3 - mean : 0.f;
  float s2 = blockReduceSum(d0 * d0 + d1 * d1 + d2 * d2 + d3 * d3);
  float rstd = rsqrtf(s2 * (1.f / 800.f) + LN_EPS_C);
  p[t] = d0 * rstd * g[t] + bb[t];
  p[t + 256] = d1 * rstd * g[t + 256] + bb[t + 256];
  p[t + 512] = d2 * rstd * g[t + 512] + bb[t + 512];
  if (t < 32) p[t + 768] = d3 * rstd * g[t + 768] + bb[t + 768];
}

// ---------------- head: sigmoid(ln @ head_w + head_b) ----------------
__global__ __launch_bounds__(256) void k_head(
    const float* __restrict__ ln, const float* __restrict__ hw, const float* __restrict__ hb,
    float* __restrict__ out) {
  const int t = threadIdx.x;
  const int o = t & 15, rsub = t >> 4;
  const size_t row = (size_t)blockIdx.x * 16 + rsub;
  const float* lp = ln + row * 800;
  float acc = hb[o];
  for (int e = 0; e < 800; ++e) acc = fmaf(lp[e], hw[e * 16 + o], acc);
  out[row * 16 + o] = 1.f / (1.f + expf(-acc));
}

// ---------------- launcher ----------------
extern "C" void kernel_launch(void* const* d_in, const int* in_sizes, int n_in,
                              void* d_out, int out_size, void* d_ws, size_t ws_size,
                              hipStream_t stream) {
  (void)in_sizes; (void)n_in; (void)out_size; (void)ws_size;
  const float* x     = (const float*)d_in[0];
  const float* w0    = (const float*)d_in[1];
  const float* b0    = (const float*)d_in[2];
  const float* g0    = (const float*)d_in[3];
  const float* be0   = (const float*)d_in[4];
  const float* mu0   = (const float*)d_in[5];
  const float* var0  = (const float*)d_in[6];
  const float* w1    = (const float*)d_in[7];
  const float* b1    = (const float*)d_in[8];
  const float* g1    = (const float*)d_in[9];
  const float* be1   = (const float*)d_in[10];
  const float* mu1   = (const float*)d_in[11];
  const float* var1  = (const float*)d_in[12];
  const float* w2c   = (const float*)d_in[13];
  const float* b2    = (const float*)d_in[14];
  const float* g2    = (const float*)d_in[15];
  const float* be2   = (const float*)d_in[16];
  const float* mu2   = (const float*)d_in[17];
  const float* var2  = (const float*)d_in[18];
  const float* w3    = (const float*)d_in[19];
  const float* b3    = (const float*)d_in[20];
  const float* g3    = (const float*)d_in[21];
  const float* be3   = (const float*)d_in[22];
  const float* mu3   = (const float*)d_in[23];
  const float* var3  = (const float*)d_in[24];
  const float* qkvw  = (const float*)d_in[25];
  const float* outw  = (const float*)d_in[26];
  const float* outbv = (const float*)d_in[27];
  const float* resw  = (const float*)d_in[28];
  const float* lng   = (const float*)d_in[29];
  const float* lnbv  = (const float*)d_in[30];
  const float* headw = (const float*)d_in[31];
  const float* headb = (const float*)d_in[32];

  char* wsb = (char*)d_ws;
  _Float16* h0   = (_Float16*)(wsb + B_H0);
  _Float16* h1   = (_Float16*)(wsb + B_H1);
  _Float16* h2   = (_Float16*)(wsb + B_H2);
  _Float16* qb   = (_Float16*)(wsb + B_Q);
  _Float16* kb   = (_Float16*)(wsb + B_K);
  _Float16* vb   = (_Float16*)(wsb + B_V);
  _Float16* kT   = (_Float16*)(wsb + B_KT);
  _Float16* tok  = (_Float16*)(wsb + B_TOK);
  _Float16* attb = (_Float16*)(wsb + B_ATT);
  _Float16* wp1  = (_Float16*)(wsb + B_WP1);
  _Float16* wp2  = (_Float16*)(wsb + B_WP2);
  _Float16* wp3  = (_Float16*)(wsb + B_WP3);
  _Float16* qkvT = (_Float16*)(wsb + B_QKVT);
  _Float16* owT  = (_Float16*)(wsb + B_OWT);
  _Float16* klh  = (_Float16*)(wsb + B_KLH);
  _Float16* w2t  = (_Float16*)(wsb + B_W2T);
  float* ql   = (float*)(wsb + B_QL);
  float* kl   = (float*)(wsb + B_KL);
  float* a2   = (float*)(wsb + B_A2);
  float* pv   = (float*)(wsb + B_PV);
  float* a3v  = (float*)(wsb + B_A3V);
  float* scal = (float*)(wsb + B_SCAL);
  float* lnb  = (float*)(wsb + B_LNB);

  // weight packing + scal init
  k_pack_w<<<(128 * 64 * 9 + 255) / 256, 256, 0, stream>>>(w1, wp1, 128, 64, 9);
  k_pack_w<<<(256 * 128 * 9 + 255) / 256, 256, 0, stream>>>(w2c, wp2, 256, 128, 9);
  k_pack_w<<<(800 * 256 * 16 + 255) / 256, 256, 0, stream>>>(w3, wp3, 800, 256, 16);
  k_pack_t<<<(800 * 1536 + 255) / 256, 256, 0, stream>>>(qkvw, qkvT, 800, 1536);
  k_pack_t<<<(512 * 800 + 255) / 256, 256, 0, stream>>>(outw, owT, 512, 800);
  k_init<<<1, 64, 0, stream>>>(scal);

  // conv stack, per image
  for (int img = 0; img < 4; ++img) {
    k_conv0<<<dim3(256), 256, 0, stream>>>(
        x + (size_t)img * 65536, w0, b0, g0, be0, mu0, var0, h0);
    k_convm<64><<<dim3(2, 256, 2), 256, 0, stream>>>(
        h0, wp1, b1, g1, be1, mu1, var1, h1, 128);
    k_convm<128><<<dim3(2, 256, 4), 256, 0, stream>>>(
        h1, wp2, b2, g2, be2, mu2, var2, h2, 256);
    k_c3<<<dim3(13, 32), 256, 0, stream>>>(
        h2, wp3, b3, g3, be3, mu3, var3, tok + (size_t)img * 4096 * 800);
  }
  // attention
  k_qkv_m<<<dim3(24, 128), 256, 0, stream>>>(tok, qkvT, qb, kb, vb);
  k_transpose<<<dim3(64, 32), 256, 0, stream>>>(kb, kT);
  k_landmark<<<dim3(64, 32), 64, 0, stream>>>(qb, kb, ql, kl, klh);
  k_a2<<<dim3(32), 64, 0, stream>>>(ql, kl, a2, scal);
  k_a3v<<<dim3(64, 32), 256, 0, stream>>>(ql, kT, vb, a3v);
  k_pinv<<<dim3(32), 256, 0, stream>>>(a2, scal, pv);
  k_w2<<<dim3(32), 256, 0, stream>>>(pv, a3v, w2t);
  k_combine_m<<<dim3(64, 8, 4), 256, 0, stream>>>(qb, klh, w2t, vb, resw, attb);
  // projection + LN + head
  k_outproj_m<<<dim3(13, 128), 256, 0, stream>>>(attb, owT, outbv, lnb);
  k_ln<<<dim3(16384), 256, 0, stream>>>(lnb, lng, lnbv);
  k_head<<<dim3(1024), 256, 0, stream>>>(lnb, headw, headb, (float*)d_out);
}

// Round 5
// 2359.735 us; speedup vs baseline: 4.8837x; 1.1234x over previous
//
#include <hip/hip_runtime.h>

#define DI __device__ __forceinline__

constexpr float BN_EPS_C = 1e-5f;
constexpr float LN_EPS_C = 1e-5f;

typedef _Float16 half8 __attribute__((ext_vector_type(8)));
typedef float f32x4 __attribute__((ext_vector_type(4)));

// ---------------- workspace layout (BYTE offsets), peak ~199.3 MB ----------------
constexpr size_t B_H0   = 0;             // f16 [256][256][64]  per-image scratch
constexpr size_t B_H1   = 8388608;       // f16 [256][256][128] per-image scratch
constexpr size_t B_H2   = 25165824;      // f16 [4][256][256][256] = 134,217,728 (full batch)
// overlays inside the h2 region once h2 is dead (after k_c3):
constexpr size_t B_Q    = 25165824;      // f16 [32][4096][64] = 16,777,216
constexpr size_t B_K    = 41943040;      // f16 16,777,216
constexpr size_t B_V    = 58720256;      // f16 16,777,216
constexpr size_t B_KT   = 75497472;      // f16 [32][64][4096] = 16,777,216 (dead after a3v)
constexpr size_t B_ATT  = 92274688;      // f16 [16384][512] = 16,777,216
constexpr size_t B_LNB  = 25165824;      // f32 [16384][800] = 52,428,800 (q/k/v,kT dead by outproj)
// tok + packed weights + small buffers:
constexpr size_t B_TOK  = 159383552;     // f16 [16384][800] = 26,214,400
constexpr size_t B_WP1  = 185597952;     // 147,456
constexpr size_t B_WP2  = 185745408;     // 589,824
constexpr size_t B_WP3  = 186335232;     // 6,553,600
constexpr size_t B_QKVT = 192888832;     // 2,457,600
constexpr size_t B_OWT  = 195346432;     // 819,200
constexpr size_t B_QL   = 196165632;     // f32 524,288
constexpr size_t B_KL   = 196689920;
constexpr size_t B_KLH  = 197214208;     // f16 262,144
constexpr size_t B_A2   = 197476352;
constexpr size_t B_PV   = 198000640;
constexpr size_t B_W2T  = 198524928;     // f16 262,144
constexpr size_t B_A3V  = 198787072;
constexpr size_t B_SCAL = 199311360;     // 2 floats

// ---------------- helpers ----------------
DI float blockReduceSum(float v) {
  #pragma unroll
  for (int o = 32; o; o >>= 1) v += __shfl_xor(v, o);
  __shared__ float red[4];
  int w = threadIdx.x >> 6;
  __syncthreads();
  if ((threadIdx.x & 63) == 0) red[w] = v;
  __syncthreads();
  return red[0] + red[1] + red[2] + red[3];
}

template <int LP, int RP>
DI void mm16(const float* L, const float* R, int r0, int c0, float reg[4][4]) {
  #pragma unroll
  for (int i = 0; i < 4; ++i)
    #pragma unroll
    for (int j = 0; j < 4; ++j) reg[i][j] = 0.f;
  for (int dd = 0; dd < 64; ++dd) {
    float l[4], r[4];
    #pragma unroll
    for (int i = 0; i < 4; ++i) l[i] = L[(size_t)(r0 + i) * LP + dd];
    #pragma unroll
    for (int j = 0; j < 4; ++j) r[j] = R[(size_t)dd * RP + c0 + j];
    #pragma unroll
    for (int i = 0; i < 4; ++i)
      #pragma unroll
      for (int j = 0; j < 4; ++j) reg[i][j] = fmaf(l[i], r[j], reg[i][j]);
  }
}

// ---------------- init ----------------
__global__ void k_init(float* scal) {
  if (threadIdx.x < 2) scal[threadIdx.x] = 0.f;
}

// ---------------- weight packing ----------------
__global__ void k_pack_w(const float* __restrict__ src, _Float16* __restrict__ dst,
                         int CO, int CI, int Q) {
  int i = blockIdx.x * 256 + threadIdx.x;
  if (i >= CO * CI * Q) return;
  int q = i % Q, ci = (i / Q) % CI, co = i / (Q * CI);
  dst[((size_t)co * Q + q) * CI + ci] = (_Float16)src[i];
}

__global__ void k_pack_t(const float* __restrict__ src, _Float16* __restrict__ dst,
                         int K, int N) {
  int i = blockIdx.x * 256 + threadIdx.x;
  if (i >= K * N) return;
  int n = i % N, k = i / N;
  dst[(size_t)n * K + k] = (_Float16)src[i];
}

// ---------------- conv0: CI=1 fp32 direct conv -> h0 NHWC f16 ----------------
__global__ __launch_bounds__(256) void k_conv0(
    const float* __restrict__ xb, const float* __restrict__ w0, const float* __restrict__ b0,
    const float* __restrict__ g0, const float* __restrict__ be0, const float* __restrict__ mu0,
    const float* __restrict__ var0, _Float16* __restrict__ h0) {
  const int t = threadIdx.x, co = t & 63, xg = t >> 6;
  const int y = blockIdx.x;
  float wreg[9];
  #pragma unroll
  for (int q = 0; q < 9; ++q) wreg[q] = w0[co * 9 + q];
  float s = g0[co] * rsqrtf(var0[co] + BN_EPS_C);
  float sh = fmaf(b0[co] - mu0[co], s, be0[co]);
  for (int xl = 0; xl < 64; ++xl) {
    int xx = xg * 64 + xl;
    float acc = 0.f;
    #pragma unroll
    for (int dy = 0; dy < 3; ++dy) {
      int yy = y + dy - 1;
      if ((unsigned)yy >= 256u) continue;
      #pragma unroll
      for (int dx = 0; dx < 3; ++dx) {
        int xi = xx + dx - 1;
        if ((unsigned)xi >= 256u) continue;
        acc = fmaf(wreg[dy * 3 + dx], xb[yy * 256 + xi], acc);
      }
    }
    float v = fmaxf(fmaf(acc, s, sh), 0.f);
    h0[((size_t)y * 256 + xx) * 64 + co] = (_Float16)v;
  }
}

// ---------------- MFMA implicit 3x3 conv, m-repeat 2, taps fully unrolled ----------------
// grid (2, 256y, CO/64)
template <int CI>
__global__ __launch_bounds__(256) void k_convm(
    const _Float16* __restrict__ in, const _Float16* __restrict__ wp,
    const float* __restrict__ bias, const float* __restrict__ g, const float* __restrict__ be,
    const float* __restrict__ mu, const float* __restrict__ var,
    _Float16* __restrict__ out, int CO) {
  const int t = threadIdx.x, w = t >> 6, lo = t & 15, hi = (t >> 4) & 3;
  const int x0 = blockIdx.x * 128;
  const int y = blockIdx.y;
  const int c0 = blockIdx.z * 64;
  const _Float16* bp4[4];
  #pragma unroll
  for (int nt = 0; nt < 4; ++nt)
    bp4[nt] = wp + (size_t)(c0 + nt * 16 + lo) * 9 * CI + 8 * hi;
  f32x4 acc[2][4] = {};
  #pragma unroll
  for (int dy = 0; dy < 3; ++dy) {
    int yy = y + dy - 1;
    bool yok = (unsigned)yy < 256u;
    #pragma unroll
    for (int dx = 0; dx < 3; ++dx) {
      int xa = x0 + w * 32 + lo + dx - 1;
      int xb2 = xa + 16;
      bool ok0 = yok && (unsigned)xa < 256u;
      bool ok1 = yok && (unsigned)xb2 < 256u;
      const _Float16* ap0 = in + ((size_t)yy * 256 + xa) * CI + 8 * hi;
      const _Float16* ap1 = ap0 + (size_t)16 * CI;
      const int qoff = (dy * 3 + dx) * CI;
      #pragma unroll
      for (int c = 0; c < CI; c += 32) {
        half8 a0 = {}, a1 = {};
        if (ok0) a0 = *reinterpret_cast<const half8*>(ap0 + c);
        if (ok1) a1 = *reinterpret_cast<const half8*>(ap1 + c);
        #pragma unroll
        for (int nt = 0; nt < 4; ++nt) {
          half8 b = *reinterpret_cast<const half8*>(bp4[nt] + qoff + c);
          acc[0][nt] = __builtin_amdgcn_mfma_f32_16x16x32_f16(a0, b, acc[0][nt], 0, 0, 0);
          acc[1][nt] = __builtin_amdgcn_mfma_f32_16x16x32_f16(a1, b, acc[1][nt], 0, 0, 0);
        }
      }
    }
  }
  #pragma unroll
  for (int nt = 0; nt < 4; ++nt) {
    int co = c0 + nt * 16 + lo;
    float s = g[co] * rsqrtf(var[co] + BN_EPS_C);
    float sh = fmaf(bias[co] - mu[co], s, be[co]);
    #pragma unroll
    for (int m = 0; m < 2; ++m)
      #pragma unroll
      for (int r = 0; r < 4; ++r) {
        int x = x0 + w * 32 + m * 16 + hi * 4 + r;
        float v = fmaxf(fmaf(acc[m][nt][r], s, sh), 0.f);
        out[((size_t)y * 256 + x) * CO + co] = (_Float16)v;
      }
  }
}

// ---------------- conv3 MFMA, full batch, m-repeat 4: grid (13, 64); 256 rows/block -------
__global__ __launch_bounds__(256) void k_c3(
    const _Float16* __restrict__ h2, const _Float16* __restrict__ wp3,
    const float* __restrict__ b3, const float* __restrict__ g3, const float* __restrict__ be3,
    const float* __restrict__ mu3, const float* __restrict__ var3,
    _Float16* __restrict__ tok) {
  const int t = threadIdx.x, w = t >> 6, lo = t & 15, hi = (t >> 4) & 3;
  const int c0 = blockIdx.x * 64;
  const int r0 = blockIdx.y * 256;
  const int img = r0 >> 12;
  const int pyw = ((r0 & 4095) >> 6) + w;
  const _Float16* h2i = h2 + (size_t)img * 16777216;
  const _Float16* bp4[4];
  #pragma unroll
  for (int nt = 0; nt < 4; ++nt)
    bp4[nt] = wp3 + (size_t)min(c0 + nt * 16 + lo, 799) * 4096 + 8 * hi;
  f32x4 acc[4][4] = {};
  #pragma unroll 2
  for (int q = 0; q < 16; ++q) {
    const int iy = q >> 2, ix = q & 3;
    const _Float16* ap[4];
    #pragma unroll
    for (int m = 0; m < 4; ++m)
      ap[m] = h2i + (((size_t)(pyw * 4 + iy)) * 256 + (m * 16 + lo) * 4 + ix) * 256 + 8 * hi;
    #pragma unroll
    for (int c = 0; c < 256; c += 32) {
      half8 a[4];
      #pragma unroll
      for (int m = 0; m < 4; ++m) a[m] = *reinterpret_cast<const half8*>(ap[m] + c);
      #pragma unroll
      for (int nt = 0; nt < 4; ++nt) {
        half8 b = *reinterpret_cast<const half8*>(bp4[nt] + q * 256 + c);
        #pragma unroll
        for (int m = 0; m < 4; ++m)
          acc[m][nt] = __builtin_amdgcn_mfma_f32_16x16x32_f16(a[m], b, acc[m][nt], 0, 0, 0);
      }
    }
  }
  #pragma unroll
  for (int nt = 0; nt < 4; ++nt) {
    int co = c0 + nt * 16 + lo;
    if (co < 800) {
      float s = g3[co] * rsqrtf(var3[co] + BN_EPS_C);
      float sh = fmaf(b3[co] - mu3[co], s, be3[co]);
      #pragma unroll
      for (int m = 0; m < 4; ++m)
        #pragma unroll
        for (int r = 0; r < 4; ++r) {
          int row = r0 + w * 64 + m * 16 + hi * 4 + r;
          float v = fmaxf(fmaf(acc[m][nt][r], s, sh), 0.f);
          tok[(size_t)row * 800 + co] = (_Float16)v;
        }
    }
  }
}

// ---------------- qkv MFMA, m-repeat 2 -> q/k/v f16 [32][4096][64]; grid (24, 128) --------
__global__ __launch_bounds__(256) void k_qkv_m(
    const _Float16* __restrict__ tok, const _Float16* __restrict__ qkvT,
    _Float16* __restrict__ qx, _Float16* __restrict__ kx, _Float16* __restrict__ vx) {
  const int t = threadIdx.x, w = t >> 6, lo = t & 15, hi = (t >> 4) & 3;
  const int c0 = blockIdx.x * 64;
  const int row0 = blockIdx.y * 128;
  const _Float16* ap0 = tok + (size_t)(row0 + w * 32 + lo) * 800 + 8 * hi;
  const _Float16* ap1 = ap0 + (size_t)16 * 800;
  const _Float16* bp4[4];
  #pragma unroll
  for (int nt = 0; nt < 4; ++nt)
    bp4[nt] = qkvT + (size_t)(c0 + nt * 16 + lo) * 800 + 8 * hi;
  f32x4 acc[2][4] = {};
  #pragma unroll 5
  for (int k = 0; k < 800; k += 32) {
    half8 a0 = *reinterpret_cast<const half8*>(ap0 + k);
    half8 a1 = *reinterpret_cast<const half8*>(ap1 + k);
    #pragma unroll
    for (int nt = 0; nt < 4; ++nt) {
      half8 b = *reinterpret_cast<const half8*>(bp4[nt] + k);
      acc[0][nt] = __builtin_amdgcn_mfma_f32_16x16x32_f16(a0, b, acc[0][nt], 0, 0, 0);
      acc[1][nt] = __builtin_amdgcn_mfma_f32_16x16x32_f16(a1, b, acc[1][nt], 0, 0, 0);
    }
  }
  const int seg = blockIdx.x >> 3, h = blockIdx.x & 7;
  const float scale = (seg == 0) ? 0.125f : 1.0f;
  _Float16* dst = (seg == 0) ? qx : (seg == 1) ? kx : vx;
  #pragma unroll
  for (int nt = 0; nt < 4; ++nt) {
    int d = nt * 16 + lo;
    #pragma unroll
    for (int m = 0; m < 2; ++m)
      #pragma unroll
      for (int r = 0; r < 4; ++r) {
        int row = row0 + w * 32 + m * 16 + hi * 4 + r;
        int b = row >> 12, nn = row & 4095;
        dst[((size_t)(b * 8 + h) * 4096 + nn) * 64 + d] = (_Float16)(acc[m][nt][r] * scale);
      }
  }
}

// ---------------- transpose k -> kT f16 [bh][d][n] ----------------
__global__ __launch_bounds__(256) void k_transpose(const _Float16* __restrict__ kx,
                                                   _Float16* __restrict__ kT) {
  __shared__ _Float16 tile[64 * 66];
  const int bh = blockIdx.y, n0 = blockIdx.x * 64;
  const _Float16* src = kx + ((size_t)bh * 4096 + n0) * 64;
  const int t = threadIdx.x;
  #pragma unroll
  for (int u = 0; u < 16; ++u) {
    int e = t + u * 256;
    int r = e >> 6, d = e & 63;
    tile[d * 66 + r] = src[e];
  }
  __syncthreads();
  _Float16* dst = kT + (size_t)bh * 262144 + n0;
  #pragma unroll
  for (int u = 0; u < 16; ++u) {
    int e = t + u * 256;
    int d = e >> 6, j = e & 63;
    dst[(size_t)d * 4096 + j] = tile[d * 66 + j];
  }
}

// ---------------- landmarks ----------------
__global__ __launch_bounds__(64) void k_landmark(
    const _Float16* __restrict__ qx, const _Float16* __restrict__ kx,
    float* __restrict__ ql, float* __restrict__ kl, _Float16* __restrict__ klh) {
  const int d = threadIdx.x;
  const int m = blockIdx.x, bh = blockIdx.y;
  const _Float16* qp = qx + ((size_t)bh * 4096 + m * 64) * 64 + d;
  const _Float16* kp = kx + ((size_t)bh * 4096 + m * 64) * 64 + d;
  float sq = 0.f, sk = 0.f;
  #pragma unroll 8
  for (int j = 0; j < 64; ++j) {
    sq += (float)qp[(size_t)j * 64];
    sk += (float)kp[(size_t)j * 64];
  }
  sq *= (1.f / 64.f);
  sk *= (1.f / 64.f);
  ql[((size_t)bh * 64 + m) * 64 + d] = sq;
  kl[((size_t)bh * 64 + m) * 64 + d] = sk;
  klh[((size_t)bh * 64 + m) * 64 + d] = (_Float16)sk;
}

// ---------------- a2 + global max row/col sums ----------------
__global__ __launch_bounds__(64) void k_a2(
    const float* __restrict__ ql, const float* __restrict__ kl,
    float* __restrict__ a2, float* __restrict__ scal) {
  __shared__ float sp[64 * 65];
  const int bh = blockIdx.x, t = threadIdx.x;
  const float* qr = ql + ((size_t)bh * 64 + t) * 64;
  const float* kb = kl + (size_t)bh * 4096;
  float mx = -1e30f;
  for (int c = 0; c < 64; ++c) {
    float acc = 0.f;
    #pragma unroll 8
    for (int dd = 0; dd < 64; ++dd) acc = fmaf(qr[dd], kb[c * 64 + dd], acc);
    sp[t * 65 + c] = acc;
    mx = fmaxf(mx, acc);
  }
  float sum = 0.f;
  for (int c = 0; c < 64; ++c) {
    float e = expf(sp[t * 65 + c] - mx);
    sp[t * 65 + c] = e;
    sum += e;
  }
  float inv = 1.f / sum;
  float rs = 0.f;
  for (int c = 0; c < 64; ++c) {
    float p = sp[t * 65 + c] * inv;
    sp[t * 65 + c] = p;
    a2[(size_t)bh * 4096 + t * 64 + c] = p;
    rs += p;
  }
  atomicMax(reinterpret_cast<int*>(scal), __float_as_int(rs));
  __syncthreads();
  float cs = 0.f;
  for (int r = 0; r < 64; ++r) cs += sp[r * 65 + t];
  atomicMax(reinterpret_cast<int*>(scal) + 1, __float_as_int(cs));
}

// ---------------- fused a3 softmax + a3@v ----------------
__global__ __launch_bounds__(256) void k_a3v(
    const float* __restrict__ ql, const _Float16* __restrict__ kT,
    const _Float16* __restrict__ vx, float* __restrict__ a3v) {
  __shared__ float sq[64];
  __shared__ float sP[4096];
  __shared__ float red[4];
  __shared__ float red2[4][64];
  const int t = threadIdx.x;
  const int m = blockIdx.x, bh = blockIdx.y;
  if (t < 64) sq[t] = ql[((size_t)bh * 64 + m) * 64 + t];
  __syncthreads();
  const _Float16* kb = kT + (size_t)bh * 262144;
  float sc[16];
  #pragma unroll
  for (int i = 0; i < 16; ++i) sc[i] = 0.f;
  for (int dd = 0; dd < 64; ++dd) {
    float qv = sq[dd];
    const _Float16* kr = kb + (size_t)dd * 4096 + t;
    #pragma unroll
    for (int i = 0; i < 16; ++i) sc[i] = fmaf(qv, (float)kr[i * 256], sc[i]);
  }
  float mx = sc[0];
  #pragma unroll
  for (int i = 1; i < 16; ++i) mx = fmaxf(mx, sc[i]);
  #pragma unroll
  for (int o = 32; o; o >>= 1) mx = fmaxf(mx, __shfl_xor(mx, o));
  if ((t & 63) == 0) red[t >> 6] = mx;
  __syncthreads();
  mx = fmaxf(fmaxf(red[0], red[1]), fmaxf(red[2], red[3]));
  __syncthreads();
  float sum = 0.f;
  #pragma unroll
  for (int i = 0; i < 16; ++i) {
    sc[i] = expf(sc[i] - mx);
    sum += sc[i];
  }
  #pragma unroll
  for (int o = 32; o; o >>= 1) sum += __shfl_xor(sum, o);
  if ((t & 63) == 0) red[t >> 6] = sum;
  __syncthreads();
  sum = red[0] + red[1] + red[2] + red[3];
  float inv = 1.f / sum;
  #pragma unroll
  for (int i = 0; i < 16; ++i) sP[t + i * 256] = sc[i] * inv;
  __syncthreads();
  const int d = t & 63, seg = t >> 6;
  const _Float16* vb = vx + (size_t)bh * 262144;
  float acc = 0.f;
  for (int n = seg * 1024; n < seg * 1024 + 1024; ++n)
    acc = fmaf(sP[n], (float)vb[(size_t)n * 64 + d], acc);
  red2[seg][d] = acc;
  __syncthreads();
  if (seg == 0)
    a3v[((size_t)bh * 64 + m) * 64 + d] = red2[0][d] + red2[1][d] + red2[2][d] + red2[3][d];
}

// ---------------- Moore-Penrose pinv (fp32) ----------------
__global__ __launch_bounds__(256) void k_pinv(
    const float* __restrict__ a2g, const float* __restrict__ scal, float* __restrict__ pv) {
  __shared__ float z[64 * 65];
  __shared__ float az[64 * 65];
  __shared__ float tb[64 * 65];
  const int bh = blockIdx.x, t = threadIdx.x;
  const int r0 = (t >> 4) << 2, c0 = (t & 15) << 2;
  const float* ag = a2g + (size_t)bh * 4096;
  const float denom = 1.f / (scal[0] * scal[1]);
  #pragma unroll
  for (int i = 0; i < 4; ++i)
    #pragma unroll
    for (int j = 0; j < 4; ++j)
      z[(r0 + i) * 65 + c0 + j] = ag[(c0 + j) * 64 + r0 + i] * denom;
  __syncthreads();
  float reg[4][4], val[4][4];
  for (int it = 0; it < 6; ++it) {
    mm16<64, 65>(ag, z, r0, c0, reg);
    #pragma unroll
    for (int i = 0; i < 4; ++i)
      #pragma unroll
      for (int j = 0; j < 4; ++j) az[(r0 + i) * 65 + c0 + j] = reg[i][j];
    __syncthreads();
    mm16<65, 65>(az, az, r0, c0, reg);
    #pragma unroll
    for (int i = 0; i < 4; ++i)
      #pragma unroll
      for (int j = 0; j < 4; ++j)
        tb[(r0 + i) * 65 + c0 + j] = 7.f * az[(r0 + i) * 65 + c0 + j] - reg[i][j];
    __syncthreads();
    mm16<65, 65>(az, tb, r0, c0, reg);
    #pragma unroll
    for (int i = 0; i < 4; ++i)
      #pragma unroll
      for (int j = 0; j < 4; ++j)
        val[i][j] = 15.f * az[(r0 + i) * 65 + c0 + j] - reg[i][j];
    __syncthreads();
    #pragma unroll
    for (int i = 0; i < 4; ++i)
      #pragma unroll
      for (int j = 0; j < 4; ++j) tb[(r0 + i) * 65 + c0 + j] = val[i][j];
    __syncthreads();
    mm16<65, 65>(z, tb, r0, c0, reg);
    #pragma unroll
    for (int i = 0; i < 4; ++i)
      #pragma unroll
      for (int j = 0; j < 4; ++j)
        val[i][j] = 0.25f * (13.f * z[(r0 + i) * 65 + c0 + j] - reg[i][j]);
    __syncthreads();
    #pragma unroll
    for (int i = 0; i < 4; ++i)
      #pragma unroll
      for (int j = 0; j < 4; ++j) z[(r0 + i) * 65 + c0 + j] = val[i][j];
    __syncthreads();
  }
  #pragma unroll
  for (int i = 0; i < 4; ++i)
    #pragma unroll
    for (int j = 0; j < 4; ++j)
      pv[(size_t)bh * 4096 + (r0 + i) * 64 + c0 + j] = z[(r0 + i) * 65 + c0 + j];
}

// ---------------- w2t = (pinv @ a3v)^T as f16 [bh][d][m] ----------------
__global__ __launch_bounds__(256) void k_w2(
    const float* __restrict__ pv, const float* __restrict__ a3v, _Float16* __restrict__ w2t) {
  const int bh = blockIdx.x, t = threadIdx.x;
  const int r0 = (t >> 4) << 2, c0 = (t & 15) << 2;
  float reg[4][4];
  mm16<64, 64>(pv + (size_t)bh * 4096, a3v + (size_t)bh * 4096, r0, c0, reg);
  #pragma unroll
  for (int i = 0; i < 4; ++i)
    #pragma unroll
    for (int j = 0; j < 4; ++j)
      w2t[(size_t)bh * 4096 + (c0 + j) * 64 + (r0 + i)] = (_Float16)reg[i][j];
}

// ------- fused MFMA combine: S=q@kl^T -> softmax -> P@W2 + Toeplitz(res)@v -> att f16 ------
__global__ __launch_bounds__(256) void k_combine_m(
    const _Float16* __restrict__ qx, const _Float16* __restrict__ klh,
    const _Float16* __restrict__ w2t, const _Float16* __restrict__ vx,
    const float* __restrict__ rw, _Float16* __restrict__ att) {
  __shared__ _Float16 sP[64 * 72];
  __shared__ _Float16 sVT[64 * 104];
  __shared__ _Float16 sT[64 * 104];
  __shared__ float sR[33];
  const int t = threadIdx.x, w = t >> 6, lo = t & 15, hi = (t >> 4) & 3;
  const int n0 = blockIdx.x * 64;
  const int h = blockIdx.y, b = blockIdx.z, bh = b * 8 + h;
  if (t < 33) sR[t] = rw[h * 33 + t];
  __syncthreads();
  const _Float16* vb = vx + (size_t)bh * 262144;
  #pragma unroll
  for (int u = 0; u < 24; ++u) {
    int e = t + u * 256;
    int r = e >> 6, d = e & 63;
    int nn = n0 - 16 + r;
    sVT[d * 104 + r] = ((unsigned)nn < 4096u) ? vb[(size_t)nn * 64 + d] : (_Float16)0.f;
  }
  #pragma unroll
  for (int u = 0; u < 24; ++u) {
    int e = t + u * 256;
    int r = e % 96, i = e / 96;
    int j = r - i;
    sT[i * 104 + r] = (j >= 0 && j < 33) ? (_Float16)sR[j] : (_Float16)0.f;
  }
  f32x4 sa[4] = {};
  const _Float16* qp = qx + ((size_t)bh * 4096 + n0 + w * 16 + lo) * 64 + 8 * hi;
  const _Float16* klp = klh + (size_t)bh * 4096;
  #pragma unroll
  for (int c = 0; c < 2; ++c) {
    half8 a = *reinterpret_cast<const half8*>(qp + 32 * c);
    #pragma unroll
    for (int ct = 0; ct < 4; ++ct) {
      half8 bf = *reinterpret_cast<const half8*>(klp + (size_t)(ct * 16 + lo) * 64 + 8 * hi + 32 * c);
      sa[ct] = __builtin_amdgcn_mfma_f32_16x16x32_f16(a, bf, sa[ct], 0, 0, 0);
    }
  }
  #pragma unroll
  for (int r = 0; r < 4; ++r) {
    float mx = fmaxf(fmaxf(sa[0][r], sa[1][r]), fmaxf(sa[2][r], sa[3][r]));
    #pragma unroll
    for (int o = 8; o; o >>= 1) mx = fmaxf(mx, __shfl_xor(mx, o));
    float e0 = expf(sa[0][r] - mx), e1 = expf(sa[1][r] - mx);
    float e2 = expf(sa[2][r] - mx), e3 = expf(sa[3][r] - mx);
    float sm = e0 + e1 + e2 + e3;
    #pragma unroll
    for (int o = 8; o; o >>= 1) sm += __shfl_xor(sm, o);
    float inv = 1.f / sm;
    int row = w * 16 + hi * 4 + r;
    sP[row * 72 + lo] = (_Float16)(e0 * inv);
    sP[row * 72 + 16 + lo] = (_Float16)(e1 * inv);
    sP[row * 72 + 32 + lo] = (_Float16)(e2 * inv);
    sP[row * 72 + 48 + lo] = (_Float16)(e3 * inv);
  }
  __syncthreads();
  f32x4 ao[4] = {};
  const _Float16* w2p = w2t + (size_t)bh * 4096;
  #pragma unroll
  for (int c = 0; c < 2; ++c) {
    half8 a = *reinterpret_cast<const half8*>(&sP[(w * 16 + lo) * 72 + 8 * hi + 32 * c]);
    #pragma unroll
    for (int ct = 0; ct < 4; ++ct) {
      half8 bf = *reinterpret_cast<const half8*>(w2p + (size_t)(ct * 16 + lo) * 64 + 8 * hi + 32 * c);
      ao[ct] = __builtin_amdgcn_mfma_f32_16x16x32_f16(a, bf, ao[ct], 0, 0, 0);
    }
  }
  #pragma unroll
  for (int c = 0; c < 3; ++c) {
    half8 a = *reinterpret_cast<const half8*>(&sT[(w * 16 + lo) * 104 + 8 * hi + 32 * c]);
    #pragma unroll
    for (int ct = 0; ct < 4; ++ct) {
      half8 bf = *reinterpret_cast<const half8*>(&sVT[(ct * 16 + lo) * 104 + 8 * hi + 32 * c]);
      ao[ct] = __builtin_amdgcn_mfma_f32_16x16x32_f16(a, bf, ao[ct], 0, 0, 0);
    }
  }
  _Float16* ab = att + ((size_t)b * 4096) * 512 + (size_t)h * 64;
  #pragma unroll
  for (int ct = 0; ct < 4; ++ct)
    #pragma unroll
    for (int r = 0; r < 4; ++r) {
      int n = n0 + w * 16 + hi * 4 + r;
      ab[(size_t)n * 512 + ct * 16 + lo] = (_Float16)ao[ct][r];
    }
}

// ---------------- out-proj MFMA, m-repeat 2: grid (13, 128) -> lnb f32 ----------------
__global__ __launch_bounds__(256) void k_outproj_m(
    const _Float16* __restrict__ attb, const _Float16* __restrict__ owT,
    const float* __restrict__ ob, float* __restrict__ lnb) {
  const int t = threadIdx.x, w = t >> 6, lo = t & 15, hi = (t >> 4) & 3;
  const int c0 = blockIdx.x * 64;
  const int row0 = blockIdx.y * 128;
  const _Float16* ap0 = attb + (size_t)(row0 + w * 32 + lo) * 512 + 8 * hi;
  const _Float16* ap1 = ap0 + (size_t)16 * 512;
  const _Float16* bp4[4];
  #pragma unroll
  for (int nt = 0; nt < 4; ++nt)
    bp4[nt] = owT + (size_t)min(c0 + nt * 16 + lo, 799) * 512 + 8 * hi;
  f32x4 acc[2][4] = {};
  #pragma unroll 4
  for (int k = 0; k < 512; k += 32) {
    half8 a0 = *reinterpret_cast<const half8*>(ap0 + k);
    half8 a1 = *reinterpret_cast<const half8*>(ap1 + k);
    #pragma unroll
    for (int nt = 0; nt < 4; ++nt) {
      half8 b = *reinterpret_cast<const half8*>(bp4[nt] + k);
      acc[0][nt] = __builtin_amdgcn_mfma_f32_16x16x32_f16(a0, b, acc[0][nt], 0, 0, 0);
      acc[1][nt] = __builtin_amdgcn_mfma_f32_16x16x32_f16(a1, b, acc[1][nt], 0, 0, 0);
    }
  }
  #pragma unroll
  for (int nt = 0; nt < 4; ++nt) {
    int co = c0 + nt * 16 + lo;
    if (co < 800) {
      float bv = ob[co];
      #pragma unroll
      for (int m = 0; m < 2; ++m)
        #pragma unroll
        for (int r = 0; r < 4; ++r) {
          int row = row0 + w * 32 + m * 16 + hi * 4 + r;
          lnb[(size_t)row * 800 + co] = acc[m][nt][r] + bv;
        }
    }
  }
}

// ---------------- LayerNorm in place over E=800 ----------------
__global__ __launch_bounds__(256) void k_ln(
    float* __restrict__ buf, const float* __restrict__ g, const float* __restrict__ bb) {
  const int t = threadIdx.x;
  float* p = buf + (size_t)blockIdx.x * 800;
  float x0 = p[t], x1 = p[t + 256], x2 = p[t + 512];
  float x3 = (t < 32) ? p[t + 768] : 0.f;
  float s = blockReduceSum(x0 + x1 + x2 + x3);
  float mean = s * (1.f / 800.f);
  float d0 = x0 - mean, d1 = x1 - mean, d2 = x2 - mean;
  float d3 = (t < 32) ? x3 - mean : 0.f;
  float s2 = blockReduceSum(d0 * d0 + d1 * d1 + d2 * d2 + d3 * d3);
  float rstd = rsqrtf(s2 * (1.f / 800.f) + LN_EPS_C);
  p[t] = d0 * rstd * g[t] + bb[t];
  p[t + 256] = d1 * rstd * g[t + 256] + bb[t + 256];
  p[t + 512] = d2 * rstd * g[t + 512] + bb[t + 512];
  if (t < 32) p[t + 768] = d3 * rstd * g[t + 768] + bb[t + 768];
}

// ---------------- head: sigmoid(ln @ head_w + head_b) ----------------
__global__ __launch_bounds__(256) void k_head(
    const float* __restrict__ ln, const float* __restrict__ hw, const float* __restrict__ hb,
    float* __restrict__ out) {
  const int t = threadIdx.x;
  const int o = t & 15, rsub = t >> 4;
  const size_t row = (size_t)blockIdx.x * 16 + rsub;
  const float* lp = ln + row * 800;
  float acc = hb[o];
  for (int e = 0; e < 800; ++e) acc = fmaf(lp[e], hw[e * 16 + o], acc);
  out[row * 16 + o] = 1.f / (1.f + expf(-acc));
}

// ---------------- launcher ----------------
extern "C" void kernel_launch(void* const* d_in, const int* in_sizes, int n_in,
                              void* d_out, int out_size, void* d_ws, size_t ws_size,
                              hipStream_t stream) {
  (void)in_sizes; (void)n_in; (void)out_size; (void)ws_size;
  const float* x     = (const float*)d_in[0];
  const float* w0    = (const float*)d_in[1];
  const float* b0    = (const float*)d_in[2];
  const float* g0    = (const float*)d_in[3];
  const float* be0   = (const float*)d_in[4];
  const float* mu0   = (const float*)d_in[5];
  const float* var0  = (const float*)d_in[6];
  const float* w1    = (const float*)d_in[7];
  const float* b1    = (const float*)d_in[8];
  const float* g1    = (const float*)d_in[9];
  const float* be1   = (const float*)d_in[10];
  const float* mu1   = (const float*)d_in[11];
  const float* var1  = (const float*)d_in[12];
  const float* w2c   = (const float*)d_in[13];
  const float* b2    = (const float*)d_in[14];
  const float* g2    = (const float*)d_in[15];
  const float* be2   = (const float*)d_in[16];
  const float* mu2   = (const float*)d_in[17];
  const float* var2  = (const float*)d_in[18];
  const float* w3    = (const float*)d_in[19];
  const float* b3    = (const float*)d_in[20];
  const float* g3    = (const float*)d_in[21];
  const float* be3   = (const float*)d_in[22];
  const float* mu3   = (const float*)d_in[23];
  const float* var3  = (const float*)d_in[24];
  const float* qkvw  = (const float*)d_in[25];
  const float* outw  = (const float*)d_in[26];
  const float* outbv = (const float*)d_in[27];
  const float* resw  = (const float*)d_in[28];
  const float* lng   = (const float*)d_in[29];
  const float* lnbv  = (const float*)d_in[30];
  const float* headw = (const float*)d_in[31];
  const float* headb = (const float*)d_in[32];

  char* wsb = (char*)d_ws;
  _Float16* h0   = (_Float16*)(wsb + B_H0);
  _Float16* h1   = (_Float16*)(wsb + B_H1);
  _Float16* h2   = (_Float16*)(wsb + B_H2);
  _Float16* qb   = (_Float16*)(wsb + B_Q);
  _Float16* kb   = (_Float16*)(wsb + B_K);
  _Float16* vb   = (_Float16*)(wsb + B_V);
  _Float16* kT   = (_Float16*)(wsb + B_KT);
  _Float16* tok  = (_Float16*)(wsb + B_TOK);
  _Float16* attb = (_Float16*)(wsb + B_ATT);
  _Float16* wp1  = (_Float16*)(wsb + B_WP1);
  _Float16* wp2  = (_Float16*)(wsb + B_WP2);
  _Float16* wp3  = (_Float16*)(wsb + B_WP3);
  _Float16* qkvT = (_Float16*)(wsb + B_QKVT);
  _Float16* owT  = (_Float16*)(wsb + B_OWT);
  _Float16* klh  = (_Float16*)(wsb + B_KLH);
  _Float16* w2t  = (_Float16*)(wsb + B_W2T);
  float* ql   = (float*)(wsb + B_QL);
  float* kl   = (float*)(wsb + B_KL);
  float* a2   = (float*)(wsb + B_A2);
  float* pv   = (float*)(wsb + B_PV);
  float* a3v  = (float*)(wsb + B_A3V);
  float* scal = (float*)(wsb + B_SCAL);
  float* lnb  = (float*)(wsb + B_LNB);

  // weight packing + scal init
  k_pack_w<<<(128 * 64 * 9 + 255) / 256, 256, 0, stream>>>(w1, wp1, 128, 64, 9);
  k_pack_w<<<(256 * 128 * 9 + 255) / 256, 256, 0, stream>>>(w2c, wp2, 256, 128, 9);
  k_pack_w<<<(800 * 256 * 16 + 255) / 256, 256, 0, stream>>>(w3, wp3, 800, 256, 16);
  k_pack_t<<<(800 * 1536 + 255) / 256, 256, 0, stream>>>(qkvw, qkvT, 800, 1536);
  k_pack_t<<<(512 * 800 + 255) / 256, 256, 0, stream>>>(outw, owT, 512, 800);
  k_init<<<1, 64, 0, stream>>>(scal);

  // conv stack: conv0..conv2 per image (h0/h1 scratch), h2 kept full-batch
  for (int img = 0; img < 4; ++img) {
    k_conv0<<<dim3(256), 256, 0, stream>>>(
        x + (size_t)img * 65536, w0, b0, g0, be0, mu0, var0, h0);
    k_convm<64><<<dim3(2, 256, 2), 256, 0, stream>>>(
        h0, wp1, b1, g1, be1, mu1, var1, h1, 128);
    k_convm<128><<<dim3(2, 256, 4), 256, 0, stream>>>(
        h1, wp2, b2, g2, be2, mu2, var2, h2 + (size_t)img * 16777216, 256);
  }
  // conv3 (patch conv) over the full batch, m-repeat 4
  k_c3<<<dim3(13, 64), 256, 0, stream>>>(h2, wp3, b3, g3, be3, mu3, var3, tok);
  // attention
  k_qkv_m<<<dim3(24, 128), 256, 0, stream>>>(tok, qkvT, qb, kb, vb);
  k_transpose<<<dim3(64, 32), 256, 0, stream>>>(kb, kT);
  k_landmark<<<dim3(64, 32), 64, 0, stream>>>(qb, kb, ql, kl, klh);
  k_a2<<<dim3(32), 64, 0, stream>>>(ql, kl, a2, scal);
  k_a3v<<<dim3(64, 32), 256, 0, stream>>>(ql, kT, vb, a3v);
  k_pinv<<<dim3(32), 256, 0, stream>>>(a2, scal, pv);
  k_w2<<<dim3(32), 256, 0, stream>>>(pv, a3v, w2t);
  k_combine_m<<<dim3(64, 8, 4), 256, 0, stream>>>(qb, klh, w2t, vb, resw, attb);
  // projection + LN + head
  k_outproj_m<<<dim3(13, 128), 256, 0, stream>>>(attb, owT, outbv, lnb);
  k_ln<<<dim3(16384), 256, 0, stream>>>(lnb, lng, lnbv);
  k_head<<<dim3(1024), 256, 0, stream>>>(lnb, headw, headb, (float*)d_out);
}

// Round 6
// 2028.990 us; speedup vs baseline: 5.6798x; 1.1630x over previous
//
#include <hip/hip_runtime.h>

#define DI __device__ __forceinline__

constexpr float BN_EPS_C = 1e-5f;
constexpr float LN_EPS_C = 1e-5f;

typedef _Float16 half8 __attribute__((ext_vector_type(8)));
typedef float f32x4 __attribute__((ext_vector_type(4)));

// ---------------- workspace layout (BYTE offsets), peak ~199.3 MB ----------------
constexpr size_t B_H0   = 0;             // f16 [256][256][64]  per-image scratch
constexpr size_t B_H1   = 8388608;       // f16 [256][256][128] per-image scratch
constexpr size_t B_H2   = 25165824;      // f16 [4][256][256][256] = 134,217,728 (full batch)
// overlays inside the h2 region once h2 is dead (after k_c3):
constexpr size_t B_Q    = 25165824;      // f16 [32][4096][64] = 16,777,216
constexpr size_t B_K    = 41943040;      // f16 16,777,216
constexpr size_t B_V    = 58720256;      // f16 16,777,216
constexpr size_t B_KT   = 75497472;      // f16 [32][64][4096] = 16,777,216 (dead after a3v)
constexpr size_t B_ATT  = 92274688;      // f16 [16384][512] = 16,777,216
constexpr size_t B_LNB  = 25165824;      // f32 [16384][800] = 52,428,800 (q/k/v,kT dead by outproj)
// tok + packed weights + small buffers:
constexpr size_t B_TOK  = 159383552;     // f16 [16384][800] = 26,214,400
constexpr size_t B_WP1  = 185597952;     // 147,456
constexpr size_t B_WP2  = 185745408;     // 589,824
constexpr size_t B_WP3  = 186335232;     // 6,553,600
constexpr size_t B_QKVT = 192888832;     // 2,457,600
constexpr size_t B_OWT  = 195346432;     // 819,200
constexpr size_t B_QL   = 196165632;     // f32 524,288
constexpr size_t B_KL   = 196689920;
constexpr size_t B_KLH  = 197214208;     // f16 262,144
constexpr size_t B_A2   = 197476352;
constexpr size_t B_PV   = 198000640;
constexpr size_t B_W2T  = 198524928;     // f16 262,144
constexpr size_t B_A3V  = 198787072;
constexpr size_t B_SCAL = 199311360;     // 2 floats

// ---------------- helpers ----------------
DI float blockReduceSum(float v) {
  #pragma unroll
  for (int o = 32; o; o >>= 1) v += __shfl_xor(v, o);
  __shared__ float red[4];
  int w = threadIdx.x >> 6;
  __syncthreads();
  if ((threadIdx.x & 63) == 0) red[w] = v;
  __syncthreads();
  return red[0] + red[1] + red[2] + red[3];
}

template <int LP, int RP>
DI void mm16(const float* L, const float* R, int r0, int c0, float reg[4][4]) {
  #pragma unroll
  for (int i = 0; i < 4; ++i)
    #pragma unroll
    for (int j = 0; j < 4; ++j) reg[i][j] = 0.f;
  for (int dd = 0; dd < 64; ++dd) {
    float l[4], r[4];
    #pragma unroll
    for (int i = 0; i < 4; ++i) l[i] = L[(size_t)(r0 + i) * LP + dd];
    #pragma unroll
    for (int j = 0; j < 4; ++j) r[j] = R[(size_t)dd * RP + c0 + j];
    #pragma unroll
    for (int i = 0; i < 4; ++i)
      #pragma unroll
      for (int j = 0; j < 4; ++j) reg[i][j] = fmaf(l[i], r[j], reg[i][j]);
  }
}

// ---------------- init ----------------
__global__ void k_init(float* scal) {
  if (threadIdx.x < 2) scal[threadIdx.x] = 0.f;
}

// ---------------- weight packing ----------------
__global__ void k_pack_w(const float* __restrict__ src, _Float16* __restrict__ dst,
                         int CO, int CI, int Q) {
  int i = blockIdx.x * 256 + threadIdx.x;
  if (i >= CO * CI * Q) return;
  int q = i % Q, ci = (i / Q) % CI, co = i / (Q * CI);
  dst[((size_t)co * Q + q) * CI + ci] = (_Float16)src[i];
}

__global__ void k_pack_t(const float* __restrict__ src, _Float16* __restrict__ dst,
                         int K, int N) {
  int i = blockIdx.x * 256 + threadIdx.x;
  if (i >= K * N) return;
  int n = i % N, k = i / N;
  dst[(size_t)n * K + k] = (_Float16)src[i];
}

// ---------------- conv0: CI=1 fp32 direct conv -> h0 NHWC f16 ----------------
__global__ __launch_bounds__(256) void k_conv0(
    const float* __restrict__ xb, const float* __restrict__ w0, const float* __restrict__ b0,
    const float* __restrict__ g0, const float* __restrict__ be0, const float* __restrict__ mu0,
    const float* __restrict__ var0, _Float16* __restrict__ h0) {
  const int t = threadIdx.x, co = t & 63, xg = t >> 6;
  const int y = blockIdx.x;
  float wreg[9];
  #pragma unroll
  for (int q = 0; q < 9; ++q) wreg[q] = w0[co * 9 + q];
  float s = g0[co] * rsqrtf(var0[co] + BN_EPS_C);
  float sh = fmaf(b0[co] - mu0[co], s, be0[co]);
  for (int xl = 0; xl < 64; ++xl) {
    int xx = xg * 64 + xl;
    float acc = 0.f;
    #pragma unroll
    for (int dy = 0; dy < 3; ++dy) {
      int yy = y + dy - 1;
      if ((unsigned)yy >= 256u) continue;
      #pragma unroll
      for (int dx = 0; dx < 3; ++dx) {
        int xi = xx + dx - 1;
        if ((unsigned)xi >= 256u) continue;
        acc = fmaf(wreg[dy * 3 + dx], xb[yy * 256 + xi], acc);
      }
    }
    float v = fmaxf(fmaf(acc, s, sh), 0.f);
    h0[((size_t)y * 256 + xx) * 64 + co] = (_Float16)v;
  }
}

// ---------------- MFMA implicit 3x3 conv, m-repeat 2, taps fully unrolled ----------------
// grid (2, 256y, CO/64)
template <int CI>
__global__ __launch_bounds__(256) void k_convm(
    const _Float16* __restrict__ in, const _Float16* __restrict__ wp,
    const float* __restrict__ bias, const float* __restrict__ g, const float* __restrict__ be,
    const float* __restrict__ mu, const float* __restrict__ var,
    _Float16* __restrict__ out, int CO) {
  const int t = threadIdx.x, w = t >> 6, lo = t & 15, hi = (t >> 4) & 3;
  const int x0 = blockIdx.x * 128;
  const int y = blockIdx.y;
  const int c0 = blockIdx.z * 64;
  const _Float16* bp4[4];
  #pragma unroll
  for (int nt = 0; nt < 4; ++nt)
    bp4[nt] = wp + (size_t)(c0 + nt * 16 + lo) * 9 * CI + 8 * hi;
  f32x4 acc[2][4] = {};
  #pragma unroll
  for (int dy = 0; dy < 3; ++dy) {
    int yy = y + dy - 1;
    bool yok = (unsigned)yy < 256u;
    #pragma unroll
    for (int dx = 0; dx < 3; ++dx) {
      int xa = x0 + w * 32 + lo + dx - 1;
      int xb2 = xa + 16;
      bool ok0 = yok && (unsigned)xa < 256u;
      bool ok1 = yok && (unsigned)xb2 < 256u;
      const _Float16* ap0 = in + ((size_t)yy * 256 + xa) * CI + 8 * hi;
      const _Float16* ap1 = ap0 + (size_t)16 * CI;
      const int qoff = (dy * 3 + dx) * CI;
      #pragma unroll
      for (int c = 0; c < CI; c += 32) {
        half8 a0 = {}, a1 = {};
        if (ok0) a0 = *reinterpret_cast<const half8*>(ap0 + c);
        if (ok1) a1 = *reinterpret_cast<const half8*>(ap1 + c);
        #pragma unroll
        for (int nt = 0; nt < 4; ++nt) {
          half8 b = *reinterpret_cast<const half8*>(bp4[nt] + qoff + c);
          acc[0][nt] = __builtin_amdgcn_mfma_f32_16x16x32_f16(a0, b, acc[0][nt], 0, 0, 0);
          acc[1][nt] = __builtin_amdgcn_mfma_f32_16x16x32_f16(a1, b, acc[1][nt], 0, 0, 0);
        }
      }
    }
  }
  #pragma unroll
  for (int nt = 0; nt < 4; ++nt) {
    int co = c0 + nt * 16 + lo;
    float s = g[co] * rsqrtf(var[co] + BN_EPS_C);
    float sh = fmaf(bias[co] - mu[co], s, be[co]);
    #pragma unroll
    for (int m = 0; m < 2; ++m)
      #pragma unroll
      for (int r = 0; r < 4; ++r) {
        int x = x0 + w * 32 + m * 16 + hi * 4 + r;
        float v = fmaxf(fmaf(acc[m][nt][r], s, sh), 0.f);
        out[((size_t)y * 256 + x) * CO + co] = (_Float16)v;
      }
  }
}

// ---------------- conv3 MFMA: m97-style staged GEMM, 128x160 tile, XCD-swizzled ------------
// M=16384 rows (patch tokens, gathered from h2), N=800 (5 col-tiles of 160), K=4096.
// 640 blocks = 8 XCD * 16 panels * 5 coltiles. 4 waves, each 64x80 (4x5 frags).
// LDS: A[128][40] f16 + B[160][40] f16, double-buffered = 45 KB. Reg-staged (gather source).
__global__ __launch_bounds__(256) void k_c3(
    const _Float16* __restrict__ h2, const _Float16* __restrict__ wp3,
    const float* __restrict__ b3, const float* __restrict__ g3, const float* __restrict__ be3,
    const float* __restrict__ mu3, const float* __restrict__ var3,
    _Float16* __restrict__ tok) {
  __shared__ _Float16 Abuf[2][128 * 40];
  __shared__ _Float16 Bbuf[2][160 * 40];
  const int t = threadIdx.x;
  // bijective XCD swizzle: col-tiles of a row-panel stay on one XCD (A-panel L2 reuse)
  const int bid = blockIdx.x;
  const int xcd = bid & 7, slot = bid >> 3;       // 640 = 8 * 80
  const int pj = slot / 5, cc = slot % 5;
  const int p = pj * 8 + xcd;                     // row panel 0..127
  const int r0 = p * 128, c0 = cc * 160;
  const int img = r0 >> 12;
  const _Float16* h2i = h2 + (size_t)img * 16777216;

  // staging slots: slot s covers LDS element block [m= ma+s*64][kga*8 .. +8)
  const int ma = t >> 2, kga = t & 3;
  const _Float16* baseA[2];
  #pragma unroll
  for (int s = 0; s < 2; ++s) {
    int m = ma + s * 64;
    int r = r0 + m;
    int py = (r & 4095) >> 6, px = r & 63;
    baseA[s] = h2i + ((size_t)py * 1024 + px * 4) * 256 + kga * 8;
  }
  const _Float16* baseB[3];
  #pragma unroll
  for (int s = 0; s < 3; ++s) {
    int cb = ma + s * 64;                          // s=2 valid only for t<128 (cb<160)
    baseB[s] = wp3 + (size_t)(c0 + (cb < 160 ? cb : 159)) * 4096 + kga * 8;
  }
  const int wo = ma * 40 + kga * 8;                // LDS f16 index; slot s adds s*64*40

  const int w = t >> 6, lo = t & 15, hi = (t >> 4) & 3;
  const int wm = w >> 1, wn = w & 1;
  const int roA = (wm * 64 + lo) * 40 + 8 * hi;    // A frag base (f16 idx), +mi*16*40
  const int roB = (wn * 80 + lo) * 40 + 8 * hi;    // B frag base, +ni*16*40

  f32x4 acc[4][5] = {};

  // prologue: stage chunk 0 (kc=0 -> q=0, aoff=0)
  {
    half8 a0 = *reinterpret_cast<const half8*>(baseA[0]);
    half8 a1 = *reinterpret_cast<const half8*>(baseA[1]);
    half8 b0v = *reinterpret_cast<const half8*>(baseB[0]);
    half8 b1v = *reinterpret_cast<const half8*>(baseB[1]);
    *reinterpret_cast<half8*>(&Abuf[0][wo]) = a0;
    *reinterpret_cast<half8*>(&Abuf[0][wo + 2560]) = a1;
    *reinterpret_cast<half8*>(&Bbuf[0][wo]) = b0v;
    *reinterpret_cast<half8*>(&Bbuf[0][wo + 2560]) = b1v;
    if (t < 128) {
      half8 b2v = *reinterpret_cast<const half8*>(baseB[2]);
      *reinterpret_cast<half8*>(&Bbuf[0][wo + 5120]) = b2v;
    }
  }
  __syncthreads();

  for (int ck = 0; ck < 128; ++ck) {
    const int cur = ck & 1;
    const bool more = (ck + 1 < 128);
    half8 rA0, rA1, rB0, rB1, rB2;
    if (more) {                                    // issue-early (T14): loads hide under MFMA
      const int kn = (ck + 1) << 5;
      const int q = kn >> 8, qk = kn & 255;
      const int aoff = (q >> 2) * 65536 + (q & 3) * 256 + qk;
      rA0 = *reinterpret_cast<const half8*>(baseA[0] + aoff);
      rA1 = *reinterpret_cast<const half8*>(baseA[1] + aoff);
      rB0 = *reinterpret_cast<const half8*>(baseB[0] + kn);
      rB1 = *reinterpret_cast<const half8*>(baseB[1] + kn);
      if (t < 128) rB2 = *reinterpret_cast<const half8*>(baseB[2] + kn);
    }
    // compute current chunk from LDS
    half8 af[4], bf[5];
    #pragma unroll
    for (int mi = 0; mi < 4; ++mi)
      af[mi] = *reinterpret_cast<const half8*>(&Abuf[cur][roA + mi * 640]);
    #pragma unroll
    for (int ni = 0; ni < 5; ++ni)
      bf[ni] = *reinterpret_cast<const half8*>(&Bbuf[cur][roB + ni * 640]);
    #pragma unroll
    for (int mi = 0; mi < 4; ++mi)
      #pragma unroll
      for (int ni = 0; ni < 5; ++ni)
        acc[mi][ni] = __builtin_amdgcn_mfma_f32_16x16x32_f16(af[mi], bf[ni], acc[mi][ni], 0, 0, 0);
    // write-late into the other buffer
    if (more) {
      *reinterpret_cast<half8*>(&Abuf[cur ^ 1][wo]) = rA0;
      *reinterpret_cast<half8*>(&Abuf[cur ^ 1][wo + 2560]) = rA1;
      *reinterpret_cast<half8*>(&Bbuf[cur ^ 1][wo]) = rB0;
      *reinterpret_cast<half8*>(&Bbuf[cur ^ 1][wo + 2560]) = rB1;
      if (t < 128) *reinterpret_cast<half8*>(&Bbuf[cur ^ 1][wo + 5120]) = rB2;
    }
    __syncthreads();
  }

  // epilogue: BN + ReLU, store f16 (cols are exact: 5*160 = 800, no guard)
  #pragma unroll
  for (int ni = 0; ni < 5; ++ni) {
    int col = c0 + wn * 80 + ni * 16 + lo;
    float s = g3[col] * rsqrtf(var3[col] + BN_EPS_C);
    float sh = fmaf(b3[col] - mu3[col], s, be3[col]);
    #pragma unroll
    for (int mi = 0; mi < 4; ++mi)
      #pragma unroll
      for (int rr = 0; rr < 4; ++rr) {
        int row = r0 + wm * 64 + mi * 16 + hi * 4 + rr;
        float v = fmaxf(fmaf(acc[mi][ni][rr], s, sh), 0.f);
        tok[(size_t)row * 800 + col] = (_Float16)v;
      }
  }
}

// ---------------- qkv MFMA, m-repeat 2 -> q/k/v f16 [32][4096][64]; grid (24, 128) --------
__global__ __launch_bounds__(256) void k_qkv_m(
    const _Float16* __restrict__ tok, const _Float16* __restrict__ qkvT,
    _Float16* __restrict__ qx, _Float16* __restrict__ kx, _Float16* __restrict__ vx) {
  const int t = threadIdx.x, w = t >> 6, lo = t & 15, hi = (t >> 4) & 3;
  const int c0 = blockIdx.x * 64;
  const int row0 = blockIdx.y * 128;
  const _Float16* ap0 = tok + (size_t)(row0 + w * 32 + lo) * 800 + 8 * hi;
  const _Float16* ap1 = ap0 + (size_t)16 * 800;
  const _Float16* bp4[4];
  #pragma unroll
  for (int nt = 0; nt < 4; ++nt)
    bp4[nt] = qkvT + (size_t)(c0 + nt * 16 + lo) * 800 + 8 * hi;
  f32x4 acc[2][4] = {};
  #pragma unroll 5
  for (int k = 0; k < 800; k += 32) {
    half8 a0 = *reinterpret_cast<const half8*>(ap0 + k);
    half8 a1 = *reinterpret_cast<const half8*>(ap1 + k);
    #pragma unroll
    for (int nt = 0; nt < 4; ++nt) {
      half8 b = *reinterpret_cast<const half8*>(bp4[nt] + k);
      acc[0][nt] = __builtin_amdgcn_mfma_f32_16x16x32_f16(a0, b, acc[0][nt], 0, 0, 0);
      acc[1][nt] = __builtin_amdgcn_mfma_f32_16x16x32_f16(a1, b, acc[1][nt], 0, 0, 0);
    }
  }
  const int seg = blockIdx.x >> 3, h = blockIdx.x & 7;
  const float scale = (seg == 0) ? 0.125f : 1.0f;
  _Float16* dst = (seg == 0) ? qx : (seg == 1) ? kx : vx;
  #pragma unroll
  for (int nt = 0; nt < 4; ++nt) {
    int d = nt * 16 + lo;
    #pragma unroll
    for (int m = 0; m < 2; ++m)
      #pragma unroll
      for (int r = 0; r < 4; ++r) {
        int row = row0 + w * 32 + m * 16 + hi * 4 + r;
        int b = row >> 12, nn = row & 4095;
        dst[((size_t)(b * 8 + h) * 4096 + nn) * 64 + d] = (_Float16)(acc[m][nt][r] * scale);
      }
  }
}

// ---------------- transpose k -> kT f16 [bh][d][n] ----------------
__global__ __launch_bounds__(256) void k_transpose(const _Float16* __restrict__ kx,
                                                   _Float16* __restrict__ kT) {
  __shared__ _Float16 tile[64 * 66];
  const int bh = blockIdx.y, n0 = blockIdx.x * 64;
  const _Float16* src = kx + ((size_t)bh * 4096 + n0) * 64;
  const int t = threadIdx.x;
  #pragma unroll
  for (int u = 0; u < 16; ++u) {
    int e = t + u * 256;
    int r = e >> 6, d = e & 63;
    tile[d * 66 + r] = src[e];
  }
  __syncthreads();
  _Float16* dst = kT + (size_t)bh * 262144 + n0;
  #pragma unroll
  for (int u = 0; u < 16; ++u) {
    int e = t + u * 256;
    int d = e >> 6, j = e & 63;
    dst[(size_t)d * 4096 + j] = tile[d * 66 + j];
  }
}

// ---------------- landmarks ----------------
__global__ __launch_bounds__(64) void k_landmark(
    const _Float16* __restrict__ qx, const _Float16* __restrict__ kx,
    float* __restrict__ ql, float* __restrict__ kl, _Float16* __restrict__ klh) {
  const int d = threadIdx.x;
  const int m = blockIdx.x, bh = blockIdx.y;
  const _Float16* qp = qx + ((size_t)bh * 4096 + m * 64) * 64 + d;
  const _Float16* kp = kx + ((size_t)bh * 4096 + m * 64) * 64 + d;
  float sq = 0.f, sk = 0.f;
  #pragma unroll 8
  for (int j = 0; j < 64; ++j) {
    sq += (float)qp[(size_t)j * 64];
    sk += (float)kp[(size_t)j * 64];
  }
  sq *= (1.f / 64.f);
  sk *= (1.f / 64.f);
  ql[((size_t)bh * 64 + m) * 64 + d] = sq;
  kl[((size_t)bh * 64 + m) * 64 + d] = sk;
  klh[((size_t)bh * 64 + m) * 64 + d] = (_Float16)sk;
}

// ---------------- a2 + global max row/col sums ----------------
__global__ __launch_bounds__(64) void k_a2(
    const float* __restrict__ ql, const float* __restrict__ kl,
    float* __restrict__ a2, float* __restrict__ scal) {
  __shared__ float sp[64 * 65];
  const int bh = blockIdx.x, t = threadIdx.x;
  const float* qr = ql + ((size_t)bh * 64 + t) * 64;
  const float* kb = kl + (size_t)bh * 4096;
  float mx = -1e30f;
  for (int c = 0; c < 64; ++c) {
    float acc = 0.f;
    #pragma unroll 8
    for (int dd = 0; dd < 64; ++dd) acc = fmaf(qr[dd], kb[c * 64 + dd], acc);
    sp[t * 65 + c] = acc;
    mx = fmaxf(mx, acc);
  }
  float sum = 0.f;
  for (int c = 0; c < 64; ++c) {
    float e = expf(sp[t * 65 + c] - mx);
    sp[t * 65 + c] = e;
    sum += e;
  }
  float inv = 1.f / sum;
  float rs = 0.f;
  for (int c = 0; c < 64; ++c) {
    float p = sp[t * 65 + c] * inv;
    sp[t * 65 + c] = p;
    a2[(size_t)bh * 4096 + t * 64 + c] = p;
    rs += p;
  }
  atomicMax(reinterpret_cast<int*>(scal), __float_as_int(rs));
  __syncthreads();
  float cs = 0.f;
  for (int r = 0; r < 64; ++r) cs += sp[r * 65 + t];
  atomicMax(reinterpret_cast<int*>(scal) + 1, __float_as_int(cs));
}

// ---------------- fused a3 softmax + a3@v ----------------
__global__ __launch_bounds__(256) void k_a3v(
    const float* __restrict__ ql, const _Float16* __restrict__ kT,
    const _Float16* __restrict__ vx, float* __restrict__ a3v) {
  __shared__ float sq[64];
  __shared__ float sP[4096];
  __shared__ float red[4];
  __shared__ float red2[4][64];
  const int t = threadIdx.x;
  const int m = blockIdx.x, bh = blockIdx.y;
  if (t < 64) sq[t] = ql[((size_t)bh * 64 + m) * 64 + t];
  __syncthreads();
  const _Float16* kb = kT + (size_t)bh * 262144;
  float sc[16];
  #pragma unroll
  for (int i = 0; i < 16; ++i) sc[i] = 0.f;
  for (int dd = 0; dd < 64; ++dd) {
    float qv = sq[dd];
    const _Float16* kr = kb + (size_t)dd * 4096 + t;
    #pragma unroll
    for (int i = 0; i < 16; ++i) sc[i] = fmaf(qv, (float)kr[i * 256], sc[i]);
  }
  float mx = sc[0];
  #pragma unroll
  for (int i = 1; i < 16; ++i) mx = fmaxf(mx, sc[i]);
  #pragma unroll
  for (int o = 32; o; o >>= 1) mx = fmaxf(mx, __shfl_xor(mx, o));
  if ((t & 63) == 0) red[t >> 6] = mx;
  __syncthreads();
  mx = fmaxf(fmaxf(red[0], red[1]), fmaxf(red[2], red[3]));
  __syncthreads();
  float sum = 0.f;
  #pragma unroll
  for (int i = 0; i < 16; ++i) {
    sc[i] = expf(sc[i] - mx);
    sum += sc[i];
  }
  #pragma unroll
  for (int o = 32; o; o >>= 1) sum += __shfl_xor(sum, o);
  if ((t & 63) == 0) red[t >> 6] = sum;
  __syncthreads();
  sum = red[0] + red[1] + red[2] + red[3];
  float inv = 1.f / sum;
  #pragma unroll
  for (int i = 0; i < 16; ++i) sP[t + i * 256] = sc[i] * inv;
  __syncthreads();
  const int d = t & 63, seg = t >> 6;
  const _Float16* vb = vx + (size_t)bh * 262144;
  float acc = 0.f;
  for (int n = seg * 1024; n < seg * 1024 + 1024; ++n)
    acc = fmaf(sP[n], (float)vb[(size_t)n * 64 + d], acc);
  red2[seg][d] = acc;
  __syncthreads();
  if (seg == 0)
    a3v[((size_t)bh * 64 + m) * 64 + d] = red2[0][d] + red2[1][d] + red2[2][d] + red2[3][d];
}

// ---------------- Moore-Penrose pinv (fp32) ----------------
__global__ __launch_bounds__(256) void k_pinv(
    const float* __restrict__ a2g, const float* __restrict__ scal, float* __restrict__ pv) {
  __shared__ float z[64 * 65];
  __shared__ float az[64 * 65];
  __shared__ float tb[64 * 65];
  const int bh = blockIdx.x, t = threadIdx.x;
  const int r0 = (t >> 4) << 2, c0 = (t & 15) << 2;
  const float* ag = a2g + (size_t)bh * 4096;
  const float denom = 1.f / (scal[0] * scal[1]);
  #pragma unroll
  for (int i = 0; i < 4; ++i)
    #pragma unroll
    for (int j = 0; j < 4; ++j)
      z[(r0 + i) * 65 + c0 + j] = ag[(c0 + j) * 64 + r0 + i] * denom;
  __syncthreads();
  float reg[4][4], val[4][4];
  for (int it = 0; it < 6; ++it) {
    mm16<64, 65>(ag, z, r0, c0, reg);
    #pragma unroll
    for (int i = 0; i < 4; ++i)
      #pragma unroll
      for (int j = 0; j < 4; ++j) az[(r0 + i) * 65 + c0 + j] = reg[i][j];
    __syncthreads();
    mm16<65, 65>(az, az, r0, c0, reg);
    #pragma unroll
    for (int i = 0; i < 4; ++i)
      #pragma unroll
      for (int j = 0; j < 4; ++j)
        tb[(r0 + i) * 65 + c0 + j] = 7.f * az[(r0 + i) * 65 + c0 + j] - reg[i][j];
    __syncthreads();
    mm16<65, 65>(az, tb, r0, c0, reg);
    #pragma unroll
    for (int i = 0; i < 4; ++i)
      #pragma unroll
      for (int j = 0; j < 4; ++j)
        val[i][j] = 15.f * az[(r0 + i) * 65 + c0 + j] - reg[i][j];
    __syncthreads();
    #pragma unroll
    for (int i = 0; i < 4; ++i)
      #pragma unroll
      for (int j = 0; j < 4; ++j) tb[(r0 + i) * 65 + c0 + j] = val[i][j];
    __syncthreads();
    mm16<65, 65>(z, tb, r0, c0, reg);
    #pragma unroll
    for (int i = 0; i < 4; ++i)
      #pragma unroll
      for (int j = 0; j < 4; ++j)
        val[i][j] = 0.25f * (13.f * z[(r0 + i) * 65 + c0 + j] - reg[i][j]);
    __syncthreads();
    #pragma unroll
    for (int i = 0; i < 4; ++i)
      #pragma unroll
      for (int j = 0; j < 4; ++j) z[(r0 + i) * 65 + c0 + j] = val[i][j];
    __syncthreads();
  }
  #pragma unroll
  for (int i = 0; i < 4; ++i)
    #pragma unroll
    for (int j = 0; j < 4; ++j)
      pv[(size_t)bh * 4096 + (r0 + i) * 64 + c0 + j] = z[(r0 + i) * 65 + c0 + j];
}

// ---------------- w2t = (pinv @ a3v)^T as f16 [bh][d][m] ----------------
__global__ __launch_bounds__(256) void k_w2(
    const float* __restrict__ pv, const float* __restrict__ a3v, _Float16* __restrict__ w2t) {
  const int bh = blockIdx.x, t = threadIdx.x;
  const int r0 = (t >> 4) << 2, c0 = (t & 15) << 2;
  float reg[4][4];
  mm16<64, 64>(pv + (size_t)bh * 4096, a3v + (size_t)bh * 4096, r0, c0, reg);
  #pragma unroll
  for (int i = 0; i < 4; ++i)
    #pragma unroll
    for (int j = 0; j < 4; ++j)
      w2t[(size_t)bh * 4096 + (c0 + j) * 64 + (r0 + i)] = (_Float16)reg[i][j];
}

// ------- fused MFMA combine: S=q@kl^T -> softmax -> P@W2 + Toeplitz(res)@v -> att f16 ------
__global__ __launch_bounds__(256) void k_combine_m(
    const _Float16* __restrict__ qx, const _Float16* __restrict__ klh,
    const _Float16* __restrict__ w2t, const _Float16* __restrict__ vx,
    const float* __restrict__ rw, _Float16* __restrict__ att) {
  __shared__ _Float16 sP[64 * 72];
  __shared__ _Float16 sVT[64 * 104];
  __shared__ _Float16 sT[64 * 104];
  __shared__ float sR[33];
  const int t = threadIdx.x, w = t >> 6, lo = t & 15, hi = (t >> 4) & 3;
  const int n0 = blockIdx.x * 64;
  const int h = blockIdx.y, b = blockIdx.z, bh = b * 8 + h;
  if (t < 33) sR[t] = rw[h * 33 + t];
  __syncthreads();
  const _Float16* vb = vx + (size_t)bh * 262144;
  #pragma unroll
  for (int u = 0; u < 24; ++u) {
    int e = t + u * 256;
    int r = e >> 6, d = e & 63;
    int nn = n0 - 16 + r;
    sVT[d * 104 + r] = ((unsigned)nn < 4096u) ? vb[(size_t)nn * 64 + d] : (_Float16)0.f;
  }
  #pragma unroll
  for (int u = 0; u < 24; ++u) {
    int e = t + u * 256;
    int r = e % 96, i = e / 96;
    int j = r - i;
    sT[i * 104 + r] = (j >= 0 && j < 33) ? (_Float16)sR[j] : (_Float16)0.f;
  }
  f32x4 sa[4] = {};
  const _Float16* qp = qx + ((size_t)bh * 4096 + n0 + w * 16 + lo) * 64 + 8 * hi;
  const _Float16* klp = klh + (size_t)bh * 4096;
  #pragma unroll
  for (int c = 0; c < 2; ++c) {
    half8 a = *reinterpret_cast<const half8*>(qp + 32 * c);
    #pragma unroll
    for (int ct = 0; ct < 4; ++ct) {
      half8 bf = *reinterpret_cast<const half8*>(klp + (size_t)(ct * 16 + lo) * 64 + 8 * hi + 32 * c);
      sa[ct] = __builtin_amdgcn_mfma_f32_16x16x32_f16(a, bf, sa[ct], 0, 0, 0);
    }
  }
  #pragma unroll
  for (int r = 0; r < 4; ++r) {
    float mx = fmaxf(fmaxf(sa[0][r], sa[1][r]), fmaxf(sa[2][r], sa[3][r]));
    #pragma unroll
    for (int o = 8; o; o >>= 1) mx = fmaxf(mx, __shfl_xor(mx, o));
    float e0 = expf(sa[0][r] - mx), e1 = expf(sa[1][r] - mx);
    float e2 = expf(sa[2][r] - mx), e3 = expf(sa[3][r] - mx);
    float sm = e0 + e1 + e2 + e3;
    #pragma unroll
    for (int o = 8; o; o >>= 1) sm += __shfl_xor(sm, o);
    float inv = 1.f / sm;
    int row = w * 16 + hi * 4 + r;
    sP[row * 72 + lo] = (_Float16)(e0 * inv);
    sP[row * 72 + 16 + lo] = (_Float16)(e1 * inv);
    sP[row * 72 + 32 + lo] = (_Float16)(e2 * inv);
    sP[row * 72 + 48 + lo] = (_Float16)(e3 * inv);
  }
  __syncthreads();
  f32x4 ao[4] = {};
  const _Float16* w2p = w2t + (size_t)bh * 4096;
  #pragma unroll
  for (int c = 0; c < 2; ++c) {
    half8 a = *reinterpret_cast<const half8*>(&sP[(w * 16 + lo) * 72 + 8 * hi + 32 * c]);
    #pragma unroll
    for (int ct = 0; ct < 4; ++ct) {
      half8 bf = *reinterpret_cast<const half8*>(w2p + (size_t)(ct * 16 + lo) * 64 + 8 * hi + 32 * c);
      ao[ct] = __builtin_amdgcn_mfma_f32_16x16x32_f16(a, bf, ao[ct], 0, 0, 0);
    }
  }
  #pragma unroll
  for (int c = 0; c < 3; ++c) {
    half8 a = *reinterpret_cast<const half8*>(&sT[(w * 16 + lo) * 104 + 8 * hi + 32 * c]);
    #pragma unroll
    for (int ct = 0; ct < 4; ++ct) {
      half8 bf = *reinterpret_cast<const half8*>(&sVT[(ct * 16 + lo) * 104 + 8 * hi + 32 * c]);
      ao[ct] = __builtin_amdgcn_mfma_f32_16x16x32_f16(a, bf, ao[ct], 0, 0, 0);
    }
  }
  _Float16* ab = att + ((size_t)b * 4096) * 512 + (size_t)h * 64;
  #pragma unroll
  for (int ct = 0; ct < 4; ++ct)
    #pragma unroll
    for (int r = 0; r < 4; ++r) {
      int n = n0 + w * 16 + hi * 4 + r;
      ab[(size_t)n * 512 + ct * 16 + lo] = (_Float16)ao[ct][r];
    }
}

// ---------------- out-proj MFMA, m-repeat 2: grid (13, 128) -> lnb f32 ----------------
__global__ __launch_bounds__(256) void k_outproj_m(
    const _Float16* __restrict__ attb, const _Float16* __restrict__ owT,
    const float* __restrict__ ob, float* __restrict__ lnb) {
  const int t = threadIdx.x, w = t >> 6, lo = t & 15, hi = (t >> 4) & 3;
  const int c0 = blockIdx.x * 64;
  const int row0 = blockIdx.y * 128;
  const _Float16* ap0 = attb + (size_t)(row0 + w * 32 + lo) * 512 + 8 * hi;
  const _Float16* ap1 = ap0 + (size_t)16 * 512;
  const _Float16* bp4[4];
  #pragma unroll
  for (int nt = 0; nt < 4; ++nt)
    bp4[nt] = owT + (size_t)min(c0 + nt * 16 + lo, 799) * 512 + 8 * hi;
  f32x4 acc[2][4] = {};
  #pragma unroll 4
  for (int k = 0; k < 512; k += 32) {
    half8 a0 = *reinterpret_cast<const half8*>(ap0 + k);
    half8 a1 = *reinterpret_cast<const half8*>(ap1 + k);
    #pragma unroll
    for (int nt = 0; nt < 4; ++nt) {
      half8 b = *reinterpret_cast<const half8*>(bp4[nt] + k);
      acc[0][nt] = __builtin_amdgcn_mfma_f32_16x16x32_f16(a0, b, acc[0][nt], 0, 0, 0);
      acc[1][nt] = __builtin_amdgcn_mfma_f32_16x16x32_f16(a1, b, acc[1][nt], 0, 0, 0);
    }
  }
  #pragma unroll
  for (int nt = 0; nt < 4; ++nt) {
    int co = c0 + nt * 16 + lo;
    if (co < 800) {
      float bv = ob[co];
      #pragma unroll
      for (int m = 0; m < 2; ++m)
        #pragma unroll
        for (int r = 0; r < 4; ++r) {
          int row = row0 + w * 32 + m * 16 + hi * 4 + r;
          lnb[(size_t)row * 800 + co] = acc[m][nt][r] + bv;
        }
    }
  }
}

// ---------------- LayerNorm in place over E=800 ----------------
__global__ __launch_bounds__(256) void k_ln(
    float* __restrict__ buf, const float* __restrict__ g, const float* __restrict__ bb) {
  const int t = threadIdx.x;
  float* p = buf + (size_t)blockIdx.x * 800;
  float x0 = p[t], x1 = p[t + 256], x2 = p[t + 512];
  float x3 = (t < 32) ? p[t + 768] : 0.f;
  float s = blockReduceSum(x0 + x1 + x2 + x3);
  float mean = s * (1.f / 800.f);
  float d0 = x0 - mean, d1 = x1 - mean, d2 = x2 - mean;
  float d3 = (t < 32) ? x3 - mean : 0.f;
  float s2 = blockReduceSum(d0 * d0 + d1 * d1 + d2 * d2 + d3 * d3);
  float rstd = rsqrtf(s2 * (1.f / 800.f) + LN_EPS_C);
  p[t] = d0 * rstd * g[t] + bb[t];
  p[t + 256] = d1 * rstd * g[t + 256] + bb[t + 256];
  p[t + 512] = d2 * rstd * g[t + 512] + bb[t + 512];
  if (t < 32) p[t + 768] = d3 * rstd * g[t + 768] + bb[t + 768];
}

// ---------------- head: sigmoid(ln @ head_w + head_b) ----------------
__global__ __launch_bounds__(256) void k_head(
    const float* __restrict__ ln, const float* __restrict__ hw, const float* __restrict__ hb,
    float* __restrict__ out) {
  const int t = threadIdx.x;
  const int o = t & 15, rsub = t >> 4;
  const size_t row = (size_t)blockIdx.x * 16 + rsub;
  const float* lp = ln + row * 800;
  float acc = hb[o];
  for (int e = 0; e < 800; ++e) acc = fmaf(lp[e], hw[e * 16 + o], acc);
  out[row * 16 + o] = 1.f / (1.f + expf(-acc));
}

// ---------------- launcher ----------------
extern "C" void kernel_launch(void* const* d_in, const int* in_sizes, int n_in,
                              void* d_out, int out_size, void* d_ws, size_t ws_size,
                              hipStream_t stream) {
  (void)in_sizes; (void)n_in; (void)out_size; (void)ws_size;
  const float* x     = (const float*)d_in[0];
  const float* w0    = (const float*)d_in[1];
  const float* b0    = (const float*)d_in[2];
  const float* g0    = (const float*)d_in[3];
  const float* be0   = (const float*)d_in[4];
  const float* mu0   = (const float*)d_in[5];
  const float* var0  = (const float*)d_in[6];
  const float* w1    = (const float*)d_in[7];
  const float* b1    = (const float*)d_in[8];
  const float* g1    = (const float*)d_in[9];
  const float* be1   = (const float*)d_in[10];
  const float* mu1   = (const float*)d_in[11];
  const float* var1  = (const float*)d_in[12];
  const float* w2c   = (const float*)d_in[13];
  const float* b2    = (const float*)d_in[14];
  const float* g2    = (const float*)d_in[15];
  const float* be2   = (const float*)d_in[16];
  const float* mu2   = (const float*)d_in[17];
  const float* var2  = (const float*)d_in[18];
  const float* w3    = (const float*)d_in[19];
  const float* b3    = (const float*)d_in[20];
  const float* g3    = (const float*)d_in[21];
  const float* be3   = (const float*)d_in[22];
  const float* mu3   = (const float*)d_in[23];
  const float* var3  = (const float*)d_in[24];
  const float* qkvw  = (const float*)d_in[25];
  const float* outw  = (const float*)d_in[26];
  const float* outbv = (const float*)d_in[27];
  const float* resw  = (const float*)d_in[28];
  const float* lng   = (const float*)d_in[29];
  const float* lnbv  = (const float*)d_in[30];
  const float* headw = (const float*)d_in[31];
  const float* headb = (const float*)d_in[32];

  char* wsb = (char*)d_ws;
  _Float16* h0   = (_Float16*)(wsb + B_H0);
  _Float16* h1   = (_Float16*)(wsb + B_H1);
  _Float16* h2   = (_Float16*)(wsb + B_H2);
  _Float16* qb   = (_Float16*)(wsb + B_Q);
  _Float16* kb   = (_Float16*)(wsb + B_K);
  _Float16* vb   = (_Float16*)(wsb + B_V);
  _Float16* kT   = (_Float16*)(wsb + B_KT);
  _Float16* tok  = (_Float16*)(wsb + B_TOK);
  _Float16* attb = (_Float16*)(wsb + B_ATT);
  _Float16* wp1  = (_Float16*)(wsb + B_WP1);
  _Float16* wp2  = (_Float16*)(wsb + B_WP2);
  _Float16* wp3  = (_Float16*)(wsb + B_WP3);
  _Float16* qkvT = (_Float16*)(wsb + B_QKVT);
  _Float16* owT  = (_Float16*)(wsb + B_OWT);
  _Float16* klh  = (_Float16*)(wsb + B_KLH);
  _Float16* w2t  = (_Float16*)(wsb + B_W2T);
  float* ql   = (float*)(wsb + B_QL);
  float* kl   = (float*)(wsb + B_KL);
  float* a2   = (float*)(wsb + B_A2);
  float* pv   = (float*)(wsb + B_PV);
  float* a3v  = (float*)(wsb + B_A3V);
  float* scal = (float*)(wsb + B_SCAL);
  float* lnb  = (float*)(wsb + B_LNB);

  // weight packing + scal init
  k_pack_w<<<(128 * 64 * 9 + 255) / 256, 256, 0, stream>>>(w1, wp1, 128, 64, 9);
  k_pack_w<<<(256 * 128 * 9 + 255) / 256, 256, 0, stream>>>(w2c, wp2, 256, 128, 9);
  k_pack_w<<<(800 * 256 * 16 + 255) / 256, 256, 0, stream>>>(w3, wp3, 800, 256, 16);
  k_pack_t<<<(800 * 1536 + 255) / 256, 256, 0, stream>>>(qkvw, qkvT, 800, 1536);
  k_pack_t<<<(512 * 800 + 255) / 256, 256, 0, stream>>>(outw, owT, 512, 800);
  k_init<<<1, 64, 0, stream>>>(scal);

  // conv stack: conv0..conv2 per image (h0/h1 scratch), h2 kept full-batch
  for (int img = 0; img < 4; ++img) {
    k_conv0<<<dim3(256), 256, 0, stream>>>(
        x + (size_t)img * 65536, w0, b0, g0, be0, mu0, var0, h0);
    k_convm<64><<<dim3(2, 256, 2), 256, 0, stream>>>(
        h0, wp1, b1, g1, be1, mu1, var1, h1, 128);
    k_convm<128><<<dim3(2, 256, 4), 256, 0, stream>>>(
        h1, wp2, b2, g2, be2, mu2, var2, h2 + (size_t)img * 16777216, 256);
  }
  // conv3 (patch conv) over the full batch: staged GEMM, 640 XCD-swizzled blocks
  k_c3<<<dim3(640), 256, 0, stream>>>(h2, wp3, b3, g3, be3, mu3, var3, tok);
  // attention
  k_qkv_m<<<dim3(24, 128), 256, 0, stream>>>(tok, qkvT, qb, kb, vb);
  k_transpose<<<dim3(64, 32), 256, 0, stream>>>(kb, kT);
  k_landmark<<<dim3(64, 32), 64, 0, stream>>>(qb, kb, ql, kl, klh);
  k_a2<<<dim3(32), 64, 0, stream>>>(ql, kl, a2, scal);
  k_a3v<<<dim3(64, 32), 256, 0, stream>>>(ql, kT, vb, a3v);
  k_pinv<<<dim3(32), 256, 0, stream>>>(a2, scal, pv);
  k_w2<<<dim3(32), 256, 0, stream>>>(pv, a3v, w2t);
  k_combine_m<<<dim3(64, 8, 4), 256, 0, stream>>>(qb, klh, w2t, vb, resw, attb);
  // projection + LN + head
  k_outproj_m<<<dim3(13, 128), 256, 0, stream>>>(attb, owT, outbv, lnb);
  k_ln<<<dim3(16384), 256, 0, stream>>>(lnb, lng, lnbv);
  k_head<<<dim3(1024), 256, 0, stream>>>(lnb, headw, headb, (float*)d_out);
}

// Round 7
// 1265.830 us; speedup vs baseline: 9.1041x; 1.6029x over previous
//
#include <hip/hip_runtime.h>

#define DI __device__ __forceinline__

constexpr float BN_EPS_C = 1e-5f;
constexpr float LN_EPS_C = 1e-5f;

typedef _Float16 half8 __attribute__((ext_vector_type(8)));
typedef float f32x4 __attribute__((ext_vector_type(4)));

// ---------------- workspace layout (BYTE offsets), peak ~199.3 MB ----------------
constexpr size_t B_H0   = 0;             // f16 [256][256][64]  per-image scratch
constexpr size_t B_H1   = 8388608;       // f16 [256][256][128] per-image scratch
constexpr size_t B_H2   = 25165824;      // f16 [4][256][256][256] = 134,217,728 (full batch)
// overlays inside the h2 region once h2 is dead (after k_c3):
constexpr size_t B_Q    = 25165824;      // f16 [32][4096][64] = 16,777,216
constexpr size_t B_K    = 41943040;      // f16 16,777,216
constexpr size_t B_V    = 58720256;      // f16 16,777,216
constexpr size_t B_KT   = 75497472;      // f16 [32][64][4096] = 16,777,216 (dead after a3v)
constexpr size_t B_ATT  = 92274688;      // f16 [16384][512] = 16,777,216
constexpr size_t B_LNB  = 25165824;      // f32 [16384][800] = 52,428,800 (q/k/v,kT dead by outproj)
// tok + packed weights + small buffers:
constexpr size_t B_TOK  = 159383552;     // f16 [16384][800] = 26,214,400
constexpr size_t B_WP1  = 185597952;     // 147,456
constexpr size_t B_WP2  = 185745408;     // 589,824
constexpr size_t B_WP3  = 186335232;     // 6,553,600
constexpr size_t B_QKVT = 192888832;     // 2,457,600
constexpr size_t B_OWT  = 195346432;     // 819,200
constexpr size_t B_QL   = 196165632;     // f32 524,288
constexpr size_t B_KL   = 196689920;
constexpr size_t B_KLH  = 197214208;     // f16 262,144
constexpr size_t B_A2   = 197476352;
constexpr size_t B_PV   = 198000640;
constexpr size_t B_W2T  = 198524928;     // f16 262,144
constexpr size_t B_A3V  = 198787072;
constexpr size_t B_SCAL = 199311360;     // 2 floats

// ---------------- helpers ----------------
DI float blockReduceSum(float v) {
  #pragma unroll
  for (int o = 32; o; o >>= 1) v += __shfl_xor(v, o);
  __shared__ float red[4];
  int w = threadIdx.x >> 6;
  __syncthreads();
  if ((threadIdx.x & 63) == 0) red[w] = v;
  __syncthreads();
  return red[0] + red[1] + red[2] + red[3];
}

template <int LP, int RP>
DI void mm16(const float* L, const float* R, int r0, int c0, float reg[4][4]) {
  #pragma unroll
  for (int i = 0; i < 4; ++i)
    #pragma unroll
    for (int j = 0; j < 4; ++j) reg[i][j] = 0.f;
  for (int dd = 0; dd < 64; ++dd) {
    float l[4], r[4];
    #pragma unroll
    for (int i = 0; i < 4; ++i) l[i] = L[(size_t)(r0 + i) * LP + dd];
    #pragma unroll
    for (int j = 0; j < 4; ++j) r[j] = R[(size_t)dd * RP + c0 + j];
    #pragma unroll
    for (int i = 0; i < 4; ++i)
      #pragma unroll
      for (int j = 0; j < 4; ++j) reg[i][j] = fmaf(l[i], r[j], reg[i][j]);
  }
}

// ---------------- init ----------------
__global__ void k_init(float* scal) {
  if (threadIdx.x < 2) scal[threadIdx.x] = 0.f;
}

// ---------------- weight packing ----------------
__global__ void k_pack_w(const float* __restrict__ src, _Float16* __restrict__ dst,
                         int CO, int CI, int Q) {
  int i = blockIdx.x * 256 + threadIdx.x;
  if (i >= CO * CI * Q) return;
  int q = i % Q, ci = (i / Q) % CI, co = i / (Q * CI);
  dst[((size_t)co * Q + q) * CI + ci] = (_Float16)src[i];
}

__global__ void k_pack_t(const float* __restrict__ src, _Float16* __restrict__ dst,
                         int K, int N) {
  int i = blockIdx.x * 256 + threadIdx.x;
  if (i >= K * N) return;
  int n = i % N, k = i / N;
  dst[(size_t)n * K + k] = (_Float16)src[i];
}

// ---------------- conv0: CI=1 fp32 direct conv -> h0 NHWC f16 ----------------
__global__ __launch_bounds__(256) void k_conv0(
    const float* __restrict__ xb, const float* __restrict__ w0, const float* __restrict__ b0,
    const float* __restrict__ g0, const float* __restrict__ be0, const float* __restrict__ mu0,
    const float* __restrict__ var0, _Float16* __restrict__ h0) {
  const int t = threadIdx.x, co = t & 63, xg = t >> 6;
  const int y = blockIdx.x;
  float wreg[9];
  #pragma unroll
  for (int q = 0; q < 9; ++q) wreg[q] = w0[co * 9 + q];
  float s = g0[co] * rsqrtf(var0[co] + BN_EPS_C);
  float sh = fmaf(b0[co] - mu0[co], s, be0[co]);
  for (int xl = 0; xl < 64; ++xl) {
    int xx = xg * 64 + xl;
    float acc = 0.f;
    #pragma unroll
    for (int dy = 0; dy < 3; ++dy) {
      int yy = y + dy - 1;
      if ((unsigned)yy >= 256u) continue;
      #pragma unroll
      for (int dx = 0; dx < 3; ++dx) {
        int xi = xx + dx - 1;
        if ((unsigned)xi >= 256u) continue;
        acc = fmaf(wreg[dy * 3 + dx], xb[yy * 256 + xi], acc);
      }
    }
    float v = fmaxf(fmaf(acc, s, sh), 0.f);
    h0[((size_t)y * 256 + xx) * 64 + co] = (_Float16)v;
  }
}

// ------- staged implicit-im2col 3x3 conv GEMM (k_c3 template): tile 128x128 ---------------
// M = 65536 pixels (one image), N = CO, K = 9*CI. Per image launch, grid = 512*(CO/128).
// LDS 40KB dbuf; reg-staged (halo gather); XCD-bijective swizzle.
template <int CI>
__global__ __launch_bounds__(256) void k_convs(
    const _Float16* __restrict__ in, const _Float16* __restrict__ wp,
    const float* __restrict__ bias, const float* __restrict__ g, const float* __restrict__ be,
    const float* __restrict__ mu, const float* __restrict__ var,
    _Float16* __restrict__ out, int CO, int NCT) {
  __shared__ _Float16 Ab[2][128 * 40];
  __shared__ _Float16 Bb[2][128 * 40];
  constexpr int CPQ = CI / 32;        // k-chunks per tap
  constexpr int NCK = 9 * CPQ;        // total k-chunks
  const int t = threadIdx.x;
  const int bid = blockIdx.x;
  const int xcd = bid & 7, slot = bid >> 3;
  const int pj = slot / NCT, cc = slot % NCT;
  const int p = pj * 8 + xcd;         // row panel 0..511
  const int r0 = p * 128, c0 = cc * 128;

  const int ma = t >> 2, kga = t & 3;
  int ry[2], rx[2];
  #pragma unroll
  for (int s = 0; s < 2; ++s) {
    int r = r0 + ma + s * 64;
    ry[s] = r >> 8;
    rx[s] = r & 255;
  }
  const _Float16* baseB[2];
  #pragma unroll
  for (int s = 0; s < 2; ++s)
    baseB[s] = wp + (size_t)(c0 + ma + s * 64) * 9 * CI + kga * 8;
  const int wo = ma * 40 + kga * 8;

  auto loadA = [&](int s, int ck) -> half8 {
    int q = ck / CPQ, coff = (ck % CPQ) * 32;
    int yy = ry[s] + q / 3 - 1;
    int xx = rx[s] + q % 3 - 1;
    half8 a = {};
    if ((unsigned)yy < 256u && (unsigned)xx < 256u)
      a = *reinterpret_cast<const half8*>(in + ((size_t)yy * 256 + xx) * CI + coff + kga * 8);
    return a;
  };

  // prologue
  {
    half8 a0 = loadA(0, 0), a1 = loadA(1, 0);
    half8 b0v = *reinterpret_cast<const half8*>(baseB[0]);
    half8 b1v = *reinterpret_cast<const half8*>(baseB[1]);
    *reinterpret_cast<half8*>(&Ab[0][wo]) = a0;
    *reinterpret_cast<half8*>(&Ab[0][wo + 2560]) = a1;
    *reinterpret_cast<half8*>(&Bb[0][wo]) = b0v;
    *reinterpret_cast<half8*>(&Bb[0][wo + 2560]) = b1v;
  }
  __syncthreads();

  const int w = t >> 6, lo = t & 15, hi = (t >> 4) & 3;
  const int wm = w >> 1, wn = w & 1;
  const int roA = (wm * 64 + lo) * 40 + 8 * hi;
  const int roB = (wn * 64 + lo) * 40 + 8 * hi;
  f32x4 acc[4][4] = {};

  for (int ck = 0; ck < NCK; ++ck) {
    const int cur = ck & 1;
    const bool more = (ck + 1 < NCK);
    half8 rA0, rA1, rB0, rB1;
    if (more) {
      rA0 = loadA(0, ck + 1);
      rA1 = loadA(1, ck + 1);
      rB0 = *reinterpret_cast<const half8*>(baseB[0] + (ck + 1) * 32);
      rB1 = *reinterpret_cast<const half8*>(baseB[1] + (ck + 1) * 32);
    }
    half8 af[4], bf[4];
    #pragma unroll
    for (int mi = 0; mi < 4; ++mi)
      af[mi] = *reinterpret_cast<const half8*>(&Ab[cur][roA + mi * 640]);
    #pragma unroll
    for (int ni = 0; ni < 4; ++ni)
      bf[ni] = *reinterpret_cast<const half8*>(&Bb[cur][roB + ni * 640]);
    #pragma unroll
    for (int mi = 0; mi < 4; ++mi)
      #pragma unroll
      for (int ni = 0; ni < 4; ++ni)
        acc[mi][ni] = __builtin_amdgcn_mfma_f32_16x16x32_f16(af[mi], bf[ni], acc[mi][ni], 0, 0, 0);
    if (more) {
      *reinterpret_cast<half8*>(&Ab[cur ^ 1][wo]) = rA0;
      *reinterpret_cast<half8*>(&Ab[cur ^ 1][wo + 2560]) = rA1;
      *reinterpret_cast<half8*>(&Bb[cur ^ 1][wo]) = rB0;
      *reinterpret_cast<half8*>(&Bb[cur ^ 1][wo + 2560]) = rB1;
    }
    __syncthreads();
  }

  #pragma unroll
  for (int ni = 0; ni < 4; ++ni) {
    int co = c0 + wn * 64 + ni * 16 + lo;
    float s = g[co] * rsqrtf(var[co] + BN_EPS_C);
    float sh = fmaf(bias[co] - mu[co], s, be[co]);
    #pragma unroll
    for (int mi = 0; mi < 4; ++mi)
      #pragma unroll
      for (int rr = 0; rr < 4; ++rr) {
        int row = r0 + wm * 64 + mi * 16 + hi * 4 + rr;
        float v = fmaxf(fmaf(acc[mi][ni][rr], s, sh), 0.f);
        out[(size_t)row * CO + co] = (_Float16)v;
      }
  }
}

// ---------------- conv3 MFMA: staged GEMM, 128x160 tile, XCD-swizzled (proven r6) ----------
__global__ __launch_bounds__(256) void k_c3(
    const _Float16* __restrict__ h2, const _Float16* __restrict__ wp3,
    const float* __restrict__ b3, const float* __restrict__ g3, const float* __restrict__ be3,
    const float* __restrict__ mu3, const float* __restrict__ var3,
    _Float16* __restrict__ tok) {
  __shared__ _Float16 Abuf[2][128 * 40];
  __shared__ _Float16 Bbuf[2][160 * 40];
  const int t = threadIdx.x;
  const int bid = blockIdx.x;
  const int xcd = bid & 7, slot = bid >> 3;
  const int pj = slot / 5, cc = slot % 5;
  const int p = pj * 8 + xcd;
  const int r0 = p * 128, c0 = cc * 160;
  const int img = r0 >> 12;
  const _Float16* h2i = h2 + (size_t)img * 16777216;

  const int ma = t >> 2, kga = t & 3;
  const _Float16* baseA[2];
  #pragma unroll
  for (int s = 0; s < 2; ++s) {
    int m = ma + s * 64;
    int r = r0 + m;
    int py = (r & 4095) >> 6, px = r & 63;
    baseA[s] = h2i + ((size_t)py * 1024 + px * 4) * 256 + kga * 8;
  }
  const _Float16* baseB[3];
  #pragma unroll
  for (int s = 0; s < 3; ++s) {
    int cb = ma + s * 64;
    baseB[s] = wp3 + (size_t)(c0 + (cb < 160 ? cb : 159)) * 4096 + kga * 8;
  }
  const int wo = ma * 40 + kga * 8;

  const int w = t >> 6, lo = t & 15, hi = (t >> 4) & 3;
  const int wm = w >> 1, wn = w & 1;
  const int roA = (wm * 64 + lo) * 40 + 8 * hi;
  const int roB = (wn * 80 + lo) * 40 + 8 * hi;

  f32x4 acc[4][5] = {};

  {
    half8 a0 = *reinterpret_cast<const half8*>(baseA[0]);
    half8 a1 = *reinterpret_cast<const half8*>(baseA[1]);
    half8 b0v = *reinterpret_cast<const half8*>(baseB[0]);
    half8 b1v = *reinterpret_cast<const half8*>(baseB[1]);
    *reinterpret_cast<half8*>(&Abuf[0][wo]) = a0;
    *reinterpret_cast<half8*>(&Abuf[0][wo + 2560]) = a1;
    *reinterpret_cast<half8*>(&Bbuf[0][wo]) = b0v;
    *reinterpret_cast<half8*>(&Bbuf[0][wo + 2560]) = b1v;
    if (t < 128) {
      half8 b2v = *reinterpret_cast<const half8*>(baseB[2]);
      *reinterpret_cast<half8*>(&Bbuf[0][wo + 5120]) = b2v;
    }
  }
  __syncthreads();

  for (int ck = 0; ck < 128; ++ck) {
    const int cur = ck & 1;
    const bool more = (ck + 1 < 128);
    half8 rA0, rA1, rB0, rB1, rB2;
    if (more) {
      const int kn = (ck + 1) << 5;
      const int q = kn >> 8, qk = kn & 255;
      const int aoff = (q >> 2) * 65536 + (q & 3) * 256 + qk;
      rA0 = *reinterpret_cast<const half8*>(baseA[0] + aoff);
      rA1 = *reinterpret_cast<const half8*>(baseA[1] + aoff);
      rB0 = *reinterpret_cast<const half8*>(baseB[0] + kn);
      rB1 = *reinterpret_cast<const half8*>(baseB[1] + kn);
      if (t < 128) rB2 = *reinterpret_cast<const half8*>(baseB[2] + kn);
    }
    half8 af[4], bf[5];
    #pragma unroll
    for (int mi = 0; mi < 4; ++mi)
      af[mi] = *reinterpret_cast<const half8*>(&Abuf[cur][roA + mi * 640]);
    #pragma unroll
    for (int ni = 0; ni < 5; ++ni)
      bf[ni] = *reinterpret_cast<const half8*>(&Bbuf[cur][roB + ni * 640]);
    #pragma unroll
    for (int mi = 0; mi < 4; ++mi)
      #pragma unroll
      for (int ni = 0; ni < 5; ++ni)
        acc[mi][ni] = __builtin_amdgcn_mfma_f32_16x16x32_f16(af[mi], bf[ni], acc[mi][ni], 0, 0, 0);
    if (more) {
      *reinterpret_cast<half8*>(&Abuf[cur ^ 1][wo]) = rA0;
      *reinterpret_cast<half8*>(&Abuf[cur ^ 1][wo + 2560]) = rA1;
      *reinterpret_cast<half8*>(&Bbuf[cur ^ 1][wo]) = rB0;
      *reinterpret_cast<half8*>(&Bbuf[cur ^ 1][wo + 2560]) = rB1;
      if (t < 128) *reinterpret_cast<half8*>(&Bbuf[cur ^ 1][wo + 5120]) = rB2;
    }
    __syncthreads();
  }

  #pragma unroll
  for (int ni = 0; ni < 5; ++ni) {
    int col = c0 + wn * 80 + ni * 16 + lo;
    float s = g3[col] * rsqrtf(var3[col] + BN_EPS_C);
    float sh = fmaf(b3[col] - mu3[col], s, be3[col]);
    #pragma unroll
    for (int mi = 0; mi < 4; ++mi)
      #pragma unroll
      for (int rr = 0; rr < 4; ++rr) {
        int row = r0 + wm * 64 + mi * 16 + hi * 4 + rr;
        float v = fmaxf(fmaf(acc[mi][ni][rr], s, sh), 0.f);
        tok[(size_t)row * 800 + col] = (_Float16)v;
      }
  }
}

// ---------------- qkv staged GEMM: M=16384, N=1536 (12 col-tiles), K=800 ------------------
__global__ __launch_bounds__(256) void k_qkv_s(
    const _Float16* __restrict__ tok, const _Float16* __restrict__ qkvT,
    _Float16* __restrict__ qx, _Float16* __restrict__ kx, _Float16* __restrict__ vx) {
  __shared__ _Float16 Ab[2][128 * 40];
  __shared__ _Float16 Bb[2][128 * 40];
  const int t = threadIdx.x;
  const int bid = blockIdx.x;
  const int xcd = bid & 7, slot = bid >> 3;     // 1536 = 8 * 192
  const int pj = slot / 12, cc = slot % 12;
  const int p = pj * 8 + xcd;                   // 0..127
  const int r0 = p * 128, c0 = cc * 128;

  const int ma = t >> 2, kga = t & 3;
  const _Float16* baseA[2];
  const _Float16* baseB[2];
  #pragma unroll
  for (int s = 0; s < 2; ++s) {
    baseA[s] = tok + (size_t)(r0 + ma + s * 64) * 800 + kga * 8;
    baseB[s] = qkvT + (size_t)(c0 + ma + s * 64) * 800 + kga * 8;
  }
  const int wo = ma * 40 + kga * 8;

  {
    half8 a0 = *reinterpret_cast<const half8*>(baseA[0]);
    half8 a1 = *reinterpret_cast<const half8*>(baseA[1]);
    half8 b0v = *reinterpret_cast<const half8*>(baseB[0]);
    half8 b1v = *reinterpret_cast<const half8*>(baseB[1]);
    *reinterpret_cast<half8*>(&Ab[0][wo]) = a0;
    *reinterpret_cast<half8*>(&Ab[0][wo + 2560]) = a1;
    *reinterpret_cast<half8*>(&Bb[0][wo]) = b0v;
    *reinterpret_cast<half8*>(&Bb[0][wo + 2560]) = b1v;
  }
  __syncthreads();

  const int w = t >> 6, lo = t & 15, hi = (t >> 4) & 3;
  const int wm = w >> 1, wn = w & 1;
  const int roA = (wm * 64 + lo) * 40 + 8 * hi;
  const int roB = (wn * 64 + lo) * 40 + 8 * hi;
  f32x4 acc[4][4] = {};

  for (int ck = 0; ck < 25; ++ck) {
    const int cur = ck & 1;
    const bool more = (ck + 1 < 25);
    half8 rA0, rA1, rB0, rB1;
    if (more) {
      const int kn = (ck + 1) * 32;
      rA0 = *reinterpret_cast<const half8*>(baseA[0] + kn);
      rA1 = *reinterpret_cast<const half8*>(baseA[1] + kn);
      rB0 = *reinterpret_cast<const half8*>(baseB[0] + kn);
      rB1 = *reinterpret_cast<const half8*>(baseB[1] + kn);
    }
    half8 af[4], bf[4];
    #pragma unroll
    for (int mi = 0; mi < 4; ++mi)
      af[mi] = *reinterpret_cast<const half8*>(&Ab[cur][roA + mi * 640]);
    #pragma unroll
    for (int ni = 0; ni < 4; ++ni)
      bf[ni] = *reinterpret_cast<const half8*>(&Bb[cur][roB + ni * 640]);
    #pragma unroll
    for (int mi = 0; mi < 4; ++mi)
      #pragma unroll
      for (int ni = 0; ni < 4; ++ni)
        acc[mi][ni] = __builtin_amdgcn_mfma_f32_16x16x32_f16(af[mi], bf[ni], acc[mi][ni], 0, 0, 0);
    if (more) {
      *reinterpret_cast<half8*>(&Ab[cur ^ 1][wo]) = rA0;
      *reinterpret_cast<half8*>(&Ab[cur ^ 1][wo + 2560]) = rA1;
      *reinterpret_cast<half8*>(&Bb[cur ^ 1][wo]) = rB0;
      *reinterpret_cast<half8*>(&Bb[cur ^ 1][wo + 2560]) = rB1;
    }
    __syncthreads();
  }

  const int seg = cc >> 2;                      // 0=q 1=k 2=v
  const float scale = (seg == 0) ? 0.125f : 1.0f;
  _Float16* dst = (seg == 0) ? qx : (seg == 1) ? kx : vx;
  #pragma unroll
  for (int ni = 0; ni < 4; ++ni) {
    int cseg = (cc & 3) * 128 + wn * 64 + ni * 16 + lo;  // 0..511
    int h = cseg >> 6, d = cseg & 63;
    #pragma unroll
    for (int mi = 0; mi < 4; ++mi)
      #pragma unroll
      for (int rr = 0; rr < 4; ++rr) {
        int row = r0 + wm * 64 + mi * 16 + hi * 4 + rr;
        int b = row >> 12, nn = row & 4095;
        dst[((size_t)(b * 8 + h) * 4096 + nn) * 64 + d] = (_Float16)(acc[mi][ni][rr] * scale);
      }
  }
}

// ---------------- transpose k -> kT f16 [bh][d][n] ----------------
__global__ __launch_bounds__(256) void k_transpose(const _Float16* __restrict__ kx,
                                                   _Float16* __restrict__ kT) {
  __shared__ _Float16 tile[64 * 66];
  const int bh = blockIdx.y, n0 = blockIdx.x * 64;
  const _Float16* src = kx + ((size_t)bh * 4096 + n0) * 64;
  const int t = threadIdx.x;
  #pragma unroll
  for (int u = 0; u < 16; ++u) {
    int e = t + u * 256;
    int r = e >> 6, d = e & 63;
    tile[d * 66 + r] = src[e];
  }
  __syncthreads();
  _Float16* dst = kT + (size_t)bh * 262144 + n0;
  #pragma unroll
  for (int u = 0; u < 16; ++u) {
    int e = t + u * 256;
    int d = e >> 6, j = e & 63;
    dst[(size_t)d * 4096 + j] = tile[d * 66 + j];
  }
}

// ---------------- landmarks ----------------
__global__ __launch_bounds__(64) void k_landmark(
    const _Float16* __restrict__ qx, const _Float16* __restrict__ kx,
    float* __restrict__ ql, float* __restrict__ kl, _Float16* __restrict__ klh) {
  const int d = threadIdx.x;
  const int m = blockIdx.x, bh = blockIdx.y;
  const _Float16* qp = qx + ((size_t)bh * 4096 + m * 64) * 64 + d;
  const _Float16* kp = kx + ((size_t)bh * 4096 + m * 64) * 64 + d;
  float sq = 0.f, sk = 0.f;
  #pragma unroll 8
  for (int j = 0; j < 64; ++j) {
    sq += (float)qp[(size_t)j * 64];
    sk += (float)kp[(size_t)j * 64];
  }
  sq *= (1.f / 64.f);
  sk *= (1.f / 64.f);
  ql[((size_t)bh * 64 + m) * 64 + d] = sq;
  kl[((size_t)bh * 64 + m) * 64 + d] = sk;
  klh[((size_t)bh * 64 + m) * 64 + d] = (_Float16)sk;
}

// ---------------- a2 + global max row/col sums ----------------
__global__ __launch_bounds__(64) void k_a2(
    const float* __restrict__ ql, const float* __restrict__ kl,
    float* __restrict__ a2, float* __restrict__ scal) {
  __shared__ float sp[64 * 65];
  const int bh = blockIdx.x, t = threadIdx.x;
  const float* qr = ql + ((size_t)bh * 64 + t) * 64;
  const float* kb = kl + (size_t)bh * 4096;
  float mx = -1e30f;
  for (int c = 0; c < 64; ++c) {
    float acc = 0.f;
    #pragma unroll 8
    for (int dd = 0; dd < 64; ++dd) acc = fmaf(qr[dd], kb[c * 64 + dd], acc);
    sp[t * 65 + c] = acc;
    mx = fmaxf(mx, acc);
  }
  float sum = 0.f;
  for (int c = 0; c < 64; ++c) {
    float e = expf(sp[t * 65 + c] - mx);
    sp[t * 65 + c] = e;
    sum += e;
  }
  float inv = 1.f / sum;
  float rs = 0.f;
  for (int c = 0; c < 64; ++c) {
    float p = sp[t * 65 + c] * inv;
    sp[t * 65 + c] = p;
    a2[(size_t)bh * 4096 + t * 64 + c] = p;
    rs += p;
  }
  atomicMax(reinterpret_cast<int*>(scal), __float_as_int(rs));
  __syncthreads();
  float cs = 0.f;
  for (int r = 0; r < 64; ++r) cs += sp[r * 65 + t];
  atomicMax(reinterpret_cast<int*>(scal) + 1, __float_as_int(cs));
}

// ---------------- fused a3 softmax + a3@v ----------------
__global__ __launch_bounds__(256) void k_a3v(
    const float* __restrict__ ql, const _Float16* __restrict__ kT,
    const _Float16* __restrict__ vx, float* __restrict__ a3v) {
  __shared__ float sq[64];
  __shared__ float sP[4096];
  __shared__ float red[4];
  __shared__ float red2[4][64];
  const int t = threadIdx.x;
  const int m = blockIdx.x, bh = blockIdx.y;
  if (t < 64) sq[t] = ql[((size_t)bh * 64 + m) * 64 + t];
  __syncthreads();
  const _Float16* kb = kT + (size_t)bh * 262144;
  float sc[16];
  #pragma unroll
  for (int i = 0; i < 16; ++i) sc[i] = 0.f;
  for (int dd = 0; dd < 64; ++dd) {
    float qv = sq[dd];
    const _Float16* kr = kb + (size_t)dd * 4096 + t;
    #pragma unroll
    for (int i = 0; i < 16; ++i) sc[i] = fmaf(qv, (float)kr[i * 256], sc[i]);
  }
  float mx = sc[0];
  #pragma unroll
  for (int i = 1; i < 16; ++i) mx = fmaxf(mx, sc[i]);
  #pragma unroll
  for (int o = 32; o; o >>= 1) mx = fmaxf(mx, __shfl_xor(mx, o));
  if ((t & 63) == 0) red[t >> 6] = mx;
  __syncthreads();
  mx = fmaxf(fmaxf(red[0], red[1]), fmaxf(red[2], red[3]));
  __syncthreads();
  float sum = 0.f;
  #pragma unroll
  for (int i = 0; i < 16; ++i) {
    sc[i] = expf(sc[i] - mx);
    sum += sc[i];
  }
  #pragma unroll
  for (int o = 32; o; o >>= 1) sum += __shfl_xor(sum, o);
  if ((t & 63) == 0) red[t >> 6] = sum;
  __syncthreads();
  sum = red[0] + red[1] + red[2] + red[3];
  float inv = 1.f / sum;
  #pragma unroll
  for (int i = 0; i < 16; ++i) sP[t + i * 256] = sc[i] * inv;
  __syncthreads();
  const int d = t & 63, seg = t >> 6;
  const _Float16* vb = vx + (size_t)bh * 262144;
  float acc = 0.f;
  for (int n = seg * 1024; n < seg * 1024 + 1024; ++n)
    acc = fmaf(sP[n], (float)vb[(size_t)n * 64 + d], acc);
  red2[seg][d] = acc;
  __syncthreads();
  if (seg == 0)
    a3v[((size_t)bh * 64 + m) * 64 + d] = red2[0][d] + red2[1][d] + red2[2][d] + red2[3][d];
}

// ---------------- Moore-Penrose pinv (fp32) ----------------
__global__ __launch_bounds__(256) void k_pinv(
    const float* __restrict__ a2g, const float* __restrict__ scal, float* __restrict__ pv) {
  __shared__ float z[64 * 65];
  __shared__ float az[64 * 65];
  __shared__ float tb[64 * 65];
  const int bh = blockIdx.x, t = threadIdx.x;
  const int r0 = (t >> 4) << 2, c0 = (t & 15) << 2;
  const float* ag = a2g + (size_t)bh * 4096;
  const float denom = 1.f / (scal[0] * scal[1]);
  #pragma unroll
  for (int i = 0; i < 4; ++i)
    #pragma unroll
    for (int j = 0; j < 4; ++j)
      z[(r0 + i) * 65 + c0 + j] = ag[(c0 + j) * 64 + r0 + i] * denom;
  __syncthreads();
  float reg[4][4], val[4][4];
  for (int it = 0; it < 6; ++it) {
    mm16<64, 65>(ag, z, r0, c0, reg);
    #pragma unroll
    for (int i = 0; i < 4; ++i)
      #pragma unroll
      for (int j = 0; j < 4; ++j) az[(r0 + i) * 65 + c0 + j] = reg[i][j];
    __syncthreads();
    mm16<65, 65>(az, az, r0, c0, reg);
    #pragma unroll
    for (int i = 0; i < 4; ++i)
      #pragma unroll
      for (int j = 0; j < 4; ++j)
        tb[(r0 + i) * 65 + c0 + j] = 7.f * az[(r0 + i) * 65 + c0 + j] - reg[i][j];
    __syncthreads();
    mm16<65, 65>(az, tb, r0, c0, reg);
    #pragma unroll
    for (int i = 0; i < 4; ++i)
      #pragma unroll
      for (int j = 0; j < 4; ++j)
        val[i][j] = 15.f * az[(r0 + i) * 65 + c0 + j] - reg[i][j];
    __syncthreads();
    #pragma unroll
    for (int i = 0; i < 4; ++i)
      #pragma unroll
      for (int j = 0; j < 4; ++j) tb[(r0 + i) * 65 + c0 + j] = val[i][j];
    __syncthreads();
    mm16<65, 65>(z, tb, r0, c0, reg);
    #pragma unroll
    for (int i = 0; i < 4; ++i)
      #pragma unroll
      for (int j = 0; j < 4; ++j)
        val[i][j] = 0.25f * (13.f * z[(r0 + i) * 65 + c0 + j] - reg[i][j]);
    __syncthreads();
    #pragma unroll
    for (int i = 0; i < 4; ++i)
      #pragma unroll
      for (int j = 0; j < 4; ++j) z[(r0 + i) * 65 + c0 + j] = val[i][j];
    __syncthreads();
  }
  #pragma unroll
  for (int i = 0; i < 4; ++i)
    #pragma unroll
    for (int j = 0; j < 4; ++j)
      pv[(size_t)bh * 4096 + (r0 + i) * 64 + c0 + j] = z[(r0 + i) * 65 + c0 + j];
}

// ---------------- w2t = (pinv @ a3v)^T as f16 [bh][d][m] ----------------
__global__ __launch_bounds__(256) void k_w2(
    const float* __restrict__ pv, const float* __restrict__ a3v, _Float16* __restrict__ w2t) {
  const int bh = blockIdx.x, t = threadIdx.x;
  const int r0 = (t >> 4) << 2, c0 = (t & 15) << 2;
  float reg[4][4];
  mm16<64, 64>(pv + (size_t)bh * 4096, a3v + (size_t)bh * 4096, r0, c0, reg);
  #pragma unroll
  for (int i = 0; i < 4; ++i)
    #pragma unroll
    for (int j = 0; j < 4; ++j)
      w2t[(size_t)bh * 4096 + (c0 + j) * 64 + (r0 + i)] = (_Float16)reg[i][j];
}

// ------- fused MFMA combine: S=q@kl^T -> softmax -> P@W2 + Toeplitz(res)@v -> att f16 ------
__global__ __launch_bounds__(256) void k_combine_m(
    const _Float16* __restrict__ qx, const _Float16* __restrict__ klh,
    const _Float16* __restrict__ w2t, const _Float16* __restrict__ vx,
    const float* __restrict__ rw, _Float16* __restrict__ att) {
  __shared__ _Float16 sP[64 * 72];
  __shared__ _Float16 sVT[64 * 104];
  __shared__ _Float16 sT[64 * 104];
  __shared__ float sR[33];
  const int t = threadIdx.x, w = t >> 6, lo = t & 15, hi = (t >> 4) & 3;
  const int n0 = blockIdx.x * 64;
  const int h = blockIdx.y, b = blockIdx.z, bh = b * 8 + h;
  if (t < 33) sR[t] = rw[h * 33 + t];
  __syncthreads();
  const _Float16* vb = vx + (size_t)bh * 262144;
  #pragma unroll
  for (int u = 0; u < 24; ++u) {
    int e = t + u * 256;
    int r = e >> 6, d = e & 63;
    int nn = n0 - 16 + r;
    sVT[d * 104 + r] = ((unsigned)nn < 4096u) ? vb[(size_t)nn * 64 + d] : (_Float16)0.f;
  }
  #pragma unroll
  for (int u = 0; u < 24; ++u) {
    int e = t + u * 256;
    int r = e % 96, i = e / 96;
    int j = r - i;
    sT[i * 104 + r] = (j >= 0 && j < 33) ? (_Float16)sR[j] : (_Float16)0.f;
  }
  f32x4 sa[4] = {};
  const _Float16* qp = qx + ((size_t)bh * 4096 + n0 + w * 16 + lo) * 64 + 8 * hi;
  const _Float16* klp = klh + (size_t)bh * 4096;
  #pragma unroll
  for (int c = 0; c < 2; ++c) {
    half8 a = *reinterpret_cast<const half8*>(qp + 32 * c);
    #pragma unroll
    for (int ct = 0; ct < 4; ++ct) {
      half8 bf = *reinterpret_cast<const half8*>(klp + (size_t)(ct * 16 + lo) * 64 + 8 * hi + 32 * c);
      sa[ct] = __builtin_amdgcn_mfma_f32_16x16x32_f16(a, bf, sa[ct], 0, 0, 0);
    }
  }
  #pragma unroll
  for (int r = 0; r < 4; ++r) {
    float mx = fmaxf(fmaxf(sa[0][r], sa[1][r]), fmaxf(sa[2][r], sa[3][r]));
    #pragma unroll
    for (int o = 8; o; o >>= 1) mx = fmaxf(mx, __shfl_xor(mx, o));
    float e0 = expf(sa[0][r] - mx), e1 = expf(sa[1][r] - mx);
    float e2 = expf(sa[2][r] - mx), e3 = expf(sa[3][r] - mx);
    float sm = e0 + e1 + e2 + e3;
    #pragma unroll
    for (int o = 8; o; o >>= 1) sm += __shfl_xor(sm, o);
    float inv = 1.f / sm;
    int row = w * 16 + hi * 4 + r;
    sP[row * 72 + lo] = (_Float16)(e0 * inv);
    sP[row * 72 + 16 + lo] = (_Float16)(e1 * inv);
    sP[row * 72 + 32 + lo] = (_Float16)(e2 * inv);
    sP[row * 72 + 48 + lo] = (_Float16)(e3 * inv);
  }
  __syncthreads();
  f32x4 ao[4] = {};
  const _Float16* w2p = w2t + (size_t)bh * 4096;
  #pragma unroll
  for (int c = 0; c < 2; ++c) {
    half8 a = *reinterpret_cast<const half8*>(&sP[(w * 16 + lo) * 72 + 8 * hi + 32 * c]);
    #pragma unroll
    for (int ct = 0; ct < 4; ++ct) {
      half8 bf = *reinterpret_cast<const half8*>(w2p + (size_t)(ct * 16 + lo) * 64 + 8 * hi + 32 * c);
      ao[ct] = __builtin_amdgcn_mfma_f32_16x16x32_f16(a, bf, ao[ct], 0, 0, 0);
    }
  }
  #pragma unroll
  for (int c = 0; c < 3; ++c) {
    half8 a = *reinterpret_cast<const half8*>(&sT[(w * 16 + lo) * 104 + 8 * hi + 32 * c]);
    #pragma unroll
    for (int ct = 0; ct < 4; ++ct) {
      half8 bf = *reinterpret_cast<const half8*>(&sVT[(ct * 16 + lo) * 104 + 8 * hi + 32 * c]);
      ao[ct] = __builtin_amdgcn_mfma_f32_16x16x32_f16(a, bf, ao[ct], 0, 0, 0);
    }
  }
  _Float16* ab = att + ((size_t)b * 4096) * 512 + (size_t)h * 64;
  #pragma unroll
  for (int ct = 0; ct < 4; ++ct)
    #pragma unroll
    for (int r = 0; r < 4; ++r) {
      int n = n0 + w * 16 + hi * 4 + r;
      ab[(size_t)n * 512 + ct * 16 + lo] = (_Float16)ao[ct][r];
    }
}

// ---------------- out-proj MFMA, m-repeat 2: grid (13, 128) -> lnb f32 ----------------
__global__ __launch_bounds__(256) void k_outproj_m(
    const _Float16* __restrict__ attb, const _Float16* __restrict__ owT,
    const float* __restrict__ ob, float* __restrict__ lnb) {
  const int t = threadIdx.x, w = t >> 6, lo = t & 15, hi = (t >> 4) & 3;
  const int c0 = blockIdx.x * 64;
  const int row0 = blockIdx.y * 128;
  const _Float16* ap0 = attb + (size_t)(row0 + w * 32 + lo) * 512 + 8 * hi;
  const _Float16* ap1 = ap0 + (size_t)16 * 512;
  const _Float16* bp4[4];
  #pragma unroll
  for (int nt = 0; nt < 4; ++nt)
    bp4[nt] = owT + (size_t)min(c0 + nt * 16 + lo, 799) * 512 + 8 * hi;
  f32x4 acc[2][4] = {};
  #pragma unroll 4
  for (int k = 0; k < 512; k += 32) {
    half8 a0 = *reinterpret_cast<const half8*>(ap0 + k);
    half8 a1 = *reinterpret_cast<const half8*>(ap1 + k);
    #pragma unroll
    for (int nt = 0; nt < 4; ++nt) {
      half8 b = *reinterpret_cast<const half8*>(bp4[nt] + k);
      acc[0][nt] = __builtin_amdgcn_mfma_f32_16x16x32_f16(a0, b, acc[0][nt], 0, 0, 0);
      acc[1][nt] = __builtin_amdgcn_mfma_f32_16x16x32_f16(a1, b, acc[1][nt], 0, 0, 0);
    }
  }
  #pragma unroll
  for (int nt = 0; nt < 4; ++nt) {
    int co = c0 + nt * 16 + lo;
    if (co < 800) {
      float bv = ob[co];
      #pragma unroll
      for (int m = 0; m < 2; ++m)
        #pragma unroll
        for (int r = 0; r < 4; ++r) {
          int row = row0 + w * 32 + m * 16 + hi * 4 + r;
          lnb[(size_t)row * 800 + co] = acc[m][nt][r] + bv;
        }
    }
  }
}

// ---------------- LayerNorm in place over E=800 ----------------
__global__ __launch_bounds__(256) void k_ln(
    float* __restrict__ buf, const float* __restrict__ g, const float* __restrict__ bb) {
  const int t = threadIdx.x;
  float* p = buf + (size_t)blockIdx.x * 800;
  float x0 = p[t], x1 = p[t + 256], x2 = p[t + 512];
  float x3 = (t < 32) ? p[t + 768] : 0.f;
  float s = blockReduceSum(x0 + x1 + x2 + x3);
  float mean = s * (1.f / 800.f);
  float d0 = x0 - mean, d1 = x1 - mean, d2 = x2 - mean;
  float d3 = (t < 32) ? x3 - mean : 0.f;
  float s2 = blockReduceSum(d0 * d0 + d1 * d1 + d2 * d2 + d3 * d3);
  float rstd = rsqrtf(s2 * (1.f / 800.f) + LN_EPS_C);
  p[t] = d0 * rstd * g[t] + bb[t];
  p[t + 256] = d1 * rstd * g[t + 256] + bb[t + 256];
  p[t + 512] = d2 * rstd * g[t + 512] + bb[t + 512];
  if (t < 32) p[t + 768] = d3 * rstd * g[t + 768] + bb[t + 768];
}

// ---------------- head: sigmoid(ln @ head_w + head_b) ----------------
__global__ __launch_bounds__(256) void k_head(
    const float* __restrict__ ln, const float* __restrict__ hw, const float* __restrict__ hb,
    float* __restrict__ out) {
  const int t = threadIdx.x;
  const int o = t & 15, rsub = t >> 4;
  const size_t row = (size_t)blockIdx.x * 16 + rsub;
  const float* lp = ln + row * 800;
  float acc = hb[o];
  for (int e = 0; e < 800; ++e) acc = fmaf(lp[e], hw[e * 16 + o], acc);
  out[row * 16 + o] = 1.f / (1.f + expf(-acc));
}

// ---------------- launcher ----------------
extern "C" void kernel_launch(void* const* d_in, const int* in_sizes, int n_in,
                              void* d_out, int out_size, void* d_ws, size_t ws_size,
                              hipStream_t stream) {
  (void)in_sizes; (void)n_in; (void)out_size; (void)ws_size;
  const float* x     = (const float*)d_in[0];
  const float* w0    = (const float*)d_in[1];
  const float* b0    = (const float*)d_in[2];
  const float* g0    = (const float*)d_in[3];
  const float* be0   = (const float*)d_in[4];
  const float* mu0   = (const float*)d_in[5];
  const float* var0  = (const float*)d_in[6];
  const float* w1    = (const float*)d_in[7];
  const float* b1    = (const float*)d_in[8];
  const float* g1    = (const float*)d_in[9];
  const float* be1   = (const float*)d_in[10];
  const float* mu1   = (const float*)d_in[11];
  const float* var1  = (const float*)d_in[12];
  const float* w2c   = (const float*)d_in[13];
  const float* b2    = (const float*)d_in[14];
  const float* g2    = (const float*)d_in[15];
  const float* be2   = (const float*)d_in[16];
  const float* mu2   = (const float*)d_in[17];
  const float* var2  = (const float*)d_in[18];
  const float* w3    = (const float*)d_in[19];
  const float* b3    = (const float*)d_in[20];
  const float* g3    = (const float*)d_in[21];
  const float* be3   = (const float*)d_in[22];
  const float* mu3   = (const float*)d_in[23];
  const float* var3  = (const float*)d_in[24];
  const float* qkvw  = (const float*)d_in[25];
  const float* outw  = (const float*)d_in[26];
  const float* outbv = (const float*)d_in[27];
  const float* resw  = (const float*)d_in[28];
  const float* lng   = (const float*)d_in[29];
  const float* lnbv  = (const float*)d_in[30];
  const float* headw = (const float*)d_in[31];
  const float* headb = (const float*)d_in[32];

  char* wsb = (char*)d_ws;
  _Float16* h0   = (_Float16*)(wsb + B_H0);
  _Float16* h1   = (_Float16*)(wsb + B_H1);
  _Float16* h2   = (_Float16*)(wsb + B_H2);
  _Float16* qb   = (_Float16*)(wsb + B_Q);
  _Float16* kb   = (_Float16*)(wsb + B_K);
  _Float16* vb   = (_Float16*)(wsb + B_V);
  _Float16* kT   = (_Float16*)(wsb + B_KT);
  _Float16* tok  = (_Float16*)(wsb + B_TOK);
  _Float16* attb = (_Float16*)(wsb + B_ATT);
  _Float16* wp1  = (_Float16*)(wsb + B_WP1);
  _Float16* wp2  = (_Float16*)(wsb + B_WP2);
  _Float16* wp3  = (_Float16*)(wsb + B_WP3);
  _Float16* qkvT = (_Float16*)(wsb + B_QKVT);
  _Float16* owT  = (_Float16*)(wsb + B_OWT);
  _Float16* klh  = (_Float16*)(wsb + B_KLH);
  _Float16* w2t  = (_Float16*)(wsb + B_W2T);
  float* ql   = (float*)(wsb + B_QL);
  float* kl   = (float*)(wsb + B_KL);
  float* a2   = (float*)(wsb + B_A2);
  float* pv   = (float*)(wsb + B_PV);
  float* a3v  = (float*)(wsb + B_A3V);
  float* scal = (float*)(wsb + B_SCAL);
  float* lnb  = (float*)(wsb + B_LNB);

  // weight packing + scal init
  k_pack_w<<<(128 * 64 * 9 + 255) / 256, 256, 0, stream>>>(w1, wp1, 128, 64, 9);
  k_pack_w<<<(256 * 128 * 9 + 255) / 256, 256, 0, stream>>>(w2c, wp2, 256, 128, 9);
  k_pack_w<<<(800 * 256 * 16 + 255) / 256, 256, 0, stream>>>(w3, wp3, 800, 256, 16);
  k_pack_t<<<(800 * 1536 + 255) / 256, 256, 0, stream>>>(qkvw, qkvT, 800, 1536);
  k_pack_t<<<(512 * 800 + 255) / 256, 256, 0, stream>>>(outw, owT, 512, 800);
  k_init<<<1, 64, 0, stream>>>(scal);

  // conv stack: conv0..conv2 per image (h0/h1 scratch), h2 kept full-batch
  for (int img = 0; img < 4; ++img) {
    k_conv0<<<dim3(256), 256, 0, stream>>>(
        x + (size_t)img * 65536, w0, b0, g0, be0, mu0, var0, h0);
    k_convs<64><<<dim3(512), 256, 0, stream>>>(
        h0, wp1, b1, g1, be1, mu1, var1, h1, 128, 1);
    k_convs<128><<<dim3(1024), 256, 0, stream>>>(
        h1, wp2, b2, g2, be2, mu2, var2, h2 + (size_t)img * 16777216, 256, 2);
  }
  // conv3 (patch conv) over the full batch: staged GEMM, 640 XCD-swizzled blocks
  k_c3<<<dim3(640), 256, 0, stream>>>(h2, wp3, b3, g3, be3, mu3, var3, tok);
  // attention
  k_qkv_s<<<dim3(1536), 256, 0, stream>>>(tok, qkvT, qb, kb, vb);
  k_transpose<<<dim3(64, 32), 256, 0, stream>>>(kb, kT);
  k_landmark<<<dim3(64, 32), 64, 0, stream>>>(qb, kb, ql, kl, klh);
  k_a2<<<dim3(32), 64, 0, stream>>>(ql, kl, a2, scal);
  k_a3v<<<dim3(64, 32), 256, 0, stream>>>(ql, kT, vb, a3v);
  k_pinv<<<dim3(32), 256, 0, stream>>>(a2, scal, pv);
  k_w2<<<dim3(32), 256, 0, stream>>>(pv, a3v, w2t);
  k_combine_m<<<dim3(64, 8, 4), 256, 0, stream>>>(qb, klh, w2t, vb, resw, attb);
  // projection + LN + head
  k_outproj_m<<<dim3(13, 128), 256, 0, stream>>>(attb, owT, outbv, lnb);
  k_ln<<<dim3(16384), 256, 0, stream>>>(lnb, lng, lnbv);
  k_head<<<dim3(1024), 256, 0, stream>>>(lnb, headw, headb, (float*)d_out);
}

// Round 8
// 1162.105 us; speedup vs baseline: 9.9167x; 1.0893x over previous
//
#include <hip/hip_runtime.h>

#define DI __device__ __forceinline__

constexpr float BN_EPS_C = 1e-5f;
constexpr float LN_EPS_C = 1e-5f;

typedef _Float16 half8 __attribute__((ext_vector_type(8)));
typedef float f32x4 __attribute__((ext_vector_type(4)));

// ---------------- workspace layout (BYTE offsets), peak ~199.34 MB ----------------
constexpr size_t B_H0   = 0;             // f16 [256][256][64]  per-image scratch
constexpr size_t B_H1   = 8388608;       // f16 [256][256][128] per-image scratch
constexpr size_t B_H2   = 25165824;      // f16 [4][256][256][256] = 134,217,728 (full batch)
// overlays inside the h2 region once h2 is dead (after k_c3):
constexpr size_t B_Q    = 25165824;      // f16 [32][4096][64] = 16,777,216
constexpr size_t B_K    = 41943040;      // f16 16,777,216
constexpr size_t B_V    = 58720256;      // f16 16,777,216
constexpr size_t B_KT   = 75497472;      // f16 [32][64][4096] = 16,777,216 (dead after a3v)
constexpr size_t B_ATT  = 92274688;      // f16 [16384][512] = 16,777,216
constexpr size_t B_LNB  = 25165824;      // f16 [16384][800] = 26,214,400 (q/k/v dead by outproj)
// tok + packed weights + small buffers:
constexpr size_t B_TOK  = 159383552;     // f16 [16384][800] = 26,214,400
constexpr size_t B_WP1  = 185597952;     // 147,456
constexpr size_t B_WP2  = 185745408;     // 589,824
constexpr size_t B_WP3  = 186335232;     // 6,553,600
constexpr size_t B_QKVT = 192888832;     // 2,457,600
constexpr size_t B_OWT  = 195346432;     // 819,200
constexpr size_t B_QL   = 196165632;     // f32 524,288
constexpr size_t B_KL   = 196689920;
constexpr size_t B_KLH  = 197214208;     // f16 262,144
constexpr size_t B_A2   = 197476352;
constexpr size_t B_PV   = 198000640;
constexpr size_t B_W2T  = 198524928;     // f16 262,144
constexpr size_t B_A3V  = 198787072;
constexpr size_t B_SCAL = 199311360;     // 2 floats
constexpr size_t B_HWH  = 199311424;     // f16 [16][800] = 25,600 (end 199,337,024)

// ---------------- helpers ----------------
DI float blockReduceSum(float v) {
  #pragma unroll
  for (int o = 32; o; o >>= 1) v += __shfl_xor(v, o);
  __shared__ float red[4];
  int w = threadIdx.x >> 6;
  __syncthreads();
  if ((threadIdx.x & 63) == 0) red[w] = v;
  __syncthreads();
  return red[0] + red[1] + red[2] + red[3];
}

template <int LP, int RP>
DI void mm16(const float* L, const float* R, int r0, int c0, float reg[4][4]) {
  #pragma unroll
  for (int i = 0; i < 4; ++i)
    #pragma unroll
    for (int j = 0; j < 4; ++j) reg[i][j] = 0.f;
  for (int dd = 0; dd < 64; ++dd) {
    float l[4], r[4];
    #pragma unroll
    for (int i = 0; i < 4; ++i) l[i] = L[(size_t)(r0 + i) * LP + dd];
    #pragma unroll
    for (int j = 0; j < 4; ++j) r[j] = R[(size_t)dd * RP + c0 + j];
    #pragma unroll
    for (int i = 0; i < 4; ++i)
      #pragma unroll
      for (int j = 0; j < 4; ++j) reg[i][j] = fmaf(l[i], r[j], reg[i][j]);
  }
}

// ---------------- init ----------------
__global__ void k_init(float* scal) {
  if (threadIdx.x < 2) scal[threadIdx.x] = 0.f;
}

// ---------------- weight packing ----------------
__global__ void k_pack_w(const float* __restrict__ src, _Float16* __restrict__ dst,
                         int CO, int CI, int Q) {
  int i = blockIdx.x * 256 + threadIdx.x;
  if (i >= CO * CI * Q) return;
  int q = i % Q, ci = (i / Q) % CI, co = i / (Q * CI);
  dst[((size_t)co * Q + q) * CI + ci] = (_Float16)src[i];
}

__global__ void k_pack_t(const float* __restrict__ src, _Float16* __restrict__ dst,
                         int K, int N) {
  int i = blockIdx.x * 256 + threadIdx.x;
  if (i >= K * N) return;
  int n = i % N, k = i / N;
  dst[(size_t)n * K + k] = (_Float16)src[i];
}

// ---------------- conv0: CI=1 fp32 direct conv -> h0 NHWC f16 ----------------
__global__ __launch_bounds__(256) void k_conv0(
    const float* __restrict__ xb, const float* __restrict__ w0, const float* __restrict__ b0,
    const float* __restrict__ g0, const float* __restrict__ be0, const float* __restrict__ mu0,
    const float* __restrict__ var0, _Float16* __restrict__ h0) {
  const int t = threadIdx.x, co = t & 63, xg = t >> 6;
  const int y = blockIdx.x;
  float wreg[9];
  #pragma unroll
  for (int q = 0; q < 9; ++q) wreg[q] = w0[co * 9 + q];
  float s = g0[co] * rsqrtf(var0[co] + BN_EPS_C);
  float sh = fmaf(b0[co] - mu0[co], s, be0[co]);
  for (int xl = 0; xl < 64; ++xl) {
    int xx = xg * 64 + xl;
    float acc = 0.f;
    #pragma unroll
    for (int dy = 0; dy < 3; ++dy) {
      int yy = y + dy - 1;
      if ((unsigned)yy >= 256u) continue;
      #pragma unroll
      for (int dx = 0; dx < 3; ++dx) {
        int xi = xx + dx - 1;
        if ((unsigned)xi >= 256u) continue;
        acc = fmaf(wreg[dy * 3 + dx], xb[yy * 256 + xi], acc);
      }
    }
    float v = fmaxf(fmaf(acc, s, sh), 0.f);
    h0[((size_t)y * 256 + xx) * 64 + co] = (_Float16)v;
  }
}

// ------- staged implicit-im2col 3x3 conv GEMM: tile 128x128 ---------------
template <int CI>
__global__ __launch_bounds__(256) void k_convs(
    const _Float16* __restrict__ in, const _Float16* __restrict__ wp,
    const float* __restrict__ bias, const float* __restrict__ g, const float* __restrict__ be,
    const float* __restrict__ mu, const float* __restrict__ var,
    _Float16* __restrict__ out, int CO, int NCT) {
  __shared__ _Float16 Ab[2][128 * 40];
  __shared__ _Float16 Bb[2][128 * 40];
  constexpr int CPQ = CI / 32;
  constexpr int NCK = 9 * CPQ;
  const int t = threadIdx.x;
  const int bid = blockIdx.x;
  const int xcd = bid & 7, slot = bid >> 3;
  const int pj = slot / NCT, cc = slot % NCT;
  const int p = pj * 8 + xcd;
  const int r0 = p * 128, c0 = cc * 128;

  const int ma = t >> 2, kga = t & 3;
  int ry[2], rx[2];
  #pragma unroll
  for (int s = 0; s < 2; ++s) {
    int r = r0 + ma + s * 64;
    ry[s] = r >> 8;
    rx[s] = r & 255;
  }
  const _Float16* baseB[2];
  #pragma unroll
  for (int s = 0; s < 2; ++s)
    baseB[s] = wp + (size_t)(c0 + ma + s * 64) * 9 * CI + kga * 8;
  const int wo = ma * 40 + kga * 8;

  auto loadA = [&](int s, int ck) -> half8 {
    int q = ck / CPQ, coff = (ck % CPQ) * 32;
    int yy = ry[s] + q / 3 - 1;
    int xx = rx[s] + q % 3 - 1;
    half8 a = {};
    if ((unsigned)yy < 256u && (unsigned)xx < 256u)
      a = *reinterpret_cast<const half8*>(in + ((size_t)yy * 256 + xx) * CI + coff + kga * 8);
    return a;
  };

  {
    half8 a0 = loadA(0, 0), a1 = loadA(1, 0);
    half8 b0v = *reinterpret_cast<const half8*>(baseB[0]);
    half8 b1v = *reinterpret_cast<const half8*>(baseB[1]);
    *reinterpret_cast<half8*>(&Ab[0][wo]) = a0;
    *reinterpret_cast<half8*>(&Ab[0][wo + 2560]) = a1;
    *reinterpret_cast<half8*>(&Bb[0][wo]) = b0v;
    *reinterpret_cast<half8*>(&Bb[0][wo + 2560]) = b1v;
  }
  __syncthreads();

  const int w = t >> 6, lo = t & 15, hi = (t >> 4) & 3;
  const int wm = w >> 1, wn = w & 1;
  const int roA = (wm * 64 + lo) * 40 + 8 * hi;
  const int roB = (wn * 64 + lo) * 40 + 8 * hi;
  f32x4 acc[4][4] = {};

  for (int ck = 0; ck < NCK; ++ck) {
    const int cur = ck & 1;
    const bool more = (ck + 1 < NCK);
    half8 rA0, rA1, rB0, rB1;
    if (more) {
      rA0 = loadA(0, ck + 1);
      rA1 = loadA(1, ck + 1);
      rB0 = *reinterpret_cast<const half8*>(baseB[0] + (ck + 1) * 32);
      rB1 = *reinterpret_cast<const half8*>(baseB[1] + (ck + 1) * 32);
    }
    half8 af[4], bf[4];
    #pragma unroll
    for (int mi = 0; mi < 4; ++mi)
      af[mi] = *reinterpret_cast<const half8*>(&Ab[cur][roA + mi * 640]);
    #pragma unroll
    for (int ni = 0; ni < 4; ++ni)
      bf[ni] = *reinterpret_cast<const half8*>(&Bb[cur][roB + ni * 640]);
    #pragma unroll
    for (int mi = 0; mi < 4; ++mi)
      #pragma unroll
      for (int ni = 0; ni < 4; ++ni)
        acc[mi][ni] = __builtin_amdgcn_mfma_f32_16x16x32_f16(af[mi], bf[ni], acc[mi][ni], 0, 0, 0);
    if (more) {
      *reinterpret_cast<half8*>(&Ab[cur ^ 1][wo]) = rA0;
      *reinterpret_cast<half8*>(&Ab[cur ^ 1][wo + 2560]) = rA1;
      *reinterpret_cast<half8*>(&Bb[cur ^ 1][wo]) = rB0;
      *reinterpret_cast<half8*>(&Bb[cur ^ 1][wo + 2560]) = rB1;
    }
    __syncthreads();
  }

  #pragma unroll
  for (int ni = 0; ni < 4; ++ni) {
    int co = c0 + wn * 64 + ni * 16 + lo;
    float s = g[co] * rsqrtf(var[co] + BN_EPS_C);
    float sh = fmaf(bias[co] - mu[co], s, be[co]);
    #pragma unroll
    for (int mi = 0; mi < 4; ++mi)
      #pragma unroll
      for (int rr = 0; rr < 4; ++rr) {
        int row = r0 + wm * 64 + mi * 16 + hi * 4 + rr;
        float v = fmaxf(fmaf(acc[mi][ni][rr], s, sh), 0.f);
        out[(size_t)row * CO + co] = (_Float16)v;
      }
  }
}

// ---------------- conv3 MFMA: staged GEMM, 128x160 tile, XCD-swizzled ----------
__global__ __launch_bounds__(256) void k_c3(
    const _Float16* __restrict__ h2, const _Float16* __restrict__ wp3,
    const float* __restrict__ b3, const float* __restrict__ g3, const float* __restrict__ be3,
    const float* __restrict__ mu3, const float* __restrict__ var3,
    _Float16* __restrict__ tok) {
  __shared__ _Float16 Abuf[2][128 * 40];
  __shared__ _Float16 Bbuf[2][160 * 40];
  const int t = threadIdx.x;
  const int bid = blockIdx.x;
  const int xcd = bid & 7, slot = bid >> 3;
  const int pj = slot / 5, cc = slot % 5;
  const int p = pj * 8 + xcd;
  const int r0 = p * 128, c0 = cc * 160;
  const int img = r0 >> 12;
  const _Float16* h2i = h2 + (size_t)img * 16777216;

  const int ma = t >> 2, kga = t & 3;
  const _Float16* baseA[2];
  #pragma unroll
  for (int s = 0; s < 2; ++s) {
    int m = ma + s * 64;
    int r = r0 + m;
    int py = (r & 4095) >> 6, px = r & 63;
    baseA[s] = h2i + ((size_t)py * 1024 + px * 4) * 256 + kga * 8;
  }
  const _Float16* baseB[3];
  #pragma unroll
  for (int s = 0; s < 3; ++s) {
    int cb = ma + s * 64;
    baseB[s] = wp3 + (size_t)(c0 + (cb < 160 ? cb : 159)) * 4096 + kga * 8;
  }
  const int wo = ma * 40 + kga * 8;

  const int w = t >> 6, lo = t & 15, hi = (t >> 4) & 3;
  const int wm = w >> 1, wn = w & 1;
  const int roA = (wm * 64 + lo) * 40 + 8 * hi;
  const int roB = (wn * 80 + lo) * 40 + 8 * hi;

  f32x4 acc[4][5] = {};

  {
    half8 a0 = *reinterpret_cast<const half8*>(baseA[0]);
    half8 a1 = *reinterpret_cast<const half8*>(baseA[1]);
    half8 b0v = *reinterpret_cast<const half8*>(baseB[0]);
    half8 b1v = *reinterpret_cast<const half8*>(baseB[1]);
    *reinterpret_cast<half8*>(&Abuf[0][wo]) = a0;
    *reinterpret_cast<half8*>(&Abuf[0][wo + 2560]) = a1;
    *reinterpret_cast<half8*>(&Bbuf[0][wo]) = b0v;
    *reinterpret_cast<half8*>(&Bbuf[0][wo + 2560]) = b1v;
    if (t < 128) {
      half8 b2v = *reinterpret_cast<const half8*>(baseB[2]);
      *reinterpret_cast<half8*>(&Bbuf[0][wo + 5120]) = b2v;
    }
  }
  __syncthreads();

  for (int ck = 0; ck < 128; ++ck) {
    const int cur = ck & 1;
    const bool more = (ck + 1 < 128);
    half8 rA0, rA1, rB0, rB1, rB2;
    if (more) {
      const int kn = (ck + 1) << 5;
      const int q = kn >> 8, qk = kn & 255;
      const int aoff = (q >> 2) * 65536 + (q & 3) * 256 + qk;
      rA0 = *reinterpret_cast<const half8*>(baseA[0] + aoff);
      rA1 = *reinterpret_cast<const half8*>(baseA[1] + aoff);
      rB0 = *reinterpret_cast<const half8*>(baseB[0] + kn);
      rB1 = *reinterpret_cast<const half8*>(baseB[1] + kn);
      if (t < 128) rB2 = *reinterpret_cast<const half8*>(baseB[2] + kn);
    }
    half8 af[4], bf[5];
    #pragma unroll
    for (int mi = 0; mi < 4; ++mi)
      af[mi] = *reinterpret_cast<const half8*>(&Abuf[cur][roA + mi * 640]);
    #pragma unroll
    for (int ni = 0; ni < 5; ++ni)
      bf[ni] = *reinterpret_cast<const half8*>(&Bbuf[cur][roB + ni * 640]);
    #pragma unroll
    for (int mi = 0; mi < 4; ++mi)
      #pragma unroll
      for (int ni = 0; ni < 5; ++ni)
        acc[mi][ni] = __builtin_amdgcn_mfma_f32_16x16x32_f16(af[mi], bf[ni], acc[mi][ni], 0, 0, 0);
    if (more) {
      *reinterpret_cast<half8*>(&Abuf[cur ^ 1][wo]) = rA0;
      *reinterpret_cast<half8*>(&Abuf[cur ^ 1][wo + 2560]) = rA1;
      *reinterpret_cast<half8*>(&Bbuf[cur ^ 1][wo]) = rB0;
      *reinterpret_cast<half8*>(&Bbuf[cur ^ 1][wo + 2560]) = rB1;
      if (t < 128) *reinterpret_cast<half8*>(&Bbuf[cur ^ 1][wo + 5120]) = rB2;
    }
    __syncthreads();
  }

  #pragma unroll
  for (int ni = 0; ni < 5; ++ni) {
    int col = c0 + wn * 80 + ni * 16 + lo;
    float s = g3[col] * rsqrtf(var3[col] + BN_EPS_C);
    float sh = fmaf(b3[col] - mu3[col], s, be3[col]);
    #pragma unroll
    for (int mi = 0; mi < 4; ++mi)
      #pragma unroll
      for (int rr = 0; rr < 4; ++rr) {
        int row = r0 + wm * 64 + mi * 16 + hi * 4 + rr;
        float v = fmaxf(fmaf(acc[mi][ni][rr], s, sh), 0.f);
        tok[(size_t)row * 800 + col] = (_Float16)v;
      }
  }
}

// ---------------- qkv staged GEMM: M=16384, N=1536 (12 col-tiles), K=800 --------------
__global__ __launch_bounds__(256) void k_qkv_s(
    const _Float16* __restrict__ tok, const _Float16* __restrict__ qkvT,
    _Float16* __restrict__ qx, _Float16* __restrict__ kx, _Float16* __restrict__ vx) {
  __shared__ _Float16 Ab[2][128 * 40];
  __shared__ _Float16 Bb[2][128 * 40];
  const int t = threadIdx.x;
  const int bid = blockIdx.x;
  const int xcd = bid & 7, slot = bid >> 3;
  const int pj = slot / 12, cc = slot % 12;
  const int p = pj * 8 + xcd;
  const int r0 = p * 128, c0 = cc * 128;

  const int ma = t >> 2, kga = t & 3;
  const _Float16* baseA[2];
  const _Float16* baseB[2];
  #pragma unroll
  for (int s = 0; s < 2; ++s) {
    baseA[s] = tok + (size_t)(r0 + ma + s * 64) * 800 + kga * 8;
    baseB[s] = qkvT + (size_t)(c0 + ma + s * 64) * 800 + kga * 8;
  }
  const int wo = ma * 40 + kga * 8;

  {
    half8 a0 = *reinterpret_cast<const half8*>(baseA[0]);
    half8 a1 = *reinterpret_cast<const half8*>(baseA[1]);
    half8 b0v = *reinterpret_cast<const half8*>(baseB[0]);
    half8 b1v = *reinterpret_cast<const half8*>(baseB[1]);
    *reinterpret_cast<half8*>(&Ab[0][wo]) = a0;
    *reinterpret_cast<half8*>(&Ab[0][wo + 2560]) = a1;
    *reinterpret_cast<half8*>(&Bb[0][wo]) = b0v;
    *reinterpret_cast<half8*>(&Bb[0][wo + 2560]) = b1v;
  }
  __syncthreads();

  const int w = t >> 6, lo = t & 15, hi = (t >> 4) & 3;
  const int wm = w >> 1, wn = w & 1;
  const int roA = (wm * 64 + lo) * 40 + 8 * hi;
  const int roB = (wn * 64 + lo) * 40 + 8 * hi;
  f32x4 acc[4][4] = {};

  for (int ck = 0; ck < 25; ++ck) {
    const int cur = ck & 1;
    const bool more = (ck + 1 < 25);
    half8 rA0, rA1, rB0, rB1;
    if (more) {
      const int kn = (ck + 1) * 32;
      rA0 = *reinterpret_cast<const half8*>(baseA[0] + kn);
      rA1 = *reinterpret_cast<const half8*>(baseA[1] + kn);
      rB0 = *reinterpret_cast<const half8*>(baseB[0] + kn);
      rB1 = *reinterpret_cast<const half8*>(baseB[1] + kn);
    }
    half8 af[4], bf[4];
    #pragma unroll
    for (int mi = 0; mi < 4; ++mi)
      af[mi] = *reinterpret_cast<const half8*>(&Ab[cur][roA + mi * 640]);
    #pragma unroll
    for (int ni = 0; ni < 4; ++ni)
      bf[ni] = *reinterpret_cast<const half8*>(&Bb[cur][roB + ni * 640]);
    #pragma unroll
    for (int mi = 0; mi < 4; ++mi)
      #pragma unroll
      for (int ni = 0; ni < 4; ++ni)
        acc[mi][ni] = __builtin_amdgcn_mfma_f32_16x16x32_f16(af[mi], bf[ni], acc[mi][ni], 0, 0, 0);
    if (more) {
      *reinterpret_cast<half8*>(&Ab[cur ^ 1][wo]) = rA0;
      *reinterpret_cast<half8*>(&Ab[cur ^ 1][wo + 2560]) = rA1;
      *reinterpret_cast<half8*>(&Bb[cur ^ 1][wo]) = rB0;
      *reinterpret_cast<half8*>(&Bb[cur ^ 1][wo + 2560]) = rB1;
    }
    __syncthreads();
  }

  const int seg = cc >> 2;
  const float scale = (seg == 0) ? 0.125f : 1.0f;
  _Float16* dst = (seg == 0) ? qx : (seg == 1) ? kx : vx;
  #pragma unroll
  for (int ni = 0; ni < 4; ++ni) {
    int cseg = (cc & 3) * 128 + wn * 64 + ni * 16 + lo;
    int h = cseg >> 6, d = cseg & 63;
    #pragma unroll
    for (int mi = 0; mi < 4; ++mi)
      #pragma unroll
      for (int rr = 0; rr < 4; ++rr) {
        int row = r0 + wm * 64 + mi * 16 + hi * 4 + rr;
        int b = row >> 12, nn = row & 4095;
        dst[((size_t)(b * 8 + h) * 4096 + nn) * 64 + d] = (_Float16)(acc[mi][ni][rr] * scale);
      }
  }
}

// ---------------- out-proj staged GEMM: M=16384, N=800 (5x160), K=512 -> f16 lnb ---------
__global__ __launch_bounds__(256) void k_op_s(
    const _Float16* __restrict__ attb, const _Float16* __restrict__ owT,
    const float* __restrict__ ob, _Float16* __restrict__ lnb) {
  __shared__ _Float16 Abuf[2][128 * 40];
  __shared__ _Float16 Bbuf[2][160 * 40];
  const int t = threadIdx.x;
  const int bid = blockIdx.x;
  const int xcd = bid & 7, slot = bid >> 3;     // 640 = 8 * 80
  const int pj = slot / 5, cc = slot % 5;
  const int p = pj * 8 + xcd;
  const int r0 = p * 128, c0 = cc * 160;

  const int ma = t >> 2, kga = t & 3;
  const _Float16* baseA[2];
  #pragma unroll
  for (int s = 0; s < 2; ++s)
    baseA[s] = attb + (size_t)(r0 + ma + s * 64) * 512 + kga * 8;
  const _Float16* baseB[3];
  #pragma unroll
  for (int s = 0; s < 3; ++s) {
    int cb = ma + s * 64;
    baseB[s] = owT + (size_t)(c0 + (cb < 160 ? cb : 159)) * 512 + kga * 8;
  }
  const int wo = ma * 40 + kga * 8;

  const int w = t >> 6, lo = t & 15, hi = (t >> 4) & 3;
  const int wm = w >> 1, wn = w & 1;
  const int roA = (wm * 64 + lo) * 40 + 8 * hi;
  const int roB = (wn * 80 + lo) * 40 + 8 * hi;

  f32x4 acc[4][5] = {};

  {
    half8 a0 = *reinterpret_cast<const half8*>(baseA[0]);
    half8 a1 = *reinterpret_cast<const half8*>(baseA[1]);
    half8 b0v = *reinterpret_cast<const half8*>(baseB[0]);
    half8 b1v = *reinterpret_cast<const half8*>(baseB[1]);
    *reinterpret_cast<half8*>(&Abuf[0][wo]) = a0;
    *reinterpret_cast<half8*>(&Abuf[0][wo + 2560]) = a1;
    *reinterpret_cast<half8*>(&Bbuf[0][wo]) = b0v;
    *reinterpret_cast<half8*>(&Bbuf[0][wo + 2560]) = b1v;
    if (t < 128) {
      half8 b2v = *reinterpret_cast<const half8*>(baseB[2]);
      *reinterpret_cast<half8*>(&Bbuf[0][wo + 5120]) = b2v;
    }
  }
  __syncthreads();

  for (int ck = 0; ck < 16; ++ck) {
    const int cur = ck & 1;
    const bool more = (ck + 1 < 16);
    half8 rA0, rA1, rB0, rB1, rB2;
    if (more) {
      const int kn = (ck + 1) << 5;
      rA0 = *reinterpret_cast<const half8*>(baseA[0] + kn);
      rA1 = *reinterpret_cast<const half8*>(baseA[1] + kn);
      rB0 = *reinterpret_cast<const half8*>(baseB[0] + kn);
      rB1 = *reinterpret_cast<const half8*>(baseB[1] + kn);
      if (t < 128) rB2 = *reinterpret_cast<const half8*>(baseB[2] + kn);
    }
    half8 af[4], bf[5];
    #pragma unroll
    for (int mi = 0; mi < 4; ++mi)
      af[mi] = *reinterpret_cast<const half8*>(&Abuf[cur][roA + mi * 640]);
    #pragma unroll
    for (int ni = 0; ni < 5; ++ni)
      bf[ni] = *reinterpret_cast<const half8*>(&Bbuf[cur][roB + ni * 640]);
    #pragma unroll
    for (int mi = 0; mi < 4; ++mi)
      #pragma unroll
      for (int ni = 0; ni < 5; ++ni)
        acc[mi][ni] = __builtin_amdgcn_mfma_f32_16x16x32_f16(af[mi], bf[ni], acc[mi][ni], 0, 0, 0);
    if (more) {
      *reinterpret_cast<half8*>(&Abuf[cur ^ 1][wo]) = rA0;
      *reinterpret_cast<half8*>(&Abuf[cur ^ 1][wo + 2560]) = rA1;
      *reinterpret_cast<half8*>(&Bbuf[cur ^ 1][wo]) = rB0;
      *reinterpret_cast<half8*>(&Bbuf[cur ^ 1][wo + 2560]) = rB1;
      if (t < 128) *reinterpret_cast<half8*>(&Bbuf[cur ^ 1][wo + 5120]) = rB2;
    }
    __syncthreads();
  }

  #pragma unroll
  for (int ni = 0; ni < 5; ++ni) {
    int col = c0 + wn * 80 + ni * 16 + lo;
    float bv = ob[col];
    #pragma unroll
    for (int mi = 0; mi < 4; ++mi)
      #pragma unroll
      for (int rr = 0; rr < 4; ++rr) {
        int row = r0 + wm * 64 + mi * 16 + hi * 4 + rr;
        lnb[(size_t)row * 800 + col] = (_Float16)(acc[mi][ni][rr] + bv);
      }
  }
}

// ---------------- transpose k -> kT f16 [bh][d][n] ----------------
__global__ __launch_bounds__(256) void k_transpose(const _Float16* __restrict__ kx,
                                                   _Float16* __restrict__ kT) {
  __shared__ _Float16 tile[64 * 66];
  const int bh = blockIdx.y, n0 = blockIdx.x * 64;
  const _Float16* src = kx + ((size_t)bh * 4096 + n0) * 64;
  const int t = threadIdx.x;
  #pragma unroll
  for (int u = 0; u < 16; ++u) {
    int e = t + u * 256;
    int r = e >> 6, d = e & 63;
    tile[d * 66 + r] = src[e];
  }
  __syncthreads();
  _Float16* dst = kT + (size_t)bh * 262144 + n0;
  #pragma unroll
  for (int u = 0; u < 16; ++u) {
    int e = t + u * 256;
    int d = e >> 6, j = e & 63;
    dst[(size_t)d * 4096 + j] = tile[d * 66 + j];
  }
}

// ---------------- landmarks ----------------
__global__ __launch_bounds__(64) void k_landmark(
    const _Float16* __restrict__ qx, const _Float16* __restrict__ kx,
    float* __restrict__ ql, float* __restrict__ kl, _Float16* __restrict__ klh) {
  const int d = threadIdx.x;
  const int m = blockIdx.x, bh = blockIdx.y;
  const _Float16* qp = qx + ((size_t)bh * 4096 + m * 64) * 64 + d;
  const _Float16* kp = kx + ((size_t)bh * 4096 + m * 64) * 64 + d;
  float sq = 0.f, sk = 0.f;
  #pragma unroll 8
  for (int j = 0; j < 64; ++j) {
    sq += (float)qp[(size_t)j * 64];
    sk += (float)kp[(size_t)j * 64];
  }
  sq *= (1.f / 64.f);
  sk *= (1.f / 64.f);
  ql[((size_t)bh * 64 + m) * 64 + d] = sq;
  kl[((size_t)bh * 64 + m) * 64 + d] = sk;
  klh[((size_t)bh * 64 + m) * 64 + d] = (_Float16)sk;
}

// ---------------- a2 + global max row/col sums ----------------
__global__ __launch_bounds__(64) void k_a2(
    const float* __restrict__ ql, const float* __restrict__ kl,
    float* __restrict__ a2, float* __restrict__ scal) {
  __shared__ float sp[64 * 65];
  const int bh = blockIdx.x, t = threadIdx.x;
  const float* qr = ql + ((size_t)bh * 64 + t) * 64;
  const float* kb = kl + (size_t)bh * 4096;
  float mx = -1e30f;
  for (int c = 0; c < 64; ++c) {
    float acc = 0.f;
    #pragma unroll 8
    for (int dd = 0; dd < 64; ++dd) acc = fmaf(qr[dd], kb[c * 64 + dd], acc);
    sp[t * 65 + c] = acc;
    mx = fmaxf(mx, acc);
  }
  float sum = 0.f;
  for (int c = 0; c < 64; ++c) {
    float e = expf(sp[t * 65 + c] - mx);
    sp[t * 65 + c] = e;
    sum += e;
  }
  float inv = 1.f / sum;
  float rs = 0.f;
  for (int c = 0; c < 64; ++c) {
    float p = sp[t * 65 + c] * inv;
    sp[t * 65 + c] = p;
    a2[(size_t)bh * 4096 + t * 64 + c] = p;
    rs += p;
  }
  atomicMax(reinterpret_cast<int*>(scal), __float_as_int(rs));
  __syncthreads();
  float cs = 0.f;
  for (int r = 0; r < 64; ++r) cs += sp[r * 65 + t];
  atomicMax(reinterpret_cast<int*>(scal) + 1, __float_as_int(cs));
}

// ---------------- fused a3 softmax + a3@v ----------------
__global__ __launch_bounds__(256) void k_a3v(
    const float* __restrict__ ql, const _Float16* __restrict__ kT,
    const _Float16* __restrict__ vx, float* __restrict__ a3v) {
  __shared__ float sq[64];
  __shared__ float sP[4096];
  __shared__ float red[4];
  __shared__ float red2[4][64];
  const int t = threadIdx.x;
  const int m = blockIdx.x, bh = blockIdx.y;
  if (t < 64) sq[t] = ql[((size_t)bh * 64 + m) * 64 + t];
  __syncthreads();
  const _Float16* kb = kT + (size_t)bh * 262144;
  float sc[16];
  #pragma unroll
  for (int i = 0; i < 16; ++i) sc[i] = 0.f;
  for (int dd = 0; dd < 64; ++dd) {
    float qv = sq[dd];
    const _Float16* kr = kb + (size_t)dd * 4096 + t;
    #pragma unroll
    for (int i = 0; i < 16; ++i) sc[i] = fmaf(qv, (float)kr[i * 256], sc[i]);
  }
  float mx = sc[0];
  #pragma unroll
  for (int i = 1; i < 16; ++i) mx = fmaxf(mx, sc[i]);
  #pragma unroll
  for (int o = 32; o; o >>= 1) mx = fmaxf(mx, __shfl_xor(mx, o));
  if ((t & 63) == 0) red[t >> 6] = mx;
  __syncthreads();
  mx = fmaxf(fmaxf(red[0], red[1]), fmaxf(red[2], red[3]));
  __syncthreads();
  float sum = 0.f;
  #pragma unroll
  for (int i = 0; i < 16; ++i) {
    sc[i] = expf(sc[i] - mx);
    sum += sc[i];
  }
  #pragma unroll
  for (int o = 32; o; o >>= 1) sum += __shfl_xor(sum, o);
  if ((t & 63) == 0) red[t >> 6] = sum;
  __syncthreads();
  sum = red[0] + red[1] + red[2] + red[3];
  float inv = 1.f / sum;
  #pragma unroll
  for (int i = 0; i < 16; ++i) sP[t + i * 256] = sc[i] * inv;
  __syncthreads();
  const int d = t & 63, seg = t >> 6;
  const _Float16* vb = vx + (size_t)bh * 262144;
  float acc = 0.f;
  for (int n = seg * 1024; n < seg * 1024 + 1024; ++n)
    acc = fmaf(sP[n], (float)vb[(size_t)n * 64 + d], acc);
  red2[seg][d] = acc;
  __syncthreads();
  if (seg == 0)
    a3v[((size_t)bh * 64 + m) * 64 + d] = red2[0][d] + red2[1][d] + red2[2][d] + red2[3][d];
}

// ---------------- Moore-Penrose pinv (fp32) ----------------
__global__ __launch_bounds__(256) void k_pinv(
    const float* __restrict__ a2g, const float* __restrict__ scal, float* __restrict__ pv) {
  __shared__ float z[64 * 65];
  __shared__ float az[64 * 65];
  __shared__ float tb[64 * 65];
  const int bh = blockIdx.x, t = threadIdx.x;
  const int r0 = (t >> 4) << 2, c0 = (t & 15) << 2;
  const float* ag = a2g + (size_t)bh * 4096;
  const float denom = 1.f / (scal[0] * scal[1]);
  #pragma unroll
  for (int i = 0; i < 4; ++i)
    #pragma unroll
    for (int j = 0; j < 4; ++j)
      z[(r0 + i) * 65 + c0 + j] = ag[(c0 + j) * 64 + r0 + i] * denom;
  __syncthreads();
  float reg[4][4], val[4][4];
  for (int it = 0; it < 6; ++it) {
    mm16<64, 65>(ag, z, r0, c0, reg);
    #pragma unroll
    for (int i = 0; i < 4; ++i)
      #pragma unroll
      for (int j = 0; j < 4; ++j) az[(r0 + i) * 65 + c0 + j] = reg[i][j];
    __syncthreads();
    mm16<65, 65>(az, az, r0, c0, reg);
    #pragma unroll
    for (int i = 0; i < 4; ++i)
      #pragma unroll
      for (int j = 0; j < 4; ++j)
        tb[(r0 + i) * 65 + c0 + j] = 7.f * az[(r0 + i) * 65 + c0 + j] - reg[i][j];
    __syncthreads();
    mm16<65, 65>(az, tb, r0, c0, reg);
    #pragma unroll
    for (int i = 0; i < 4; ++i)
      #pragma unroll
      for (int j = 0; j < 4; ++j)
        val[i][j] = 15.f * az[(r0 + i) * 65 + c0 + j] - reg[i][j];
    __syncthreads();
    #pragma unroll
    for (int i = 0; i < 4; ++i)
      #pragma unroll
      for (int j = 0; j < 4; ++j) tb[(r0 + i) * 65 + c0 + j] = val[i][j];
    __syncthreads();
    mm16<65, 65>(z, tb, r0, c0, reg);
    #pragma unroll
    for (int i = 0; i < 4; ++i)
      #pragma unroll
      for (int j = 0; j < 4; ++j)
        val[i][j] = 0.25f * (13.f * z[(r0 + i) * 65 + c0 + j] - reg[i][j]);
    __syncthreads();
    #pragma unroll
    for (int i = 0; i < 4; ++i)
      #pragma unroll
      for (int j = 0; j < 4; ++j) z[(r0 + i) * 65 + c0 + j] = val[i][j];
    __syncthreads();
  }
  #pragma unroll
  for (int i = 0; i < 4; ++i)
    #pragma unroll
    for (int j = 0; j < 4; ++j)
      pv[(size_t)bh * 4096 + (r0 + i) * 64 + c0 + j] = z[(r0 + i) * 65 + c0 + j];
}

// ---------------- w2t = (pinv @ a3v)^T as f16 [bh][d][m] ----------------
__global__ __launch_bounds__(256) void k_w2(
    const float* __restrict__ pv, const float* __restrict__ a3v, _Float16* __restrict__ w2t) {
  const int bh = blockIdx.x, t = threadIdx.x;
  const int r0 = (t >> 4) << 2, c0 = (t & 15) << 2;
  float reg[4][4];
  mm16<64, 64>(pv + (size_t)bh * 4096, a3v + (size_t)bh * 4096, r0, c0, reg);
  #pragma unroll
  for (int i = 0; i < 4; ++i)
    #pragma unroll
    for (int j = 0; j < 4; ++j)
      w2t[(size_t)bh * 4096 + (c0 + j) * 64 + (r0 + i)] = (_Float16)reg[i][j];
}

// ------- fused MFMA combine: S=q@kl^T -> softmax -> P@W2 + Toeplitz(res)@v -> att f16 ------
__global__ __launch_bounds__(256) void k_combine_m(
    const _Float16* __restrict__ qx, const _Float16* __restrict__ klh,
    const _Float16* __restrict__ w2t, const _Float16* __restrict__ vx,
    const float* __restrict__ rw, _Float16* __restrict__ att) {
  __shared__ _Float16 sP[64 * 72];
  __shared__ _Float16 sVT[64 * 104];
  __shared__ _Float16 sT[64 * 104];
  __shared__ float sR[33];
  const int t = threadIdx.x, w = t >> 6, lo = t & 15, hi = (t >> 4) & 3;
  const int n0 = blockIdx.x * 64;
  const int h = blockIdx.y, b = blockIdx.z, bh = b * 8 + h;
  if (t < 33) sR[t] = rw[h * 33 + t];
  __syncthreads();
  const _Float16* vb = vx + (size_t)bh * 262144;
  #pragma unroll
  for (int u = 0; u < 24; ++u) {
    int e = t + u * 256;
    int r = e >> 6, d = e & 63;
    int nn = n0 - 16 + r;
    sVT[d * 104 + r] = ((unsigned)nn < 4096u) ? vb[(size_t)nn * 64 + d] : (_Float16)0.f;
  }
  #pragma unroll
  for (int u = 0; u < 24; ++u) {
    int e = t + u * 256;
    int r = e % 96, i = e / 96;
    int j = r - i;
    sT[i * 104 + r] = (j >= 0 && j < 33) ? (_Float16)sR[j] : (_Float16)0.f;
  }
  f32x4 sa[4] = {};
  const _Float16* qp = qx + ((size_t)bh * 4096 + n0 + w * 16 + lo) * 64 + 8 * hi;
  const _Float16* klp = klh + (size_t)bh * 4096;
  #pragma unroll
  for (int c = 0; c < 2; ++c) {
    half8 a = *reinterpret_cast<const half8*>(qp + 32 * c);
    #pragma unroll
    for (int ct = 0; ct < 4; ++ct) {
      half8 bf = *reinterpret_cast<const half8*>(klp + (size_t)(ct * 16 + lo) * 64 + 8 * hi + 32 * c);
      sa[ct] = __builtin_amdgcn_mfma_f32_16x16x32_f16(a, bf, sa[ct], 0, 0, 0);
    }
  }
  #pragma unroll
  for (int r = 0; r < 4; ++r) {
    float mx = fmaxf(fmaxf(sa[0][r], sa[1][r]), fmaxf(sa[2][r], sa[3][r]));
    #pragma unroll
    for (int o = 8; o; o >>= 1) mx = fmaxf(mx, __shfl_xor(mx, o));
    float e0 = expf(sa[0][r] - mx), e1 = expf(sa[1][r] - mx);
    float e2 = expf(sa[2][r] - mx), e3 = expf(sa[3][r] - mx);
    float sm = e0 + e1 + e2 + e3;
    #pragma unroll
    for (int o = 8; o; o >>= 1) sm += __shfl_xor(sm, o);
    float inv = 1.f / sm;
    int row = w * 16 + hi * 4 + r;
    sP[row * 72 + lo] = (_Float16)(e0 * inv);
    sP[row * 72 + 16 + lo] = (_Float16)(e1 * inv);
    sP[row * 72 + 32 + lo] = (_Float16)(e2 * inv);
    sP[row * 72 + 48 + lo] = (_Float16)(e3 * inv);
  }
  __syncthreads();
  f32x4 ao[4] = {};
  const _Float16* w2p = w2t + (size_t)bh * 4096;
  #pragma unroll
  for (int c = 0; c < 2; ++c) {
    half8 a = *reinterpret_cast<const half8*>(&sP[(w * 16 + lo) * 72 + 8 * hi + 32 * c]);
    #pragma unroll
    for (int ct = 0; ct < 4; ++ct) {
      half8 bf = *reinterpret_cast<const half8*>(w2p + (size_t)(ct * 16 + lo) * 64 + 8 * hi + 32 * c);
      ao[ct] = __builtin_amdgcn_mfma_f32_16x16x32_f16(a, bf, ao[ct], 0, 0, 0);
    }
  }
  #pragma unroll
  for (int c = 0; c < 3; ++c) {
    half8 a = *reinterpret_cast<const half8*>(&sT[(w * 16 + lo) * 104 + 8 * hi + 32 * c]);
    #pragma unroll
    for (int ct = 0; ct < 4; ++ct) {
      half8 bf = *reinterpret_cast<const half8*>(&sVT[(ct * 16 + lo) * 104 + 8 * hi + 32 * c]);
      ao[ct] = __builtin_amdgcn_mfma_f32_16x16x32_f16(a, bf, ao[ct], 0, 0, 0);
    }
  }
  _Float16* ab = att + ((size_t)b * 4096) * 512 + (size_t)h * 64;
  #pragma unroll
  for (int ct = 0; ct < 4; ++ct)
    #pragma unroll
    for (int r = 0; r < 4; ++r) {
      int n = n0 + w * 16 + hi * 4 + r;
      ab[(size_t)n * 512 + ct * 16 + lo] = (_Float16)ao[ct][r];
    }
}

// ---------------- LayerNorm in place over E=800, f16 buffer ----------------
__global__ __launch_bounds__(256) void k_ln16(
    _Float16* __restrict__ buf, const float* __restrict__ g, const float* __restrict__ bb) {
  const int t = threadIdx.x;
  _Float16* p = buf + (size_t)blockIdx.x * 800;
  float x0 = (float)p[t], x1 = (float)p[t + 256], x2 = (float)p[t + 512];
  float x3 = (t < 32) ? (float)p[t + 768] : 0.f;
  float s = blockReduceSum(x0 + x1 + x2 + x3);
  float mean = s * (1.f / 800.f);
  float d0 = x0 - mean, d1 = x1 - mean, d2 = x2 - mean;
  float d3 = (t < 32) ? x3 - mean : 0.f;
  float s2 = blockReduceSum(d0 * d0 + d1 * d1 + d2 * d2 + d3 * d3);
  float rstd = rsqrtf(s2 * (1.f / 800.f) + LN_EPS_C);
  p[t] = (_Float16)(d0 * rstd * g[t] + bb[t]);
  p[t + 256] = (_Float16)(d1 * rstd * g[t + 256] + bb[t + 256]);
  p[t + 512] = (_Float16)(d2 * rstd * g[t + 512] + bb[t + 512]);
  if (t < 32) p[t + 768] = (_Float16)(d3 * rstd * g[t + 768] + bb[t + 768]);
}

// ---------------- head MFMA: out[16384,16] = sigmoid(lnb @ hwh^T + hb) ----------------
__global__ __launch_bounds__(256) void k_head_m(
    const _Float16* __restrict__ ln, const _Float16* __restrict__ hwh,
    const float* __restrict__ hb, float* __restrict__ out) {
  const int t = threadIdx.x, w = t >> 6, lo = t & 15, hi = (t >> 4) & 3;
  const int row0 = blockIdx.x * 64 + w * 16;
  const _Float16* ap = ln + (size_t)(row0 + lo) * 800 + 8 * hi;
  const _Float16* bp = hwh + (size_t)lo * 800 + 8 * hi;
  f32x4 acc = {};
  #pragma unroll 5
  for (int k = 0; k < 800; k += 32) {
    half8 a = *reinterpret_cast<const half8*>(ap + k);
    half8 b = *reinterpret_cast<const half8*>(bp + k);
    acc = __builtin_amdgcn_mfma_f32_16x16x32_f16(a, b, acc, 0, 0, 0);
  }
  float bv = hb[lo];
  #pragma unroll
  for (int r = 0; r < 4; ++r) {
    int row = row0 + hi * 4 + r;
    out[(size_t)row * 16 + lo] = 1.f / (1.f + expf(-(acc[r] + bv)));
  }
}

// ---------------- launcher ----------------
extern "C" void kernel_launch(void* const* d_in, const int* in_sizes, int n_in,
                              void* d_out, int out_size, void* d_ws, size_t ws_size,
                              hipStream_t stream) {
  (void)in_sizes; (void)n_in; (void)out_size; (void)ws_size;
  const float* x     = (const float*)d_in[0];
  const float* w0    = (const float*)d_in[1];
  const float* b0    = (const float*)d_in[2];
  const float* g0    = (const float*)d_in[3];
  const float* be0   = (const float*)d_in[4];
  const float* mu0   = (const float*)d_in[5];
  const float* var0  = (const float*)d_in[6];
  const float* w1    = (const float*)d_in[7];
  const float* b1    = (const float*)d_in[8];
  const float* g1    = (const float*)d_in[9];
  const float* be1   = (const float*)d_in[10];
  const float* mu1   = (const float*)d_in[11];
  const float* var1  = (const float*)d_in[12];
  const float* w2c   = (const float*)d_in[13];
  const float* b2    = (const float*)d_in[14];
  const float* g2    = (const float*)d_in[15];
  const float* be2   = (const float*)d_in[16];
  const float* mu2   = (const float*)d_in[17];
  const float* var2  = (const float*)d_in[18];
  const float* w3    = (const float*)d_in[19];
  const float* b3    = (const float*)d_in[20];
  const float* g3    = (const float*)d_in[21];
  const float* be3   = (const float*)d_in[22];
  const float* mu3   = (const float*)d_in[23];
  const float* var3  = (const float*)d_in[24];
  const float* qkvw  = (const float*)d_in[25];
  const float* outw  = (const float*)d_in[26];
  const float* outbv = (const float*)d_in[27];
  const float* resw  = (const float*)d_in[28];
  const float* lng   = (const float*)d_in[29];
  const float* lnbv  = (const float*)d_in[30];
  const float* headw = (const float*)d_in[31];
  const float* headb = (const float*)d_in[32];

  char* wsb = (char*)d_ws;
  _Float16* h0   = (_Float16*)(wsb + B_H0);
  _Float16* h1   = (_Float16*)(wsb + B_H1);
  _Float16* h2   = (_Float16*)(wsb + B_H2);
  _Float16* qb   = (_Float16*)(wsb + B_Q);
  _Float16* kb   = (_Float16*)(wsb + B_K);
  _Float16* vb   = (_Float16*)(wsb + B_V);
  _Float16* kT   = (_Float16*)(wsb + B_KT);
  _Float16* tok  = (_Float16*)(wsb + B_TOK);
  _Float16* attb = (_Float16*)(wsb + B_ATT);
  _Float16* wp1  = (_Float16*)(wsb + B_WP1);
  _Float16* wp2  = (_Float16*)(wsb + B_WP2);
  _Float16* wp3  = (_Float16*)(wsb + B_WP3);
  _Float16* qkvT = (_Float16*)(wsb + B_QKVT);
  _Float16* owT  = (_Float16*)(wsb + B_OWT);
  _Float16* klh  = (_Float16*)(wsb + B_KLH);
  _Float16* w2t  = (_Float16*)(wsb + B_W2T);
  _Float16* hwh  = (_Float16*)(wsb + B_HWH);
  _Float16* lnb16 = (_Float16*)(wsb + B_LNB);
  float* ql   = (float*)(wsb + B_QL);
  float* kl   = (float*)(wsb + B_KL);
  float* a2   = (float*)(wsb + B_A2);
  float* pv   = (float*)(wsb + B_PV);
  float* a3v  = (float*)(wsb + B_A3V);
  float* scal = (float*)(wsb + B_SCAL);

  // weight packing + scal init
  k_pack_w<<<(128 * 64 * 9 + 255) / 256, 256, 0, stream>>>(w1, wp1, 128, 64, 9);
  k_pack_w<<<(256 * 128 * 9 + 255) / 256, 256, 0, stream>>>(w2c, wp2, 256, 128, 9);
  k_pack_w<<<(800 * 256 * 16 + 255) / 256, 256, 0, stream>>>(w3, wp3, 800, 256, 16);
  k_pack_t<<<(800 * 1536 + 255) / 256, 256, 0, stream>>>(qkvw, qkvT, 800, 1536);
  k_pack_t<<<(512 * 800 + 255) / 256, 256, 0, stream>>>(outw, owT, 512, 800);
  k_pack_t<<<(800 * 16 + 255) / 256, 256, 0, stream>>>(headw, hwh, 800, 16);
  k_init<<<1, 64, 0, stream>>>(scal);

  // conv stack: conv0..conv2 per image (h0/h1 scratch), h2 kept full-batch
  for (int img = 0; img < 4; ++img) {
    k_conv0<<<dim3(256), 256, 0, stream>>>(
        x + (size_t)img * 65536, w0, b0, g0, be0, mu0, var0, h0);
    k_convs<64><<<dim3(512), 256, 0, stream>>>(
        h0, wp1, b1, g1, be1, mu1, var1, h1, 128, 1);
    k_convs<128><<<dim3(1024), 256, 0, stream>>>(
        h1, wp2, b2, g2, be2, mu2, var2, h2 + (size_t)img * 16777216, 256, 2);
  }
  // conv3 (patch conv) over the full batch: staged GEMM, 640 XCD-swizzled blocks
  k_c3<<<dim3(640), 256, 0, stream>>>(h2, wp3, b3, g3, be3, mu3, var3, tok);
  // attention
  k_qkv_s<<<dim3(1536), 256, 0, stream>>>(tok, qkvT, qb, kb, vb);
  k_transpose<<<dim3(64, 32), 256, 0, stream>>>(kb, kT);
  k_landmark<<<dim3(64, 32), 64, 0, stream>>>(qb, kb, ql, kl, klh);
  k_a2<<<dim3(32), 64, 0, stream>>>(ql, kl, a2, scal);
  k_a3v<<<dim3(64, 32), 256, 0, stream>>>(ql, kT, vb, a3v);
  k_pinv<<<dim3(32), 256, 0, stream>>>(a2, scal, pv);
  k_w2<<<dim3(32), 256, 0, stream>>>(pv, a3v, w2t);
  k_combine_m<<<dim3(64, 8, 4), 256, 0, stream>>>(qb, klh, w2t, vb, resw, attb);
  // projection + LN + head
  k_op_s<<<dim3(640), 256, 0, stream>>>(attb, owT, outbv, lnb16);
  k_ln16<<<dim3(16384), 256, 0, stream>>>(lnb16, lng, lnbv);
  k_head_m<<<dim3(256), 256, 0, stream>>>(lnb16, hwh, headb, (float*)d_out);
}

// Round 9
// 1153.034 us; speedup vs baseline: 9.9948x; 1.0079x over previous
//
#include <hip/hip_runtime.h>

#define DI __device__ __forceinline__

constexpr float BN_EPS_C = 1e-5f;
constexpr float LN_EPS_C = 1e-5f;

typedef _Float16 half8 __attribute__((ext_vector_type(8)));
typedef float f32x4 __attribute__((ext_vector_type(4)));

// ---------------- workspace layout (BYTE offsets), peak ~199.34 MB ----------------
constexpr size_t B_H0   = 0;             // f16 [256][256][64]  per-image scratch
constexpr size_t B_H1   = 8388608;       // f16 [256][256][128] per-image scratch
constexpr size_t B_H2   = 25165824;      // f16 [4][256][256][256] = 134,217,728 (full batch)
// overlays inside the h2 region once h2 is dead (after k_c3):
constexpr size_t B_Q    = 25165824;      // f16 [32][4096][64] = 16,777,216
constexpr size_t B_V    = 58720256;      // f16 16,777,216
constexpr size_t B_KT   = 75497472;      // f16 [32][64][4096] = 16,777,216
constexpr size_t B_ATT  = 92274688;      // f16 [16384][512] = 16,777,216
constexpr size_t B_LNB  = 25165824;      // f16 [16384][800] = 26,214,400 (q dead by outproj)
// tok + packed weights + small buffers:
constexpr size_t B_TOK  = 159383552;     // f16 [16384][800] = 26,214,400
constexpr size_t B_WP1  = 185597952;     // 147,456
constexpr size_t B_WP2  = 185745408;     // 589,824
constexpr size_t B_WP3  = 186335232;     // 6,553,600
constexpr size_t B_QKVT = 192888832;     // 2,457,600
constexpr size_t B_OWT  = 195346432;     // 819,200
constexpr size_t B_QL   = 196165632;     // f32 524,288
constexpr size_t B_KL   = 196689920;
constexpr size_t B_KLH  = 197214208;     // f16 262,144
constexpr size_t B_A2   = 197476352;
constexpr size_t B_W2T  = 198524928;     // f16 262,144
constexpr size_t B_A3V  = 198787072;
constexpr size_t B_SCAL = 199311360;     // 2 floats
constexpr size_t B_HWH  = 199311424;     // f16 [16][800] = 25,600 (end 199,337,024)

// ---------------- helpers ----------------
DI float blockReduceSum(float v) {
  #pragma unroll
  for (int o = 32; o; o >>= 1) v += __shfl_xor(v, o);
  __shared__ float red[4];
  int w = threadIdx.x >> 6;
  __syncthreads();
  if ((threadIdx.x & 63) == 0) red[w] = v;
  __syncthreads();
  return red[0] + red[1] + red[2] + red[3];
}

template <int LP, int RP>
DI void mm16(const float* L, const float* R, int r0, int c0, float reg[4][4]) {
  #pragma unroll
  for (int i = 0; i < 4; ++i)
    #pragma unroll
    for (int j = 0; j < 4; ++j) reg[i][j] = 0.f;
  for (int dd = 0; dd < 64; ++dd) {
    float l[4], r[4];
    #pragma unroll
    for (int i = 0; i < 4; ++i) l[i] = L[(size_t)(r0 + i) * LP + dd];
    #pragma unroll
    for (int j = 0; j < 4; ++j) r[j] = R[(size_t)dd * RP + c0 + j];
    #pragma unroll
    for (int i = 0; i < 4; ++i)
      #pragma unroll
      for (int j = 0; j < 4; ++j) reg[i][j] = fmaf(l[i], r[j], reg[i][j]);
  }
}

// ---------------- mega-pack: all weight packs + scal init in one launch ----------------
// seg sizes: wp1 73728 | wp2 294912 | wp3 3276800 | qkvT 1228800 | owT 409600 | hwh 12800 | scal 2
__global__ void k_pack_all(
    const float* __restrict__ w1, const float* __restrict__ w2c, const float* __restrict__ w3,
    const float* __restrict__ qkvw, const float* __restrict__ outw, const float* __restrict__ headw,
    _Float16* __restrict__ wp1, _Float16* __restrict__ wp2, _Float16* __restrict__ wp3,
    _Float16* __restrict__ qkvT, _Float16* __restrict__ owT, _Float16* __restrict__ hwh,
    float* __restrict__ scal) {
  size_t i = (size_t)blockIdx.x * 256 + threadIdx.x;
  if (i < 73728) {
    int q = i % 9, ci = (i / 9) % 64, co = i / (9 * 64);
    wp1[((size_t)co * 9 + q) * 64 + ci] = (_Float16)w1[i];
  } else if (i < 368640) {
    size_t j = i - 73728;
    int q = j % 9, ci = (j / 9) % 128, co = j / (9 * 128);
    wp2[((size_t)co * 9 + q) * 128 + ci] = (_Float16)w2c[j];
  } else if (i < 3645440) {
    size_t j = i - 368640;
    int q = j % 16, ci = (j / 16) % 256, co = j / (16 * 256);
    wp3[((size_t)co * 16 + q) * 256 + ci] = (_Float16)w3[j];
  } else if (i < 4874240) {
    size_t j = i - 3645440;
    int n = j % 1536, k = j / 1536;
    qkvT[(size_t)n * 800 + k] = (_Float16)qkvw[j];
  } else if (i < 5283840) {
    size_t j = i - 4874240;
    int n = j % 800, k = j / 800;
    owT[(size_t)n * 512 + k] = (_Float16)outw[j];
  } else if (i < 5296640) {
    size_t j = i - 5283840;
    int n = j % 16, k = j / 16;
    hwh[(size_t)n * 800 + k] = (_Float16)headw[j];
  } else if (i < 5296642) {
    scal[i - 5296640] = 0.f;
  }
}

// ---------------- conv0: CI=1 fp32 direct conv -> h0 NHWC f16 ----------------
__global__ __launch_bounds__(256) void k_conv0(
    const float* __restrict__ xb, const float* __restrict__ w0, const float* __restrict__ b0,
    const float* __restrict__ g0, const float* __restrict__ be0, const float* __restrict__ mu0,
    const float* __restrict__ var0, _Float16* __restrict__ h0) {
  const int t = threadIdx.x, co = t & 63, xg = t >> 6;
  const int y = blockIdx.x;
  float wreg[9];
  #pragma unroll
  for (int q = 0; q < 9; ++q) wreg[q] = w0[co * 9 + q];
  float s = g0[co] * rsqrtf(var0[co] + BN_EPS_C);
  float sh = fmaf(b0[co] - mu0[co], s, be0[co]);
  for (int xl = 0; xl < 64; ++xl) {
    int xx = xg * 64 + xl;
    float acc = 0.f;
    #pragma unroll
    for (int dy = 0; dy < 3; ++dy) {
      int yy = y + dy - 1;
      if ((unsigned)yy >= 256u) continue;
      #pragma unroll
      for (int dx = 0; dx < 3; ++dx) {
        int xi = xx + dx - 1;
        if ((unsigned)xi >= 256u) continue;
        acc = fmaf(wreg[dy * 3 + dx], xb[yy * 256 + xi], acc);
      }
    }
    float v = fmaxf(fmaf(acc, s, sh), 0.f);
    h0[((size_t)y * 256 + xx) * 64 + co] = (_Float16)v;
  }
}

// ------- staged implicit-im2col 3x3 conv GEMM: tile 128x128 ---------------
template <int CI>
__global__ __launch_bounds__(256) void k_convs(
    const _Float16* __restrict__ in, const _Float16* __restrict__ wp,
    const float* __restrict__ bias, const float* __restrict__ g, const float* __restrict__ be,
    const float* __restrict__ mu, const float* __restrict__ var,
    _Float16* __restrict__ out, int CO, int NCT) {
  __shared__ _Float16 Ab[2][128 * 40];
  __shared__ _Float16 Bb[2][128 * 40];
  constexpr int CPQ = CI / 32;
  constexpr int NCK = 9 * CPQ;
  const int t = threadIdx.x;
  const int bid = blockIdx.x;
  const int xcd = bid & 7, slot = bid >> 3;
  const int pj = slot / NCT, cc = slot % NCT;
  const int p = pj * 8 + xcd;
  const int r0 = p * 128, c0 = cc * 128;

  const int ma = t >> 2, kga = t & 3;
  int ry[2], rx[2];
  #pragma unroll
  for (int s = 0; s < 2; ++s) {
    int r = r0 + ma + s * 64;
    ry[s] = r >> 8;
    rx[s] = r & 255;
  }
  const _Float16* baseB[2];
  #pragma unroll
  for (int s = 0; s < 2; ++s)
    baseB[s] = wp + (size_t)(c0 + ma + s * 64) * 9 * CI + kga * 8;
  const int wo = ma * 40 + kga * 8;

  auto loadA = [&](int s, int ck) -> half8 {
    int q = ck / CPQ, coff = (ck % CPQ) * 32;
    int yy = ry[s] + q / 3 - 1;
    int xx = rx[s] + q % 3 - 1;
    half8 a = {};
    if ((unsigned)yy < 256u && (unsigned)xx < 256u)
      a = *reinterpret_cast<const half8*>(in + ((size_t)yy * 256 + xx) * CI + coff + kga * 8);
    return a;
  };

  {
    half8 a0 = loadA(0, 0), a1 = loadA(1, 0);
    half8 b0v = *reinterpret_cast<const half8*>(baseB[0]);
    half8 b1v = *reinterpret_cast<const half8*>(baseB[1]);
    *reinterpret_cast<half8*>(&Ab[0][wo]) = a0;
    *reinterpret_cast<half8*>(&Ab[0][wo + 2560]) = a1;
    *reinterpret_cast<half8*>(&Bb[0][wo]) = b0v;
    *reinterpret_cast<half8*>(&Bb[0][wo + 2560]) = b1v;
  }
  __syncthreads();

  const int w = t >> 6, lo = t & 15, hi = (t >> 4) & 3;
  const int wm = w >> 1, wn = w & 1;
  const int roA = (wm * 64 + lo) * 40 + 8 * hi;
  const int roB = (wn * 64 + lo) * 40 + 8 * hi;
  f32x4 acc[4][4] = {};

  for (int ck = 0; ck < NCK; ++ck) {
    const int cur = ck & 1;
    const bool more = (ck + 1 < NCK);
    half8 rA0, rA1, rB0, rB1;
    if (more) {
      rA0 = loadA(0, ck + 1);
      rA1 = loadA(1, ck + 1);
      rB0 = *reinterpret_cast<const half8*>(baseB[0] + (ck + 1) * 32);
      rB1 = *reinterpret_cast<const half8*>(baseB[1] + (ck + 1) * 32);
    }
    half8 af[4], bf[4];
    #pragma unroll
    for (int mi = 0; mi < 4; ++mi)
      af[mi] = *reinterpret_cast<const half8*>(&Ab[cur][roA + mi * 640]);
    #pragma unroll
    for (int ni = 0; ni < 4; ++ni)
      bf[ni] = *reinterpret_cast<const half8*>(&Bb[cur][roB + ni * 640]);
    #pragma unroll
    for (int mi = 0; mi < 4; ++mi)
      #pragma unroll
      for (int ni = 0; ni < 4; ++ni)
        acc[mi][ni] = __builtin_amdgcn_mfma_f32_16x16x32_f16(af[mi], bf[ni], acc[mi][ni], 0, 0, 0);
    if (more) {
      *reinterpret_cast<half8*>(&Ab[cur ^ 1][wo]) = rA0;
      *reinterpret_cast<half8*>(&Ab[cur ^ 1][wo + 2560]) = rA1;
      *reinterpret_cast<half8*>(&Bb[cur ^ 1][wo]) = rB0;
      *reinterpret_cast<half8*>(&Bb[cur ^ 1][wo + 2560]) = rB1;
    }
    __syncthreads();
  }

  #pragma unroll
  for (int ni = 0; ni < 4; ++ni) {
    int co = c0 + wn * 64 + ni * 16 + lo;
    float s = g[co] * rsqrtf(var[co] + BN_EPS_C);
    float sh = fmaf(bias[co] - mu[co], s, be[co]);
    #pragma unroll
    for (int mi = 0; mi < 4; ++mi)
      #pragma unroll
      for (int rr = 0; rr < 4; ++rr) {
        int row = r0 + wm * 64 + mi * 16 + hi * 4 + rr;
        float v = fmaxf(fmaf(acc[mi][ni][rr], s, sh), 0.f);
        out[(size_t)row * CO + co] = (_Float16)v;
      }
  }
}

// ---------------- conv3 MFMA: staged GEMM, 128x160 tile, XCD-swizzled ----------
__global__ __launch_bounds__(256) void k_c3(
    const _Float16* __restrict__ h2, const _Float16* __restrict__ wp3,
    const float* __restrict__ b3, const float* __restrict__ g3, const float* __restrict__ be3,
    const float* __restrict__ mu3, const float* __restrict__ var3,
    _Float16* __restrict__ tok) {
  __shared__ _Float16 Abuf[2][128 * 40];
  __shared__ _Float16 Bbuf[2][160 * 40];
  const int t = threadIdx.x;
  const int bid = blockIdx.x;
  const int xcd = bid & 7, slot = bid >> 3;
  const int pj = slot / 5, cc = slot % 5;
  const int p = pj * 8 + xcd;
  const int r0 = p * 128, c0 = cc * 160;
  const int img = r0 >> 12;
  const _Float16* h2i = h2 + (size_t)img * 16777216;

  const int ma = t >> 2, kga = t & 3;
  const _Float16* baseA[2];
  #pragma unroll
  for (int s = 0; s < 2; ++s) {
    int m = ma + s * 64;
    int r = r0 + m;
    int py = (r & 4095) >> 6, px = r & 63;
    baseA[s] = h2i + ((size_t)py * 1024 + px * 4) * 256 + kga * 8;
  }
  const _Float16* baseB[3];
  #pragma unroll
  for (int s = 0; s < 3; ++s) {
    int cb = ma + s * 64;
    baseB[s] = wp3 + (size_t)(c0 + (cb < 160 ? cb : 159)) * 4096 + kga * 8;
  }
  const int wo = ma * 40 + kga * 8;

  const int w = t >> 6, lo = t & 15, hi = (t >> 4) & 3;
  const int wm = w >> 1, wn = w & 1;
  const int roA = (wm * 64 + lo) * 40 + 8 * hi;
  const int roB = (wn * 80 + lo) * 40 + 8 * hi;

  f32x4 acc[4][5] = {};

  {
    half8 a0 = *reinterpret_cast<const half8*>(baseA[0]);
    half8 a1 = *reinterpret_cast<const half8*>(baseA[1]);
    half8 b0v = *reinterpret_cast<const half8*>(baseB[0]);
    half8 b1v = *reinterpret_cast<const half8*>(baseB[1]);
    *reinterpret_cast<half8*>(&Abuf[0][wo]) = a0;
    *reinterpret_cast<half8*>(&Abuf[0][wo + 2560]) = a1;
    *reinterpret_cast<half8*>(&Bbuf[0][wo]) = b0v;
    *reinterpret_cast<half8*>(&Bbuf[0][wo + 2560]) = b1v;
    if (t < 128) {
      half8 b2v = *reinterpret_cast<const half8*>(baseB[2]);
      *reinterpret_cast<half8*>(&Bbuf[0][wo + 5120]) = b2v;
    }
  }
  __syncthreads();

  for (int ck = 0; ck < 128; ++ck) {
    const int cur = ck & 1;
    const bool more = (ck + 1 < 128);
    half8 rA0, rA1, rB0, rB1, rB2;
    if (more) {
      const int kn = (ck + 1) << 5;
      const int q = kn >> 8, qk = kn & 255;
      const int aoff = (q >> 2) * 65536 + (q & 3) * 256 + qk;
      rA0 = *reinterpret_cast<const half8*>(baseA[0] + aoff);
      rA1 = *reinterpret_cast<const half8*>(baseA[1] + aoff);
      rB0 = *reinterpret_cast<const half8*>(baseB[0] + kn);
      rB1 = *reinterpret_cast<const half8*>(baseB[1] + kn);
      if (t < 128) rB2 = *reinterpret_cast<const half8*>(baseB[2] + kn);
    }
    half8 af[4], bf[5];
    #pragma unroll
    for (int mi = 0; mi < 4; ++mi)
      af[mi] = *reinterpret_cast<const half8*>(&Abuf[cur][roA + mi * 640]);
    #pragma unroll
    for (int ni = 0; ni < 5; ++ni)
      bf[ni] = *reinterpret_cast<const half8*>(&Bbuf[cur][roB + ni * 640]);
    #pragma unroll
    for (int mi = 0; mi < 4; ++mi)
      #pragma unroll
      for (int ni = 0; ni < 5; ++ni)
        acc[mi][ni] = __builtin_amdgcn_mfma_f32_16x16x32_f16(af[mi], bf[ni], acc[mi][ni], 0, 0, 0);
    if (more) {
      *reinterpret_cast<half8*>(&Abuf[cur ^ 1][wo]) = rA0;
      *reinterpret_cast<half8*>(&Abuf[cur ^ 1][wo + 2560]) = rA1;
      *reinterpret_cast<half8*>(&Bbuf[cur ^ 1][wo]) = rB0;
      *reinterpret_cast<half8*>(&Bbuf[cur ^ 1][wo + 2560]) = rB1;
      if (t < 128) *reinterpret_cast<half8*>(&Bbuf[cur ^ 1][wo + 5120]) = rB2;
    }
    __syncthreads();
  }

  #pragma unroll
  for (int ni = 0; ni < 5; ++ni) {
    int col = c0 + wn * 80 + ni * 16 + lo;
    float s = g3[col] * rsqrtf(var3[col] + BN_EPS_C);
    float sh = fmaf(b3[col] - mu3[col], s, be3[col]);
    #pragma unroll
    for (int mi = 0; mi < 4; ++mi)
      #pragma unroll
      for (int rr = 0; rr < 4; ++rr) {
        int row = r0 + wm * 64 + mi * 16 + hi * 4 + rr;
        float v = fmaxf(fmaf(acc[mi][ni][rr], s, sh), 0.f);
        tok[(size_t)row * 800 + col] = (_Float16)v;
      }
  }
}

// ---------------- qkv staged GEMM: writes q, v in [bh][n][d]; k directly as kT [bh][d][n] --
__global__ __launch_bounds__(256) void k_qkv_s(
    const _Float16* __restrict__ tok, const _Float16* __restrict__ qkvT,
    _Float16* __restrict__ qx, _Float16* __restrict__ kTg, _Float16* __restrict__ vx) {
  __shared__ _Float16 Ab[2][128 * 40];
  __shared__ _Float16 Bb[2][128 * 40];
  const int t = threadIdx.x;
  const int bid = blockIdx.x;
  const int xcd = bid & 7, slot = bid >> 3;
  const int pj = slot / 12, cc = slot % 12;
  const int p = pj * 8 + xcd;
  const int r0 = p * 128, c0 = cc * 128;

  const int ma = t >> 2, kga = t & 3;
  const _Float16* baseA[2];
  const _Float16* baseB[2];
  #pragma unroll
  for (int s = 0; s < 2; ++s) {
    baseA[s] = tok + (size_t)(r0 + ma + s * 64) * 800 + kga * 8;
    baseB[s] = qkvT + (size_t)(c0 + ma + s * 64) * 800 + kga * 8;
  }
  const int wo = ma * 40 + kga * 8;

  {
    half8 a0 = *reinterpret_cast<const half8*>(baseA[0]);
    half8 a1 = *reinterpret_cast<const half8*>(baseA[1]);
    half8 b0v = *reinterpret_cast<const half8*>(baseB[0]);
    half8 b1v = *reinterpret_cast<const half8*>(baseB[1]);
    *reinterpret_cast<half8*>(&Ab[0][wo]) = a0;
    *reinterpret_cast<half8*>(&Ab[0][wo + 2560]) = a1;
    *reinterpret_cast<half8*>(&Bb[0][wo]) = b0v;
    *reinterpret_cast<half8*>(&Bb[0][wo + 2560]) = b1v;
  }
  __syncthreads();

  const int w = t >> 6, lo = t & 15, hi = (t >> 4) & 3;
  const int wm = w >> 1, wn = w & 1;
  const int roA = (wm * 64 + lo) * 40 + 8 * hi;
  const int roB = (wn * 64 + lo) * 40 + 8 * hi;
  f32x4 acc[4][4] = {};

  for (int ck = 0; ck < 25; ++ck) {
    const int cur = ck & 1;
    const bool more = (ck + 1 < 25);
    half8 rA0, rA1, rB0, rB1;
    if (more) {
      const int kn = (ck + 1) * 32;
      rA0 = *reinterpret_cast<const half8*>(baseA[0] + kn);
      rA1 = *reinterpret_cast<const half8*>(baseA[1] + kn);
      rB0 = *reinterpret_cast<const half8*>(baseB[0] + kn);
      rB1 = *reinterpret_cast<const half8*>(baseB[1] + kn);
    }
    half8 af[4], bf[4];
    #pragma unroll
    for (int mi = 0; mi < 4; ++mi)
      af[mi] = *reinterpret_cast<const half8*>(&Ab[cur][roA + mi * 640]);
    #pragma unroll
    for (int ni = 0; ni < 4; ++ni)
      bf[ni] = *reinterpret_cast<const half8*>(&Bb[cur][roB + ni * 640]);
    #pragma unroll
    for (int mi = 0; mi < 4; ++mi)
      #pragma unroll
      for (int ni = 0; ni < 4; ++ni)
        acc[mi][ni] = __builtin_amdgcn_mfma_f32_16x16x32_f16(af[mi], bf[ni], acc[mi][ni], 0, 0, 0);
    if (more) {
      *reinterpret_cast<half8*>(&Ab[cur ^ 1][wo]) = rA0;
      *reinterpret_cast<half8*>(&Ab[cur ^ 1][wo + 2560]) = rA1;
      *reinterpret_cast<half8*>(&Bb[cur ^ 1][wo]) = rB0;
      *reinterpret_cast<half8*>(&Bb[cur ^ 1][wo + 2560]) = rB1;
    }
    __syncthreads();
  }

  const int seg = cc >> 2;
  if (seg == 1) {
    // k: write transposed layout kT[bh][d][n] directly
    #pragma unroll
    for (int ni = 0; ni < 4; ++ni) {
      int cseg = (cc & 3) * 128 + wn * 64 + ni * 16 + lo;
      int h = cseg >> 6, d = cseg & 63;
      #pragma unroll
      for (int mi = 0; mi < 4; ++mi)
        #pragma unroll
        for (int rr = 0; rr < 4; ++rr) {
          int row = r0 + wm * 64 + mi * 16 + hi * 4 + rr;
          int b = row >> 12, nn = row & 4095;
          kTg[((size_t)(b * 8 + h) * 64 + d) * 4096 + nn] = (_Float16)acc[mi][ni][rr];
        }
    }
  } else {
    const float scale = (seg == 0) ? 0.125f : 1.0f;
    _Float16* dst = (seg == 0) ? qx : vx;
    #pragma unroll
    for (int ni = 0; ni < 4; ++ni) {
      int cseg = (cc & 3) * 128 + wn * 64 + ni * 16 + lo;
      int h = cseg >> 6, d = cseg & 63;
      #pragma unroll
      for (int mi = 0; mi < 4; ++mi)
        #pragma unroll
        for (int rr = 0; rr < 4; ++rr) {
          int row = r0 + wm * 64 + mi * 16 + hi * 4 + rr;
          int b = row >> 12, nn = row & 4095;
          dst[((size_t)(b * 8 + h) * 4096 + nn) * 64 + d] = (_Float16)(acc[mi][ni][rr] * scale);
        }
    }
  }
}

// ---------------- out-proj staged GEMM: M=16384, N=800 (5x160), K=512 -> f16 lnb ---------
__global__ __launch_bounds__(256) void k_op_s(
    const _Float16* __restrict__ attb, const _Float16* __restrict__ owT,
    const float* __restrict__ ob, _Float16* __restrict__ lnb) {
  __shared__ _Float16 Abuf[2][128 * 40];
  __shared__ _Float16 Bbuf[2][160 * 40];
  const int t = threadIdx.x;
  const int bid = blockIdx.x;
  const int xcd = bid & 7, slot = bid >> 3;
  const int pj = slot / 5, cc = slot % 5;
  const int p = pj * 8 + xcd;
  const int r0 = p * 128, c0 = cc * 160;

  const int ma = t >> 2, kga = t & 3;
  const _Float16* baseA[2];
  #pragma unroll
  for (int s = 0; s < 2; ++s)
    baseA[s] = attb + (size_t)(r0 + ma + s * 64) * 512 + kga * 8;
  const _Float16* baseB[3];
  #pragma unroll
  for (int s = 0; s < 3; ++s) {
    int cb = ma + s * 64;
    baseB[s] = owT + (size_t)(c0 + (cb < 160 ? cb : 159)) * 512 + kga * 8;
  }
  const int wo = ma * 40 + kga * 8;

  const int w = t >> 6, lo = t & 15, hi = (t >> 4) & 3;
  const int wm = w >> 1, wn = w & 1;
  const int roA = (wm * 64 + lo) * 40 + 8 * hi;
  const int roB = (wn * 80 + lo) * 40 + 8 * hi;

  f32x4 acc[4][5] = {};

  {
    half8 a0 = *reinterpret_cast<const half8*>(baseA[0]);
    half8 a1 = *reinterpret_cast<const half8*>(baseA[1]);
    half8 b0v = *reinterpret_cast<const half8*>(baseB[0]);
    half8 b1v = *reinterpret_cast<const half8*>(baseB[1]);
    *reinterpret_cast<half8*>(&Abuf[0][wo]) = a0;
    *reinterpret_cast<half8*>(&Abuf[0][wo + 2560]) = a1;
    *reinterpret_cast<half8*>(&Bbuf[0][wo]) = b0v;
    *reinterpret_cast<half8*>(&Bbuf[0][wo + 2560]) = b1v;
    if (t < 128) {
      half8 b2v = *reinterpret_cast<const half8*>(baseB[2]);
      *reinterpret_cast<half8*>(&Bbuf[0][wo + 5120]) = b2v;
    }
  }
  __syncthreads();

  for (int ck = 0; ck < 16; ++ck) {
    const int cur = ck & 1;
    const bool more = (ck + 1 < 16);
    half8 rA0, rA1, rB0, rB1, rB2;
    if (more) {
      const int kn = (ck + 1) << 5;
      rA0 = *reinterpret_cast<const half8*>(baseA[0] + kn);
      rA1 = *reinterpret_cast<const half8*>(baseA[1] + kn);
      rB0 = *reinterpret_cast<const half8*>(baseB[0] + kn);
      rB1 = *reinterpret_cast<const half8*>(baseB[1] + kn);
      if (t < 128) rB2 = *reinterpret_cast<const half8*>(baseB[2] + kn);
    }
    half8 af[4], bf[5];
    #pragma unroll
    for (int mi = 0; mi < 4; ++mi)
      af[mi] = *reinterpret_cast<const half8*>(&Abuf[cur][roA + mi * 640]);
    #pragma unroll
    for (int ni = 0; ni < 5; ++ni)
      bf[ni] = *reinterpret_cast<const half8*>(&Bbuf[cur][roB + ni * 640]);
    #pragma unroll
    for (int mi = 0; mi < 4; ++mi)
      #pragma unroll
      for (int ni = 0; ni < 5; ++ni)
        acc[mi][ni] = __builtin_amdgcn_mfma_f32_16x16x32_f16(af[mi], bf[ni], acc[mi][ni], 0, 0, 0);
    if (more) {
      *reinterpret_cast<half8*>(&Abuf[cur ^ 1][wo]) = rA0;
      *reinterpret_cast<half8*>(&Abuf[cur ^ 1][wo + 2560]) = rA1;
      *reinterpret_cast<half8*>(&Bbuf[cur ^ 1][wo]) = rB0;
      *reinterpret_cast<half8*>(&Bbuf[cur ^ 1][wo + 2560]) = rB1;
      if (t < 128) *reinterpret_cast<half8*>(&Bbuf[cur ^ 1][wo + 5120]) = rB2;
    }
    __syncthreads();
  }

  #pragma unroll
  for (int ni = 0; ni < 5; ++ni) {
    int col = c0 + wn * 80 + ni * 16 + lo;
    float bv = ob[col];
    #pragma unroll
    for (int mi = 0; mi < 4; ++mi)
      #pragma unroll
      for (int rr = 0; rr < 4; ++rr) {
        int row = r0 + wm * 64 + mi * 16 + hi * 4 + rr;
        lnb[(size_t)row * 800 + col] = (_Float16)(acc[mi][ni][rr] + bv);
      }
  }
}

// ---------------- landmarks (q strided, k from kT contiguous) ----------------
__global__ __launch_bounds__(64) void k_landmark(
    const _Float16* __restrict__ qx, const _Float16* __restrict__ kT,
    float* __restrict__ ql, float* __restrict__ kl, _Float16* __restrict__ klh) {
  const int d = threadIdx.x;
  const int m = blockIdx.x, bh = blockIdx.y;
  const _Float16* qp = qx + ((size_t)bh * 4096 + m * 64) * 64 + d;
  const _Float16* kp = kT + ((size_t)bh * 64 + d) * 4096 + m * 64;
  float sq = 0.f, sk = 0.f;
  #pragma unroll 8
  for (int j = 0; j < 64; ++j) sq += (float)qp[(size_t)j * 64];
  #pragma unroll
  for (int j = 0; j < 64; j += 8) {
    half8 kv = *reinterpret_cast<const half8*>(kp + j);
    #pragma unroll
    for (int u = 0; u < 8; ++u) sk += (float)kv[u];
  }
  sq *= (1.f / 64.f);
  sk *= (1.f / 64.f);
  ql[((size_t)bh * 64 + m) * 64 + d] = sq;
  kl[((size_t)bh * 64 + m) * 64 + d] = sk;
  klh[((size_t)bh * 64 + m) * 64 + d] = (_Float16)sk;
}

// ---------------- a2 + global max row/col sums ----------------
__global__ __launch_bounds__(64) void k_a2(
    const float* __restrict__ ql, const float* __restrict__ kl,
    float* __restrict__ a2, float* __restrict__ scal) {
  __shared__ float sp[64 * 65];
  const int bh = blockIdx.x, t = threadIdx.x;
  const float* qr = ql + ((size_t)bh * 64 + t) * 64;
  const float* kb = kl + (size_t)bh * 4096;
  float mx = -1e30f;
  for (int c = 0; c < 64; ++c) {
    float acc = 0.f;
    #pragma unroll 8
    for (int dd = 0; dd < 64; ++dd) acc = fmaf(qr[dd], kb[c * 64 + dd], acc);
    sp[t * 65 + c] = acc;
    mx = fmaxf(mx, acc);
  }
  float sum = 0.f;
  for (int c = 0; c < 64; ++c) {
    float e = expf(sp[t * 65 + c] - mx);
    sp[t * 65 + c] = e;
    sum += e;
  }
  float inv = 1.f / sum;
  float rs = 0.f;
  for (int c = 0; c < 64; ++c) {
    float p = sp[t * 65 + c] * inv;
    sp[t * 65 + c] = p;
    a2[(size_t)bh * 4096 + t * 64 + c] = p;
    rs += p;
  }
  atomicMax(reinterpret_cast<int*>(scal), __float_as_int(rs));
  __syncthreads();
  float cs = 0.f;
  for (int r = 0; r < 64; ++r) cs += sp[r * 65 + t];
  atomicMax(reinterpret_cast<int*>(scal) + 1, __float_as_int(cs));
}

// ---------------- fused a3 softmax + a3@v ----------------
__global__ __launch_bounds__(256) void k_a3v(
    const float* __restrict__ ql, const _Float16* __restrict__ kT,
    const _Float16* __restrict__ vx, float* __restrict__ a3v) {
  __shared__ float sq[64];
  __shared__ float sP[4096];
  __shared__ float red[4];
  __shared__ float red2[4][64];
  const int t = threadIdx.x;
  const int m = blockIdx.x, bh = blockIdx.y;
  if (t < 64) sq[t] = ql[((size_t)bh * 64 + m) * 64 + t];
  __syncthreads();
  const _Float16* kb = kT + (size_t)bh * 262144;
  float sc[16];
  #pragma unroll
  for (int i = 0; i < 16; ++i) sc[i] = 0.f;
  for (int dd = 0; dd < 64; ++dd) {
    float qv = sq[dd];
    const _Float16* kr = kb + (size_t)dd * 4096 + t;
    #pragma unroll
    for (int i = 0; i < 16; ++i) sc[i] = fmaf(qv, (float)kr[i * 256], sc[i]);
  }
  float mx = sc[0];
  #pragma unroll
  for (int i = 1; i < 16; ++i) mx = fmaxf(mx, sc[i]);
  #pragma unroll
  for (int o = 32; o; o >>= 1) mx = fmaxf(mx, __shfl_xor(mx, o));
  if ((t & 63) == 0) red[t >> 6] = mx;
  __syncthreads();
  mx = fmaxf(fmaxf(red[0], red[1]), fmaxf(red[2], red[3]));
  __syncthreads();
  float sum = 0.f;
  #pragma unroll
  for (int i = 0; i < 16; ++i) {
    sc[i] = expf(sc[i] - mx);
    sum += sc[i];
  }
  #pragma unroll
  for (int o = 32; o; o >>= 1) sum += __shfl_xor(sum, o);
  if ((t & 63) == 0) red[t >> 6] = sum;
  __syncthreads();
  sum = red[0] + red[1] + red[2] + red[3];
  float inv = 1.f / sum;
  #pragma unroll
  for (int i = 0; i < 16; ++i) sP[t + i * 256] = sc[i] * inv;
  __syncthreads();
  const int d = t & 63, seg = t >> 6;
  const _Float16* vb = vx + (size_t)bh * 262144;
  float acc = 0.f;
  for (int n = seg * 1024; n < seg * 1024 + 1024; ++n)
    acc = fmaf(sP[n], (float)vb[(size_t)n * 64 + d], acc);
  red2[seg][d] = acc;
  __syncthreads();
  if (seg == 0)
    a3v[((size_t)bh * 64 + m) * 64 + d] = red2[0][d] + red2[1][d] + red2[2][d] + red2[3][d];
}

// ---------------- Moore-Penrose pinv (fp32) + fused w2t = (pinv @ a3v)^T ----------------
__global__ __launch_bounds__(256) void k_pinv(
    const float* __restrict__ a2g, const float* __restrict__ scal,
    const float* __restrict__ a3vg, _Float16* __restrict__ w2t) {
  __shared__ float z[64 * 65];
  __shared__ float az[64 * 65];
  __shared__ float tb[64 * 65];
  const int bh = blockIdx.x, t = threadIdx.x;
  const int r0 = (t >> 4) << 2, c0 = (t & 15) << 2;
  const float* ag = a2g + (size_t)bh * 4096;
  const float denom = 1.f / (scal[0] * scal[1]);
  #pragma unroll
  for (int i = 0; i < 4; ++i)
    #pragma unroll
    for (int j = 0; j < 4; ++j)
      z[(r0 + i) * 65 + c0 + j] = ag[(c0 + j) * 64 + r0 + i] * denom;
  __syncthreads();
  float reg[4][4], val[4][4];
  for (int it = 0; it < 6; ++it) {
    mm16<64, 65>(ag, z, r0, c0, reg);
    #pragma unroll
    for (int i = 0; i < 4; ++i)
      #pragma unroll
      for (int j = 0; j < 4; ++j) az[(r0 + i) * 65 + c0 + j] = reg[i][j];
    __syncthreads();
    mm16<65, 65>(az, az, r0, c0, reg);
    #pragma unroll
    for (int i = 0; i < 4; ++i)
      #pragma unroll
      for (int j = 0; j < 4; ++j)
        tb[(r0 + i) * 65 + c0 + j] = 7.f * az[(r0 + i) * 65 + c0 + j] - reg[i][j];
    __syncthreads();
    mm16<65, 65>(az, tb, r0, c0, reg);
    #pragma unroll
    for (int i = 0; i < 4; ++i)
      #pragma unroll
      for (int j = 0; j < 4; ++j)
        val[i][j] = 15.f * az[(r0 + i) * 65 + c0 + j] - reg[i][j];
    __syncthreads();
    #pragma unroll
    for (int i = 0; i < 4; ++i)
      #pragma unroll
      for (int j = 0; j < 4; ++j) tb[(r0 + i) * 65 + c0 + j] = val[i][j];
    __syncthreads();
    mm16<65, 65>(z, tb, r0, c0, reg);
    #pragma unroll
    for (int i = 0; i < 4; ++i)
      #pragma unroll
      for (int j = 0; j < 4; ++j)
        val[i][j] = 0.25f * (13.f * z[(r0 + i) * 65 + c0 + j] - reg[i][j]);
    __syncthreads();
    #pragma unroll
    for (int i = 0; i < 4; ++i)
      #pragma unroll
      for (int j = 0; j < 4; ++j) z[(r0 + i) * 65 + c0 + j] = val[i][j];
    __syncthreads();
  }
  // fused: w2 = pinv @ a3v, store transposed f16 [bh][d][m]
  mm16<65, 64>(z, a3vg + (size_t)bh * 4096, r0, c0, reg);
  #pragma unroll
  for (int i = 0; i < 4; ++i)
    #pragma unroll
    for (int j = 0; j < 4; ++j)
      w2t[(size_t)bh * 4096 + (c0 + j) * 64 + (r0 + i)] = (_Float16)reg[i][j];
}

// ------- fused MFMA combine: S=q@kl^T -> softmax -> P@W2 + Toeplitz(res)@v -> att f16 ------
__global__ __launch_bounds__(256) void k_combine_m(
    const _Float16* __restrict__ qx, const _Float16* __restrict__ klh,
    const _Float16* __restrict__ w2t, const _Float16* __restrict__ vx,
    const float* __restrict__ rw, _Float16* __restrict__ att) {
  __shared__ _Float16 sP[64 * 72];
  __shared__ _Float16 sVT[64 * 104];
  __shared__ _Float16 sT[64 * 104];
  __shared__ float sR[33];
  const int t = threadIdx.x, w = t >> 6, lo = t & 15, hi = (t >> 4) & 3;
  const int n0 = blockIdx.x * 64;
  const int h = blockIdx.y, b = blockIdx.z, bh = b * 8 + h;
  if (t < 33) sR[t] = rw[h * 33 + t];
  __syncthreads();
  const _Float16* vb = vx + (size_t)bh * 262144;
  #pragma unroll
  for (int u = 0; u < 24; ++u) {
    int e = t + u * 256;
    int r = e >> 6, d = e & 63;
    int nn = n0 - 16 + r;
    sVT[d * 104 + r] = ((unsigned)nn < 4096u) ? vb[(size_t)nn * 64 + d] : (_Float16)0.f;
  }
  #pragma unroll
  for (int u = 0; u < 24; ++u) {
    int e = t + u * 256;
    int r = e % 96, i = e / 96;
    int j = r - i;
    sT[i * 104 + r] = (j >= 0 && j < 33) ? (_Float16)sR[j] : (_Float16)0.f;
  }
  f32x4 sa[4] = {};
  const _Float16* qp = qx + ((size_t)bh * 4096 + n0 + w * 16 + lo) * 64 + 8 * hi;
  const _Float16* klp = klh + (size_t)bh * 4096;
  #pragma unroll
  for (int c = 0; c < 2; ++c) {
    half8 a = *reinterpret_cast<const half8*>(qp + 32 * c);
    #pragma unroll
    for (int ct = 0; ct < 4; ++ct) {
      half8 bf = *reinterpret_cast<const half8*>(klp + (size_t)(ct * 16 + lo) * 64 + 8 * hi + 32 * c);
      sa[ct] = __builtin_amdgcn_mfma_f32_16x16x32_f16(a, bf, sa[ct], 0, 0, 0);
    }
  }
  #pragma unroll
  for (int r = 0; r < 4; ++r) {
    float mx = fmaxf(fmaxf(sa[0][r], sa[1][r]), fmaxf(sa[2][r], sa[3][r]));
    #pragma unroll
    for (int o = 8; o; o >>= 1) mx = fmaxf(mx, __shfl_xor(mx, o));
    float e0 = expf(sa[0][r] - mx), e1 = expf(sa[1][r] - mx);
    float e2 = expf(sa[2][r] - mx), e3 = expf(sa[3][r] - mx);
    float sm = e0 + e1 + e2 + e3;
    #pragma unroll
    for (int o = 8; o; o >>= 1) sm += __shfl_xor(sm, o);
    float inv = 1.f / sm;
    int row = w * 16 + hi * 4 + r;
    sP[row * 72 + lo] = (_Float16)(e0 * inv);
    sP[row * 72 + 16 + lo] = (_Float16)(e1 * inv);
    sP[row * 72 + 32 + lo] = (_Float16)(e2 * inv);
    sP[row * 72 + 48 + lo] = (_Float16)(e3 * inv);
  }
  __syncthreads();
  f32x4 ao[4] = {};
  const _Float16* w2p = w2t + (size_t)bh * 4096;
  #pragma unroll
  for (int c = 0; c < 2; ++c) {
    half8 a = *reinterpret_cast<const half8*>(&sP[(w * 16 + lo) * 72 + 8 * hi + 32 * c]);
    #pragma unroll
    for (int ct = 0; ct < 4; ++ct) {
      half8 bf = *reinterpret_cast<const half8*>(w2p + (size_t)(ct * 16 + lo) * 64 + 8 * hi + 32 * c);
      ao[ct] = __builtin_amdgcn_mfma_f32_16x16x32_f16(a, bf, ao[ct], 0, 0, 0);
    }
  }
  #pragma unroll
  for (int c = 0; c < 3; ++c) {
    half8 a = *reinterpret_cast<const half8*>(&sT[(w * 16 + lo) * 104 + 8 * hi + 32 * c]);
    #pragma unroll
    for (int ct = 0; ct < 4; ++ct) {
      half8 bf = *reinterpret_cast<const half8*>(&sVT[(ct * 16 + lo) * 104 + 8 * hi + 32 * c]);
      ao[ct] = __builtin_amdgcn_mfma_f32_16x16x32_f16(a, bf, ao[ct], 0, 0, 0);
    }
  }
  _Float16* ab = att + ((size_t)b * 4096) * 512 + (size_t)h * 64;
  #pragma unroll
  for (int ct = 0; ct < 4; ++ct)
    #pragma unroll
    for (int r = 0; r < 4; ++r) {
      int n = n0 + w * 16 + hi * 4 + r;
      ab[(size_t)n * 512 + ct * 16 + lo] = (_Float16)ao[ct][r];
    }
}

// ---------------- LayerNorm in place over E=800, f16 buffer ----------------
__global__ __launch_bounds__(256) void k_ln16(
    _Float16* __restrict__ buf, const float* __restrict__ g, const float* __restrict__ bb) {
  const int t = threadIdx.x;
  _Float16* p = buf + (size_t)blockIdx.x * 800;
  float x0 = (float)p[t], x1 = (float)p[t + 256], x2 = (float)p[t + 512];
  float x3 = (t < 32) ? (float)p[t + 768] : 0.f;
  float s = blockReduceSum(x0 + x1 + x2 + x3);
  float mean = s * (1.f / 800.f);
  float d0 = x0 - mean, d1 = x1 - mean, d2 = x2 - mean;
  float d3 = (t < 32) ? x3 - mean : 0.f;
  float s2 = blockReduceSum(d0 * d0 + d1 * d1 + d2 * d2 + d3 * d3);
  float rstd = rsqrtf(s2 * (1.f / 800.f) + LN_EPS_C);
  p[t] = (_Float16)(d0 * rstd * g[t] + bb[t]);
  p[t + 256] = (_Float16)(d1 * rstd * g[t + 256] + bb[t + 256]);
  p[t + 512] = (_Float16)(d2 * rstd * g[t + 512] + bb[t + 512]);
  if (t < 32) p[t + 768] = (_Float16)(d3 * rstd * g[t + 768] + bb[t + 768]);
}

// ---------------- head MFMA: out[16384,16] = sigmoid(lnb @ hwh^T + hb) ----------------
__global__ __launch_bounds__(256) void k_head_m(
    const _Float16* __restrict__ ln, const _Float16* __restrict__ hwh,
    const float* __restrict__ hb, float* __restrict__ out) {
  const int t = threadIdx.x, w = t >> 6, lo = t & 15, hi = (t >> 4) & 3;
  const int row0 = blockIdx.x * 64 + w * 16;
  const _Float16* ap = ln + (size_t)(row0 + lo) * 800 + 8 * hi;
  const _Float16* bp = hwh + (size_t)lo * 800 + 8 * hi;
  f32x4 acc = {};
  #pragma unroll 5
  for (int k = 0; k < 800; k += 32) {
    half8 a = *reinterpret_cast<const half8*>(ap + k);
    half8 b = *reinterpret_cast<const half8*>(bp + k);
    acc = __builtin_amdgcn_mfma_f32_16x16x32_f16(a, b, acc, 0, 0, 0);
  }
  float bv = hb[lo];
  #pragma unroll
  for (int r = 0; r < 4; ++r) {
    int row = row0 + hi * 4 + r;
    out[(size_t)row * 16 + lo] = 1.f / (1.f + expf(-(acc[r] + bv)));
  }
}

// ---------------- launcher ----------------
extern "C" void kernel_launch(void* const* d_in, const int* in_sizes, int n_in,
                              void* d_out, int out_size, void* d_ws, size_t ws_size,
                              hipStream_t stream) {
  (void)in_sizes; (void)n_in; (void)out_size; (void)ws_size;
  const float* x     = (const float*)d_in[0];
  const float* w0    = (const float*)d_in[1];
  const float* b0    = (const float*)d_in[2];
  const float* g0    = (const float*)d_in[3];
  const float* be0   = (const float*)d_in[4];
  const float* mu0   = (const float*)d_in[5];
  const float* var0  = (const float*)d_in[6];
  const float* w1    = (const float*)d_in[7];
  const float* b1    = (const float*)d_in[8];
  const float* g1    = (const float*)d_in[9];
  const float* be1   = (const float*)d_in[10];
  const float* mu1   = (const float*)d_in[11];
  const float* var1  = (const float*)d_in[12];
  const float* w2c   = (const float*)d_in[13];
  const float* b2    = (const float*)d_in[14];
  const float* g2    = (const float*)d_in[15];
  const float* be2   = (const float*)d_in[16];
  const float* mu2   = (const float*)d_in[17];
  const float* var2  = (const float*)d_in[18];
  const float* w3    = (const float*)d_in[19];
  const float* b3    = (const float*)d_in[20];
  const float* g3    = (const float*)d_in[21];
  const float* be3   = (const float*)d_in[22];
  const float* mu3   = (const float*)d_in[23];
  const float* var3  = (const float*)d_in[24];
  const float* qkvw  = (const float*)d_in[25];
  const float* outw  = (const float*)d_in[26];
  const float* outbv = (const float*)d_in[27];
  const float* resw  = (const float*)d_in[28];
  const float* lng   = (const float*)d_in[29];
  const float* lnbv  = (const float*)d_in[30];
  const float* headw = (const float*)d_in[31];
  const float* headb = (const float*)d_in[32];

  char* wsb = (char*)d_ws;
  _Float16* h0   = (_Float16*)(wsb + B_H0);
  _Float16* h1   = (_Float16*)(wsb + B_H1);
  _Float16* h2   = (_Float16*)(wsb + B_H2);
  _Float16* qb   = (_Float16*)(wsb + B_Q);
  _Float16* vb   = (_Float16*)(wsb + B_V);
  _Float16* kT   = (_Float16*)(wsb + B_KT);
  _Float16* tok  = (_Float16*)(wsb + B_TOK);
  _Float16* attb = (_Float16*)(wsb + B_ATT);
  _Float16* wp1  = (_Float16*)(wsb + B_WP1);
  _Float16* wp2  = (_Float16*)(wsb + B_WP2);
  _Float16* wp3  = (_Float16*)(wsb + B_WP3);
  _Float16* qkvT = (_Float16*)(wsb + B_QKVT);
  _Float16* owT  = (_Float16*)(wsb + B_OWT);
  _Float16* klh  = (_Float16*)(wsb + B_KLH);
  _Float16* w2t  = (_Float16*)(wsb + B_W2T);
  _Float16* hwh  = (_Float16*)(wsb + B_HWH);
  _Float16* lnb16 = (_Float16*)(wsb + B_LNB);
  float* ql   = (float*)(wsb + B_QL);
  float* kl   = (float*)(wsb + B_KL);
  float* a2   = (float*)(wsb + B_A2);
  float* a3v  = (float*)(wsb + B_A3V);
  float* scal = (float*)(wsb + B_SCAL);

  // all weight packing + scal init in one launch
  k_pack_all<<<dim3(20691), 256, 0, stream>>>(
      w1, w2c, w3, qkvw, outw, headw, wp1, wp2, wp3, qkvT, owT, hwh, scal);

  // conv stack: conv0..conv2 per image (h0/h1 scratch), h2 kept full-batch
  for (int img = 0; img < 4; ++img) {
    k_conv0<<<dim3(256), 256, 0, stream>>>(
        x + (size_t)img * 65536, w0, b0, g0, be0, mu0, var0, h0);
    k_convs<64><<<dim3(512), 256, 0, stream>>>(
        h0, wp1, b1, g1, be1, mu1, var1, h1, 128, 1);
    k_convs<128><<<dim3(1024), 256, 0, stream>>>(
        h1, wp2, b2, g2, be2, mu2, var2, h2 + (size_t)img * 16777216, 256, 2);
  }
  // conv3 (patch conv) over the full batch: staged GEMM, 640 XCD-swizzled blocks
  k_c3<<<dim3(640), 256, 0, stream>>>(h2, wp3, b3, g3, be3, mu3, var3, tok);
  // attention (k written directly transposed by qkv)
  k_qkv_s<<<dim3(1536), 256, 0, stream>>>(tok, qkvT, qb, kT, vb);
  k_landmark<<<dim3(64, 32), 64, 0, stream>>>(qb, kT, ql, kl, klh);
  k_a2<<<dim3(32), 64, 0, stream>>>(ql, kl, a2, scal);
  k_a3v<<<dim3(64, 32), 256, 0, stream>>>(ql, kT, vb, a3v);
  k_pinv<<<dim3(32), 256, 0, stream>>>(a2, scal, a3v, w2t);
  k_combine_m<<<dim3(64, 8, 4), 256, 0, stream>>>(qb, klh, w2t, vb, resw, attb);
  // projection + LN + head
  k_op_s<<<dim3(640), 256, 0, stream>>>(attb, owT, outbv, lnb16);
  k_ln16<<<dim3(16384), 256, 0, stream>>>(lnb16, lng, lnbv);
  k_head_m<<<dim3(256), 256, 0, stream>>>(lnb16, hwh, headb, (float*)d_out);
}

// Round 10
// 1114.381 us; speedup vs baseline: 10.3414x; 1.0347x over previous
//
#include <hip/hip_runtime.h>

#define DI __device__ __forceinline__

constexpr float BN_EPS_C = 1e-5f;
constexpr float LN_EPS_C = 1e-5f;

typedef _Float16 half8 __attribute__((ext_vector_type(8)));
typedef float f32x4 __attribute__((ext_vector_type(4)));

// ---------------- workspace layout (BYTE offsets), peak ~199.34 MB ----------------
constexpr size_t B_H0   = 0;             // f16 [256][256][64]  per-image scratch
constexpr size_t B_H1   = 8388608;       // f16 [256][256][128] per-image scratch
constexpr size_t B_H2   = 25165824;      // f16 [4][256][256][256] = 134,217,728 (full batch)
// overlays inside the h2 region once h2 is dead (after k_c3):
constexpr size_t B_Q    = 25165824;      // f16 [32][4096][64] = 16,777,216
constexpr size_t B_V    = 58720256;      // f16 16,777,216
constexpr size_t B_KT   = 75497472;      // f16 [32][64][4096] = 16,777,216
constexpr size_t B_ATT  = 92274688;      // f16 [16384][512] = 16,777,216
constexpr size_t B_LNB  = 25165824;      // f16 [16384][800] = 26,214,400 (q dead by outproj)
// tok + packed weights + small buffers:
constexpr size_t B_TOK  = 159383552;     // f16 [16384][800] = 26,214,400
constexpr size_t B_WP1  = 185597952;     // 147,456
constexpr size_t B_WP2  = 185745408;     // 589,824
constexpr size_t B_WP3  = 186335232;     // 6,553,600
constexpr size_t B_QKVT = 192888832;     // 2,457,600
constexpr size_t B_OWT  = 195346432;     // 819,200
constexpr size_t B_QL   = 196165632;     // f32 524,288
constexpr size_t B_KL   = 196689920;
constexpr size_t B_KLH  = 197214208;     // f16 262,144
constexpr size_t B_A2   = 197476352;
constexpr size_t B_W2T  = 198524928;     // f16 262,144
constexpr size_t B_A3V  = 198787072;
constexpr size_t B_SCAL = 199311360;     // 2 floats
constexpr size_t B_HWH  = 199311424;     // f16 [16][800] = 25,600 (end 199,337,024)

// ---------------- helpers ----------------
DI float blockReduceSum(float v) {
  #pragma unroll
  for (int o = 32; o; o >>= 1) v += __shfl_xor(v, o);
  __shared__ float red[4];
  int w = threadIdx.x >> 6;
  __syncthreads();
  if ((threadIdx.x & 63) == 0) red[w] = v;
  __syncthreads();
  return red[0] + red[1] + red[2] + red[3];
}

// float4-vectorized 64-deep 4x4 tile product (rows must be 16B-aligned: LP,RP mult of 4)
template <int LP, int RP>
DI void mm16v(const float* L, const float* R, int r0, int c0, float reg[4][4]) {
  #pragma unroll
  for (int i = 0; i < 4; ++i)
    #pragma unroll
    for (int j = 0; j < 4; ++j) reg[i][j] = 0.f;
  #pragma unroll 4
  for (int dd = 0; dd < 64; dd += 4) {
    f32x4 l[4], rv[4];
    #pragma unroll
    for (int i = 0; i < 4; ++i)
      l[i] = *reinterpret_cast<const f32x4*>(&L[(size_t)(r0 + i) * LP + dd]);
    #pragma unroll
    for (int u = 0; u < 4; ++u)
      rv[u] = *reinterpret_cast<const f32x4*>(&R[(size_t)(dd + u) * RP + c0]);
    #pragma unroll
    for (int i = 0; i < 4; ++i)
      #pragma unroll
      for (int u = 0; u < 4; ++u)
        #pragma unroll
        for (int j = 0; j < 4; ++j)
          reg[i][j] = fmaf(l[i][u], rv[u][j], reg[i][j]);
  }
}

// ---------------- mega-pack: all weight packs + scal init in one launch ----------------
__global__ void k_pack_all(
    const float* __restrict__ w1, const float* __restrict__ w2c, const float* __restrict__ w3,
    const float* __restrict__ qkvw, const float* __restrict__ outw, const float* __restrict__ headw,
    _Float16* __restrict__ wp1, _Float16* __restrict__ wp2, _Float16* __restrict__ wp3,
    _Float16* __restrict__ qkvT, _Float16* __restrict__ owT, _Float16* __restrict__ hwh,
    float* __restrict__ scal) {
  size_t i = (size_t)blockIdx.x * 256 + threadIdx.x;
  if (i < 73728) {
    int q = i % 9, ci = (i / 9) % 64, co = i / (9 * 64);
    wp1[((size_t)co * 9 + q) * 64 + ci] = (_Float16)w1[i];
  } else if (i < 368640) {
    size_t j = i - 73728;
    int q = j % 9, ci = (j / 9) % 128, co = j / (9 * 128);
    wp2[((size_t)co * 9 + q) * 128 + ci] = (_Float16)w2c[j];
  } else if (i < 3645440) {
    size_t j = i - 368640;
    int q = j % 16, ci = (j / 16) % 256, co = j / (16 * 256);
    wp3[((size_t)co * 16 + q) * 256 + ci] = (_Float16)w3[j];
  } else if (i < 4874240) {
    size_t j = i - 3645440;
    int n = j % 1536, k = j / 1536;
    qkvT[(size_t)n * 800 + k] = (_Float16)qkvw[j];
  } else if (i < 5283840) {
    size_t j = i - 4874240;
    int n = j % 800, k = j / 800;
    owT[(size_t)n * 512 + k] = (_Float16)outw[j];
  } else if (i < 5296640) {
    size_t j = i - 5283840;
    int n = j % 16, k = j / 16;
    hwh[(size_t)n * 800 + k] = (_Float16)headw[j];
  } else if (i < 5296642) {
    scal[i - 5296640] = 0.f;
  }
}

// ---------------- conv0: CI=1 fp32 direct conv -> h0 NHWC f16 ----------------
__global__ __launch_bounds__(256) void k_conv0(
    const float* __restrict__ xb, const float* __restrict__ w0, const float* __restrict__ b0,
    const float* __restrict__ g0, const float* __restrict__ be0, const float* __restrict__ mu0,
    const float* __restrict__ var0, _Float16* __restrict__ h0) {
  const int t = threadIdx.x, co = t & 63, xg = t >> 6;
  const int y = blockIdx.x;
  float wreg[9];
  #pragma unroll
  for (int q = 0; q < 9; ++q) wreg[q] = w0[co * 9 + q];
  float s = g0[co] * rsqrtf(var0[co] + BN_EPS_C);
  float sh = fmaf(b0[co] - mu0[co], s, be0[co]);
  for (int xl = 0; xl < 64; ++xl) {
    int xx = xg * 64 + xl;
    float acc = 0.f;
    #pragma unroll
    for (int dy = 0; dy < 3; ++dy) {
      int yy = y + dy - 1;
      if ((unsigned)yy >= 256u) continue;
      #pragma unroll
      for (int dx = 0; dx < 3; ++dx) {
        int xi = xx + dx - 1;
        if ((unsigned)xi >= 256u) continue;
        acc = fmaf(wreg[dy * 3 + dx], xb[yy * 256 + xi], acc);
      }
    }
    float v = fmaxf(fmaf(acc, s, sh), 0.f);
    h0[((size_t)y * 256 + xx) * 64 + co] = (_Float16)v;
  }
}

// ------- staged implicit-im2col 3x3 conv GEMM: tile 128x128 ---------------
template <int CI>
__global__ __launch_bounds__(256) void k_convs(
    const _Float16* __restrict__ in, const _Float16* __restrict__ wp,
    const float* __restrict__ bias, const float* __restrict__ g, const float* __restrict__ be,
    const float* __restrict__ mu, const float* __restrict__ var,
    _Float16* __restrict__ out, int CO, int NCT) {
  __shared__ _Float16 Ab[2][128 * 40];
  __shared__ _Float16 Bb[2][128 * 40];
  constexpr int CPQ = CI / 32;
  constexpr int NCK = 9 * CPQ;
  const int t = threadIdx.x;
  const int bid = blockIdx.x;
  const int xcd = bid & 7, slot = bid >> 3;
  const int pj = slot / NCT, cc = slot % NCT;
  const int p = pj * 8 + xcd;
  const int r0 = p * 128, c0 = cc * 128;

  const int ma = t >> 2, kga = t & 3;
  int ry[2], rx[2];
  #pragma unroll
  for (int s = 0; s < 2; ++s) {
    int r = r0 + ma + s * 64;
    ry[s] = r >> 8;
    rx[s] = r & 255;
  }
  const _Float16* baseB[2];
  #pragma unroll
  for (int s = 0; s < 2; ++s)
    baseB[s] = wp + (size_t)(c0 + ma + s * 64) * 9 * CI + kga * 8;
  const int wo = ma * 40 + kga * 8;

  auto loadA = [&](int s, int ck) -> half8 {
    int q = ck / CPQ, coff = (ck % CPQ) * 32;
    int yy = ry[s] + q / 3 - 1;
    int xx = rx[s] + q % 3 - 1;
    half8 a = {};
    if ((unsigned)yy < 256u && (unsigned)xx < 256u)
      a = *reinterpret_cast<const half8*>(in + ((size_t)yy * 256 + xx) * CI + coff + kga * 8);
    return a;
  };

  {
    half8 a0 = loadA(0, 0), a1 = loadA(1, 0);
    half8 b0v = *reinterpret_cast<const half8*>(baseB[0]);
    half8 b1v = *reinterpret_cast<const half8*>(baseB[1]);
    *reinterpret_cast<half8*>(&Ab[0][wo]) = a0;
    *reinterpret_cast<half8*>(&Ab[0][wo + 2560]) = a1;
    *reinterpret_cast<half8*>(&Bb[0][wo]) = b0v;
    *reinterpret_cast<half8*>(&Bb[0][wo + 2560]) = b1v;
  }
  __syncthreads();

  const int w = t >> 6, lo = t & 15, hi = (t >> 4) & 3;
  const int wm = w >> 1, wn = w & 1;
  const int roA = (wm * 64 + lo) * 40 + 8 * hi;
  const int roB = (wn * 64 + lo) * 40 + 8 * hi;
  f32x4 acc[4][4] = {};

  for (int ck = 0; ck < NCK; ++ck) {
    const int cur = ck & 1;
    const bool more = (ck + 1 < NCK);
    half8 rA0, rA1, rB0, rB1;
    if (more) {
      rA0 = loadA(0, ck + 1);
      rA1 = loadA(1, ck + 1);
      rB0 = *reinterpret_cast<const half8*>(baseB[0] + (ck + 1) * 32);
      rB1 = *reinterpret_cast<const half8*>(baseB[1] + (ck + 1) * 32);
    }
    half8 af[4], bf[4];
    #pragma unroll
    for (int mi = 0; mi < 4; ++mi)
      af[mi] = *reinterpret_cast<const half8*>(&Ab[cur][roA + mi * 640]);
    #pragma unroll
    for (int ni = 0; ni < 4; ++ni)
      bf[ni] = *reinterpret_cast<const half8*>(&Bb[cur][roB + ni * 640]);
    #pragma unroll
    for (int mi = 0; mi < 4; ++mi)
      #pragma unroll
      for (int ni = 0; ni < 4; ++ni)
        acc[mi][ni] = __builtin_amdgcn_mfma_f32_16x16x32_f16(af[mi], bf[ni], acc[mi][ni], 0, 0, 0);
    if (more) {
      *reinterpret_cast<half8*>(&Ab[cur ^ 1][wo]) = rA0;
      *reinterpret_cast<half8*>(&Ab[cur ^ 1][wo + 2560]) = rA1;
      *reinterpret_cast<half8*>(&Bb[cur ^ 1][wo]) = rB0;
      *reinterpret_cast<half8*>(&Bb[cur ^ 1][wo + 2560]) = rB1;
    }
    __syncthreads();
  }

  #pragma unroll
  for (int ni = 0; ni < 4; ++ni) {
    int co = c0 + wn * 64 + ni * 16 + lo;
    float s = g[co] * rsqrtf(var[co] + BN_EPS_C);
    float sh = fmaf(bias[co] - mu[co], s, be[co]);
    #pragma unroll
    for (int mi = 0; mi < 4; ++mi)
      #pragma unroll
      for (int rr = 0; rr < 4; ++rr) {
        int row = r0 + wm * 64 + mi * 16 + hi * 4 + rr;
        float v = fmaxf(fmaf(acc[mi][ni][rr], s, sh), 0.f);
        out[(size_t)row * CO + co] = (_Float16)v;
      }
  }
}

// ---------------- conv3 MFMA: staged GEMM, 128x160 tile, XCD-swizzled ----------
__global__ __launch_bounds__(256) void k_c3(
    const _Float16* __restrict__ h2, const _Float16* __restrict__ wp3,
    const float* __restrict__ b3, const float* __restrict__ g3, const float* __restrict__ be3,
    const float* __restrict__ mu3, const float* __restrict__ var3,
    _Float16* __restrict__ tok) {
  __shared__ _Float16 Abuf[2][128 * 40];
  __shared__ _Float16 Bbuf[2][160 * 40];
  const int t = threadIdx.x;
  const int bid = blockIdx.x;
  const int xcd = bid & 7, slot = bid >> 3;
  const int pj = slot / 5, cc = slot % 5;
  const int p = pj * 8 + xcd;
  const int r0 = p * 128, c0 = cc * 160;
  const int img = r0 >> 12;
  const _Float16* h2i = h2 + (size_t)img * 16777216;

  const int ma = t >> 2, kga = t & 3;
  const _Float16* baseA[2];
  #pragma unroll
  for (int s = 0; s < 2; ++s) {
    int m = ma + s * 64;
    int r = r0 + m;
    int py = (r & 4095) >> 6, px = r & 63;
    baseA[s] = h2i + ((size_t)py * 1024 + px * 4) * 256 + kga * 8;
  }
  const _Float16* baseB[3];
  #pragma unroll
  for (int s = 0; s < 3; ++s) {
    int cb = ma + s * 64;
    baseB[s] = wp3 + (size_t)(c0 + (cb < 160 ? cb : 159)) * 4096 + kga * 8;
  }
  const int wo = ma * 40 + kga * 8;

  const int w = t >> 6, lo = t & 15, hi = (t >> 4) & 3;
  const int wm = w >> 1, wn = w & 1;
  const int roA = (wm * 64 + lo) * 40 + 8 * hi;
  const int roB = (wn * 80 + lo) * 40 + 8 * hi;

  f32x4 acc[4][5] = {};

  {
    half8 a0 = *reinterpret_cast<const half8*>(baseA[0]);
    half8 a1 = *reinterpret_cast<const half8*>(baseA[1]);
    half8 b0v = *reinterpret_cast<const half8*>(baseB[0]);
    half8 b1v = *reinterpret_cast<const half8*>(baseB[1]);
    *reinterpret_cast<half8*>(&Abuf[0][wo]) = a0;
    *reinterpret_cast<half8*>(&Abuf[0][wo + 2560]) = a1;
    *reinterpret_cast<half8*>(&Bbuf[0][wo]) = b0v;
    *reinterpret_cast<half8*>(&Bbuf[0][wo + 2560]) = b1v;
    if (t < 128) {
      half8 b2v = *reinterpret_cast<const half8*>(baseB[2]);
      *reinterpret_cast<half8*>(&Bbuf[0][wo + 5120]) = b2v;
    }
  }
  __syncthreads();

  for (int ck = 0; ck < 128; ++ck) {
    const int cur = ck & 1;
    const bool more = (ck + 1 < 128);
    half8 rA0, rA1, rB0, rB1, rB2;
    if (more) {
      const int kn = (ck + 1) << 5;
      const int q = kn >> 8, qk = kn & 255;
      const int aoff = (q >> 2) * 65536 + (q & 3) * 256 + qk;
      rA0 = *reinterpret_cast<const half8*>(baseA[0] + aoff);
      rA1 = *reinterpret_cast<const half8*>(baseA[1] + aoff);
      rB0 = *reinterpret_cast<const half8*>(baseB[0] + kn);
      rB1 = *reinterpret_cast<const half8*>(baseB[1] + kn);
      if (t < 128) rB2 = *reinterpret_cast<const half8*>(baseB[2] + kn);
    }
    half8 af[4], bf[5];
    #pragma unroll
    for (int mi = 0; mi < 4; ++mi)
      af[mi] = *reinterpret_cast<const half8*>(&Abuf[cur][roA + mi * 640]);
    #pragma unroll
    for (int ni = 0; ni < 5; ++ni)
      bf[ni] = *reinterpret_cast<const half8*>(&Bbuf[cur][roB + ni * 640]);
    #pragma unroll
    for (int mi = 0; mi < 4; ++mi)
      #pragma unroll
      for (int ni = 0; ni < 5; ++ni)
        acc[mi][ni] = __builtin_amdgcn_mfma_f32_16x16x32_f16(af[mi], bf[ni], acc[mi][ni], 0, 0, 0);
    if (more) {
      *reinterpret_cast<half8*>(&Abuf[cur ^ 1][wo]) = rA0;
      *reinterpret_cast<half8*>(&Abuf[cur ^ 1][wo + 2560]) = rA1;
      *reinterpret_cast<half8*>(&Bbuf[cur ^ 1][wo]) = rB0;
      *reinterpret_cast<half8*>(&Bbuf[cur ^ 1][wo + 2560]) = rB1;
      if (t < 128) *reinterpret_cast<half8*>(&Bbuf[cur ^ 1][wo + 5120]) = rB2;
    }
    __syncthreads();
  }

  #pragma unroll
  for (int ni = 0; ni < 5; ++ni) {
    int col = c0 + wn * 80 + ni * 16 + lo;
    float s = g3[col] * rsqrtf(var3[col] + BN_EPS_C);
    float sh = fmaf(b3[col] - mu3[col], s, be3[col]);
    #pragma unroll
    for (int mi = 0; mi < 4; ++mi)
      #pragma unroll
      for (int rr = 0; rr < 4; ++rr) {
        int row = r0 + wm * 64 + mi * 16 + hi * 4 + rr;
        float v = fmaxf(fmaf(acc[mi][ni][rr], s, sh), 0.f);
        tok[(size_t)row * 800 + col] = (_Float16)v;
      }
  }
}

// ---------------- qkv staged GEMM + fused landmark means ----------------
// q,v in [bh][n][d]; k directly as kT [bh][d][n]; each block covers 2 full landmark groups.
__global__ __launch_bounds__(256) void k_qkv_s(
    const _Float16* __restrict__ tok, const _Float16* __restrict__ qkvT,
    _Float16* __restrict__ qx, _Float16* __restrict__ kTg, _Float16* __restrict__ vx,
    float* __restrict__ ql, float* __restrict__ kl, _Float16* __restrict__ klh) {
  __shared__ _Float16 Ab[2][128 * 40];
  __shared__ _Float16 Bb[2][128 * 40];
  const int t = threadIdx.x;
  const int bid = blockIdx.x;
  const int xcd = bid & 7, slot = bid >> 3;
  const int pj = slot / 12, cc = slot % 12;
  const int p = pj * 8 + xcd;
  const int r0 = p * 128, c0 = cc * 128;

  const int ma = t >> 2, kga = t & 3;
  const _Float16* baseA[2];
  const _Float16* baseB[2];
  #pragma unroll
  for (int s = 0; s < 2; ++s) {
    baseA[s] = tok + (size_t)(r0 + ma + s * 64) * 800 + kga * 8;
    baseB[s] = qkvT + (size_t)(c0 + ma + s * 64) * 800 + kga * 8;
  }
  const int wo = ma * 40 + kga * 8;

  {
    half8 a0 = *reinterpret_cast<const half8*>(baseA[0]);
    half8 a1 = *reinterpret_cast<const half8*>(baseA[1]);
    half8 b0v = *reinterpret_cast<const half8*>(baseB[0]);
    half8 b1v = *reinterpret_cast<const half8*>(baseB[1]);
    *reinterpret_cast<half8*>(&Ab[0][wo]) = a0;
    *reinterpret_cast<half8*>(&Ab[0][wo + 2560]) = a1;
    *reinterpret_cast<half8*>(&Bb[0][wo]) = b0v;
    *reinterpret_cast<half8*>(&Bb[0][wo + 2560]) = b1v;
  }
  __syncthreads();

  const int w = t >> 6, lo = t & 15, hi = (t >> 4) & 3;
  const int wm = w >> 1, wn = w & 1;
  const int roA = (wm * 64 + lo) * 40 + 8 * hi;
  const int roB = (wn * 64 + lo) * 40 + 8 * hi;
  f32x4 acc[4][4] = {};

  for (int ck = 0; ck < 25; ++ck) {
    const int cur = ck & 1;
    const bool more = (ck + 1 < 25);
    half8 rA0, rA1, rB0, rB1;
    if (more) {
      const int kn = (ck + 1) * 32;
      rA0 = *reinterpret_cast<const half8*>(baseA[0] + kn);
      rA1 = *reinterpret_cast<const half8*>(baseA[1] + kn);
      rB0 = *reinterpret_cast<const half8*>(baseB[0] + kn);
      rB1 = *reinterpret_cast<const half8*>(baseB[1] + kn);
    }
    half8 af[4], bf[4];
    #pragma unroll
    for (int mi = 0; mi < 4; ++mi)
      af[mi] = *reinterpret_cast<const half8*>(&Ab[cur][roA + mi * 640]);
    #pragma unroll
    for (int ni = 0; ni < 4; ++ni)
      bf[ni] = *reinterpret_cast<const half8*>(&Bb[cur][roB + ni * 640]);
    #pragma unroll
    for (int mi = 0; mi < 4; ++mi)
      #pragma unroll
      for (int ni = 0; ni < 4; ++ni)
        acc[mi][ni] = __builtin_amdgcn_mfma_f32_16x16x32_f16(af[mi], bf[ni], acc[mi][ni], 0, 0, 0);
    if (more) {
      *reinterpret_cast<half8*>(&Ab[cur ^ 1][wo]) = rA0;
      *reinterpret_cast<half8*>(&Ab[cur ^ 1][wo + 2560]) = rA1;
      *reinterpret_cast<half8*>(&Bb[cur ^ 1][wo]) = rB0;
      *reinterpret_cast<half8*>(&Bb[cur ^ 1][wo + 2560]) = rB1;
    }
    __syncthreads();
  }

  const int seg = cc >> 2;
  const int b = r0 >> 12;
  const int m = ((r0 & 4095) >> 6) + wm;   // this wave's landmark group
  if (seg == 1) {
    // k: write transposed layout kT[bh][d][n] directly
    #pragma unroll
    for (int ni = 0; ni < 4; ++ni) {
      int cseg = (cc & 3) * 128 + wn * 64 + ni * 16 + lo;
      int h = cseg >> 6, d = cseg & 63;
      #pragma unroll
      for (int mi = 0; mi < 4; ++mi)
        #pragma unroll
        for (int rr = 0; rr < 4; ++rr) {
          int row = r0 + wm * 64 + mi * 16 + hi * 4 + rr;
          int nn = row & 4095;
          kTg[((size_t)(b * 8 + h) * 64 + d) * 4096 + nn] = (_Float16)acc[mi][ni][rr];
        }
    }
  } else {
    const float scale = (seg == 0) ? 0.125f : 1.0f;
    _Float16* dst = (seg == 0) ? qx : vx;
    #pragma unroll
    for (int ni = 0; ni < 4; ++ni) {
      int cseg = (cc & 3) * 128 + wn * 64 + ni * 16 + lo;
      int h = cseg >> 6, d = cseg & 63;
      #pragma unroll
      for (int mi = 0; mi < 4; ++mi)
        #pragma unroll
        for (int rr = 0; rr < 4; ++rr) {
          int row = r0 + wm * 64 + mi * 16 + hi * 4 + rr;
          int nn = row & 4095;
          dst[((size_t)(b * 8 + h) * 4096 + nn) * 64 + d] = (_Float16)(acc[mi][ni][rr] * scale);
        }
    }
  }
  // fused landmark means for q (seg 0) and k (seg 1): sum the wave's 64 rows
  if (seg <= 1) {
    const float lscale = ((seg == 0) ? 0.125f : 1.0f) * (1.f / 64.f);
    #pragma unroll
    for (int ni = 0; ni < 4; ++ni) {
      float sum = 0.f;
      #pragma unroll
      for (int mi = 0; mi < 4; ++mi)
        #pragma unroll
        for (int rr = 0; rr < 4; ++rr) sum += acc[mi][ni][rr];
      sum += __shfl_xor(sum, 16);
      sum += __shfl_xor(sum, 32);
      if (hi == 0) {
        int cseg = (cc & 3) * 128 + wn * 64 + ni * 16 + lo;
        int h = cseg >> 6, d = cseg & 63;
        int bh = b * 8 + h;
        float lm = sum * lscale;
        if (seg == 0) {
          ql[((size_t)bh * 64 + m) * 64 + d] = lm;
        } else {
          kl[((size_t)bh * 64 + m) * 64 + d] = lm;
          klh[((size_t)bh * 64 + m) * 64 + d] = (_Float16)lm;
        }
      }
    }
  }
}

// ---------------- out-proj staged GEMM: M=16384, N=800 (5x160), K=512 -> f16 lnb ---------
__global__ __launch_bounds__(256) void k_op_s(
    const _Float16* __restrict__ attb, const _Float16* __restrict__ owT,
    const float* __restrict__ ob, _Float16* __restrict__ lnb) {
  __shared__ _Float16 Abuf[2][128 * 40];
  __shared__ _Float16 Bbuf[2][160 * 40];
  const int t = threadIdx.x;
  const int bid = blockIdx.x;
  const int xcd = bid & 7, slot = bid >> 3;
  const int pj = slot / 5, cc = slot % 5;
  const int p = pj * 8 + xcd;
  const int r0 = p * 128, c0 = cc * 160;

  const int ma = t >> 2, kga = t & 3;
  const _Float16* baseA[2];
  #pragma unroll
  for (int s = 0; s < 2; ++s)
    baseA[s] = attb + (size_t)(r0 + ma + s * 64) * 512 + kga * 8;
  const _Float16* baseB[3];
  #pragma unroll
  for (int s = 0; s < 3; ++s) {
    int cb = ma + s * 64;
    baseB[s] = owT + (size_t)(c0 + (cb < 160 ? cb : 159)) * 512 + kga * 8;
  }
  const int wo = ma * 40 + kga * 8;

  const int w = t >> 6, lo = t & 15, hi = (t >> 4) & 3;
  const int wm = w >> 1, wn = w & 1;
  const int roA = (wm * 64 + lo) * 40 + 8 * hi;
  const int roB = (wn * 80 + lo) * 40 + 8 * hi;

  f32x4 acc[4][5] = {};

  {
    half8 a0 = *reinterpret_cast<const half8*>(baseA[0]);
    half8 a1 = *reinterpret_cast<const half8*>(baseA[1]);
    half8 b0v = *reinterpret_cast<const half8*>(baseB[0]);
    half8 b1v = *reinterpret_cast<const half8*>(baseB[1]);
    *reinterpret_cast<half8*>(&Abuf[0][wo]) = a0;
    *reinterpret_cast<half8*>(&Abuf[0][wo + 2560]) = a1;
    *reinterpret_cast<half8*>(&Bbuf[0][wo]) = b0v;
    *reinterpret_cast<half8*>(&Bbuf[0][wo + 2560]) = b1v;
    if (t < 128) {
      half8 b2v = *reinterpret_cast<const half8*>(baseB[2]);
      *reinterpret_cast<half8*>(&Bbuf[0][wo + 5120]) = b2v;
    }
  }
  __syncthreads();

  for (int ck = 0; ck < 16; ++ck) {
    const int cur = ck & 1;
    const bool more = (ck + 1 < 16);
    half8 rA0, rA1, rB0, rB1, rB2;
    if (more) {
      const int kn = (ck + 1) << 5;
      rA0 = *reinterpret_cast<const half8*>(baseA[0] + kn);
      rA1 = *reinterpret_cast<const half8*>(baseA[1] + kn);
      rB0 = *reinterpret_cast<const half8*>(baseB[0] + kn);
      rB1 = *reinterpret_cast<const half8*>(baseB[1] + kn);
      if (t < 128) rB2 = *reinterpret_cast<const half8*>(baseB[2] + kn);
    }
    half8 af[4], bf[5];
    #pragma unroll
    for (int mi = 0; mi < 4; ++mi)
      af[mi] = *reinterpret_cast<const half8*>(&Abuf[cur][roA + mi * 640]);
    #pragma unroll
    for (int ni = 0; ni < 5; ++ni)
      bf[ni] = *reinterpret_cast<const half8*>(&Bbuf[cur][roB + ni * 640]);
    #pragma unroll
    for (int mi = 0; mi < 4; ++mi)
      #pragma unroll
      for (int ni = 0; ni < 5; ++ni)
        acc[mi][ni] = __builtin_amdgcn_mfma_f32_16x16x32_f16(af[mi], bf[ni], acc[mi][ni], 0, 0, 0);
    if (more) {
      *reinterpret_cast<half8*>(&Abuf[cur ^ 1][wo]) = rA0;
      *reinterpret_cast<half8*>(&Abuf[cur ^ 1][wo + 2560]) = rA1;
      *reinterpret_cast<half8*>(&Bbuf[cur ^ 1][wo]) = rB0;
      *reinterpret_cast<half8*>(&Bbuf[cur ^ 1][wo + 2560]) = rB1;
      if (t < 128) *reinterpret_cast<half8*>(&Bbuf[cur ^ 1][wo + 5120]) = rB2;
    }
    __syncthreads();
  }

  #pragma unroll
  for (int ni = 0; ni < 5; ++ni) {
    int col = c0 + wn * 80 + ni * 16 + lo;
    float bv = ob[col];
    #pragma unroll
    for (int mi = 0; mi < 4; ++mi)
      #pragma unroll
      for (int rr = 0; rr < 4; ++rr) {
        int row = r0 + wm * 64 + mi * 16 + hi * 4 + rr;
        lnb[(size_t)row * 800 + col] = (_Float16)(acc[mi][ni][rr] + bv);
      }
  }
}

// ---------------- a2 + global max row/col sums ----------------
__global__ __launch_bounds__(64) void k_a2(
    const float* __restrict__ ql, const float* __restrict__ kl,
    float* __restrict__ a2, float* __restrict__ scal) {
  __shared__ float sp[64 * 65];
  const int bh = blockIdx.x, t = threadIdx.x;
  const float* qr = ql + ((size_t)bh * 64 + t) * 64;
  const float* kb = kl + (size_t)bh * 4096;
  float mx = -1e30f;
  for (int c = 0; c < 64; ++c) {
    float acc = 0.f;
    #pragma unroll 8
    for (int dd = 0; dd < 64; ++dd) acc = fmaf(qr[dd], kb[c * 64 + dd], acc);
    sp[t * 65 + c] = acc;
    mx = fmaxf(mx, acc);
  }
  float sum = 0.f;
  for (int c = 0; c < 64; ++c) {
    float e = expf(sp[t * 65 + c] - mx);
    sp[t * 65 + c] = e;
    sum += e;
  }
  float inv = 1.f / sum;
  float rs = 0.f;
  for (int c = 0; c < 64; ++c) {
    float p = sp[t * 65 + c] * inv;
    sp[t * 65 + c] = p;
    a2[(size_t)bh * 4096 + t * 64 + c] = p;
    rs += p;
  }
  atomicMax(reinterpret_cast<int*>(scal), __float_as_int(rs));
  __syncthreads();
  float cs = 0.f;
  for (int r = 0; r < 64; ++r) cs += sp[r * 65 + t];
  atomicMax(reinterpret_cast<int*>(scal) + 1, __float_as_int(cs));
}

// ---------------- fused a3 softmax + a3@v (vectorized score loads) ----------------
__global__ __launch_bounds__(256) void k_a3v(
    const float* __restrict__ ql, const _Float16* __restrict__ kT,
    const _Float16* __restrict__ vx, float* __restrict__ a3v) {
  __shared__ float sq[64];
  __shared__ float sP[4096];
  __shared__ float red[4];
  __shared__ float red2[4][64];
  const int t = threadIdx.x;
  const int m = blockIdx.x, bh = blockIdx.y;
  if (t < 64) sq[t] = ql[((size_t)bh * 64 + m) * 64 + t];
  __syncthreads();
  const _Float16* kb = kT + (size_t)bh * 262144;
  float sc[16];
  #pragma unroll
  for (int i = 0; i < 16; ++i) sc[i] = 0.f;
  // thread t owns n in [16t, 16t+16): half8 loads, coalesced across lanes
  for (int dd = 0; dd < 64; ++dd) {
    float qv = sq[dd];
    const half8* kr = reinterpret_cast<const half8*>(kb + (size_t)dd * 4096 + t * 16);
    half8 k0 = kr[0], k1 = kr[1];
    #pragma unroll
    for (int i = 0; i < 8; ++i) sc[i] = fmaf(qv, (float)k0[i], sc[i]);
    #pragma unroll
    for (int i = 0; i < 8; ++i) sc[8 + i] = fmaf(qv, (float)k1[i], sc[8 + i]);
  }
  float mx = sc[0];
  #pragma unroll
  for (int i = 1; i < 16; ++i) mx = fmaxf(mx, sc[i]);
  #pragma unroll
  for (int o = 32; o; o >>= 1) mx = fmaxf(mx, __shfl_xor(mx, o));
  if ((t & 63) == 0) red[t >> 6] = mx;
  __syncthreads();
  mx = fmaxf(fmaxf(red[0], red[1]), fmaxf(red[2], red[3]));
  __syncthreads();
  float sum = 0.f;
  #pragma unroll
  for (int i = 0; i < 16; ++i) {
    sc[i] = expf(sc[i] - mx);
    sum += sc[i];
  }
  #pragma unroll
  for (int o = 32; o; o >>= 1) sum += __shfl_xor(sum, o);
  if ((t & 63) == 0) red[t >> 6] = sum;
  __syncthreads();
  sum = red[0] + red[1] + red[2] + red[3];
  float inv = 1.f / sum;
  #pragma unroll
  for (int i = 0; i < 16; ++i) sP[t * 16 + i] = sc[i] * inv;
  __syncthreads();
  const int d = t & 63, seg = t >> 6;
  const _Float16* vb = vx + (size_t)bh * 262144;
  float acc = 0.f;
  for (int n = seg * 1024; n < seg * 1024 + 1024; ++n)
    acc = fmaf(sP[n], (float)vb[(size_t)n * 64 + d], acc);
  red2[seg][d] = acc;
  __syncthreads();
  if (seg == 0)
    a3v[((size_t)bh * 64 + m) * 64 + d] = red2[0][d] + red2[1][d] + red2[2][d] + red2[3][d];
}

// ---------------- Moore-Penrose pinv (fp32, float4 LDS) + fused w2t ----------------
__global__ __launch_bounds__(256) void k_pinv(
    const float* __restrict__ a2g, const float* __restrict__ scal,
    const float* __restrict__ a3vg, _Float16* __restrict__ w2t) {
  __shared__ float z[64 * 68];
  __shared__ float az[64 * 68];
  __shared__ float tb[64 * 68];
  const int bh = blockIdx.x, t = threadIdx.x;
  const int r0 = (t >> 4) << 2, c0 = (t & 15) << 2;
  const float* ag = a2g + (size_t)bh * 4096;
  const float denom = 1.f / (scal[0] * scal[1]);
  #pragma unroll
  for (int i = 0; i < 4; ++i)
    #pragma unroll
    for (int j = 0; j < 4; ++j)
      z[(r0 + i) * 68 + c0 + j] = ag[(c0 + j) * 64 + r0 + i] * denom;
  __syncthreads();
  float reg[4][4], val[4][4];
  for (int it = 0; it < 6; ++it) {
    mm16v<64, 68>(ag, z, r0, c0, reg);
    #pragma unroll
    for (int i = 0; i < 4; ++i)
      #pragma unroll
      for (int j = 0; j < 4; ++j) az[(r0 + i) * 68 + c0 + j] = reg[i][j];
    __syncthreads();
    mm16v<68, 68>(az, az, r0, c0, reg);
    #pragma unroll
    for (int i = 0; i < 4; ++i)
      #pragma unroll
      for (int j = 0; j < 4; ++j)
        tb[(r0 + i) * 68 + c0 + j] = 7.f * az[(r0 + i) * 68 + c0 + j] - reg[i][j];
    __syncthreads();
    mm16v<68, 68>(az, tb, r0, c0, reg);
    #pragma unroll
    for (int i = 0; i < 4; ++i)
      #pragma unroll
      for (int j = 0; j < 4; ++j)
        val[i][j] = 15.f * az[(r0 + i) * 68 + c0 + j] - reg[i][j];
    __syncthreads();
    #pragma unroll
    for (int i = 0; i < 4; ++i)
      #pragma unroll
      for (int j = 0; j < 4; ++j) tb[(r0 + i) * 68 + c0 + j] = val[i][j];
    __syncthreads();
    mm16v<68, 68>(z, tb, r0, c0, reg);
    #pragma unroll
    for (int i = 0; i < 4; ++i)
      #pragma unroll
      for (int j = 0; j < 4; ++j)
        val[i][j] = 0.25f * (13.f * z[(r0 + i) * 68 + c0 + j] - reg[i][j]);
    __syncthreads();
    #pragma unroll
    for (int i = 0; i < 4; ++i)
      #pragma unroll
      for (int j = 0; j < 4; ++j) z[(r0 + i) * 68 + c0 + j] = val[i][j];
    __syncthreads();
  }
  // fused: w2 = pinv @ a3v, store transposed f16 [bh][d][m]
  mm16v<68, 64>(z, a3vg + (size_t)bh * 4096, r0, c0, reg);
  #pragma unroll
  for (int i = 0; i < 4; ++i)
    #pragma unroll
    for (int j = 0; j < 4; ++j)
      w2t[(size_t)bh * 4096 + (c0 + j) * 64 + (r0 + i)] = (_Float16)reg[i][j];
}

// ------- fused MFMA combine: S=q@kl^T -> softmax -> P@W2 + Toeplitz(res)@v -> att f16 ------
__global__ __launch_bounds__(256) void k_combine_m(
    const _Float16* __restrict__ qx, const _Float16* __restrict__ klh,
    const _Float16* __restrict__ w2t, const _Float16* __restrict__ vx,
    const float* __restrict__ rw, _Float16* __restrict__ att) {
  __shared__ _Float16 sP[64 * 72];
  __shared__ _Float16 sVT[64 * 104];
  __shared__ _Float16 sT[64 * 104];
  __shared__ float sR[33];
  const int t = threadIdx.x, w = t >> 6, lo = t & 15, hi = (t >> 4) & 3;
  const int n0 = blockIdx.x * 64;
  const int h = blockIdx.y, b = blockIdx.z, bh = b * 8 + h;
  if (t < 33) sR[t] = rw[h * 33 + t];
  __syncthreads();
  const _Float16* vb = vx + (size_t)bh * 262144;
  #pragma unroll
  for (int u = 0; u < 24; ++u) {
    int e = t + u * 256;
    int r = e >> 6, d = e & 63;
    int nn = n0 - 16 + r;
    sVT[d * 104 + r] = ((unsigned)nn < 4096u) ? vb[(size_t)nn * 64 + d] : (_Float16)0.f;
  }
  #pragma unroll
  for (int u = 0; u < 24; ++u) {
    int e = t + u * 256;
    int r = e % 96, i = e / 96;
    int j = r - i;
    sT[i * 104 + r] = (j >= 0 && j < 33) ? (_Float16)sR[j] : (_Float16)0.f;
  }
  f32x4 sa[4] = {};
  const _Float16* qp = qx + ((size_t)bh * 4096 + n0 + w * 16 + lo) * 64 + 8 * hi;
  const _Float16* klp = klh + (size_t)bh * 4096;
  #pragma unroll
  for (int c = 0; c < 2; ++c) {
    half8 a = *reinterpret_cast<const half8*>(qp + 32 * c);
    #pragma unroll
    for (int ct = 0; ct < 4; ++ct) {
      half8 bf = *reinterpret_cast<const half8*>(klp + (size_t)(ct * 16 + lo) * 64 + 8 * hi + 32 * c);
      sa[ct] = __builtin_amdgcn_mfma_f32_16x16x32_f16(a, bf, sa[ct], 0, 0, 0);
    }
  }
  #pragma unroll
  for (int r = 0; r < 4; ++r) {
    float mx = fmaxf(fmaxf(sa[0][r], sa[1][r]), fmaxf(sa[2][r], sa[3][r]));
    #pragma unroll
    for (int o = 8; o; o >>= 1) mx = fmaxf(mx, __shfl_xor(mx, o));
    float e0 = expf(sa[0][r] - mx), e1 = expf(sa[1][r] - mx);
    float e2 = expf(sa[2][r] - mx), e3 = expf(sa[3][r] - mx);
    float sm = e0 + e1 + e2 + e3;
    #pragma unroll
    for (int o = 8; o; o >>= 1) sm += __shfl_xor(sm, o);
    float inv = 1.f / sm;
    int row = w * 16 + hi * 4 + r;
    sP[row * 72 + lo] = (_Float16)(e0 * inv);
    sP[row * 72 + 16 + lo] = (_Float16)(e1 * inv);
    sP[row * 72 + 32 + lo] = (_Float16)(e2 * inv);
    sP[row * 72 + 48 + lo] = (_Float16)(e3 * inv);
  }
  __syncthreads();
  f32x4 ao[4] = {};
  const _Float16* w2p = w2t + (size_t)bh * 4096;
  #pragma unroll
  for (int c = 0; c < 2; ++c) {
    half8 a = *reinterpret_cast<const half8*>(&sP[(w * 16 + lo) * 72 + 8 * hi + 32 * c]);
    #pragma unroll
    for (int ct = 0; ct < 4; ++ct) {
      half8 bf = *reinterpret_cast<const half8*>(w2p + (size_t)(ct * 16 + lo) * 64 + 8 * hi + 32 * c);
      ao[ct] = __builtin_amdgcn_mfma_f32_16x16x32_f16(a, bf, ao[ct], 0, 0, 0);
    }
  }
  #pragma unroll
  for (int c = 0; c < 3; ++c) {
    half8 a = *reinterpret_cast<const half8*>(&sT[(w * 16 + lo) * 104 + 8 * hi + 32 * c]);
    #pragma unroll
    for (int ct = 0; ct < 4; ++ct) {
      half8 bf = *reinterpret_cast<const half8*>(&sVT[(ct * 16 + lo) * 104 + 8 * hi + 32 * c]);
      ao[ct] = __builtin_amdgcn_mfma_f32_16x16x32_f16(a, bf, ao[ct], 0, 0, 0);
    }
  }
  _Float16* ab = att + ((size_t)b * 4096) * 512 + (size_t)h * 64;
  #pragma unroll
  for (int ct = 0; ct < 4; ++ct)
    #pragma unroll
    for (int r = 0; r < 4; ++r) {
      int n = n0 + w * 16 + hi * 4 + r;
      ab[(size_t)n * 512 + ct * 16 + lo] = (_Float16)ao[ct][r];
    }
}

// ---------------- LayerNorm in place over E=800, f16 buffer ----------------
__global__ __launch_bounds__(256) void k_ln16(
    _Float16* __restrict__ buf, const float* __restrict__ g, const float* __restrict__ bb) {
  const int t = threadIdx.x;
  _Float16* p = buf + (size_t)blockIdx.x * 800;
  float x0 = (float)p[t], x1 = (float)p[t + 256], x2 = (float)p[t + 512];
  float x3 = (t < 32) ? (float)p[t + 768] : 0.f;
  float s = blockReduceSum(x0 + x1 + x2 + x3);
  float mean = s * (1.f / 800.f);
  float d0 = x0 - mean, d1 = x1 - mean, d2 = x2 - mean;
  float d3 = (t < 32) ? x3 - mean : 0.f;
  float s2 = blockReduceSum(d0 * d0 + d1 * d1 + d2 * d2 + d3 * d3);
  float rstd = rsqrtf(s2 * (1.f / 800.f) + LN_EPS_C);
  p[t] = (_Float16)(d0 * rstd * g[t] + bb[t]);
  p[t + 256] = (_Float16)(d1 * rstd * g[t + 256] + bb[t + 256]);
  p[t + 512] = (_Float16)(d2 * rstd * g[t + 512] + bb[t + 512]);
  if (t < 32) p[t + 768] = (_Float16)(d3 * rstd * g[t + 768] + bb[t + 768]);
}

// ---------------- head MFMA: out[16384,16] = sigmoid(lnb @ hwh^T + hb) ----------------
__global__ __launch_bounds__(256) void k_head_m(
    const _Float16* __restrict__ ln, const _Float16* __restrict__ hwh,
    const float* __restrict__ hb, float* __restrict__ out) {
  const int t = threadIdx.x, w = t >> 6, lo = t & 15, hi = (t >> 4) & 3;
  const int row0 = blockIdx.x * 64 + w * 16;
  const _Float16* ap = ln + (size_t)(row0 + lo) * 800 + 8 * hi;
  const _Float16* bp = hwh + (size_t)lo * 800 + 8 * hi;
  f32x4 acc = {};
  #pragma unroll 5
  for (int k = 0; k < 800; k += 32) {
    half8 a = *reinterpret_cast<const half8*>(ap + k);
    half8 b = *reinterpret_cast<const half8*>(bp + k);
    acc = __builtin_amdgcn_mfma_f32_16x16x32_f16(a, b, acc, 0, 0, 0);
  }
  float bv = hb[lo];
  #pragma unroll
  for (int r = 0; r < 4; ++r) {
    int row = row0 + hi * 4 + r;
    out[(size_t)row * 16 + lo] = 1.f / (1.f + expf(-(acc[r] + bv)));
  }
}

// ---------------- launcher ----------------
extern "C" void kernel_launch(void* const* d_in, const int* in_sizes, int n_in,
                              void* d_out, int out_size, void* d_ws, size_t ws_size,
                              hipStream_t stream) {
  (void)in_sizes; (void)n_in; (void)out_size; (void)ws_size;
  const float* x     = (const float*)d_in[0];
  const float* w0    = (const float*)d_in[1];
  const float* b0    = (const float*)d_in[2];
  const float* g0    = (const float*)d_in[3];
  const float* be0   = (const float*)d_in[4];
  const float* mu0   = (const float*)d_in[5];
  const float* var0  = (const float*)d_in[6];
  const float* w1    = (const float*)d_in[7];
  const float* b1    = (const float*)d_in[8];
  const float* g1    = (const float*)d_in[9];
  const float* be1   = (const float*)d_in[10];
  const float* mu1   = (const float*)d_in[11];
  const float* var1  = (const float*)d_in[12];
  const float* w2c   = (const float*)d_in[13];
  const float* b2    = (const float*)d_in[14];
  const float* g2    = (const float*)d_in[15];
  const float* be2   = (const float*)d_in[16];
  const float* mu2   = (const float*)d_in[17];
  const float* var2  = (const float*)d_in[18];
  const float* w3    = (const float*)d_in[19];
  const float* b3    = (const float*)d_in[20];
  const float* g3    = (const float*)d_in[21];
  const float* be3   = (const float*)d_in[22];
  const float* mu3   = (const float*)d_in[23];
  const float* var3  = (const float*)d_in[24];
  const float* qkvw  = (const float*)d_in[25];
  const float* outw  = (const float*)d_in[26];
  const float* outbv = (const float*)d_in[27];
  const float* resw  = (const float*)d_in[28];
  const float* lng   = (const float*)d_in[29];
  const float* lnbv  = (const float*)d_in[30];
  const float* headw = (const float*)d_in[31];
  const float* headb = (const float*)d_in[32];

  char* wsb = (char*)d_ws;
  _Float16* h0   = (_Float16*)(wsb + B_H0);
  _Float16* h1   = (_Float16*)(wsb + B_H1);
  _Float16* h2   = (_Float16*)(wsb + B_H2);
  _Float16* qb   = (_Float16*)(wsb + B_Q);
  _Float16* vb   = (_Float16*)(wsb + B_V);
  _Float16* kT   = (_Float16*)(wsb + B_KT);
  _Float16* tok  = (_Float16*)(wsb + B_TOK);
  _Float16* attb = (_Float16*)(wsb + B_ATT);
  _Float16* wp1  = (_Float16*)(wsb + B_WP1);
  _Float16* wp2  = (_Float16*)(wsb + B_WP2);
  _Float16* wp3  = (_Float16*)(wsb + B_WP3);
  _Float16* qkvT = (_Float16*)(wsb + B_QKVT);
  _Float16* owT  = (_Float16*)(wsb + B_OWT);
  _Float16* klh  = (_Float16*)(wsb + B_KLH);
  _Float16* w2t  = (_Float16*)(wsb + B_W2T);
  _Float16* hwh  = (_Float16*)(wsb + B_HWH);
  _Float16* lnb16 = (_Float16*)(wsb + B_LNB);
  float* ql   = (float*)(wsb + B_QL);
  float* kl   = (float*)(wsb + B_KL);
  float* a2   = (float*)(wsb + B_A2);
  float* a3v  = (float*)(wsb + B_A3V);
  float* scal = (float*)(wsb + B_SCAL);

  // all weight packing + scal init in one launch
  k_pack_all<<<dim3(20691), 256, 0, stream>>>(
      w1, w2c, w3, qkvw, outw, headw, wp1, wp2, wp3, qkvT, owT, hwh, scal);

  // conv stack: conv0..conv2 per image (h0/h1 scratch), h2 kept full-batch
  for (int img = 0; img < 4; ++img) {
    k_conv0<<<dim3(256), 256, 0, stream>>>(
        x + (size_t)img * 65536, w0, b0, g0, be0, mu0, var0, h0);
    k_convs<64><<<dim3(512), 256, 0, stream>>>(
        h0, wp1, b1, g1, be1, mu1, var1, h1, 128, 1);
    k_convs<128><<<dim3(1024), 256, 0, stream>>>(
        h1, wp2, b2, g2, be2, mu2, var2, h2 + (size_t)img * 16777216, 256, 2);
  }
  // conv3 (patch conv) over the full batch: staged GEMM, 640 XCD-swizzled blocks
  k_c3<<<dim3(640), 256, 0, stream>>>(h2, wp3, b3, g3, be3, mu3, var3, tok);
  // attention (k written directly transposed; landmarks fused into qkv epilogue)
  k_qkv_s<<<dim3(1536), 256, 0, stream>>>(tok, qkvT, qb, kT, vb, ql, kl, klh);
  k_a2<<<dim3(32), 64, 0, stream>>>(ql, kl, a2, scal);
  k_a3v<<<dim3(64, 32), 256, 0, stream>>>(ql, kT, vb, a3v);
  k_pinv<<<dim3(32), 256, 0, stream>>>(a2, scal, a3v, w2t);
  k_combine_m<<<dim3(64, 8, 4), 256, 0, stream>>>(qb, klh, w2t, vb, resw, attb);
  // projection + LN + head
  k_op_s<<<dim3(640), 256, 0, stream>>>(attb, owT, outbv, lnb16);
  k_ln16<<<dim3(16384), 256, 0, stream>>>(lnb16, lng, lnbv);
  k_head_m<<<dim3(256), 256, 0, stream>>>(lnb16, hwh, headb, (float*)d_out);
}

// Round 11
// 947.834 us; speedup vs baseline: 12.1586x; 1.1757x over previous
//
#include <hip/hip_runtime.h>

#define DI __device__ __forceinline__

constexpr float BN_EPS_C = 1e-5f;
constexpr float LN_EPS_C = 1e-5f;

typedef _Float16 half8 __attribute__((ext_vector_type(8)));
typedef float f32x4 __attribute__((ext_vector_type(4)));

// ---------------- workspace layout (BYTE offsets), peak ~199.34 MB ----------------
constexpr size_t B_H0   = 0;             // f16 [256][256][64]  per-image scratch
constexpr size_t B_H1   = 8388608;       // f16 [256][256][128] per-image scratch
constexpr size_t B_H2   = 25165824;      // f16 [4][256][256][256] = 134,217,728 (full batch)
// overlays inside the h2 region once h2 is dead (after k_c3):
constexpr size_t B_Q    = 25165824;      // f16 [32][4096][64] = 16,777,216
constexpr size_t B_V    = 58720256;      // f16 16,777,216
constexpr size_t B_KT   = 75497472;      // f16 [32][64][4096] = 16,777,216
constexpr size_t B_ATT  = 92274688;      // f16 [16384][512] = 16,777,216
constexpr size_t B_LNB  = 25165824;      // f16 [16384][800] = 26,214,400 (q dead by outproj)
// tok + packed weights + small buffers:
constexpr size_t B_TOK  = 159383552;     // f16 [16384][800] = 26,214,400
constexpr size_t B_WP1  = 185597952;     // 147,456
constexpr size_t B_WP2  = 185745408;     // 589,824
constexpr size_t B_WP3  = 186335232;     // 6,553,600
constexpr size_t B_QKVT = 192888832;     // 2,457,600
constexpr size_t B_OWT  = 195346432;     // 819,200
constexpr size_t B_QL   = 196165632;     // f32 524,288
constexpr size_t B_KL   = 196689920;
constexpr size_t B_KLH  = 197214208;     // f16 262,144
constexpr size_t B_A2   = 197476352;
constexpr size_t B_W2T  = 198524928;     // f16 262,144
constexpr size_t B_A3V  = 198787072;
constexpr size_t B_SCAL = 199311360;     // 2 floats
constexpr size_t B_HWH  = 199311424;     // f16 [16][800] = 25,600 (end 199,337,024)

// ---------------- helpers ----------------
DI float blockReduceSum(float v) {
  #pragma unroll
  for (int o = 32; o; o >>= 1) v += __shfl_xor(v, o);
  __shared__ float red[4];
  int w = threadIdx.x >> 6;
  __syncthreads();
  if ((threadIdx.x & 63) == 0) red[w] = v;
  __syncthreads();
  return red[0] + red[1] + red[2] + red[3];
}

// float4-vectorized 64-deep 4x4 tile product (rows must be 16B-aligned: LP,RP mult of 4)
template <int LP, int RP>
DI void mm16v(const float* L, const float* R, int r0, int c0, float reg[4][4]) {
  #pragma unroll
  for (int i = 0; i < 4; ++i)
    #pragma unroll
    for (int j = 0; j < 4; ++j) reg[i][j] = 0.f;
  #pragma unroll 4
  for (int dd = 0; dd < 64; dd += 4) {
    f32x4 l[4], rv[4];
    #pragma unroll
    for (int i = 0; i < 4; ++i)
      l[i] = *reinterpret_cast<const f32x4*>(&L[(size_t)(r0 + i) * LP + dd]);
    #pragma unroll
    for (int u = 0; u < 4; ++u)
      rv[u] = *reinterpret_cast<const f32x4*>(&R[(size_t)(dd + u) * RP + c0]);
    #pragma unroll
    for (int i = 0; i < 4; ++i)
      #pragma unroll
      for (int u = 0; u < 4; ++u)
        #pragma unroll
        for (int j = 0; j < 4; ++j)
          reg[i][j] = fmaf(l[i][u], rv[u][j], reg[i][j]);
  }
}

// ---------------- mega-pack: all weight packs + scal init in one launch ----------------
__global__ void k_pack_all(
    const float* __restrict__ w1, const float* __restrict__ w2c, const float* __restrict__ w3,
    const float* __restrict__ qkvw, const float* __restrict__ outw, const float* __restrict__ headw,
    _Float16* __restrict__ wp1, _Float16* __restrict__ wp2, _Float16* __restrict__ wp3,
    _Float16* __restrict__ qkvT, _Float16* __restrict__ owT, _Float16* __restrict__ hwh,
    float* __restrict__ scal) {
  size_t i = (size_t)blockIdx.x * 256 + threadIdx.x;
  if (i < 73728) {
    int q = i % 9, ci = (i / 9) % 64, co = i / (9 * 64);
    wp1[((size_t)co * 9 + q) * 64 + ci] = (_Float16)w1[i];
  } else if (i < 368640) {
    size_t j = i - 73728;
    int q = j % 9, ci = (j / 9) % 128, co = j / (9 * 128);
    wp2[((size_t)co * 9 + q) * 128 + ci] = (_Float16)w2c[j];
  } else if (i < 3645440) {
    size_t j = i - 368640;
    int q = j % 16, ci = (j / 16) % 256, co = j / (16 * 256);
    wp3[((size_t)co * 16 + q) * 256 + ci] = (_Float16)w3[j];
  } else if (i < 4874240) {
    size_t j = i - 3645440;
    int n = j % 1536, k = j / 1536;
    qkvT[(size_t)n * 800 + k] = (_Float16)qkvw[j];
  } else if (i < 5283840) {
    size_t j = i - 4874240;
    int n = j % 800, k = j / 800;
    owT[(size_t)n * 512 + k] = (_Float16)outw[j];
  } else if (i < 5296640) {
    size_t j = i - 5283840;
    int n = j % 16, k = j / 16;
    hwh[(size_t)n * 800 + k] = (_Float16)headw[j];
  } else if (i < 5296642) {
    scal[i - 5296640] = 0.f;
  }
}

// ---------------- conv0: CI=1 fp32 direct conv -> h0 NHWC f16, grid (256y, 4xq) -----------
__global__ __launch_bounds__(256) void k_conv0(
    const float* __restrict__ xb, const float* __restrict__ w0, const float* __restrict__ b0,
    const float* __restrict__ g0, const float* __restrict__ be0, const float* __restrict__ mu0,
    const float* __restrict__ var0, _Float16* __restrict__ h0) {
  const int t = threadIdx.x, co = t & 63, xg = t >> 6;
  const int y = blockIdx.x;
  const int x0 = blockIdx.y * 64 + xg * 16;
  float wreg[9];
  #pragma unroll
  for (int q = 0; q < 9; ++q) wreg[q] = w0[co * 9 + q];
  float s = g0[co] * rsqrtf(var0[co] + BN_EPS_C);
  float sh = fmaf(b0[co] - mu0[co], s, be0[co]);
  #pragma unroll 4
  for (int xl = 0; xl < 16; ++xl) {
    int xx = x0 + xl;
    float acc = 0.f;
    #pragma unroll
    for (int dy = 0; dy < 3; ++dy) {
      int yy = y + dy - 1;
      if ((unsigned)yy >= 256u) continue;
      #pragma unroll
      for (int dx = 0; dx < 3; ++dx) {
        int xi = xx + dx - 1;
        if ((unsigned)xi >= 256u) continue;
        acc = fmaf(wreg[dy * 3 + dx], xb[yy * 256 + xi], acc);
      }
    }
    float v = fmaxf(fmaf(acc, s, sh), 0.f);
    h0[((size_t)y * 256 + xx) * 64 + co] = (_Float16)v;
  }
}

// ------- staged implicit-im2col 3x3 conv GEMM: tile 128x128 ---------------
template <int CI>
__global__ __launch_bounds__(256) void k_convs(
    const _Float16* __restrict__ in, const _Float16* __restrict__ wp,
    const float* __restrict__ bias, const float* __restrict__ g, const float* __restrict__ be,
    const float* __restrict__ mu, const float* __restrict__ var,
    _Float16* __restrict__ out, int CO, int NCT) {
  __shared__ _Float16 Ab[2][128 * 40];
  __shared__ _Float16 Bb[2][128 * 40];
  constexpr int CPQ = CI / 32;
  constexpr int NCK = 9 * CPQ;
  const int t = threadIdx.x;
  const int bid = blockIdx.x;
  const int xcd = bid & 7, slot = bid >> 3;
  const int pj = slot / NCT, cc = slot % NCT;
  const int p = pj * 8 + xcd;
  const int r0 = p * 128, c0 = cc * 128;

  const int ma = t >> 2, kga = t & 3;
  int ry[2], rx[2];
  #pragma unroll
  for (int s = 0; s < 2; ++s) {
    int r = r0 + ma + s * 64;
    ry[s] = r >> 8;
    rx[s] = r & 255;
  }
  const _Float16* baseB[2];
  #pragma unroll
  for (int s = 0; s < 2; ++s)
    baseB[s] = wp + (size_t)(c0 + ma + s * 64) * 9 * CI + kga * 8;
  const int wo = ma * 40 + kga * 8;

  auto loadA = [&](int s, int ck) -> half8 {
    int q = ck / CPQ, coff = (ck % CPQ) * 32;
    int yy = ry[s] + q / 3 - 1;
    int xx = rx[s] + q % 3 - 1;
    half8 a = {};
    if ((unsigned)yy < 256u && (unsigned)xx < 256u)
      a = *reinterpret_cast<const half8*>(in + ((size_t)yy * 256 + xx) * CI + coff + kga * 8);
    return a;
  };

  {
    half8 a0 = loadA(0, 0), a1 = loadA(1, 0);
    half8 b0v = *reinterpret_cast<const half8*>(baseB[0]);
    half8 b1v = *reinterpret_cast<const half8*>(baseB[1]);
    *reinterpret_cast<half8*>(&Ab[0][wo]) = a0;
    *reinterpret_cast<half8*>(&Ab[0][wo + 2560]) = a1;
    *reinterpret_cast<half8*>(&Bb[0][wo]) = b0v;
    *reinterpret_cast<half8*>(&Bb[0][wo + 2560]) = b1v;
  }
  __syncthreads();

  const int w = t >> 6, lo = t & 15, hi = (t >> 4) & 3;
  const int wm = w >> 1, wn = w & 1;
  const int roA = (wm * 64 + lo) * 40 + 8 * hi;
  const int roB = (wn * 64 + lo) * 40 + 8 * hi;
  f32x4 acc[4][4] = {};

  for (int ck = 0; ck < NCK; ++ck) {
    const int cur = ck & 1;
    const bool more = (ck + 1 < NCK);
    half8 rA0, rA1, rB0, rB1;
    if (more) {
      rA0 = loadA(0, ck + 1);
      rA1 = loadA(1, ck + 1);
      rB0 = *reinterpret_cast<const half8*>(baseB[0] + (ck + 1) * 32);
      rB1 = *reinterpret_cast<const half8*>(baseB[1] + (ck + 1) * 32);
    }
    half8 af[4], bf[4];
    #pragma unroll
    for (int mi = 0; mi < 4; ++mi)
      af[mi] = *reinterpret_cast<const half8*>(&Ab[cur][roA + mi * 640]);
    #pragma unroll
    for (int ni = 0; ni < 4; ++ni)
      bf[ni] = *reinterpret_cast<const half8*>(&Bb[cur][roB + ni * 640]);
    #pragma unroll
    for (int mi = 0; mi < 4; ++mi)
      #pragma unroll
      for (int ni = 0; ni < 4; ++ni)
        acc[mi][ni] = __builtin_amdgcn_mfma_f32_16x16x32_f16(af[mi], bf[ni], acc[mi][ni], 0, 0, 0);
    if (more) {
      *reinterpret_cast<half8*>(&Ab[cur ^ 1][wo]) = rA0;
      *reinterpret_cast<half8*>(&Ab[cur ^ 1][wo + 2560]) = rA1;
      *reinterpret_cast<half8*>(&Bb[cur ^ 1][wo]) = rB0;
      *reinterpret_cast<half8*>(&Bb[cur ^ 1][wo + 2560]) = rB1;
    }
    __syncthreads();
  }

  #pragma unroll
  for (int ni = 0; ni < 4; ++ni) {
    int co = c0 + wn * 64 + ni * 16 + lo;
    float s = g[co] * rsqrtf(var[co] + BN_EPS_C);
    float sh = fmaf(bias[co] - mu[co], s, be[co]);
    #pragma unroll
    for (int mi = 0; mi < 4; ++mi)
      #pragma unroll
      for (int rr = 0; rr < 4; ++rr) {
        int row = r0 + wm * 64 + mi * 16 + hi * 4 + rr;
        float v = fmaxf(fmaf(acc[mi][ni][rr], s, sh), 0.f);
        out[(size_t)row * CO + co] = (_Float16)v;
      }
  }
}

// ---------------- conv3 MFMA: staged GEMM, 128x160 tile, XCD-swizzled ----------
__global__ __launch_bounds__(256) void k_c3(
    const _Float16* __restrict__ h2, const _Float16* __restrict__ wp3,
    const float* __restrict__ b3, const float* __restrict__ g3, const float* __restrict__ be3,
    const float* __restrict__ mu3, const float* __restrict__ var3,
    _Float16* __restrict__ tok) {
  __shared__ _Float16 Abuf[2][128 * 40];
  __shared__ _Float16 Bbuf[2][160 * 40];
  const int t = threadIdx.x;
  const int bid = blockIdx.x;
  const int xcd = bid & 7, slot = bid >> 3;
  const int pj = slot / 5, cc = slot % 5;
  const int p = pj * 8 + xcd;
  const int r0 = p * 128, c0 = cc * 160;
  const int img = r0 >> 12;
  const _Float16* h2i = h2 + (size_t)img * 16777216;

  const int ma = t >> 2, kga = t & 3;
  const _Float16* baseA[2];
  #pragma unroll
  for (int s = 0; s < 2; ++s) {
    int m = ma + s * 64;
    int r = r0 + m;
    int py = (r & 4095) >> 6, px = r & 63;
    baseA[s] = h2i + ((size_t)py * 1024 + px * 4) * 256 + kga * 8;
  }
  const _Float16* baseB[3];
  #pragma unroll
  for (int s = 0; s < 3; ++s) {
    int cb = ma + s * 64;
    baseB[s] = wp3 + (size_t)(c0 + (cb < 160 ? cb : 159)) * 4096 + kga * 8;
  }
  const int wo = ma * 40 + kga * 8;

  const int w = t >> 6, lo = t & 15, hi = (t >> 4) & 3;
  const int wm = w >> 1, wn = w & 1;
  const int roA = (wm * 64 + lo) * 40 + 8 * hi;
  const int roB = (wn * 80 + lo) * 40 + 8 * hi;

  f32x4 acc[4][5] = {};

  {
    half8 a0 = *reinterpret_cast<const half8*>(baseA[0]);
    half8 a1 = *reinterpret_cast<const half8*>(baseA[1]);
    half8 b0v = *reinterpret_cast<const half8*>(baseB[0]);
    half8 b1v = *reinterpret_cast<const half8*>(baseB[1]);
    *reinterpret_cast<half8*>(&Abuf[0][wo]) = a0;
    *reinterpret_cast<half8*>(&Abuf[0][wo + 2560]) = a1;
    *reinterpret_cast<half8*>(&Bbuf[0][wo]) = b0v;
    *reinterpret_cast<half8*>(&Bbuf[0][wo + 2560]) = b1v;
    if (t < 128) {
      half8 b2v = *reinterpret_cast<const half8*>(baseB[2]);
      *reinterpret_cast<half8*>(&Bbuf[0][wo + 5120]) = b2v;
    }
  }
  __syncthreads();

  for (int ck = 0; ck < 128; ++ck) {
    const int cur = ck & 1;
    const bool more = (ck + 1 < 128);
    half8 rA0, rA1, rB0, rB1, rB2;
    if (more) {
      const int kn = (ck + 1) << 5;
      const int q = kn >> 8, qk = kn & 255;
      const int aoff = (q >> 2) * 65536 + (q & 3) * 256 + qk;
      rA0 = *reinterpret_cast<const half8*>(baseA[0] + aoff);
      rA1 = *reinterpret_cast<const half8*>(baseA[1] + aoff);
      rB0 = *reinterpret_cast<const half8*>(baseB[0] + kn);
      rB1 = *reinterpret_cast<const half8*>(baseB[1] + kn);
      if (t < 128) rB2 = *reinterpret_cast<const half8*>(baseB[2] + kn);
    }
    half8 af[4], bf[5];
    #pragma unroll
    for (int mi = 0; mi < 4; ++mi)
      af[mi] = *reinterpret_cast<const half8*>(&Abuf[cur][roA + mi * 640]);
    #pragma unroll
    for (int ni = 0; ni < 5; ++ni)
      bf[ni] = *reinterpret_cast<const half8*>(&Bbuf[cur][roB + ni * 640]);
    #pragma unroll
    for (int mi = 0; mi < 4; ++mi)
      #pragma unroll
      for (int ni = 0; ni < 5; ++ni)
        acc[mi][ni] = __builtin_amdgcn_mfma_f32_16x16x32_f16(af[mi], bf[ni], acc[mi][ni], 0, 0, 0);
    if (more) {
      *reinterpret_cast<half8*>(&Abuf[cur ^ 1][wo]) = rA0;
      *reinterpret_cast<half8*>(&Abuf[cur ^ 1][wo + 2560]) = rA1;
      *reinterpret_cast<half8*>(&Bbuf[cur ^ 1][wo]) = rB0;
      *reinterpret_cast<half8*>(&Bbuf[cur ^ 1][wo + 2560]) = rB1;
      if (t < 128) *reinterpret_cast<half8*>(&Bbuf[cur ^ 1][wo + 5120]) = rB2;
    }
    __syncthreads();
  }

  #pragma unroll
  for (int ni = 0; ni < 5; ++ni) {
    int col = c0 + wn * 80 + ni * 16 + lo;
    float s = g3[col] * rsqrtf(var3[col] + BN_EPS_C);
    float sh = fmaf(b3[col] - mu3[col], s, be3[col]);
    #pragma unroll
    for (int mi = 0; mi < 4; ++mi)
      #pragma unroll
      for (int rr = 0; rr < 4; ++rr) {
        int row = r0 + wm * 64 + mi * 16 + hi * 4 + rr;
        float v = fmaxf(fmaf(acc[mi][ni][rr], s, sh), 0.f);
        tok[(size_t)row * 800 + col] = (_Float16)v;
      }
  }
}

// ---------------- qkv staged GEMM + fused landmarks; kT via LDS transpose -----------------
__global__ __launch_bounds__(256) void k_qkv_s(
    const _Float16* __restrict__ tok, const _Float16* __restrict__ qkvT,
    _Float16* __restrict__ qx, _Float16* __restrict__ kTg, _Float16* __restrict__ vx,
    float* __restrict__ ql, float* __restrict__ kl, _Float16* __restrict__ klh) {
  __shared__ _Float16 SH[20480];           // Ab[2][5120] | Bb[2][5120]; reused for transpose
  _Float16* AbP = SH;
  _Float16* BbP = SH + 10240;
  const int t = threadIdx.x;
  const int bid = blockIdx.x;
  const int xcd = bid & 7, slot = bid >> 3;
  const int pj = slot / 12, cc = slot % 12;
  const int p = pj * 8 + xcd;
  const int r0 = p * 128, c0 = cc * 128;

  const int ma = t >> 2, kga = t & 3;
  const _Float16* baseA[2];
  const _Float16* baseB[2];
  #pragma unroll
  for (int s = 0; s < 2; ++s) {
    baseA[s] = tok + (size_t)(r0 + ma + s * 64) * 800 + kga * 8;
    baseB[s] = qkvT + (size_t)(c0 + ma + s * 64) * 800 + kga * 8;
  }
  const int wo = ma * 40 + kga * 8;

  {
    half8 a0 = *reinterpret_cast<const half8*>(baseA[0]);
    half8 a1 = *reinterpret_cast<const half8*>(baseA[1]);
    half8 b0v = *reinterpret_cast<const half8*>(baseB[0]);
    half8 b1v = *reinterpret_cast<const half8*>(baseB[1]);
    *reinterpret_cast<half8*>(&AbP[wo]) = a0;
    *reinterpret_cast<half8*>(&AbP[wo + 2560]) = a1;
    *reinterpret_cast<half8*>(&BbP[wo]) = b0v;
    *reinterpret_cast<half8*>(&BbP[wo + 2560]) = b1v;
  }
  __syncthreads();

  const int w = t >> 6, lo = t & 15, hi = (t >> 4) & 3;
  const int wm = w >> 1, wn = w & 1;
  const int roA = (wm * 64 + lo) * 40 + 8 * hi;
  const int roB = (wn * 64 + lo) * 40 + 8 * hi;
  f32x4 acc[4][4] = {};

  for (int ck = 0; ck < 25; ++ck) {
    const int cur = ck & 1;
    const bool more = (ck + 1 < 25);
    half8 rA0, rA1, rB0, rB1;
    if (more) {
      const int kn = (ck + 1) * 32;
      rA0 = *reinterpret_cast<const half8*>(baseA[0] + kn);
      rA1 = *reinterpret_cast<const half8*>(baseA[1] + kn);
      rB0 = *reinterpret_cast<const half8*>(baseB[0] + kn);
      rB1 = *reinterpret_cast<const half8*>(baseB[1] + kn);
    }
    half8 af[4], bf[4];
    #pragma unroll
    for (int mi = 0; mi < 4; ++mi)
      af[mi] = *reinterpret_cast<const half8*>(&AbP[cur * 5120 + roA + mi * 640]);
    #pragma unroll
    for (int ni = 0; ni < 4; ++ni)
      bf[ni] = *reinterpret_cast<const half8*>(&BbP[cur * 5120 + roB + ni * 640]);
    #pragma unroll
    for (int mi = 0; mi < 4; ++mi)
      #pragma unroll
      for (int ni = 0; ni < 4; ++ni)
        acc[mi][ni] = __builtin_amdgcn_mfma_f32_16x16x32_f16(af[mi], bf[ni], acc[mi][ni], 0, 0, 0);
    if (more) {
      *reinterpret_cast<half8*>(&AbP[(cur ^ 1) * 5120 + wo]) = rA0;
      *reinterpret_cast<half8*>(&AbP[(cur ^ 1) * 5120 + wo + 2560]) = rA1;
      *reinterpret_cast<half8*>(&BbP[(cur ^ 1) * 5120 + wo]) = rB0;
      *reinterpret_cast<half8*>(&BbP[(cur ^ 1) * 5120 + wo + 2560]) = rB1;
    }
    __syncthreads();
  }

  const int seg = cc >> 2;
  const int b = r0 >> 12;
  const int m = ((r0 & 4095) >> 6) + wm;   // this wave's landmark group
  if (seg == 1) {
    // k: transpose the 128x128 tile through LDS, write kT[bh][d][n] coalesced
    #pragma unroll
    for (int ni = 0; ni < 4; ++ni) {
      int cl = wn * 64 + ni * 16 + lo;
      #pragma unroll
      for (int mi = 0; mi < 4; ++mi)
        #pragma unroll
        for (int rr = 0; rr < 4; ++rr) {
          int nl = wm * 64 + mi * 16 + hi * 4 + rr;
          SH[cl * 136 + nl] = (_Float16)acc[mi][ni][rr];
        }
    }
    __syncthreads();
    const int base_row = b * 512 + (cc & 3) * 128;   // kT row = (b*8+h)*64+d, contiguous
    const int base_n = (p & 31) * 128;
    #pragma unroll
    for (int e = t; e < 2048; e += 256) {
      int cl = e >> 4, ch = e & 15;
      half8 vvv = *reinterpret_cast<const half8*>(&SH[cl * 136 + ch * 8]);
      *reinterpret_cast<half8*>(&kTg[(size_t)(base_row + cl) * 4096 + base_n + ch * 8]) = vvv;
    }
  } else {
    const float scale = (seg == 0) ? 0.125f : 1.0f;
    _Float16* dst = (seg == 0) ? qx : vx;
    #pragma unroll
    for (int ni = 0; ni < 4; ++ni) {
      int cseg = (cc & 3) * 128 + wn * 64 + ni * 16 + lo;
      int h = cseg >> 6, d = cseg & 63;
      #pragma unroll
      for (int mi = 0; mi < 4; ++mi)
        #pragma unroll
        for (int rr = 0; rr < 4; ++rr) {
          int row = r0 + wm * 64 + mi * 16 + hi * 4 + rr;
          int nn = row & 4095;
          dst[((size_t)(b * 8 + h) * 4096 + nn) * 64 + d] = (_Float16)(acc[mi][ni][rr] * scale);
        }
    }
  }
  // fused landmark means for q (seg 0) and k (seg 1)
  if (seg <= 1) {
    const float lscale = ((seg == 0) ? 0.125f : 1.0f) * (1.f / 64.f);
    #pragma unroll
    for (int ni = 0; ni < 4; ++ni) {
      float sum = 0.f;
      #pragma unroll
      for (int mi = 0; mi < 4; ++mi)
        #pragma unroll
        for (int rr = 0; rr < 4; ++rr) sum += acc[mi][ni][rr];
      sum += __shfl_xor(sum, 16);
      sum += __shfl_xor(sum, 32);
      if (hi == 0) {
        int cseg = (cc & 3) * 128 + wn * 64 + ni * 16 + lo;
        int h = cseg >> 6, d = cseg & 63;
        int bh = b * 8 + h;
        float lm = sum * lscale;
        if (seg == 0) {
          ql[((size_t)bh * 64 + m) * 64 + d] = lm;
        } else {
          kl[((size_t)bh * 64 + m) * 64 + d] = lm;
          klh[((size_t)bh * 64 + m) * 64 + d] = (_Float16)lm;
        }
      }
    }
  }
}

// ---------------- out-proj staged GEMM: M=16384, N=800 (5x160), K=512 -> f16 lnb ---------
__global__ __launch_bounds__(256) void k_op_s(
    const _Float16* __restrict__ attb, const _Float16* __restrict__ owT,
    const float* __restrict__ ob, _Float16* __restrict__ lnb) {
  __shared__ _Float16 Abuf[2][128 * 40];
  __shared__ _Float16 Bbuf[2][160 * 40];
  const int t = threadIdx.x;
  const int bid = blockIdx.x;
  const int xcd = bid & 7, slot = bid >> 3;
  const int pj = slot / 5, cc = slot % 5;
  const int p = pj * 8 + xcd;
  const int r0 = p * 128, c0 = cc * 160;

  const int ma = t >> 2, kga = t & 3;
  const _Float16* baseA[2];
  #pragma unroll
  for (int s = 0; s < 2; ++s)
    baseA[s] = attb + (size_t)(r0 + ma + s * 64) * 512 + kga * 8;
  const _Float16* baseB[3];
  #pragma unroll
  for (int s = 0; s < 3; ++s) {
    int cb = ma + s * 64;
    baseB[s] = owT + (size_t)(c0 + (cb < 160 ? cb : 159)) * 512 + kga * 8;
  }
  const int wo = ma * 40 + kga * 8;

  const int w = t >> 6, lo = t & 15, hi = (t >> 4) & 3;
  const int wm = w >> 1, wn = w & 1;
  const int roA = (wm * 64 + lo) * 40 + 8 * hi;
  const int roB = (wn * 80 + lo) * 40 + 8 * hi;

  f32x4 acc[4][5] = {};

  {
    half8 a0 = *reinterpret_cast<const half8*>(baseA[0]);
    half8 a1 = *reinterpret_cast<const half8*>(baseA[1]);
    half8 b0v = *reinterpret_cast<const half8*>(baseB[0]);
    half8 b1v = *reinterpret_cast<const half8*>(baseB[1]);
    *reinterpret_cast<half8*>(&Abuf[0][wo]) = a0;
    *reinterpret_cast<half8*>(&Abuf[0][wo + 2560]) = a1;
    *reinterpret_cast<half8*>(&Bbuf[0][wo]) = b0v;
    *reinterpret_cast<half8*>(&Bbuf[0][wo + 2560]) = b1v;
    if (t < 128) {
      half8 b2v = *reinterpret_cast<const half8*>(baseB[2]);
      *reinterpret_cast<half8*>(&Bbuf[0][wo + 5120]) = b2v;
    }
  }
  __syncthreads();

  for (int ck = 0; ck < 16; ++ck) {
    const int cur = ck & 1;
    const bool more = (ck + 1 < 16);
    half8 rA0, rA1, rB0, rB1, rB2;
    if (more) {
      const int kn = (ck + 1) << 5;
      rA0 = *reinterpret_cast<const half8*>(baseA[0] + kn);
      rA1 = *reinterpret_cast<const half8*>(baseA[1] + kn);
      rB0 = *reinterpret_cast<const half8*>(baseB[0] + kn);
      rB1 = *reinterpret_cast<const half8*>(baseB[1] + kn);
      if (t < 128) rB2 = *reinterpret_cast<const half8*>(baseB[2] + kn);
    }
    half8 af[4], bf[5];
    #pragma unroll
    for (int mi = 0; mi < 4; ++mi)
      af[mi] = *reinterpret_cast<const half8*>(&Abuf[cur][roA + mi * 640]);
    #pragma unroll
    for (int ni = 0; ni < 5; ++ni)
      bf[ni] = *reinterpret_cast<const half8*>(&Bbuf[cur][roB + ni * 640]);
    #pragma unroll
    for (int mi = 0; mi < 4; ++mi)
      #pragma unroll
      for (int ni = 0; ni < 5; ++ni)
        acc[mi][ni] = __builtin_amdgcn_mfma_f32_16x16x32_f16(af[mi], bf[ni], acc[mi][ni], 0, 0, 0);
    if (more) {
      *reinterpret_cast<half8*>(&Abuf[cur ^ 1][wo]) = rA0;
      *reinterpret_cast<half8*>(&Abuf[cur ^ 1][wo + 2560]) = rA1;
      *reinterpret_cast<half8*>(&Bbuf[cur ^ 1][wo]) = rB0;
      *reinterpret_cast<half8*>(&Bbuf[cur ^ 1][wo + 2560]) = rB1;
      if (t < 128) *reinterpret_cast<half8*>(&Bbuf[cur ^ 1][wo + 5120]) = rB2;
    }
    __syncthreads();
  }

  #pragma unroll
  for (int ni = 0; ni < 5; ++ni) {
    int col = c0 + wn * 80 + ni * 16 + lo;
    float bv = ob[col];
    #pragma unroll
    for (int mi = 0; mi < 4; ++mi)
      #pragma unroll
      for (int rr = 0; rr < 4; ++rr) {
        int row = r0 + wm * 64 + mi * 16 + hi * 4 + rr;
        lnb[(size_t)row * 800 + col] = (_Float16)(acc[mi][ni][rr] + bv);
      }
  }
}

// ---------------- a2 + global max row/col sums ----------------
__global__ __launch_bounds__(64) void k_a2(
    const float* __restrict__ ql, const float* __restrict__ kl,
    float* __restrict__ a2, float* __restrict__ scal) {
  __shared__ float sp[64 * 65];
  const int bh = blockIdx.x, t = threadIdx.x;
  const float* qr = ql + ((size_t)bh * 64 + t) * 64;
  const float* kb = kl + (size_t)bh * 4096;
  float mx = -1e30f;
  for (int c = 0; c < 64; ++c) {
    float acc = 0.f;
    #pragma unroll 8
    for (int dd = 0; dd < 64; ++dd) acc = fmaf(qr[dd], kb[c * 64 + dd], acc);
    sp[t * 65 + c] = acc;
    mx = fmaxf(mx, acc);
  }
  float sum = 0.f;
  for (int c = 0; c < 64; ++c) {
    float e = expf(sp[t * 65 + c] - mx);
    sp[t * 65 + c] = e;
    sum += e;
  }
  float inv = 1.f / sum;
  float rs = 0.f;
  for (int c = 0; c < 64; ++c) {
    float p = sp[t * 65 + c] * inv;
    sp[t * 65 + c] = p;
    a2[(size_t)bh * 4096 + t * 64 + c] = p;
    rs += p;
  }
  atomicMax(reinterpret_cast<int*>(scal), __float_as_int(rs));
  __syncthreads();
  float cs = 0.f;
  for (int r = 0; r < 64; ++r) cs += sp[r * 65 + t];
  atomicMax(reinterpret_cast<int*>(scal) + 1, __float_as_int(cs));
}

// ---------------- fused a3 softmax + a3@v (vectorized both phases) ----------------
__global__ __launch_bounds__(256) void k_a3v(
    const float* __restrict__ ql, const _Float16* __restrict__ kT,
    const _Float16* __restrict__ vx, float* __restrict__ a3v) {
  __shared__ float sq[64];
  __shared__ float sP[4096];
  __shared__ float red[4];
  __shared__ float red2[4][64];
  const int t = threadIdx.x;
  const int m = blockIdx.x, bh = blockIdx.y;
  if (t < 64) sq[t] = ql[((size_t)bh * 64 + m) * 64 + t];
  __syncthreads();
  const _Float16* kb = kT + (size_t)bh * 262144;
  float sc[16];
  #pragma unroll
  for (int i = 0; i < 16; ++i) sc[i] = 0.f;
  for (int dd = 0; dd < 64; ++dd) {
    float qv = sq[dd];
    const half8* kr = reinterpret_cast<const half8*>(kb + (size_t)dd * 4096 + t * 16);
    half8 k0 = kr[0], k1 = kr[1];
    #pragma unroll
    for (int i = 0; i < 8; ++i) sc[i] = fmaf(qv, (float)k0[i], sc[i]);
    #pragma unroll
    for (int i = 0; i < 8; ++i) sc[8 + i] = fmaf(qv, (float)k1[i], sc[8 + i]);
  }
  float mx = sc[0];
  #pragma unroll
  for (int i = 1; i < 16; ++i) mx = fmaxf(mx, sc[i]);
  #pragma unroll
  for (int o = 32; o; o >>= 1) mx = fmaxf(mx, __shfl_xor(mx, o));
  if ((t & 63) == 0) red[t >> 6] = mx;
  __syncthreads();
  mx = fmaxf(fmaxf(red[0], red[1]), fmaxf(red[2], red[3]));
  __syncthreads();
  float sum = 0.f;
  #pragma unroll
  for (int i = 0; i < 16; ++i) {
    sc[i] = expf(sc[i] - mx);
    sum += sc[i];
  }
  #pragma unroll
  for (int o = 32; o; o >>= 1) sum += __shfl_xor(sum, o);
  if ((t & 63) == 0) red[t >> 6] = sum;
  __syncthreads();
  sum = red[0] + red[1] + red[2] + red[3];
  float inv = 1.f / sum;
  #pragma unroll
  for (int i = 0; i < 16; ++i) sP[t * 16 + i] = sc[i] * inv;
  __syncthreads();
  // PV: each wave (seg) covers 1024 n; lane l: n-slot l>>3, d-range (l&7)*8..+8
  const int seg = t >> 6, l = t & 63;
  const int nl = l >> 3, dblk = (l & 7) * 8;
  const _Float16* vb = vx + (size_t)bh * 262144;
  float acc8[8] = {};
  for (int it = 0; it < 128; ++it) {
    int n8 = seg * 1024 + it * 8;
    half8 vv = *reinterpret_cast<const half8*>(&vb[(size_t)(n8 + nl) * 64 + dblk]);
    float pc = sP[n8 + nl];
    #pragma unroll
    for (int u = 0; u < 8; ++u) acc8[u] = fmaf(pc, (float)vv[u], acc8[u]);
  }
  #pragma unroll
  for (int off = 8; off <= 32; off <<= 1)
    #pragma unroll
    for (int u = 0; u < 8; ++u) acc8[u] += __shfl_xor(acc8[u], off);
  if (nl == 0) {
    #pragma unroll
    for (int u = 0; u < 8; ++u) red2[seg][dblk + u] = acc8[u];
  }
  __syncthreads();
  if (seg == 0)
    a3v[((size_t)bh * 64 + m) * 64 + l] = red2[0][l] + red2[1][l] + red2[2][l] + red2[3][l];
}

// ---------------- Moore-Penrose pinv (fp32, float4 LDS) + fused w2t ----------------
__global__ __launch_bounds__(256) void k_pinv(
    const float* __restrict__ a2g, const float* __restrict__ scal,
    const float* __restrict__ a3vg, _Float16* __restrict__ w2t) {
  __shared__ float z[64 * 68];
  __shared__ float az[64 * 68];
  __shared__ float tb[64 * 68];
  const int bh = blockIdx.x, t = threadIdx.x;
  const int r0 = (t >> 4) << 2, c0 = (t & 15) << 2;
  const float* ag = a2g + (size_t)bh * 4096;
  const float denom = 1.f / (scal[0] * scal[1]);
  #pragma unroll
  for (int i = 0; i < 4; ++i)
    #pragma unroll
    for (int j = 0; j < 4; ++j)
      z[(r0 + i) * 68 + c0 + j] = ag[(c0 + j) * 64 + r0 + i] * denom;
  __syncthreads();
  float reg[4][4], val[4][4];
  for (int it = 0; it < 6; ++it) {
    mm16v<64, 68>(ag, z, r0, c0, reg);
    #pragma unroll
    for (int i = 0; i < 4; ++i)
      #pragma unroll
      for (int j = 0; j < 4; ++j) az[(r0 + i) * 68 + c0 + j] = reg[i][j];
    __syncthreads();
    mm16v<68, 68>(az, az, r0, c0, reg);
    #pragma unroll
    for (int i = 0; i < 4; ++i)
      #pragma unroll
      for (int j = 0; j < 4; ++j)
        tb[(r0 + i) * 68 + c0 + j] = 7.f * az[(r0 + i) * 68 + c0 + j] - reg[i][j];
    __syncthreads();
    mm16v<68, 68>(az, tb, r0, c0, reg);
    #pragma unroll
    for (int i = 0; i < 4; ++i)
      #pragma unroll
      for (int j = 0; j < 4; ++j)
        val[i][j] = 15.f * az[(r0 + i) * 68 + c0 + j] - reg[i][j];
    __syncthreads();
    #pragma unroll
    for (int i = 0; i < 4; ++i)
      #pragma unroll
      for (int j = 0; j < 4; ++j) tb[(r0 + i) * 68 + c0 + j] = val[i][j];
    __syncthreads();
    mm16v<68, 68>(z, tb, r0, c0, reg);
    #pragma unroll
    for (int i = 0; i < 4; ++i)
      #pragma unroll
      for (int j = 0; j < 4; ++j)
        val[i][j] = 0.25f * (13.f * z[(r0 + i) * 68 + c0 + j] - reg[i][j]);
    __syncthreads();
    #pragma unroll
    for (int i = 0; i < 4; ++i)
      #pragma unroll
      for (int j = 0; j < 4; ++j) z[(r0 + i) * 68 + c0 + j] = val[i][j];
    __syncthreads();
  }
  mm16v<68, 64>(z, a3vg + (size_t)bh * 4096, r0, c0, reg);
  #pragma unroll
  for (int i = 0; i < 4; ++i)
    #pragma unroll
    for (int j = 0; j < 4; ++j)
      w2t[(size_t)bh * 4096 + (c0 + j) * 64 + (r0 + i)] = (_Float16)reg[i][j];
}

// ------- fused MFMA combine: S=q@kl^T -> softmax -> P@W2 + Toeplitz(res)@v -> att f16 ------
__global__ __launch_bounds__(256) void k_combine_m(
    const _Float16* __restrict__ qx, const _Float16* __restrict__ klh,
    const _Float16* __restrict__ w2t, const _Float16* __restrict__ vx,
    const float* __restrict__ rw, _Float16* __restrict__ att) {
  __shared__ _Float16 sP[64 * 72];
  __shared__ _Float16 sVT[64 * 104];
  __shared__ _Float16 sT[64 * 104];
  __shared__ float sR[33];
  const int t = threadIdx.x, w = t >> 6, lo = t & 15, hi = (t >> 4) & 3;
  const int n0 = blockIdx.x * 64;
  const int h = blockIdx.y, b = blockIdx.z, bh = b * 8 + h;
  if (t < 33) sR[t] = rw[h * 33 + t];
  __syncthreads();
  const _Float16* vb = vx + (size_t)bh * 262144;
  #pragma unroll
  for (int u = 0; u < 24; ++u) {
    int e = t + u * 256;
    int r = e >> 6, d = e & 63;
    int nn = n0 - 16 + r;
    sVT[d * 104 + r] = ((unsigned)nn < 4096u) ? vb[(size_t)nn * 64 + d] : (_Float16)0.f;
  }
  #pragma unroll
  for (int u = 0; u < 24; ++u) {
    int e = t + u * 256;
    int r = e % 96, i = e / 96;
    int j = r - i;
    sT[i * 104 + r] = (j >= 0 && j < 33) ? (_Float16)sR[j] : (_Float16)0.f;
  }
  f32x4 sa[4] = {};
  const _Float16* qp = qx + ((size_t)bh * 4096 + n0 + w * 16 + lo) * 64 + 8 * hi;
  const _Float16* klp = klh + (size_t)bh * 4096;
  #pragma unroll
  for (int c = 0; c < 2; ++c) {
    half8 a = *reinterpret_cast<const half8*>(qp + 32 * c);
    #pragma unroll
    for (int ct = 0; ct < 4; ++ct) {
      half8 bf = *reinterpret_cast<const half8*>(klp + (size_t)(ct * 16 + lo) * 64 + 8 * hi + 32 * c);
      sa[ct] = __builtin_amdgcn_mfma_f32_16x16x32_f16(a, bf, sa[ct], 0, 0, 0);
    }
  }
  #pragma unroll
  for (int r = 0; r < 4; ++r) {
    float mx = fmaxf(fmaxf(sa[0][r], sa[1][r]), fmaxf(sa[2][r], sa[3][r]));
    #pragma unroll
    for (int o = 8; o; o >>= 1) mx = fmaxf(mx, __shfl_xor(mx, o));
    float e0 = expf(sa[0][r] - mx), e1 = expf(sa[1][r] - mx);
    float e2 = expf(sa[2][r] - mx), e3 = expf(sa[3][r] - mx);
    float sm = e0 + e1 + e2 + e3;
    #pragma unroll
    for (int o = 8; o; o >>= 1) sm += __shfl_xor(sm, o);
    float inv = 1.f / sm;
    int row = w * 16 + hi * 4 + r;
    sP[row * 72 + lo] = (_Float16)(e0 * inv);
    sP[row * 72 + 16 + lo] = (_Float16)(e1 * inv);
    sP[row * 72 + 32 + lo] = (_Float16)(e2 * inv);
    sP[row * 72 + 48 + lo] = (_Float16)(e3 * inv);
  }
  __syncthreads();
  f32x4 ao[4] = {};
  const _Float16* w2p = w2t + (size_t)bh * 4096;
  #pragma unroll
  for (int c = 0; c < 2; ++c) {
    half8 a = *reinterpret_cast<const half8*>(&sP[(w * 16 + lo) * 72 + 8 * hi + 32 * c]);
    #pragma unroll
    for (int ct = 0; ct < 4; ++ct) {
      half8 bf = *reinterpret_cast<const half8*>(w2p + (size_t)(ct * 16 + lo) * 64 + 8 * hi + 32 * c);
      ao[ct] = __builtin_amdgcn_mfma_f32_16x16x32_f16(a, bf, ao[ct], 0, 0, 0);
    }
  }
  #pragma unroll
  for (int c = 0; c < 3; ++c) {
    half8 a = *reinterpret_cast<const half8*>(&sT[(w * 16 + lo) * 104 + 8 * hi + 32 * c]);
    #pragma unroll
    for (int ct = 0; ct < 4; ++ct) {
      half8 bf = *reinterpret_cast<const half8*>(&sVT[(ct * 16 + lo) * 104 + 8 * hi + 32 * c]);
      ao[ct] = __builtin_amdgcn_mfma_f32_16x16x32_f16(a, bf, ao[ct], 0, 0, 0);
    }
  }
  _Float16* ab = att + ((size_t)b * 4096) * 512 + (size_t)h * 64;
  #pragma unroll
  for (int ct = 0; ct < 4; ++ct)
    #pragma unroll
    for (int r = 0; r < 4; ++r) {
      int n = n0 + w * 16 + hi * 4 + r;
      ab[(size_t)n * 512 + ct * 16 + lo] = (_Float16)ao[ct][r];
    }
}

// ---------------- LayerNorm in place over E=800, f16 buffer ----------------
__global__ __launch_bounds__(256) void k_ln16(
    _Float16* __restrict__ buf, const float* __restrict__ g, const float* __restrict__ bb) {
  const int t = threadIdx.x;
  _Float16* p = buf + (size_t)blockIdx.x * 800;
  float x0 = (float)p[t], x1 = (float)p[t + 256], x2 = (float)p[t + 512];
  float x3 = (t < 32) ? (float)p[t + 768] : 0.f;
  float s = blockReduceSum(x0 + x1 + x2 + x3);
  float mean = s * (1.f / 800.f);
  float d0 = x0 - mean, d1 = x1 - mean, d2 = x2 - mean;
  float d3 = (t < 32) ? x3 - mean : 0.f;
  float s2 = blockReduceSum(d0 * d0 + d1 * d1 + d2 * d2 + d3 * d3);
  float rstd = rsqrtf(s2 * (1.f / 800.f) + LN_EPS_C);
  p[t] = (_Float16)(d0 * rstd * g[t] + bb[t]);
  p[t + 256] = (_Float16)(d1 * rstd * g[t + 256] + bb[t + 256]);
  p[t + 512] = (_Float16)(d2 * rstd * g[t + 512] + bb[t + 512]);
  if (t < 32) p[t + 768] = (_Float16)(d3 * rstd * g[t + 768] + bb[t + 768]);
}

// ---------------- head MFMA: out[16384,16] = sigmoid(lnb @ hwh^T + hb) ----------------
__global__ __launch_bounds__(256) void k_head_m(
    const _Float16* __restrict__ ln, const _Float16* __restrict__ hwh,
    const float* __restrict__ hb, float* __restrict__ out) {
  const int t = threadIdx.x, w = t >> 6, lo = t & 15, hi = (t >> 4) & 3;
  const int row0 = blockIdx.x * 64 + w * 16;
  const _Float16* ap = ln + (size_t)(row0 + lo) * 800 + 8 * hi;
  const _Float16* bp = hwh + (size_t)lo * 800 + 8 * hi;
  f32x4 acc = {};
  #pragma unroll 5
  for (int k = 0; k < 800; k += 32) {
    half8 a = *reinterpret_cast<const half8*>(ap + k);
    half8 b = *reinterpret_cast<const half8*>(bp + k);
    acc = __builtin_amdgcn_mfma_f32_16x16x32_f16(a, b, acc, 0, 0, 0);
  }
  float bv = hb[lo];
  #pragma unroll
  for (int r = 0; r < 4; ++r) {
    int row = row0 + hi * 4 + r;
    out[(size_t)row * 16 + lo] = 1.f / (1.f + expf(-(acc[r] + bv)));
  }
}

// ---------------- launcher ----------------
extern "C" void kernel_launch(void* const* d_in, const int* in_sizes, int n_in,
                              void* d_out, int out_size, void* d_ws, size_t ws_size,
                              hipStream_t stream) {
  (void)in_sizes; (void)n_in; (void)out_size; (void)ws_size;
  const float* x     = (const float*)d_in[0];
  const float* w0    = (const float*)d_in[1];
  const float* b0    = (const float*)d_in[2];
  const float* g0    = (const float*)d_in[3];
  const float* be0   = (const float*)d_in[4];
  const float* mu0   = (const float*)d_in[5];
  const float* var0  = (const float*)d_in[6];
  const float* w1    = (const float*)d_in[7];
  const float* b1    = (const float*)d_in[8];
  const float* g1    = (const float*)d_in[9];
  const float* be1   = (const float*)d_in[10];
  const float* mu1   = (const float*)d_in[11];
  const float* var1  = (const float*)d_in[12];
  const float* w2c   = (const float*)d_in[13];
  const float* b2    = (const float*)d_in[14];
  const float* g2    = (const float*)d_in[15];
  const float* be2   = (const float*)d_in[16];
  const float* mu2   = (const float*)d_in[17];
  const float* var2  = (const float*)d_in[18];
  const float* w3    = (const float*)d_in[19];
  const float* b3    = (const float*)d_in[20];
  const float* g3    = (const float*)d_in[21];
  const float* be3   = (const float*)d_in[22];
  const float* mu3   = (const float*)d_in[23];
  const float* var3  = (const float*)d_in[24];
  const float* qkvw  = (const float*)d_in[25];
  const float* outw  = (const float*)d_in[26];
  const float* outbv = (const float*)d_in[27];
  const float* resw  = (const float*)d_in[28];
  const float* lng   = (const float*)d_in[29];
  const float* lnbv  = (const float*)d_in[30];
  const float* headw = (const float*)d_in[31];
  const float* headb = (const float*)d_in[32];

  char* wsb = (char*)d_ws;
  _Float16* h0   = (_Float16*)(wsb + B_H0);
  _Float16* h1   = (_Float16*)(wsb + B_H1);
  _Float16* h2   = (_Float16*)(wsb + B_H2);
  _Float16* qb   = (_Float16*)(wsb + B_Q);
  _Float16* vb   = (_Float16*)(wsb + B_V);
  _Float16* kT   = (_Float16*)(wsb + B_KT);
  _Float16* tok  = (_Float16*)(wsb + B_TOK);
  _Float16* attb = (_Float16*)(wsb + B_ATT);
  _Float16* wp1  = (_Float16*)(wsb + B_WP1);
  _Float16* wp2  = (_Float16*)(wsb + B_WP2);
  _Float16* wp3  = (_Float16*)(wsb + B_WP3);
  _Float16* qkvT = (_Float16*)(wsb + B_QKVT);
  _Float16* owT  = (_Float16*)(wsb + B_OWT);
  _Float16* klh  = (_Float16*)(wsb + B_KLH);
  _Float16* w2t  = (_Float16*)(wsb + B_W2T);
  _Float16* hwh  = (_Float16*)(wsb + B_HWH);
  _Float16* lnb16 = (_Float16*)(wsb + B_LNB);
  float* ql   = (float*)(wsb + B_QL);
  float* kl   = (float*)(wsb + B_KL);
  float* a2   = (float*)(wsb + B_A2);
  float* a3v  = (float*)(wsb + B_A3V);
  float* scal = (float*)(wsb + B_SCAL);

  // all weight packing + scal init in one launch
  k_pack_all<<<dim3(20691), 256, 0, stream>>>(
      w1, w2c, w3, qkvw, outw, headw, wp1, wp2, wp3, qkvT, owT, hwh, scal);

  // conv stack: conv0..conv2 per image (h0/h1 scratch), h2 kept full-batch
  for (int img = 0; img < 4; ++img) {
    k_conv0<<<dim3(256, 4), 256, 0, stream>>>(
        x + (size_t)img * 65536, w0, b0, g0, be0, mu0, var0, h0);
    k_convs<64><<<dim3(512), 256, 0, stream>>>(
        h0, wp1, b1, g1, be1, mu1, var1, h1, 128, 1);
    k_convs<128><<<dim3(1024), 256, 0, stream>>>(
        h1, wp2, b2, g2, be2, mu2, var2, h2 + (size_t)img * 16777216, 256, 2);
  }
  // conv3 (patch conv) over the full batch: staged GEMM, 640 XCD-swizzled blocks
  k_c3<<<dim3(640), 256, 0, stream>>>(h2, wp3, b3, g3, be3, mu3, var3, tok);
  // attention (k transposed through LDS inside qkv; landmarks fused)
  k_qkv_s<<<dim3(1536), 256, 0, stream>>>(tok, qkvT, qb, kT, vb, ql, kl, klh);
  k_a2<<<dim3(32), 64, 0, stream>>>(ql, kl, a2, scal);
  k_a3v<<<dim3(64, 32), 256, 0, stream>>>(ql, kT, vb, a3v);
  k_pinv<<<dim3(32), 256, 0, stream>>>(a2, scal, a3v, w2t);
  k_combine_m<<<dim3(64, 8, 4), 256, 0, stream>>>(qb, klh, w2t, vb, resw, attb);
  // projection + LN + head
  k_op_s<<<dim3(640), 256, 0, stream>>>(attb, owT, outbv, lnb16);
  k_ln16<<<dim3(16384), 256, 0, stream>>>(lnb16, lng, lnbv);
  k_head_m<<<dim3(256), 256, 0, stream>>>(lnb16, hwh, headb, (float*)d_out);
}